// Round 9
// baseline (596.061 us; speedup 1.0000x reference)
//
#include <hip/hip_runtime.h>
#include <hip/hip_bf16.h>
#include <math.h>

// ---- problem constants ----
#define S_LEN   2048
#define HIDDIM  2048
#define NKH     16
#define NVH     32
#define DKD     128
#define DVD     128
#define CCH     64          // chunk
#define NCHK    32          // S/chunk
#define KEY_DIM 2048
#define VAL_DIM 4096
#define CONV_DIM 8192

#define PA_LDS_BYTES (16384 + 16384 + 32768 + 4096 + 4096 + 256 + 256 + 256)
#define PB_LDS_BYTES ((8192+8192+4096+8192+2048+1024+1024)*2 + 64*4)
// gemm8p: 2 buffers x (A 256x64 + B 256x64) bf16 = 2 x 65536 B
#define G8P_LDS_BYTES (2 * 65536)        // 131072
// gemm128: 3 bufs x (A 128x64 + B 128x64) = 3 x 16384 ushorts
#define G128_LDS_BYTES (3 * 16384 * 2)   // 98304

typedef __bf16 bf16x8 __attribute__((ext_vector_type(8)));
typedef float f32x4 __attribute__((ext_vector_type(4)));

__device__ __forceinline__ float sigmoid_f(float x) { return 1.f / (1.f + __expf(-x)); }
__device__ __forceinline__ float silu_f(float x) { return x * sigmoid_f(x); }
__device__ __forceinline__ ushort f2bf(float f) {
    unsigned u = __float_as_uint(f);
    u += 0x7fffu + ((u >> 16) & 1u);          // RNE (inputs finite)
    return (ushort)(u >> 16);
}
__device__ __forceinline__ float bf2f(ushort u) {
    return __uint_as_float((unsigned)u << 16);
}

#define GLL(srcp, dstp) __builtin_amdgcn_global_load_lds( \
    (const __attribute__((address_space(1))) void*)(srcp), \
    (__attribute__((address_space(3))) void*)(dstp), 16, 0, 0)

// ================= fp32 -> bf16 cast (8 elems/thread) =======================
__global__ __launch_bounds__(256) void cast_kernel(
    const float* __restrict__ in, ushort* __restrict__ out, int n8)
{
    int t = blockIdx.x * 256 + threadIdx.x;
    if (t >= n8) return;
    float4 v0 = *(const float4*)(in + (size_t)t * 8);
    float4 v1 = *(const float4*)(in + (size_t)t * 8 + 4);
    union { ushort u[8]; uint4 v; } r;
    r.u[0] = f2bf(v0.x); r.u[1] = f2bf(v0.y); r.u[2] = f2bf(v0.z); r.u[3] = f2bf(v0.w);
    r.u[4] = f2bf(v1.x); r.u[5] = f2bf(v1.y); r.u[6] = f2bf(v1.z); r.u[7] = f2bf(v1.w);
    *(uint4*)(out + (size_t)t * 8) = r.v;
}

// ====== W_a,W_b -> one padded bf16 weight [128,2048] (rows 64..127 zero) ====
__global__ __launch_bounds__(256) void cast_ab_kernel(
    const float* __restrict__ Wa, const float* __restrict__ Wb, ushort* __restrict__ out)
{
    int t = blockIdx.x * 256 + threadIdx.x;          // 128*2048/8 = 32768 threads
    int row = t >> 8;
    int c8 = (t & 255) * 8;
    union { ushort u[8]; uint4 v; } r;
    if (row < 64) {
        const float* src = (row < 32) ? (Wa + (size_t)row * HIDDIM + c8)
                                      : (Wb + (size_t)(row - 32) * HIDDIM + c8);
        float4 v0 = *(const float4*)(src);
        float4 v1 = *(const float4*)(src + 4);
        r.u[0] = f2bf(v0.x); r.u[1] = f2bf(v0.y); r.u[2] = f2bf(v0.z); r.u[3] = f2bf(v0.w);
        r.u[4] = f2bf(v1.x); r.u[5] = f2bf(v1.y); r.u[6] = f2bf(v1.z); r.u[7] = f2bf(v1.w);
    } else {
        r.u[0] = r.u[1] = r.u[2] = r.u[3] = r.u[4] = r.u[5] = r.u[6] = r.u[7] = 0;
    }
    *(uint4*)(out + (size_t)t * 8) = r.v;
}

// ============ 256x256 8-phase bf16 GEMM (m201 schedule), dual output ========
// C[M,Ntot] = A[M,K] @ B[Ntot,K]^T ; block cols < NSPLIT -> C0 else C1.
// 512 thr = 8 waves (2M x 4N), wave out 128x64 (acc[8][4]). BK=64.
// 2 LDS buffers (64 KB each, frag-ordered -> conflict-free ds_read_b128).
// Per iteration = 2 K-tiles = 8 phases: {quadrant ds-reads, 2 staging GLLs,
// barrier, setprio(1) + 16 MFMA + setprio(0), [vmcnt at switch], barrier}.
// Counted vmcnt(2) at phase 3/7 END (before closing barrier) -> staged data
// published race-free; vmcnt never drained to 0 in steady state.
__global__ __launch_bounds__(512, 2) void gemm8p_kernel(
    const ushort* __restrict__ A, const ushort* __restrict__ B,
    float* __restrict__ C0, float* __restrict__ C1,
    int K, int NSPLIT, int ldc0, int ldc1)
{
    extern __shared__ ushort g8s[];   // [2][A 16384 us | B 16384 us]
    const int tid = threadIdx.x;
    const int wv = tid >> 6, ln = tid & 63;
    const int wm = wv >> 2, wn = wv & 3;
    const int lrow = ln & 15, lkg = ln >> 4;
    const int bm = blockIdx.y * 256, bn = blockIdx.x * 256;

    // staging source offsets (element units): granule gr = g*512 + tid;
    // frag = gr>>7, ks = (gr>>6)&1, l = gr&63 ->
    // elem (frag*16 + (l&15), ks*32 + (l>>4)*8)
    int soff[4];
#pragma unroll
    for (int g = 0; g < 4; ++g) {
        int gr = g * 512 + tid;
        int frag = gr >> 7, ks = (gr >> 6) & 1, l = gr & 63;
        soff[g] = (frag * 16 + (l & 15)) * K + ks * 32 + (l >> 4) * 8;
    }
    const ushort* Ag = A + (size_t)bm * K;
    const ushort* Bg = B + (size_t)bn * K;

#define STG_A(bsel, g, kk) GLL(Ag + soff[g] + (kk), \
        g8s + (bsel) * 32768 + ((g) * 512 + wv * 64) * 8)
#define STG_B(bsel, g, kk) GLL(Bg + soff[g] + (kk), \
        g8s + (bsel) * 32768 + 16384 + ((g) * 512 + wv * 64) * 8)
#define BARX() do { asm volatile("" ::: "memory"); __builtin_amdgcn_s_barrier(); } while (0)
#define VMW(n) asm volatile("s_waitcnt vmcnt(" #n ")" ::: "memory")

    f32x4 acc[8][4];
#pragma unroll
    for (int m = 0; m < 8; ++m)
#pragma unroll
        for (int n = 0; n < 4; ++n) {
            f32x4 z = {0.f, 0.f, 0.f, 0.f};
            acc[m][n] = z;
        }

    const ushort* LA0 = g8s;
    const ushort* LB0 = g8s + 16384;
    const ushort* LA1 = g8s + 32768;
    const ushort* LB1 = g8s + 49152;

    // ---- prologue: buf0 <- tile 0 (8 GLL), buf1 A g0,g1 <- tile 1 ----
#pragma unroll
    for (int g = 0; g < 4; ++g) STG_A(0, g, 0);
#pragma unroll
    for (int g = 0; g < 4; ++g) STG_B(0, g, 0);
    STG_A(1, 0, 64); STG_A(1, 1, 64);
    VMW(2);
    BARX();

    const int T2 = K >> 7;               // iterations (2 K-tiles each)
    for (int it = 0; it < T2; ++it) {
        const int kc = it * 128;
        const bool more = (it + 1 < T2);
        bf16x8 a[4][2], b0[2][2], b1[2][2];

        // ================== buf0 half (K-tile kc) ==================
        // ---- P0: read a(mf0-3), b0; stage buf1 A g2,g3 ----
#pragma unroll
        for (int mf = 0; mf < 4; ++mf)
#pragma unroll
            for (int ks = 0; ks < 2; ++ks)
                a[mf][ks] = *(const bf16x8*)&LA0[(((wm * 8 + mf) * 2 + ks) * 64 + ln) * 8];
#pragma unroll
        for (int nf = 0; nf < 2; ++nf)
#pragma unroll
            for (int ks = 0; ks < 2; ++ks)
                b0[nf][ks] = *(const bf16x8*)&LB0[(((wn * 4 + nf) * 2 + ks) * 64 + ln) * 8];
        STG_A(1, 2, kc + 64); STG_A(1, 3, kc + 64);
        BARX();
        __builtin_amdgcn_s_setprio(1);
#pragma unroll
        for (int mf = 0; mf < 4; ++mf)
#pragma unroll
            for (int nf = 0; nf < 2; ++nf)
#pragma unroll
                for (int ks = 0; ks < 2; ++ks)
                    acc[mf][nf] = __builtin_amdgcn_mfma_f32_16x16x32_bf16(
                        a[mf][ks], b0[nf][ks], acc[mf][nf], 0, 0, 0);
        __builtin_amdgcn_s_setprio(0);
        BARX();
        // ---- P1: read b1; stage buf1 B g0,g1 ----
#pragma unroll
        for (int nf = 0; nf < 2; ++nf)
#pragma unroll
            for (int ks = 0; ks < 2; ++ks)
                b1[nf][ks] = *(const bf16x8*)&LB0[(((wn * 4 + 2 + nf) * 2 + ks) * 64 + ln) * 8];
        STG_B(1, 0, kc + 64); STG_B(1, 1, kc + 64);
        BARX();
        __builtin_amdgcn_s_setprio(1);
#pragma unroll
        for (int mf = 0; mf < 4; ++mf)
#pragma unroll
            for (int nf = 0; nf < 2; ++nf)
#pragma unroll
                for (int ks = 0; ks < 2; ++ks)
                    acc[mf][2 + nf] = __builtin_amdgcn_mfma_f32_16x16x32_bf16(
                        a[mf][ks], b1[nf][ks], acc[mf][2 + nf], 0, 0, 0);
        __builtin_amdgcn_s_setprio(0);
        BARX();
        // ---- P2: read a(mf4-7); stage buf1 B g2,g3 ----
#pragma unroll
        for (int mf = 0; mf < 4; ++mf)
#pragma unroll
            for (int ks = 0; ks < 2; ++ks)
                a[mf][ks] = *(const bf16x8*)&LA0[(((wm * 8 + 4 + mf) * 2 + ks) * 64 + ln) * 8];
        STG_B(1, 2, kc + 64); STG_B(1, 3, kc + 64);
        BARX();
        __builtin_amdgcn_s_setprio(1);
#pragma unroll
        for (int mf = 0; mf < 4; ++mf)
#pragma unroll
            for (int nf = 0; nf < 2; ++nf)
#pragma unroll
                for (int ks = 0; ks < 2; ++ks)
                    acc[4 + mf][nf] = __builtin_amdgcn_mfma_f32_16x16x32_bf16(
                        a[mf][ks], b0[nf][ks], acc[4 + mf][nf], 0, 0, 0);
        __builtin_amdgcn_s_setprio(0);
        BARX();
        // ---- P3: no reads; stage buf0 A g0,g1 (next-next tile) ----
        if (more) { STG_A(0, 0, kc + 128); STG_A(0, 1, kc + 128); }
        BARX();
        __builtin_amdgcn_s_setprio(1);
#pragma unroll
        for (int mf = 0; mf < 4; ++mf)
#pragma unroll
            for (int nf = 0; nf < 2; ++nf)
#pragma unroll
                for (int ks = 0; ks < 2; ++ks)
                    acc[4 + mf][2 + nf] = __builtin_amdgcn_mfma_f32_16x16x32_bf16(
                        a[mf][ks], b1[nf][ks], acc[4 + mf][2 + nf], 0, 0, 0);
        __builtin_amdgcn_s_setprio(0);
        if (more) { VMW(2); } else { VMW(0); }   // buf1 published at next barrier
        BARX();

        // ================== buf1 half (K-tile kc+64) ==================
        // ---- P4: read a(mf0-3), b0 from buf1; stage buf0 A g2,g3 ----
#pragma unroll
        for (int mf = 0; mf < 4; ++mf)
#pragma unroll
            for (int ks = 0; ks < 2; ++ks)
                a[mf][ks] = *(const bf16x8*)&LA1[(((wm * 8 + mf) * 2 + ks) * 64 + ln) * 8];
#pragma unroll
        for (int nf = 0; nf < 2; ++nf)
#pragma unroll
            for (int ks = 0; ks < 2; ++ks)
                b0[nf][ks] = *(const bf16x8*)&LB1[(((wn * 4 + nf) * 2 + ks) * 64 + ln) * 8];
        if (more) { STG_A(0, 2, kc + 128); STG_A(0, 3, kc + 128); }
        BARX();
        __builtin_amdgcn_s_setprio(1);
#pragma unroll
        for (int mf = 0; mf < 4; ++mf)
#pragma unroll
            for (int nf = 0; nf < 2; ++nf)
#pragma unroll
                for (int ks = 0; ks < 2; ++ks)
                    acc[mf][nf] = __builtin_amdgcn_mfma_f32_16x16x32_bf16(
                        a[mf][ks], b0[nf][ks], acc[mf][nf], 0, 0, 0);
        __builtin_amdgcn_s_setprio(0);
        BARX();
        // ---- P5: read b1 from buf1; stage buf0 B g0,g1 ----
#pragma unroll
        for (int nf = 0; nf < 2; ++nf)
#pragma unroll
            for (int ks = 0; ks < 2; ++ks)
                b1[nf][ks] = *(const bf16x8*)&LB1[(((wn * 4 + 2 + nf) * 2 + ks) * 64 + ln) * 8];
        if (more) { STG_B(0, 0, kc + 128); STG_B(0, 1, kc + 128); }
        BARX();
        __builtin_amdgcn_s_setprio(1);
#pragma unroll
        for (int mf = 0; mf < 4; ++mf)
#pragma unroll
            for (int nf = 0; nf < 2; ++nf)
#pragma unroll
                for (int ks = 0; ks < 2; ++ks)
                    acc[mf][2 + nf] = __builtin_amdgcn_mfma_f32_16x16x32_bf16(
                        a[mf][ks], b1[nf][ks], acc[mf][2 + nf], 0, 0, 0);
        __builtin_amdgcn_s_setprio(0);
        BARX();
        // ---- P6: read a(mf4-7) from buf1; stage buf0 B g2,g3 ----
#pragma unroll
        for (int mf = 0; mf < 4; ++mf)
#pragma unroll
            for (int ks = 0; ks < 2; ++ks)
                a[mf][ks] = *(const bf16x8*)&LA1[(((wm * 8 + 4 + mf) * 2 + ks) * 64 + ln) * 8];
        if (more) { STG_B(0, 2, kc + 128); STG_B(0, 3, kc + 128); }
        BARX();
        __builtin_amdgcn_s_setprio(1);
#pragma unroll
        for (int mf = 0; mf < 4; ++mf)
#pragma unroll
            for (int nf = 0; nf < 2; ++nf)
#pragma unroll
                for (int ks = 0; ks < 2; ++ks)
                    acc[4 + mf][nf] = __builtin_amdgcn_mfma_f32_16x16x32_bf16(
                        a[mf][ks], b0[nf][ks], acc[4 + mf][nf], 0, 0, 0);
        __builtin_amdgcn_s_setprio(0);
        BARX();
        // ---- P7: no reads; stage buf1 A g0,g1 (tile kc+192) ----
        if (more) { STG_A(1, 0, kc + 192); STG_A(1, 1, kc + 192); }
        BARX();
        __builtin_amdgcn_s_setprio(1);
#pragma unroll
        for (int mf = 0; mf < 4; ++mf)
#pragma unroll
            for (int nf = 0; nf < 2; ++nf)
#pragma unroll
                for (int ks = 0; ks < 2; ++ks)
                    acc[4 + mf][2 + nf] = __builtin_amdgcn_mfma_f32_16x16x32_bf16(
                        a[mf][ks], b1[nf][ks], acc[4 + mf][2 + nf], 0, 0, 0);
        __builtin_amdgcn_s_setprio(0);
        VMW(2);                          // buf0 published at next barrier
        BARX();
    }
#undef STG_A
#undef STG_B
#undef BARX
#undef VMW

    // epilogue: dual-output split (NSPLIT % 256 == 0 -> block on one side)
    const bool inC1 = (bn >= NSPLIT);
    float* Cp = inC1 ? C1 : C0;
    const int ldc = inC1 ? ldc1 : ldc0;
    const int cb = bn + wn * 64 - (inC1 ? NSPLIT : 0);
#pragma unroll
    for (int mf = 0; mf < 8; ++mf) {
        const int row0 = bm + wm * 128 + mf * 16 + lkg * 4;
#pragma unroll
        for (int nf = 0; nf < 4; ++nf) {
            float* cp = Cp + (size_t)row0 * ldc + cb + nf * 16 + lrow;
#pragma unroll
            for (int j = 0; j < 4; ++j) cp[(size_t)j * ldc] = acc[mf][nf][j];
        }
    }
}

// ======== 128x128 triple-buffered counted-vmcnt bf16 GEMM ===================
__global__ __launch_bounds__(256, 2) void gemm128_kernel(
    const ushort* __restrict__ A, const ushort* __restrict__ B,
    float* __restrict__ C, int N, int K)
{
    extern __shared__ ushort g1s[];          // [3][A 8192 | B 8192] ushorts
    const int tid = threadIdx.x;
    const int wv = tid >> 6, ln = tid & 63;
    const int wm = wv >> 1, wn = wv & 1;
    const int lrow = ln & 15, lkg = ln >> 4;
    const int bm = blockIdx.y * 128, bn = blockIdx.x * 128;

    int soff[4];
#pragma unroll
    for (int j = 0; j < 4; ++j) {
        int g = tid + j * 256;
        int frag = g >> 7, ks = (g >> 6) & 1, l = g & 63;
        soff[j] = (frag * 16 + (l & 15)) * K + ks * 32 + (l >> 4) * 8;
    }
    const ushort* Abase = A + (size_t)bm * K;
    const ushort* Bbase = B + (size_t)bn * K;

    f32x4 acc[4][4];
#pragma unroll
    for (int m = 0; m < 4; ++m)
#pragma unroll
        for (int n = 0; n < 4; ++n) {
            f32x4 z = {0.f, 0.f, 0.f, 0.f};
            acc[m][n] = z;
        }

#define G128_STAGE(bb, k0) do {                                            \
        ushort* bufA_ = g1s + (bb) * 16384;                                \
        ushort* bufB_ = bufA_ + 8192;                                      \
        _Pragma("unroll")                                                  \
        for (int j_ = 0; j_ < 4; ++j_) {                                   \
            GLL(Abase + soff[j_] + (k0), bufA_ + (j_ * 256 + wv * 64) * 8);\
            GLL(Bbase + soff[j_] + (k0), bufB_ + (j_ * 256 + wv * 64) * 8);\
        }                                                                  \
    } while (0)

    const int T = K >> 6;
    G128_STAGE(0, 0);
    G128_STAGE(1, 64);
    int bb = 0;
    for (int t = 0; t < T; ++t) {
        if (t + 1 < T) {
            asm volatile("s_waitcnt vmcnt(8)" ::: "memory");
        } else {
            asm volatile("s_waitcnt vmcnt(0)" ::: "memory");
        }
        __builtin_amdgcn_s_barrier();
        if (t + 2 < T) G128_STAGE((bb >= 1) ? (bb - 1) : (bb + 2), (t + 2) * 64);
        const ushort* LA = g1s + bb * 16384;
        const ushort* LB = LA + 8192;
        __builtin_amdgcn_s_setprio(1);
#pragma unroll
        for (int ks = 0; ks < 2; ++ks) {
            bf16x8 afv[4], bfv[4];
#pragma unroll
            for (int mf = 0; mf < 4; ++mf)
                afv[mf] = *(const bf16x8*)&LA[(((wm * 4 + mf) * 2 + ks) * 64 + ln) * 8];
#pragma unroll
            for (int nf = 0; nf < 4; ++nf)
                bfv[nf] = *(const bf16x8*)&LB[(((wn * 4 + nf) * 2 + ks) * 64 + ln) * 8];
#pragma unroll
            for (int mf = 0; mf < 4; ++mf)
#pragma unroll
                for (int nf = 0; nf < 4; ++nf)
                    acc[mf][nf] = __builtin_amdgcn_mfma_f32_16x16x32_bf16(
                        afv[mf], bfv[nf], acc[mf][nf], 0, 0, 0);
        }
        __builtin_amdgcn_s_setprio(0);
        bb = (bb == 2) ? 0 : bb + 1;
    }
#undef G128_STAGE

#pragma unroll
    for (int mf = 0; mf < 4; ++mf) {
        const int row0 = bm + wm * 64 + mf * 16 + lkg * 4;
#pragma unroll
        for (int nf = 0; nf < 4; ++nf) {
            float* cp = C + (size_t)row0 * N + bn + wn * 64 + nf * 16 + lrow;
#pragma unroll
            for (int j = 0; j < 4; ++j) cp[(size_t)j * N] = acc[mf][nf][j];
        }
    }
}

// ================= causal depthwise conv1d (K=4) + SiLU =====================
__global__ __launch_bounds__(256) void conv_silu_kernel(
    const float* __restrict__ pre, const float* __restrict__ cw, float* __restrict__ out)
{
    int idx = blockIdx.x * 256 + threadIdx.x;
    const int NC4 = CONV_DIM / 4;
    int s = idx / NC4;
    int c = (idx % NC4) * 4;
    float w[4][4];
#pragma unroll
    for (int j = 0; j < 4; ++j) {
        float4 wj = *(const float4*)(cw + (size_t)(c + j) * 4);
        w[j][0] = wj.x; w[j][1] = wj.y; w[j][2] = wj.z; w[j][3] = wj.w;
    }
    float acc[4] = {0.f, 0.f, 0.f, 0.f};
#pragma unroll
    for (int t = 0; t < 4; ++t) {
        int ss = s - 3 + t;
        if (ss >= 0) {
            float4 x = *(const float4*)(pre + (size_t)ss * CONV_DIM + c);
            acc[0] = fmaf(x.x, w[0][t], acc[0]);
            acc[1] = fmaf(x.y, w[1][t], acc[1]);
            acc[2] = fmaf(x.z, w[2][t], acc[2]);
            acc[3] = fmaf(x.w, w[3][t], acc[3]);
        }
    }
    float4 o = make_float4(silu_f(acc[0]), silu_f(acc[1]), silu_f(acc[2]), silu_f(acc[3]));
    *(float4*)(out + (size_t)s * CONV_DIM + c) = o;
}

// ====== g = -exp(A_log)*softplus(a+dt_bias), beta = sigmoid(b) ==============
__global__ __launch_bounds__(256) void gb_kernel(
    const float* __restrict__ ab, const float* __restrict__ dt_bias,
    const float* __restrict__ A_log, float* __restrict__ g, float* __restrict__ beta)
{
    int idx = blockIdx.x * 256 + threadIdx.x;
    int s = idx >> 5, h = idx & 31;
    float av = ab[(size_t)s * 128 + h] + dt_bias[h];
    float sp = (av > 20.f) ? av : log1pf(__expf(av));
    g[idx] = -__expf(A_log[h]) * sp;
    beta[idx] = sigmoid_f(ab[(size_t)s * 128 + 32 + h]);
}

// ===== l2norm q,k: q -> bf16 (qnb), k -> f32 (kn) ===========================
__global__ __launch_bounds__(256) void l2norm_kernel(
    const float* __restrict__ mixed, ushort* __restrict__ qnb, float* __restrict__ kn)
{
    int gw = (blockIdx.x * 256 + threadIdx.x) >> 6;
    int lane = threadIdx.x & 63;
    int isk = gw >= S_LEN * NKH;
    int r = gw - isk * S_LEN * NKH;
    int s = r / NKH, kh = r % NKH;
    const float* src = mixed + (size_t)s * CONV_DIM + isk * KEY_DIM + kh * DKD;
    float2 x = *(const float2*)(src + lane * 2);
    float ss = x.x * x.x + x.y * x.y;
#pragma unroll
    for (int m = 1; m < 64; m <<= 1) ss += __shfl_xor(ss, m, 64);
    float scale = rsqrtf(ss + 1e-6f);
    if (!isk) {
        scale *= 0.08838834764831843f;   // DK^-0.5
        union { ushort u[2]; uint v; } p;
        p.u[0] = f2bf(x.x * scale); p.u[1] = f2bf(x.y * scale);
        *(uint*)(qnb + ((size_t)(s * NKH + kh)) * DKD + lane * 2) = p.v;
    } else {
        float* dst = kn + ((size_t)(s * NKH + kh)) * DKD + lane * 2;
        *(float2*)dst = make_float2(x.x * scale, x.y * scale);
    }
}

// ================= Phase A: per (head, chunk) intra-chunk work ==============
// blocked WY solve: off-diagonal via MFMA, 16x16 diagonal solves scalar fp32.
__global__ __launch_bounds__(256) void phaseA_kernel(
    const ushort* __restrict__ qnb, const float* __restrict__ kn,
    const float* __restrict__ mixed, const float* __restrict__ gbuf,
    const float* __restrict__ betabuf,
    float* __restrict__ u, ushort* __restrict__ kcd,
    ushort* __restrict__ scores, float* __restrict__ gcs_out,
    ushort* __restrict__ knT)
{
    extern __shared__ char pasm[];
    ushort* kb    = (ushort*)(pasm);            // 16KB frag [m4][ks4][64][8]
    ushort* qb    = (ushort*)(pasm + 16384);    // 16KB frag; later P f32[16][256]
    ushort* Xb    = (ushort*)(pasm + 32768);    // 32KB [t2(2)][ct(16)][64][8]
    float*  Adiag = (float*)(pasm + 65536);     // 4KB [4][16][16] fp32 diag blocks
    ushort* Ab    = (ushort*)(pasm + 69632);    // 4KB: 4 frags 16x32 bf16 (K=32 padded)
    float*  gcs_s = (float*)(pasm + 73728);     // 64 f
    float*  bet_s = (float*)(pasm + 73984);     // 64 f
    float*  scK_s = (float*)(pasm + 74240);     // 64 f : beta*exp(gcs)
    float*  Pf    = (float*)qb;                 // alias (qb dead after QK^T MFMA)

    const int n = blockIdx.x, h = blockIdx.y, kh = h >> 1;
    const int tid = threadIdx.x;
    const int s0 = n * CCH;
    const int wv = tid >> 6, ln = tid & 63;
    const int lrow = ln & 15, lkg = ln >> 4;

    float xr[64];
    if (tid < 128) {
        const float* vp = mixed + (size_t)s0 * CONV_DIM + 2 * KEY_DIM + h * DVD + tid;
#pragma unroll
        for (int i = 0; i < 64; ++i) xr[i] = vp[(size_t)i * CONV_DIM];
    } else {
        const float* kp = kn + ((size_t)s0 * NKH + kh) * DKD + (tid - 128);
#pragma unroll
        for (int i = 0; i < 64; ++i) xr[i] = kp[(size_t)i * (NKH * DKD)];
    }

    {
        uint4 z = {0, 0, 0, 0};
#pragma unroll
        for (int i = 0; i < 8; ++i)
            *(uint4*)&Xb[(i * 256 + tid) * 8] = z;
        *(uint4*)&Ab[tid * 8] = z;
    }

    if (tid < 64) {
        float gv = gbuf[(size_t)(s0 + tid) * NVH + h];
#pragma unroll
        for (int off = 1; off < 64; off <<= 1) {
            float pv = __shfl_up(gv, off, 64);
            if (tid >= off) gv += pv;
        }
        float bv = betabuf[(size_t)(s0 + tid) * NVH + h];
        gcs_s[tid] = gv;
        bet_s[tid] = bv;
        scK_s[tid] = bv * __expf(gv);
        gcs_out[(size_t)h * S_LEN + s0 + tid] = gv;
    }

    {
        const int r = tid >> 2, c0 = (tid & 3) * 32;
        const int mbase = (((r >> 4) * 4 + (tid & 3)) * 64 + (r & 15)) * 8;
        const float* ksrc = kn + ((size_t)(s0 + r) * NKH + kh) * DKD + c0;
#pragma unroll
        for (int j0 = 0; j0 < 4; ++j0) {
            float4 v0 = *(const float4*)(ksrc + j0 * 8);
            float4 v1 = *(const float4*)(ksrc + j0 * 8 + 4);
            union { ushort us[8]; uint4 v; } p;
            p.us[0] = f2bf(v0.x); p.us[1] = f2bf(v0.y); p.us[2] = f2bf(v0.z); p.us[3] = f2bf(v0.w);
            p.us[4] = f2bf(v1.x); p.us[5] = f2bf(v1.y); p.us[6] = f2bf(v1.z); p.us[7] = f2bf(v1.w);
            *(uint4*)&kb[mbase + (j0 << 7)] = p.v;
        }
        const ushort* qsrc = qnb + ((size_t)(s0 + r) * NKH + kh) * DKD + c0;
#pragma unroll
        for (int j0 = 0; j0 < 4; ++j0) {
            uint4 v = *(const uint4*)(qsrc + j0 * 8);
            *(uint4*)&qb[mbase + (j0 << 7)] = v;
        }
    }
    __syncthreads();    // B1

    f32x4 accA[4], accQ[4];
#pragma unroll
    for (int j = 0; j < 4; ++j) {
        f32x4 z = {0.f, 0.f, 0.f, 0.f};
        accA[j] = z; accQ[j] = z;
    }
#pragma unroll
    for (int ks = 0; ks < 4; ++ks) {
        bf16x8 a_k = *(const bf16x8*)&kb[((wv * 4 + ks) * 64 + ln) * 8];
        bf16x8 a_q = *(const bf16x8*)&qb[((wv * 4 + ks) * 64 + ln) * 8];
#pragma unroll
        for (int j = 0; j < 4; ++j) {
            bf16x8 b_k = *(const bf16x8*)&kb[((j * 4 + ks) * 64 + ln) * 8];
            accA[j] = __builtin_amdgcn_mfma_f32_16x16x32_bf16(a_k, b_k, accA[j], 0, 0, 0);
            accQ[j] = __builtin_amdgcn_mfma_f32_16x16x32_bf16(a_q, b_k, accQ[j], 0, 0, 0);
        }
    }
    {
        ushort* scp = scores + (size_t)(h * NCHK + n) * (CCH * CCH);
#pragma unroll
        for (int j = 0; j < 4; ++j) {
            const int c = j * 16 + lrow;
            const float gc = gcs_s[c];
#pragma unroll
            for (int jj = 0; jj < 4; ++jj) {
                const int i = wv * 16 + lkg * 4 + jj;
                const float e = __expf(gcs_s[i] - gc);
                float sv = (i >= c) ? (accQ[j][jj] * e) : 0.f;
                scp[i * CCH + c] = f2bf(sv);
                float aval = (i > c) ? (-bet_s[i] * accA[j][jj] * e) : 0.f;
                if (j == wv) {
                    Adiag[wv * 256 + (i & 15) * 16 + lrow] = aval;
                } else if (j < wv) {
                    const int f = (wv == 1) ? 0 : ((wv == 2) ? 1 : (2 + (j >> 1)));
                    const int lk = ((j & 1) << 4) | lrow;
                    const int lane2 = (i & 15) | ((lk >> 3) << 4);
                    Ab[(f * 64 + lane2) * 8 + (lk & 7)] = f2bf(aval);
                }
            }
        }
    }
    if (tid < 128) {
#pragma unroll
        for (int i4 = 0; i4 < 16; ++i4) {
            float4 b4 = *(const float4*)&bet_s[i4 * 4];
            xr[i4 * 4 + 0] *= b4.x; xr[i4 * 4 + 1] *= b4.y;
            xr[i4 * 4 + 2] *= b4.z; xr[i4 * 4 + 3] *= b4.w;
        }
    } else {
#pragma unroll
        for (int i4 = 0; i4 < 16; ++i4) {
            float4 b4 = *(const float4*)&scK_s[i4 * 4];
            xr[i4 * 4 + 0] *= b4.x; xr[i4 * 4 + 1] *= b4.y;
            xr[i4 * 4 + 2] *= b4.z; xr[i4 * 4 + 3] *= b4.w;
        }
    }
    __syncthreads();    // B2

    const int ct = tid >> 4, lct = tid & 15;
#pragma unroll
    for (int s = 0; s < 4; ++s) {
        float y[16];
        float pr[16];
        if (s > 0) {
#pragma unroll
            for (int r = 0; r < 16; ++r) pr[r] = Pf[r * 256 + tid];
        } else {
#pragma unroll
            for (int r = 0; r < 16; ++r) pr[r] = 0.f;
        }
#pragma unroll
        for (int r = 0; r < 16; ++r) {
            float acc = xr[s * 16 + r] + pr[r];
#pragma unroll
            for (int k4 = 0; k4 < 16; k4 += 4) {
                if (k4 < r) {
                    float4 a4 = *(const float4*)&Adiag[s * 256 + r * 16 + k4];
                    if (k4 + 0 < r) acc = fmaf(a4.x, y[k4 + 0], acc);
                    if (k4 + 1 < r) acc = fmaf(a4.y, y[k4 + 1], acc);
                    if (k4 + 2 < r) acc = fmaf(a4.z, y[k4 + 2], acc);
                    if (k4 + 3 < r) acc = fmaf(a4.w, y[k4 + 3], acc);
                }
            }
            y[r] = acc;
        }
        if (tid < 128) {
            float* up = u + (size_t)(h * NCHK + n) * (CCH * DVD) + (s * 16) * DVD + tid;
#pragma unroll
            for (int r = 0; r < 16; ++r) up[r * DVD] = y[r];
        } else {
            ushort* kp = kcd + (size_t)(h * NCHK + n) * (CCH * DKD) + (s * 16) * DKD + (tid - 128);
#pragma unroll
            for (int r = 0; r < 16; ++r) kp[r * DKD] = f2bf(y[r]);
        }
        if (s < 3) {
#pragma unroll
            for (int half = 0; half < 2; ++half) {
                union { ushort us[8]; uint4 v; } p;
#pragma unroll
                for (int e = 0; e < 8; ++e) p.us[e] = f2bf(y[half * 8 + e]);
                const int kg = (s & 1) * 2 + half;
                *(uint4*)&Xb[(((s >> 1) * 16 + ct) * 64 + (kg * 16 + lct)) * 8] = p.v;
            }
            __syncthreads();
            const int snx = s + 1;
            const int nT2 = (snx + 1) >> 1;
            f32x4 accP[4];
#pragma unroll
            for (int ctl = 0; ctl < 4; ++ctl) {
                f32x4 z = {0.f, 0.f, 0.f, 0.f};
                accP[ctl] = z;
            }
#pragma unroll
            for (int t2 = 0; t2 < 2; ++t2) {
                if (t2 < nT2) {
                    const int f = (snx == 1) ? 0 : ((snx == 2) ? 1 : (2 + t2));
                    bf16x8 a = *(const bf16x8*)&Ab[(f * 64 + ln) * 8];
#pragma unroll
                    for (int ctl = 0; ctl < 4; ++ctl) {
                        bf16x8 b = *(const bf16x8*)&Xb[((t2 * 16 + wv * 4 + ctl) * 64 + ln) * 8];
                        accP[ctl] = __builtin_amdgcn_mfma_f32_16x16x32_bf16(a, b, accP[ctl], 0, 0, 0);
                    }
                }
            }
#pragma unroll
            for (int ctl = 0; ctl < 4; ++ctl)
#pragma unroll
                for (int jj = 0; jj < 4; ++jj)
                    Pf[(lkg * 4 + jj) * 256 + wv * 64 + ctl * 16 + lrow] = accP[ctl][jj];
            __syncthreads();
        }
    }

    if (!(h & 1)) {
        const int dk = tid >> 1, ch = (tid & 1) * 32;
        ushort* dst = knT + ((size_t)(kh * NCHK + n) * DKD + dk) * CCH + ch;
        const int kpart = ((dk >> 5) * 64) * 8 + (((dk >> 3) & 3) << 4) * 8 + (dk & 7);
#pragma unroll
        for (int j0 = 0; j0 < 32; j0 += 8) {
            union { ushort us[8]; uint4 v; } p;
#pragma unroll
            for (int j = 0; j < 8; ++j) {
                const int row = ch + j0 + j;
                p.us[j] = kb[((row >> 4) * 4 * 64 + (row & 15)) * 8 + kpart];
            }
            *(uint4*)(dst + j0) = p.v;
        }
    }
}

// ================= Phase B: inter-chunk state scan (MFMA) ===================
__global__ __launch_bounds__(256) void phaseB_kernel(
    const ushort* __restrict__ qnb, const ushort* __restrict__ knT,
    const float* __restrict__ u, const ushort* __restrict__ kcd,
    const ushort* __restrict__ sc, const float* __restrict__ gcs,
    float* __restrict__ obuf)
{
    extern __shared__ ushort smu[];
    ushort* qorg  = smu;             // 8192  [m4][ks4][64][8]
    ushort* kcorg = smu + 8192;      // 8192
    ushort* scorg = smu + 16384;     // 4096
    ushort* kTorg = smu + 20480;     // 8192
    ushort* storg = smu + 28672;     // 2048  S^T bf16
    ushort* vnorg = smu + 30720;     // 1024
    ushort* vnsorg= smu + 31744;     // 1024
    float* gcs_s  = (float*)(smu + 32768);   // 64

    const int h = blockIdx.x;
    const int dvb = blockIdx.y;
    const int d0 = dvb * 16;
    const int kh = h >> 1;
    const int tid = threadIdx.x;
    const int wv = tid >> 6, ln = tid & 63;
    const int lrow = ln & 15, lkg = ln >> 4;

    for (int i = tid; i < 2048 / 8; i += 256) {
        uint4 z = {0, 0, 0, 0};
        *(uint4*)&storg[i * 8] = z;
    }

    const int q_lane  = lrow * (NKH * DKD) + kh * DKD + wv * 32 + lkg * 8;
    const int kc_lane = lrow * DKD + wv * 32 + lkg * 8;
    const int st_lane = ((tid >> 7) * 16 + lrow) * 64 + ((tid >> 6) & 1) * 32 + lkg * 8;
    const int dst_e   = wv * 512;

    f32x4 accS0 = {0.f, 0.f, 0.f, 0.f}, accS1 = {0.f, 0.f, 0.f, 0.f};

    for (int n = 0; n < NCHK; ++n) {
        const int s0 = n * CCH;
        const ushort* qsrc  = qnb + (size_t)s0 * (NKH * DKD);
        const ushort* kcsrc = kcd + (size_t)(h * NCHK + n) * (CCH * DKD);
        const ushort* scsrc = sc  + (size_t)(h * NCHK + n) * (CCH * CCH);
        const ushort* kTsrc = knT + (size_t)(kh * NCHK + n) * (DKD * CCH);
#pragma unroll
        for (int r = 0; r < 4; ++r) {
            GLL(qsrc + q_lane + r * 32768, &qorg[r * 2048 + dst_e]);
            GLL(kcsrc + kc_lane + r * 2048, &kcorg[r * 2048 + dst_e]);
            GLL(kTsrc + st_lane + r * 2048, &kTorg[r * 2048 + dst_e]);
        }
#pragma unroll
        for (int r = 0; r < 2; ++r)
            GLL(scsrc + st_lane + r * 2048, &scorg[r * 2048 + dst_e]);
        if (tid < 64) gcs_s[tid] = gcs[(size_t)h * S_LEN + s0 + tid];
        __syncthreads();                 // B1

        f32x4 accv = {0.f, 0.f, 0.f, 0.f};
        f32x4 acco = {0.f, 0.f, 0.f, 0.f};
#pragma unroll
        for (int ks = 0; ks < 4; ++ks) {
            bf16x8 b_st = *(const bf16x8*)&storg[(ks * 64 + ln) * 8];
            bf16x8 a_kc = *(const bf16x8*)&kcorg[((wv * 4 + ks) * 64 + ln) * 8];
            bf16x8 a_q  = *(const bf16x8*)&qorg[((wv * 4 + ks) * 64 + ln) * 8];
            accv = __builtin_amdgcn_mfma_f32_16x16x32_bf16(a_kc, b_st, accv, 0, 0, 0);
            acco = __builtin_amdgcn_mfma_f32_16x16x32_bf16(a_q, b_st, acco, 0, 0, 0);
        }
        const float* up = u + (size_t)(h * NCHK + n) * (CCH * DVD)
                            + (wv * 16 + lkg * 4) * DVD + d0 + lrow;
        float u0 = up[0], u1 = up[DVD], u2 = up[2 * DVD], u3 = up[3 * DVD];
        const float gl = gcs_s[63];
        float vn0 = u0 - accv[0], vn1 = u1 - accv[1];
        float vn2 = u2 - accv[2], vn3 = u3 - accv[3];
        {
            const int row = wv * 16 + lkg * 4;
            float g0 = gcs_s[row], g1 = gcs_s[row + 1], g2 = gcs_s[row + 2], g3 = gcs_s[row + 3];
            acco[0] *= __expf(g0); acco[1] *= __expf(g1);
            acco[2] *= __expf(g2); acco[3] *= __expf(g3);
            const int eb = ((wv >> 1) * 64 + ((wv & 1) * 2 + (lkg >> 1)) * 16 + lrow) * 8
                         + (lkg & 1) * 4;
            union { ushort u2a[4]; uint2 v; } pa, pb;
            pa.u2a[0] = f2bf(vn0); pa.u2a[1] = f2bf(vn1);
            pa.u2a[2] = f2bf(vn2); pa.u2a[3] = f2bf(vn3);
            pb.u2a[0] = f2bf(vn0 * __expf(gl - g0)); pb.u2a[1] = f2bf(vn1 * __expf(gl - g1));
            pb.u2a[2] = f2bf(vn2 * __expf(gl - g2)); pb.u2a[3] = f2bf(vn3 * __expf(gl - g3));
            *(uint2*)&vnorg[eb] = pa.v;
            *(uint2*)&vnsorg[eb] = pb.v;
        }
        __syncthreads();                 // B2

#pragma unroll
        for (int ks = 0; ks < 2; ++ks) {
            bf16x8 a_sc = *(const bf16x8*)&scorg[((wv * 2 + ks) * 64 + ln) * 8];
            bf16x8 b_vn = *(const bf16x8*)&vnorg[(ks * 64 + ln) * 8];
            acco = __builtin_amdgcn_mfma_f32_16x16x32_bf16(a_sc, b_vn, acco, 0, 0, 0);
        }
        float* op = obuf + (size_t)(s0 + wv * 16 + lkg * 4) * VAL_DIM + h * DVD + d0 + lrow;
        op[0] = acco[0]; op[VAL_DIM] = acco[1];
        op[2 * VAL_DIM] = acco[2]; op[3 * VAL_DIM] = acco[3];

        const float egl = __expf(gl);
        accS0 *= egl; accS1 *= egl;
#pragma unroll
        for (int ks = 0; ks < 2; ++ks) {
            bf16x8 a_vs = *(const bf16x8*)&vnsorg[(ks * 64 + ln) * 8];
            bf16x8 b_k0 = *(const bf16x8*)&kTorg[(((wv * 2 + 0) * 2 + ks) * 64 + ln) * 8];
            bf16x8 b_k1 = *(const bf16x8*)&kTorg[(((wv * 2 + 1) * 2 + ks) * 64 + ln) * 8];
            accS0 = __builtin_amdgcn_mfma_f32_16x16x32_bf16(a_vs, b_k0, accS0, 0, 0, 0);
            accS1 = __builtin_amdgcn_mfma_f32_16x16x32_bf16(a_vs, b_k1, accS1, 0, 0, 0);
        }
#pragma unroll
        for (int j = 0; j < 4; ++j) {
            storg[(wv * 64 + ((lrow >> 3)) * 16 + lkg * 4 + j) * 8 + (lrow & 7)] = f2bf(accS0[j]);
            storg[(wv * 64 + (2 + (lrow >> 3)) * 16 + lkg * 4 + j) * 8 + (lrow & 7)] = f2bf(accS1[j]);
        }
        __syncthreads();                 // B3
    }
}

// ================= RMSNorm * norm_w * silu(z) -> bf16 =======================
__global__ __launch_bounds__(256) void norm_kernel(
    const float* __restrict__ obuf, const float* __restrict__ z,
    const float* __restrict__ nw, ushort* __restrict__ hbuf)
{
    int row = (blockIdx.x * 256 + threadIdx.x) >> 6;
    int lane = threadIdx.x & 63;
    float2 x = *(const float2*)(obuf + (size_t)row * DVD + lane * 2);
    float ss = x.x * x.x + x.y * x.y;
#pragma unroll
    for (int m = 1; m < 64; m <<= 1) ss += __shfl_xor(ss, m, 64);
    float scale = rsqrtf(ss * (1.f / DVD) + 1e-6f);
    float2 zz = *(const float2*)(z + (size_t)row * DVD + lane * 2);
    float2 w2 = *(const float2*)(nw + lane * 2);
    float h0 = x.x * scale * w2.x * silu_f(zz.x);
    float h1 = x.y * scale * w2.y * silu_f(zz.y);
    union { ushort u[2]; uint v; } r;
    r.u[0] = f2bf(h0); r.u[1] = f2bf(h1);
    *(uint*)(hbuf + (size_t)row * DVD + lane * 2) = r.v;
}

// ============================================================================
extern "C" void kernel_launch(void* const* d_in, const int* in_sizes, int n_in,
                              void* d_out, int out_size, void* d_ws, size_t ws_size,
                              hipStream_t stream)
{
    (void)in_sizes; (void)n_in; (void)out_size; (void)ws_size;
    const float* x      = (const float*)d_in[0];
    const float* W_qkv  = (const float*)d_in[1];
    const float* W_z    = (const float*)d_in[2];
    const float* W_a    = (const float*)d_in[3];
    const float* W_b    = (const float*)d_in[4];
    const float* conv_w = (const float*)d_in[5];
    const float* dt_b   = (const float*)d_in[6];
    const float* A_log  = (const float*)d_in[7];
    const float* norm_w = (const float*)d_in[8];
    const float* W_out  = (const float*)d_in[9];
    float* out = (float*)d_out;

    // ---- workspace layout (bytes), overlaid by liveness; total ~202.1 MB ---
    char* ws = (char*)d_ws;
    // region A @0 (67,108,864): mixed_pre -> {u f32, kcd bf16, knT bf16}
    float*  mixed_pre = (float*)(ws);
    float*  u_buf     = (float*)(ws);                   // 33,554,432
    ushort* kcd_buf   = (ushort*)(ws + 33554432);       // 16,777,216
    ushort* knT_buf   = (ushort*)(ws + 50331648);       //  8,388,608
    // region B @67,108,864 (67,108,864): {wqz 50.3MB, xb 8.4MB} -> mixed ->
    //   {obuf 33.6, hbuf 16.8, wob 16.8}
    ushort* wqz       = (ushort*)(ws + 67108864);       // 50,331,648 (12288x2048)
    ushort* xb        = (ushort*)(ws + 117440512);      //  8,388,608
    float*  mixed     = (float*)(ws + 67108864);
    float*  obuf      = (float*)(ws + 67108864);
    ushort* hbuf      = (ushort*)(ws + 100663296);
    ushort* wob       = (ushort*)(ws + 117440512);
    // fixed regions
    float*  z_buf     = (float*)(ws + 134217728);       // 33,554,432
    ushort* sc_buf    = (ushort*)(ws + 167772160);      //  8,388,608 (step>=6)
    ushort* wabb      = (ushort*)(ws + 167772160);      //    524,288 (steps 1-3)
    float*  ab_buf    = (float*)(ws + 168296448);       //  1,048,576 (steps 3-4)
    ushort* qnb       = (ushort*)(ws + 176160768);      //  8,388,608
    float*  kn        = (float*)(ws + 184549376);       // 16,777,216
    float*  g_buf     = (float*)(ws + 201326592);       //    262,144
    float*  bet_buf   = (float*)(ws + 201588736);       //    262,144
    float*  gcs_buf   = (float*)(ws + 201850880);       //    262,144

    hipFuncSetAttribute((const void*)phaseA_kernel,
                        hipFuncAttributeMaxDynamicSharedMemorySize, PA_LDS_BYTES);
    hipFuncSetAttribute((const void*)phaseB_kernel,
                        hipFuncAttributeMaxDynamicSharedMemorySize, PB_LDS_BYTES);
    hipFuncSetAttribute((const void*)gemm8p_kernel,
                        hipFuncAttributeMaxDynamicSharedMemorySize, G8P_LDS_BYTES);
    hipFuncSetAttribute((const void*)gemm128_kernel,
                        hipFuncAttributeMaxDynamicSharedMemorySize, G128_LDS_BYTES);

    dim3 blk(256);
    // 1) casts to bf16 (W_qkv and W_z fused contiguously into wqz)
    cast_kernel<<<(S_LEN * HIDDIM / 8) / 256, blk, 0, stream>>>(x, xb, S_LEN * HIDDIM / 8);
    cast_kernel<<<(CONV_DIM * HIDDIM / 8) / 256, blk, 0, stream>>>(W_qkv, wqz, CONV_DIM * HIDDIM / 8);
    cast_kernel<<<(VAL_DIM * HIDDIM / 8) / 256, blk, 0, stream>>>(W_z, wqz + (size_t)CONV_DIM * HIDDIM, VAL_DIM * HIDDIM / 8);
    cast_ab_kernel<<<(128 * HIDDIM / 8) / 256, blk, 0, stream>>>(W_a, W_b, wabb);
    // 2) fused qkv+z projection (256^2 8-phase, 384 blocks)
    gemm8p_kernel<<<dim3((CONV_DIM + VAL_DIM) / 256, S_LEN / 256), dim3(512), G8P_LDS_BYTES, stream>>>(
        xb, wqz, mixed_pre, z_buf, HIDDIM, CONV_DIM, CONV_DIM, VAL_DIM);
    // 3) a/b projection
    gemm128_kernel<<<dim3(1, S_LEN / 128), blk, G128_LDS_BYTES, stream>>>(
        xb, wabb, ab_buf, 128, HIDDIM);
    // 4) conv + silu (fp32)
    conv_silu_kernel<<<(S_LEN * CONV_DIM / 4) / 256, blk, 0, stream>>>(mixed_pre, conv_w, mixed);
    // 5) gates
    gb_kernel<<<(S_LEN * NVH) / 256, blk, 0, stream>>>(ab_buf, dt_b, A_log, g_buf, bet_buf);
    // 6) l2norm q,k
    l2norm_kernel<<<(2 * S_LEN * NKH * 64) / 256, blk, 0, stream>>>(mixed, qnb, kn);
    // 7) phase A (intra-chunk, blocked-MFMA solve)
    phaseA_kernel<<<dim3(NCHK, NVH), blk, PA_LDS_BYTES, stream>>>(
        qnb, kn, mixed, g_buf, bet_buf, u_buf, kcd_buf, sc_buf, gcs_buf, knT_buf);
    // 8) phase B (inter-chunk scan, MFMA)
    phaseB_kernel<<<dim3(NVH, 8), blk, PB_LDS_BYTES, stream>>>(
        qnb, knT_buf, u_buf, kcd_buf, sc_buf, gcs_buf, obuf);
    // 9) W_out cast (mixed region now dead) + gated RMSNorm -> bf16
    cast_kernel<<<(HIDDIM * VAL_DIM / 8) / 256, blk, 0, stream>>>(W_out, wob, HIDDIM * VAL_DIM / 8);
    norm_kernel<<<(S_LEN * NVH * 64) / 256, blk, 0, stream>>>(obuf, z_buf, norm_w, hbuf);
    // 10) output projection (128^2 triple-buffered, 256 blocks = 1x256)
    gemm128_kernel<<<dim3(HIDDIM / 128, S_LEN / 128), blk, G128_LDS_BYTES, stream>>>(
        hbuf, wob, out, HIDDIM, VAL_DIM);
}

// Round 10
// 509.086 us; speedup vs baseline: 1.1708x; 1.1708x over previous
//
#include <hip/hip_runtime.h>
#include <hip/hip_bf16.h>
#include <math.h>

// ---- problem constants ----
#define S_LEN   2048
#define HIDDIM  2048
#define NKH     16
#define NVH     32
#define DKD     128
#define DVD     128
#define CCH     64          // chunk
#define NCHK    32          // S/chunk
#define KEY_DIM 2048
#define VAL_DIM 4096
#define CONV_DIM 8192

#define PA_LDS_BYTES (16384 + 16384 + 32768 + 4096 + 4096 + 256 + 256 + 256)
#define PB_LDS_BYTES ((8192+8192+4096+8192+2048+1024+1024)*2 + 64*4)
// gemm256: 3 bufs x (A 128x64 + B 256x64) bf16 = 3 x 24576 ushorts
#define G256_LDS_BYTES (3 * 24576 * 2)   // 147456
// gemm128: 3 bufs x (A 128x64 + B 128x64) = 3 x 16384 ushorts
#define G128_LDS_BYTES (3 * 16384 * 2)   // 98304

typedef __bf16 bf16x8 __attribute__((ext_vector_type(8)));
typedef float f32x4 __attribute__((ext_vector_type(4)));

__device__ __forceinline__ float sigmoid_f(float x) { return 1.f / (1.f + __expf(-x)); }
__device__ __forceinline__ float silu_f(float x) { return x * sigmoid_f(x); }
__device__ __forceinline__ ushort f2bf(float f) {
    unsigned u = __float_as_uint(f);
    u += 0x7fffu + ((u >> 16) & 1u);          // RNE (inputs finite)
    return (ushort)(u >> 16);
}
__device__ __forceinline__ float bf2f(ushort u) {
    return __uint_as_float((unsigned)u << 16);
}

#define GLL(srcp, dstp) __builtin_amdgcn_global_load_lds( \
    (const __attribute__((address_space(1))) void*)(srcp), \
    (__attribute__((address_space(3))) void*)(dstp), 16, 0, 0)

// ================= fp32 -> bf16 cast (8 elems/thread) =======================
__global__ __launch_bounds__(256) void cast_kernel(
    const float* __restrict__ in, ushort* __restrict__ out, int n8)
{
    int t = blockIdx.x * 256 + threadIdx.x;
    if (t >= n8) return;
    float4 v0 = *(const float4*)(in + (size_t)t * 8);
    float4 v1 = *(const float4*)(in + (size_t)t * 8 + 4);
    union { ushort u[8]; uint4 v; } r;
    r.u[0] = f2bf(v0.x); r.u[1] = f2bf(v0.y); r.u[2] = f2bf(v0.z); r.u[3] = f2bf(v0.w);
    r.u[4] = f2bf(v1.x); r.u[5] = f2bf(v1.y); r.u[6] = f2bf(v1.z); r.u[7] = f2bf(v1.w);
    *(uint4*)(out + (size_t)t * 8) = r.v;
}

// === W_a,W_b -> one padded bf16 weight [256,2048] (rows 64..255 zero) =======
__global__ __launch_bounds__(256) void cast_ab_kernel(
    const float* __restrict__ Wa, const float* __restrict__ Wb, ushort* __restrict__ out)
{
    int t = blockIdx.x * 256 + threadIdx.x;          // 256*2048/8 = 65536 threads
    int row = t >> 8;
    int c8 = (t & 255) * 8;
    union { ushort u[8]; uint4 v; } r;
    if (row < 64) {
        const float* src = (row < 32) ? (Wa + (size_t)row * HIDDIM + c8)
                                      : (Wb + (size_t)(row - 32) * HIDDIM + c8);
        float4 v0 = *(const float4*)(src);
        float4 v1 = *(const float4*)(src + 4);
        r.u[0] = f2bf(v0.x); r.u[1] = f2bf(v0.y); r.u[2] = f2bf(v0.z); r.u[3] = f2bf(v0.w);
        r.u[4] = f2bf(v1.x); r.u[5] = f2bf(v1.y); r.u[6] = f2bf(v1.z); r.u[7] = f2bf(v1.w);
    } else {
        r.u[0] = r.u[1] = r.u[2] = r.u[3] = r.u[4] = r.u[5] = r.u[6] = r.u[7] = 0;
    }
    *(uint4*)(out + (size_t)t * 8) = r.v;
}

// ======== 128x256 triple-buffered counted-vmcnt bf16 GEMM, 3-way output =====
// C[M,Ntot] = A[M,K] @ B[Ntot,K]^T ; block cols < NS1 -> C0, < NS2 -> C1,
// else C2 (NS1, NS2 multiples of 256 -> a block lands entirely in one region).
// 512 thr = 8 waves (2M x 4N), wave tile 64x64. BK=64, 3 LDS buffers:
// tile t computes buf t%3; tile t+2 staged into buf (t+2)%3 during tile t.
// Top-of-tile wait = vmcnt(6) (t+1's loads stay in flight). 1 barrier/tile.
__global__ __launch_bounds__(512, 2) void gemm256_kernel(
    const ushort* __restrict__ A, const ushort* __restrict__ B,
    float* __restrict__ C0, float* __restrict__ C1, float* __restrict__ C2,
    int K, int NS1, int NS2, int ldc0, int ldc1, int ldc2)
{
    extern __shared__ ushort g2s[];          // [3][A 8192 | B 16384] ushorts
    const int tid = threadIdx.x;
    const int wv = tid >> 6, ln = tid & 63;
    const int wm = wv >> 2, wn = wv & 3;
    const int lrow = ln & 15, lkg = ln >> 4;
    const int bm = blockIdx.y * 128, bn = blockIdx.x * 256;

    // staging source offsets: granule g -> frag=g>>7, ks=(g>>6)&1, l=g&63
    // elem (frag*16+(l&15), ks*32+(l>>4)*8); A: g=tid+j*512 (j<2), B: j<4
    int soffA[2], soffB[4];
#pragma unroll
    for (int j = 0; j < 4; ++j) {
        int g = tid + j * 512;
        int frag = g >> 7, ks = (g >> 6) & 1, l = g & 63;
        int off = (frag * 16 + (l & 15)) * K + ks * 32 + (l >> 4) * 8;
        if (j < 2) soffA[j] = off;
        soffB[j] = off;
    }
    const ushort* Abase = A + (size_t)bm * K;
    const ushort* Bbase = B + (size_t)bn * K;

    f32x4 acc[4][4];
#pragma unroll
    for (int m = 0; m < 4; ++m)
#pragma unroll
        for (int n = 0; n < 4; ++n) {
            f32x4 z = {0.f, 0.f, 0.f, 0.f};
            acc[m][n] = z;
        }

#define G256_STAGE(bb, k0) do {                                            \
        ushort* bufA_ = g2s + (bb) * 24576;                                \
        ushort* bufB_ = bufA_ + 8192;                                      \
        _Pragma("unroll")                                                  \
        for (int j_ = 0; j_ < 2; ++j_)                                     \
            GLL(Abase + soffA[j_] + (k0), bufA_ + (j_ * 512 + wv * 64) * 8);\
        _Pragma("unroll")                                                  \
        for (int j_ = 0; j_ < 4; ++j_)                                     \
            GLL(Bbase + soffB[j_] + (k0), bufB_ + (j_ * 512 + wv * 64) * 8);\
    } while (0)

    const int T = K >> 6;
    G256_STAGE(0, 0);
    G256_STAGE(1, 64);
    int bb = 0;
    for (int t = 0; t < T; ++t) {
        if (t + 1 < T) {
            asm volatile("s_waitcnt vmcnt(6)" ::: "memory");
        } else {
            asm volatile("s_waitcnt vmcnt(0)" ::: "memory");
        }
        __builtin_amdgcn_s_barrier();          // all threads' tile-t loads landed
        // stage target = (bb+2)%3 : 0->2, 1->0, 2->1
        if (t + 2 < T) G256_STAGE((bb >= 1) ? (bb - 1) : (bb + 2), (t + 2) * 64);
        const ushort* LA = g2s + bb * 24576;
        const ushort* LB = LA + 8192;
        __builtin_amdgcn_s_setprio(1);
#pragma unroll
        for (int ks = 0; ks < 2; ++ks) {
            bf16x8 afv[4], bfv[4];
#pragma unroll
            for (int mf = 0; mf < 4; ++mf)
                afv[mf] = *(const bf16x8*)&LA[(((wm * 4 + mf) * 2 + ks) * 64 + ln) * 8];
#pragma unroll
            for (int nf = 0; nf < 4; ++nf)
                bfv[nf] = *(const bf16x8*)&LB[(((wn * 4 + nf) * 2 + ks) * 64 + ln) * 8];
#pragma unroll
            for (int mf = 0; mf < 4; ++mf)
#pragma unroll
                for (int nf = 0; nf < 4; ++nf)
                    acc[mf][nf] = __builtin_amdgcn_mfma_f32_16x16x32_bf16(
                        afv[mf], bfv[nf], acc[mf][nf], 0, 0, 0);
        }
        __builtin_amdgcn_s_setprio(0);
        bb = (bb == 2) ? 0 : bb + 1;
    }
#undef G256_STAGE

    // epilogue: 3-way output split
    float* Cp; int ldc, coff;
    if (bn < NS1)      { Cp = C0; ldc = ldc0; coff = bn; }
    else if (bn < NS2) { Cp = C1; ldc = ldc1; coff = bn - NS1; }
    else               { Cp = C2; ldc = ldc2; coff = bn - NS2; }
#pragma unroll
    for (int mf = 0; mf < 4; ++mf) {
        const int row0 = bm + wm * 64 + mf * 16 + lkg * 4;
#pragma unroll
        for (int nf = 0; nf < 4; ++nf) {
            float* cp = Cp + (size_t)row0 * ldc + coff + wn * 64 + nf * 16 + lrow;
#pragma unroll
            for (int j = 0; j < 4; ++j) cp[(size_t)j * ldc] = acc[mf][nf][j];
        }
    }
}

// ======== 128x128 triple-buffered counted-vmcnt bf16 GEMM ===================
__global__ __launch_bounds__(256, 2) void gemm128_kernel(
    const ushort* __restrict__ A, const ushort* __restrict__ B,
    float* __restrict__ C, int N, int K)
{
    extern __shared__ ushort g1s[];          // [3][A 8192 | B 8192] ushorts
    const int tid = threadIdx.x;
    const int wv = tid >> 6, ln = tid & 63;
    const int wm = wv >> 1, wn = wv & 1;
    const int lrow = ln & 15, lkg = ln >> 4;
    const int bm = blockIdx.y * 128, bn = blockIdx.x * 128;

    int soff[4];
#pragma unroll
    for (int j = 0; j < 4; ++j) {
        int g = tid + j * 256;
        int frag = g >> 7, ks = (g >> 6) & 1, l = g & 63;
        soff[j] = (frag * 16 + (l & 15)) * K + ks * 32 + (l >> 4) * 8;
    }
    const ushort* Abase = A + (size_t)bm * K;
    const ushort* Bbase = B + (size_t)bn * K;

    f32x4 acc[4][4];
#pragma unroll
    for (int m = 0; m < 4; ++m)
#pragma unroll
        for (int n = 0; n < 4; ++n) {
            f32x4 z = {0.f, 0.f, 0.f, 0.f};
            acc[m][n] = z;
        }

#define G128_STAGE(bb, k0) do {                                            \
        ushort* bufA_ = g1s + (bb) * 16384;                                \
        ushort* bufB_ = bufA_ + 8192;                                      \
        _Pragma("unroll")                                                  \
        for (int j_ = 0; j_ < 4; ++j_) {                                   \
            GLL(Abase + soff[j_] + (k0), bufA_ + (j_ * 256 + wv * 64) * 8);\
            GLL(Bbase + soff[j_] + (k0), bufB_ + (j_ * 256 + wv * 64) * 8);\
        }                                                                  \
    } while (0)

    const int T = K >> 6;
    G128_STAGE(0, 0);
    G128_STAGE(1, 64);
    int bb = 0;
    for (int t = 0; t < T; ++t) {
        if (t + 1 < T) {
            asm volatile("s_waitcnt vmcnt(8)" ::: "memory");
        } else {
            asm volatile("s_waitcnt vmcnt(0)" ::: "memory");
        }
        __builtin_amdgcn_s_barrier();
        if (t + 2 < T) G128_STAGE((bb >= 1) ? (bb - 1) : (bb + 2), (t + 2) * 64);
        const ushort* LA = g1s + bb * 16384;
        const ushort* LB = LA + 8192;
        __builtin_amdgcn_s_setprio(1);
#pragma unroll
        for (int ks = 0; ks < 2; ++ks) {
            bf16x8 afv[4], bfv[4];
#pragma unroll
            for (int mf = 0; mf < 4; ++mf)
                afv[mf] = *(const bf16x8*)&LA[(((wm * 4 + mf) * 2 + ks) * 64 + ln) * 8];
#pragma unroll
            for (int nf = 0; nf < 4; ++nf)
                bfv[nf] = *(const bf16x8*)&LB[(((wn * 4 + nf) * 2 + ks) * 64 + ln) * 8];
#pragma unroll
            for (int mf = 0; mf < 4; ++mf)
#pragma unroll
                for (int nf = 0; nf < 4; ++nf)
                    acc[mf][nf] = __builtin_amdgcn_mfma_f32_16x16x32_bf16(
                        afv[mf], bfv[nf], acc[mf][nf], 0, 0, 0);
        }
        __builtin_amdgcn_s_setprio(0);
        bb = (bb == 2) ? 0 : bb + 1;
    }
#undef G128_STAGE

#pragma unroll
    for (int mf = 0; mf < 4; ++mf) {
        const int row0 = bm + wm * 64 + mf * 16 + lkg * 4;
#pragma unroll
        for (int nf = 0; nf < 4; ++nf) {
            float* cp = C + (size_t)row0 * N + bn + wn * 64 + nf * 16 + lrow;
#pragma unroll
            for (int j = 0; j < 4; ++j) cp[(size_t)j * N] = acc[mf][nf][j];
        }
    }
}

// ================= causal depthwise conv1d (K=4) + SiLU =====================
__global__ __launch_bounds__(256) void conv_silu_kernel(
    const float* __restrict__ pre, const float* __restrict__ cw, float* __restrict__ out)
{
    int idx = blockIdx.x * 256 + threadIdx.x;
    const int NC4 = CONV_DIM / 4;
    int s = idx / NC4;
    int c = (idx % NC4) * 4;
    float w[4][4];
#pragma unroll
    for (int j = 0; j < 4; ++j) {
        float4 wj = *(const float4*)(cw + (size_t)(c + j) * 4);
        w[j][0] = wj.x; w[j][1] = wj.y; w[j][2] = wj.z; w[j][3] = wj.w;
    }
    float acc[4] = {0.f, 0.f, 0.f, 0.f};
#pragma unroll
    for (int t = 0; t < 4; ++t) {
        int ss = s - 3 + t;
        if (ss >= 0) {
            float4 x = *(const float4*)(pre + (size_t)ss * CONV_DIM + c);
            acc[0] = fmaf(x.x, w[0][t], acc[0]);
            acc[1] = fmaf(x.y, w[1][t], acc[1]);
            acc[2] = fmaf(x.z, w[2][t], acc[2]);
            acc[3] = fmaf(x.w, w[3][t], acc[3]);
        }
    }
    float4 o = make_float4(silu_f(acc[0]), silu_f(acc[1]), silu_f(acc[2]), silu_f(acc[3]));
    *(float4*)(out + (size_t)s * CONV_DIM + c) = o;
}

// ====== g = -exp(A_log)*softplus(a+dt_bias), beta = sigmoid(b) ==============
// ab buffer layout: [S][256], a at cols 0..31, b at cols 32..63
__global__ __launch_bounds__(256) void gb_kernel(
    const float* __restrict__ ab, const float* __restrict__ dt_bias,
    const float* __restrict__ A_log, float* __restrict__ g, float* __restrict__ beta)
{
    int idx = blockIdx.x * 256 + threadIdx.x;
    int s = idx >> 5, h = idx & 31;
    float av = ab[(size_t)s * 256 + h] + dt_bias[h];
    float sp = (av > 20.f) ? av : log1pf(__expf(av));
    g[idx] = -__expf(A_log[h]) * sp;
    beta[idx] = sigmoid_f(ab[(size_t)s * 256 + 32 + h]);
}

// ===== l2norm q,k: q -> bf16 (qnb), k -> f32 (kn) ===========================
__global__ __launch_bounds__(256) void l2norm_kernel(
    const float* __restrict__ mixed, ushort* __restrict__ qnb, float* __restrict__ kn)
{
    int gw = (blockIdx.x * 256 + threadIdx.x) >> 6;
    int lane = threadIdx.x & 63;
    int isk = gw >= S_LEN * NKH;
    int r = gw - isk * S_LEN * NKH;
    int s = r / NKH, kh = r % NKH;
    const float* src = mixed + (size_t)s * CONV_DIM + isk * KEY_DIM + kh * DKD;
    float2 x = *(const float2*)(src + lane * 2);
    float ss = x.x * x.x + x.y * x.y;
#pragma unroll
    for (int m = 1; m < 64; m <<= 1) ss += __shfl_xor(ss, m, 64);
    float scale = rsqrtf(ss + 1e-6f);
    if (!isk) {
        scale *= 0.08838834764831843f;   // DK^-0.5
        union { ushort u[2]; uint v; } p;
        p.u[0] = f2bf(x.x * scale); p.u[1] = f2bf(x.y * scale);
        *(uint*)(qnb + ((size_t)(s * NKH + kh)) * DKD + lane * 2) = p.v;
    } else {
        float* dst = kn + ((size_t)(s * NKH + kh)) * DKD + lane * 2;
        *(float2*)dst = make_float2(x.x * scale, x.y * scale);
    }
}

// ================= Phase A: per (head, chunk) intra-chunk work ==============
// blocked WY solve: off-diagonal via MFMA, 16x16 diagonal solves scalar fp32.
__global__ __launch_bounds__(256) void phaseA_kernel(
    const ushort* __restrict__ qnb, const float* __restrict__ kn,
    const float* __restrict__ mixed, const float* __restrict__ gbuf,
    const float* __restrict__ betabuf,
    float* __restrict__ u, ushort* __restrict__ kcd,
    ushort* __restrict__ scores, float* __restrict__ gcs_out,
    ushort* __restrict__ knT)
{
    extern __shared__ char pasm[];
    ushort* kb    = (ushort*)(pasm);            // 16KB frag [m4][ks4][64][8]
    ushort* qb    = (ushort*)(pasm + 16384);    // 16KB frag; later P f32[16][256]
    ushort* Xb    = (ushort*)(pasm + 32768);    // 32KB [t2(2)][ct(16)][64][8]
    float*  Adiag = (float*)(pasm + 65536);     // 4KB [4][16][16] fp32 diag blocks
    ushort* Ab    = (ushort*)(pasm + 69632);    // 4KB: 4 frags 16x32 bf16 (K=32 padded)
    float*  gcs_s = (float*)(pasm + 73728);     // 64 f
    float*  bet_s = (float*)(pasm + 73984);     // 64 f
    float*  scK_s = (float*)(pasm + 74240);     // 64 f : beta*exp(gcs)
    float*  Pf    = (float*)qb;                 // alias (qb dead after QK^T MFMA)

    const int n = blockIdx.x, h = blockIdx.y, kh = h >> 1;
    const int tid = threadIdx.x;
    const int s0 = n * CCH;
    const int wv = tid >> 6, ln = tid & 63;
    const int lrow = ln & 15, lkg = ln >> 4;

    float xr[64];
    if (tid < 128) {
        const float* vp = mixed + (size_t)s0 * CONV_DIM + 2 * KEY_DIM + h * DVD + tid;
#pragma unroll
        for (int i = 0; i < 64; ++i) xr[i] = vp[(size_t)i * CONV_DIM];
    } else {
        const float* kp = kn + ((size_t)s0 * NKH + kh) * DKD + (tid - 128);
#pragma unroll
        for (int i = 0; i < 64; ++i) xr[i] = kp[(size_t)i * (NKH * DKD)];
    }

    {
        uint4 z = {0, 0, 0, 0};
#pragma unroll
        for (int i = 0; i < 8; ++i)
            *(uint4*)&Xb[(i * 256 + tid) * 8] = z;
        *(uint4*)&Ab[tid * 8] = z;
    }

    if (tid < 64) {
        float gv = gbuf[(size_t)(s0 + tid) * NVH + h];
#pragma unroll
        for (int off = 1; off < 64; off <<= 1) {
            float pv = __shfl_up(gv, off, 64);
            if (tid >= off) gv += pv;
        }
        float bv = betabuf[(size_t)(s0 + tid) * NVH + h];
        gcs_s[tid] = gv;
        bet_s[tid] = bv;
        scK_s[tid] = bv * __expf(gv);
        gcs_out[(size_t)h * S_LEN + s0 + tid] = gv;
    }

    {
        const int r = tid >> 2, c0 = (tid & 3) * 32;
        const int mbase = (((r >> 4) * 4 + (tid & 3)) * 64 + (r & 15)) * 8;
        const float* ksrc = kn + ((size_t)(s0 + r) * NKH + kh) * DKD + c0;
#pragma unroll
        for (int j0 = 0; j0 < 4; ++j0) {
            float4 v0 = *(const float4*)(ksrc + j0 * 8);
            float4 v1 = *(const float4*)(ksrc + j0 * 8 + 4);
            union { ushort us[8]; uint4 v; } p;
            p.us[0] = f2bf(v0.x); p.us[1] = f2bf(v0.y); p.us[2] = f2bf(v0.z); p.us[3] = f2bf(v0.w);
            p.us[4] = f2bf(v1.x); p.us[5] = f2bf(v1.y); p.us[6] = f2bf(v1.z); p.us[7] = f2bf(v1.w);
            *(uint4*)&kb[mbase + (j0 << 7)] = p.v;
        }
        const ushort* qsrc = qnb + ((size_t)(s0 + r) * NKH + kh) * DKD + c0;
#pragma unroll
        for (int j0 = 0; j0 < 4; ++j0) {
            uint4 v = *(const uint4*)(qsrc + j0 * 8);
            *(uint4*)&qb[mbase + (j0 << 7)] = v;
        }
    }
    __syncthreads();    // B1

    f32x4 accA[4], accQ[4];
#pragma unroll
    for (int j = 0; j < 4; ++j) {
        f32x4 z = {0.f, 0.f, 0.f, 0.f};
        accA[j] = z; accQ[j] = z;
    }
#pragma unroll
    for (int ks = 0; ks < 4; ++ks) {
        bf16x8 a_k = *(const bf16x8*)&kb[((wv * 4 + ks) * 64 + ln) * 8];
        bf16x8 a_q = *(const bf16x8*)&qb[((wv * 4 + ks) * 64 + ln) * 8];
#pragma unroll
        for (int j = 0; j < 4; ++j) {
            bf16x8 b_k = *(const bf16x8*)&kb[((j * 4 + ks) * 64 + ln) * 8];
            accA[j] = __builtin_amdgcn_mfma_f32_16x16x32_bf16(a_k, b_k, accA[j], 0, 0, 0);
            accQ[j] = __builtin_amdgcn_mfma_f32_16x16x32_bf16(a_q, b_k, accQ[j], 0, 0, 0);
        }
    }
    {
        ushort* scp = scores + (size_t)(h * NCHK + n) * (CCH * CCH);
#pragma unroll
        for (int j = 0; j < 4; ++j) {
            const int c = j * 16 + lrow;
            const float gc = gcs_s[c];
#pragma unroll
            for (int jj = 0; jj < 4; ++jj) {
                const int i = wv * 16 + lkg * 4 + jj;
                const float e = __expf(gcs_s[i] - gc);
                float sv = (i >= c) ? (accQ[j][jj] * e) : 0.f;
                scp[i * CCH + c] = f2bf(sv);
                float aval = (i > c) ? (-bet_s[i] * accA[j][jj] * e) : 0.f;
                if (j == wv) {
                    Adiag[wv * 256 + (i & 15) * 16 + lrow] = aval;
                } else if (j < wv) {
                    const int f = (wv == 1) ? 0 : ((wv == 2) ? 1 : (2 + (j >> 1)));
                    const int lk = ((j & 1) << 4) | lrow;
                    const int lane2 = (i & 15) | ((lk >> 3) << 4);
                    Ab[(f * 64 + lane2) * 8 + (lk & 7)] = f2bf(aval);
                }
            }
        }
    }
    if (tid < 128) {
#pragma unroll
        for (int i4 = 0; i4 < 16; ++i4) {
            float4 b4 = *(const float4*)&bet_s[i4 * 4];
            xr[i4 * 4 + 0] *= b4.x; xr[i4 * 4 + 1] *= b4.y;
            xr[i4 * 4 + 2] *= b4.z; xr[i4 * 4 + 3] *= b4.w;
        }
    } else {
#pragma unroll
        for (int i4 = 0; i4 < 16; ++i4) {
            float4 b4 = *(const float4*)&scK_s[i4 * 4];
            xr[i4 * 4 + 0] *= b4.x; xr[i4 * 4 + 1] *= b4.y;
            xr[i4 * 4 + 2] *= b4.z; xr[i4 * 4 + 3] *= b4.w;
        }
    }
    __syncthreads();    // B2

    const int ct = tid >> 4, lct = tid & 15;
#pragma unroll
    for (int s = 0; s < 4; ++s) {
        float y[16];
        float pr[16];
        if (s > 0) {
#pragma unroll
            for (int r = 0; r < 16; ++r) pr[r] = Pf[r * 256 + tid];
        } else {
#pragma unroll
            for (int r = 0; r < 16; ++r) pr[r] = 0.f;
        }
#pragma unroll
        for (int r = 0; r < 16; ++r) {
            float acc = xr[s * 16 + r] + pr[r];
#pragma unroll
            for (int k4 = 0; k4 < 16; k4 += 4) {
                if (k4 < r) {
                    float4 a4 = *(const float4*)&Adiag[s * 256 + r * 16 + k4];
                    if (k4 + 0 < r) acc = fmaf(a4.x, y[k4 + 0], acc);
                    if (k4 + 1 < r) acc = fmaf(a4.y, y[k4 + 1], acc);
                    if (k4 + 2 < r) acc = fmaf(a4.z, y[k4 + 2], acc);
                    if (k4 + 3 < r) acc = fmaf(a4.w, y[k4 + 3], acc);
                }
            }
            y[r] = acc;
        }
        if (tid < 128) {
            float* up = u + (size_t)(h * NCHK + n) * (CCH * DVD) + (s * 16) * DVD + tid;
#pragma unroll
            for (int r = 0; r < 16; ++r) up[r * DVD] = y[r];
        } else {
            ushort* kp = kcd + (size_t)(h * NCHK + n) * (CCH * DKD) + (s * 16) * DKD + (tid - 128);
#pragma unroll
            for (int r = 0; r < 16; ++r) kp[r * DKD] = f2bf(y[r]);
        }
        if (s < 3) {
#pragma unroll
            for (int half = 0; half < 2; ++half) {
                union { ushort us[8]; uint4 v; } p;
#pragma unroll
                for (int e = 0; e < 8; ++e) p.us[e] = f2bf(y[half * 8 + e]);
                const int kg = (s & 1) * 2 + half;
                *(uint4*)&Xb[(((s >> 1) * 16 + ct) * 64 + (kg * 16 + lct)) * 8] = p.v;
            }
            __syncthreads();
            const int snx = s + 1;
            const int nT2 = (snx + 1) >> 1;
            f32x4 accP[4];
#pragma unroll
            for (int ctl = 0; ctl < 4; ++ctl) {
                f32x4 z = {0.f, 0.f, 0.f, 0.f};
                accP[ctl] = z;
            }
#pragma unroll
            for (int t2 = 0; t2 < 2; ++t2) {
                if (t2 < nT2) {
                    const int f = (snx == 1) ? 0 : ((snx == 2) ? 1 : (2 + t2));
                    bf16x8 a = *(const bf16x8*)&Ab[(f * 64 + ln) * 8];
#pragma unroll
                    for (int ctl = 0; ctl < 4; ++ctl) {
                        bf16x8 b = *(const bf16x8*)&Xb[((t2 * 16 + wv * 4 + ctl) * 64 + ln) * 8];
                        accP[ctl] = __builtin_amdgcn_mfma_f32_16x16x32_bf16(a, b, accP[ctl], 0, 0, 0);
                    }
                }
            }
#pragma unroll
            for (int ctl = 0; ctl < 4; ++ctl)
#pragma unroll
                for (int jj = 0; jj < 4; ++jj)
                    Pf[(lkg * 4 + jj) * 256 + wv * 64 + ctl * 16 + lrow] = accP[ctl][jj];
            __syncthreads();
        }
    }

    if (!(h & 1)) {
        const int dk = tid >> 1, ch = (tid & 1) * 32;
        ushort* dst = knT + ((size_t)(kh * NCHK + n) * DKD + dk) * CCH + ch;
        const int kpart = ((dk >> 5) * 64) * 8 + (((dk >> 3) & 3) << 4) * 8 + (dk & 7);
#pragma unroll
        for (int j0 = 0; j0 < 32; j0 += 8) {
            union { ushort us[8]; uint4 v; } p;
#pragma unroll
            for (int j = 0; j < 8; ++j) {
                const int row = ch + j0 + j;
                p.us[j] = kb[((row >> 4) * 4 * 64 + (row & 15)) * 8 + kpart];
            }
            *(uint4*)(dst + j0) = p.v;
        }
    }
}

// ================= Phase B: inter-chunk state scan (MFMA) ===================
__global__ __launch_bounds__(256) void phaseB_kernel(
    const ushort* __restrict__ qnb, const ushort* __restrict__ knT,
    const float* __restrict__ u, const ushort* __restrict__ kcd,
    const ushort* __restrict__ sc, const float* __restrict__ gcs,
    float* __restrict__ obuf)
{
    extern __shared__ ushort smu[];
    ushort* qorg  = smu;             // 8192  [m4][ks4][64][8]
    ushort* kcorg = smu + 8192;      // 8192
    ushort* scorg = smu + 16384;     // 4096
    ushort* kTorg = smu + 20480;     // 8192
    ushort* storg = smu + 28672;     // 2048  S^T bf16
    ushort* vnorg = smu + 30720;     // 1024
    ushort* vnsorg= smu + 31744;     // 1024
    float* gcs_s  = (float*)(smu + 32768);   // 64

    const int h = blockIdx.x;
    const int dvb = blockIdx.y;
    const int d0 = dvb * 16;
    const int kh = h >> 1;
    const int tid = threadIdx.x;
    const int wv = tid >> 6, ln = tid & 63;
    const int lrow = ln & 15, lkg = ln >> 4;

    for (int i = tid; i < 2048 / 8; i += 256) {
        uint4 z = {0, 0, 0, 0};
        *(uint4*)&storg[i * 8] = z;
    }

    const int q_lane  = lrow * (NKH * DKD) + kh * DKD + wv * 32 + lkg * 8;
    const int kc_lane = lrow * DKD + wv * 32 + lkg * 8;
    const int st_lane = ((tid >> 7) * 16 + lrow) * 64 + ((tid >> 6) & 1) * 32 + lkg * 8;
    const int dst_e   = wv * 512;

    f32x4 accS0 = {0.f, 0.f, 0.f, 0.f}, accS1 = {0.f, 0.f, 0.f, 0.f};

    for (int n = 0; n < NCHK; ++n) {
        const int s0 = n * CCH;
        const ushort* qsrc  = qnb + (size_t)s0 * (NKH * DKD);
        const ushort* kcsrc = kcd + (size_t)(h * NCHK + n) * (CCH * DKD);
        const ushort* scsrc = sc  + (size_t)(h * NCHK + n) * (CCH * CCH);
        const ushort* kTsrc = knT + (size_t)(kh * NCHK + n) * (DKD * CCH);
#pragma unroll
        for (int r = 0; r < 4; ++r) {
            GLL(qsrc + q_lane + r * 32768, &qorg[r * 2048 + dst_e]);
            GLL(kcsrc + kc_lane + r * 2048, &kcorg[r * 2048 + dst_e]);
            GLL(kTsrc + st_lane + r * 2048, &kTorg[r * 2048 + dst_e]);
        }
#pragma unroll
        for (int r = 0; r < 2; ++r)
            GLL(scsrc + st_lane + r * 2048, &scorg[r * 2048 + dst_e]);
        if (tid < 64) gcs_s[tid] = gcs[(size_t)h * S_LEN + s0 + tid];
        __syncthreads();                 // B1

        f32x4 accv = {0.f, 0.f, 0.f, 0.f};
        f32x4 acco = {0.f, 0.f, 0.f, 0.f};
#pragma unroll
        for (int ks = 0; ks < 4; ++ks) {
            bf16x8 b_st = *(const bf16x8*)&storg[(ks * 64 + ln) * 8];
            bf16x8 a_kc = *(const bf16x8*)&kcorg[((wv * 4 + ks) * 64 + ln) * 8];
            bf16x8 a_q  = *(const bf16x8*)&qorg[((wv * 4 + ks) * 64 + ln) * 8];
            accv = __builtin_amdgcn_mfma_f32_16x16x32_bf16(a_kc, b_st, accv, 0, 0, 0);
            acco = __builtin_amdgcn_mfma_f32_16x16x32_bf16(a_q, b_st, acco, 0, 0, 0);
        }
        const float* up = u + (size_t)(h * NCHK + n) * (CCH * DVD)
                            + (wv * 16 + lkg * 4) * DVD + d0 + lrow;
        float u0 = up[0], u1 = up[DVD], u2 = up[2 * DVD], u3 = up[3 * DVD];
        const float gl = gcs_s[63];
        float vn0 = u0 - accv[0], vn1 = u1 - accv[1];
        float vn2 = u2 - accv[2], vn3 = u3 - accv[3];
        {
            const int row = wv * 16 + lkg * 4;
            float g0 = gcs_s[row], g1 = gcs_s[row + 1], g2 = gcs_s[row + 2], g3 = gcs_s[row + 3];
            acco[0] *= __expf(g0); acco[1] *= __expf(g1);
            acco[2] *= __expf(g2); acco[3] *= __expf(g3);
            const int eb = ((wv >> 1) * 64 + ((wv & 1) * 2 + (lkg >> 1)) * 16 + lrow) * 8
                         + (lkg & 1) * 4;
            union { ushort u2a[4]; uint2 v; } pa, pb;
            pa.u2a[0] = f2bf(vn0); pa.u2a[1] = f2bf(vn1);
            pa.u2a[2] = f2bf(vn2); pa.u2a[3] = f2bf(vn3);
            pb.u2a[0] = f2bf(vn0 * __expf(gl - g0)); pb.u2a[1] = f2bf(vn1 * __expf(gl - g1));
            pb.u2a[2] = f2bf(vn2 * __expf(gl - g2)); pb.u2a[3] = f2bf(vn3 * __expf(gl - g3));
            *(uint2*)&vnorg[eb] = pa.v;
            *(uint2*)&vnsorg[eb] = pb.v;
        }
        __syncthreads();                 // B2

#pragma unroll
        for (int ks = 0; ks < 2; ++ks) {
            bf16x8 a_sc = *(const bf16x8*)&scorg[((wv * 2 + ks) * 64 + ln) * 8];
            bf16x8 b_vn = *(const bf16x8*)&vnorg[(ks * 64 + ln) * 8];
            acco = __builtin_amdgcn_mfma_f32_16x16x32_bf16(a_sc, b_vn, acco, 0, 0, 0);
        }
        float* op = obuf + (size_t)(s0 + wv * 16 + lkg * 4) * VAL_DIM + h * DVD + d0 + lrow;
        op[0] = acco[0]; op[VAL_DIM] = acco[1];
        op[2 * VAL_DIM] = acco[2]; op[3 * VAL_DIM] = acco[3];

        const float egl = __expf(gl);
        accS0 *= egl; accS1 *= egl;
#pragma unroll
        for (int ks = 0; ks < 2; ++ks) {
            bf16x8 a_vs = *(const bf16x8*)&vnsorg[(ks * 64 + ln) * 8];
            bf16x8 b_k0 = *(const bf16x8*)&kTorg[(((wv * 2 + 0) * 2 + ks) * 64 + ln) * 8];
            bf16x8 b_k1 = *(const bf16x8*)&kTorg[(((wv * 2 + 1) * 2 + ks) * 64 + ln) * 8];
            accS0 = __builtin_amdgcn_mfma_f32_16x16x32_bf16(a_vs, b_k0, accS0, 0, 0, 0);
            accS1 = __builtin_amdgcn_mfma_f32_16x16x32_bf16(a_vs, b_k1, accS1, 0, 0, 0);
        }
#pragma unroll
        for (int j = 0; j < 4; ++j) {
            storg[(wv * 64 + ((lrow >> 3)) * 16 + lkg * 4 + j) * 8 + (lrow & 7)] = f2bf(accS0[j]);
            storg[(wv * 64 + (2 + (lrow >> 3)) * 16 + lkg * 4 + j) * 8 + (lrow & 7)] = f2bf(accS1[j]);
        }
        __syncthreads();                 // B3
    }
}

// ================= RMSNorm * norm_w * silu(z) -> bf16 =======================
__global__ __launch_bounds__(256) void norm_kernel(
    const float* __restrict__ obuf, const float* __restrict__ z,
    const float* __restrict__ nw, ushort* __restrict__ hbuf)
{
    int row = (blockIdx.x * 256 + threadIdx.x) >> 6;
    int lane = threadIdx.x & 63;
    float2 x = *(const float2*)(obuf + (size_t)row * DVD + lane * 2);
    float ss = x.x * x.x + x.y * x.y;
#pragma unroll
    for (int m = 1; m < 64; m <<= 1) ss += __shfl_xor(ss, m, 64);
    float scale = rsqrtf(ss * (1.f / DVD) + 1e-6f);
    float2 zz = *(const float2*)(z + (size_t)row * DVD + lane * 2);
    float2 w2 = *(const float2*)(nw + lane * 2);
    float h0 = x.x * scale * w2.x * silu_f(zz.x);
    float h1 = x.y * scale * w2.y * silu_f(zz.y);
    union { ushort u[2]; uint v; } r;
    r.u[0] = f2bf(h0); r.u[1] = f2bf(h1);
    *(uint*)(hbuf + (size_t)row * DVD + lane * 2) = r.v;
}

// ============================================================================
extern "C" void kernel_launch(void* const* d_in, const int* in_sizes, int n_in,
                              void* d_out, int out_size, void* d_ws, size_t ws_size,
                              hipStream_t stream)
{
    (void)in_sizes; (void)n_in; (void)out_size; (void)ws_size;
    const float* x      = (const float*)d_in[0];
    const float* W_qkv  = (const float*)d_in[1];
    const float* W_z    = (const float*)d_in[2];
    const float* W_a    = (const float*)d_in[3];
    const float* W_b    = (const float*)d_in[4];
    const float* conv_w = (const float*)d_in[5];
    const float* dt_b   = (const float*)d_in[6];
    const float* A_log  = (const float*)d_in[7];
    const float* norm_w = (const float*)d_in[8];
    const float* W_out  = (const float*)d_in[9];
    float* out = (float*)d_out;

    // ---- workspace layout (bytes), overlaid by liveness; total ~202.1 MB ---
    char* ws = (char*)d_ws;
    // region A @0 (67,108,864): mixed_pre -> {u f32, kcd bf16, knT bf16}
    float*  mixed_pre = (float*)(ws);
    float*  u_buf     = (float*)(ws);                   // 33,554,432
    ushort* kcd_buf   = (ushort*)(ws + 33554432);       // 16,777,216
    ushort* knT_buf   = (ushort*)(ws + 50331648);       //  8,388,608
    // region B @67,108,864 (67,108,864):
    //   steps 1-2: wqz+wab (51.4MB) + xb (8.4MB) ; steps 4-7: mixed ;
    //   steps 8-10: obuf, hbuf, wob
    ushort* wqz       = (ushort*)(ws + 67108864);       // 50,331,648 (12288x2048)
    ushort* wabb      = (ushort*)(ws + 117440512);      //  1,048,576 (rows 12288..12543)
    ushort* xb        = (ushort*)(ws + 118489088);      //  8,388,608 (-> 126,877,696)
    float*  mixed     = (float*)(ws + 67108864);
    float*  obuf      = (float*)(ws + 67108864);
    ushort* hbuf      = (ushort*)(ws + 100663296);
    ushort* wob       = (ushort*)(ws + 117440512);      // 16,777,216 (step >=9)
    // fixed regions
    float*  z_buf     = (float*)(ws + 134217728);       // 33,554,432
    float*  ab_buf    = (float*)(ws + 167772160);       //  2,097,152 (steps 2-5)
    ushort* sc_buf    = (ushort*)(ws + 167772160);      //  8,388,608 (step >=7)
    ushort* qnb       = (ushort*)(ws + 176160768);      //  8,388,608
    float*  kn        = (float*)(ws + 184549376);       // 16,777,216
    float*  g_buf     = (float*)(ws + 201326592);       //    262,144
    float*  bet_buf   = (float*)(ws + 201588736);       //    262,144
    float*  gcs_buf   = (float*)(ws + 201850880);       //    262,144

    hipFuncSetAttribute((const void*)phaseA_kernel,
                        hipFuncAttributeMaxDynamicSharedMemorySize, PA_LDS_BYTES);
    hipFuncSetAttribute((const void*)phaseB_kernel,
                        hipFuncAttributeMaxDynamicSharedMemorySize, PB_LDS_BYTES);
    hipFuncSetAttribute((const void*)gemm256_kernel,
                        hipFuncAttributeMaxDynamicSharedMemorySize, G256_LDS_BYTES);
    hipFuncSetAttribute((const void*)gemm128_kernel,
                        hipFuncAttributeMaxDynamicSharedMemorySize, G128_LDS_BYTES);

    dim3 blk(256);
    // 1) casts to bf16 (W_qkv | W_z | W_ab fused contiguously at wqz)
    cast_kernel<<<(S_LEN * HIDDIM / 8) / 256, blk, 0, stream>>>(x, xb, S_LEN * HIDDIM / 8);
    cast_kernel<<<(CONV_DIM * HIDDIM / 8) / 256, blk, 0, stream>>>(W_qkv, wqz, CONV_DIM * HIDDIM / 8);
    cast_kernel<<<(VAL_DIM * HIDDIM / 8) / 256, blk, 0, stream>>>(W_z, wqz + (size_t)CONV_DIM * HIDDIM, VAL_DIM * HIDDIM / 8);
    cast_ab_kernel<<<(256 * HIDDIM / 8) / 256, blk, 0, stream>>>(W_a, W_b, wabb);
    // 2) fused qkv+z+ab projection (128x256 triple-buffered, 49x16 blocks)
    gemm256_kernel<<<dim3((CONV_DIM + VAL_DIM + 256) / 256, S_LEN / 128), dim3(512), G256_LDS_BYTES, stream>>>(
        xb, wqz, mixed_pre, z_buf, ab_buf, HIDDIM,
        CONV_DIM, CONV_DIM + VAL_DIM, CONV_DIM, VAL_DIM, 256);
    // 4) conv + silu (fp32)
    conv_silu_kernel<<<(S_LEN * CONV_DIM / 4) / 256, blk, 0, stream>>>(mixed_pre, conv_w, mixed);
    // 5) gates (ab stride 256)
    gb_kernel<<<(S_LEN * NVH) / 256, blk, 0, stream>>>(ab_buf, dt_b, A_log, g_buf, bet_buf);
    // 6) l2norm q,k
    l2norm_kernel<<<(2 * S_LEN * NKH * 64) / 256, blk, 0, stream>>>(mixed, qnb, kn);
    // 7) phase A (intra-chunk, blocked-MFMA solve)
    phaseA_kernel<<<dim3(NCHK, NVH), blk, PA_LDS_BYTES, stream>>>(
        qnb, kn, mixed, g_buf, bet_buf, u_buf, kcd_buf, sc_buf, gcs_buf, knT_buf);
    // 8) phase B (inter-chunk scan, MFMA)
    phaseB_kernel<<<dim3(NVH, 8), blk, PB_LDS_BYTES, stream>>>(
        qnb, knT_buf, u_buf, kcd_buf, sc_buf, gcs_buf, obuf);
    // 9) W_out cast (mixed region now dead) + gated RMSNorm -> bf16
    cast_kernel<<<(HIDDIM * VAL_DIM / 8) / 256, blk, 0, stream>>>(W_out, wob, HIDDIM * VAL_DIM / 8);
    norm_kernel<<<(S_LEN * NVH * 64) / 256, blk, 0, stream>>>(obuf, z_buf, norm_w, hbuf);
    // 10) output projection (128^2 triple-buffered, 256 blocks = 1x256)
    gemm128_kernel<<<dim3(HIDDIM / 128, S_LEN / 128), blk, G128_LDS_BYTES, stream>>>(
        hbuf, wob, out, HIDDIM, VAL_DIM);
}

// Round 11
// 491.761 us; speedup vs baseline: 1.2121x; 1.0352x over previous
//
#include <hip/hip_runtime.h>
#include <hip/hip_bf16.h>
#include <math.h>

// ---- problem constants ----
#define S_LEN   2048
#define HIDDIM  2048
#define NKH     16
#define NVH     32
#define DKD     128
#define DVD     128
#define CCH     64          // chunk
#define NCHK    32          // S/chunk
#define KEY_DIM 2048
#define VAL_DIM 4096
#define CONV_DIM 8192

#define PA_LDS_BYTES (16384 + 16384 + 32768 + 4096 + 4096 + 256 + 256 + 256)
#define PB_LDS_BYTES ((8192+8192+4096+8192+2048+1024+1024)*2 + 64*4)
// gemm256: 3 bufs x (A 128x32 + B 256x32) bf16 = 3 x 12288 ushorts = 72 KB
#define G256_LDS_BYTES (3 * 12288 * 2)
// gemm128: 3 bufs x (A 128x32 + B 128x32) = 3 x 8192 ushorts = 48 KB
#define G128_LDS_BYTES (3 * 8192 * 2)

typedef __bf16 bf16x8 __attribute__((ext_vector_type(8)));
typedef float f32x4 __attribute__((ext_vector_type(4)));

__device__ __forceinline__ float sigmoid_f(float x) { return 1.f / (1.f + __expf(-x)); }
__device__ __forceinline__ float silu_f(float x) { return x * sigmoid_f(x); }
__device__ __forceinline__ ushort f2bf(float f) {
    unsigned u = __float_as_uint(f);
    u += 0x7fffu + ((u >> 16) & 1u);          // RNE (inputs finite)
    return (ushort)(u >> 16);
}
__device__ __forceinline__ float bf2f(ushort u) {
    return __uint_as_float((unsigned)u << 16);
}

#define GLL(srcp, dstp) __builtin_amdgcn_global_load_lds( \
    (const __attribute__((address_space(1))) void*)(srcp), \
    (__attribute__((address_space(3))) void*)(dstp), 16, 0, 0)

// ================= fp32 -> bf16 cast (8 elems/thread) =======================
__global__ __launch_bounds__(256) void cast_kernel(
    const float* __restrict__ in, ushort* __restrict__ out, int n8)
{
    int t = blockIdx.x * 256 + threadIdx.x;
    if (t >= n8) return;
    float4 v0 = *(const float4*)(in + (size_t)t * 8);
    float4 v1 = *(const float4*)(in + (size_t)t * 8 + 4);
    union { ushort u[8]; uint4 v; } r;
    r.u[0] = f2bf(v0.x); r.u[1] = f2bf(v0.y); r.u[2] = f2bf(v0.z); r.u[3] = f2bf(v0.w);
    r.u[4] = f2bf(v1.x); r.u[5] = f2bf(v1.y); r.u[6] = f2bf(v1.z); r.u[7] = f2bf(v1.w);
    *(uint4*)(out + (size_t)t * 8) = r.v;
}

// ====== W_a,W_b -> one padded bf16 weight [128,2048] (rows 64..127 zero) ====
__global__ __launch_bounds__(256) void cast_ab_kernel(
    const float* __restrict__ Wa, const float* __restrict__ Wb, ushort* __restrict__ out)
{
    int t = blockIdx.x * 256 + threadIdx.x;          // 128*2048/8 = 32768 threads
    int row = t >> 8;
    int c8 = (t & 255) * 8;
    union { ushort u[8]; uint4 v; } r;
    if (row < 64) {
        const float* src = (row < 32) ? (Wa + (size_t)row * HIDDIM + c8)
                                      : (Wb + (size_t)(row - 32) * HIDDIM + c8);
        float4 v0 = *(const float4*)(src);
        float4 v1 = *(const float4*)(src + 4);
        r.u[0] = f2bf(v0.x); r.u[1] = f2bf(v0.y); r.u[2] = f2bf(v0.z); r.u[3] = f2bf(v0.w);
        r.u[4] = f2bf(v1.x); r.u[5] = f2bf(v1.y); r.u[6] = f2bf(v1.z); r.u[7] = f2bf(v1.w);
    } else {
        r.u[0] = r.u[1] = r.u[2] = r.u[3] = r.u[4] = r.u[5] = r.u[6] = r.u[7] = 0;
    }
    *(uint4*)(out + (size_t)t * 8) = r.v;
}

// ==== 128x256 triple-buffered counted-vmcnt bf16 GEMM (BK=32), dual out =====
// C[M,Ntot] = A[M,K] @ B[Ntot,K]^T ; block cols < NSPLIT -> C0 else C1.
// 512 thr = 8 waves (2M x 4N), wave tile 64x64. BK=32, 3 LDS buffers (72 KB
// total -> 2 blocks/CU, cross-block TLP covers barrier stalls). Tile t
// computes buf t%3; tile t+2 staged during t; top-of-tile wait vmcnt(3).
__global__ __launch_bounds__(512, 2) void gemm256_kernel(
    const ushort* __restrict__ A, const ushort* __restrict__ B,
    float* __restrict__ C0, float* __restrict__ C1,
    int K, int NSPLIT, int ldc0, int ldc1)
{
    extern __shared__ ushort g2s[];          // [3][A 4096 | B 8192] ushorts
    const int tid = threadIdx.x;
    const int wv = tid >> 6, ln = tid & 63;
    const int wm = wv >> 2, wn = wv & 3;
    const int lrow = ln & 15, lkg = ln >> 4;
    const int bm = blockIdx.y * 128, bn = blockIdx.x * 256;

    // staging source offsets: granule g -> frag=g>>6, l=g&63 ->
    // elem (frag*16+(l&15), (l>>4)*8). A: g=tid (1 GLL), B: g=tid+j*512 (2)
    int soffA, soffB[2];
    {
        int l = tid & 63;
        soffA = (((tid >> 6) * 16) + (l & 15)) * K + (l >> 4) * 8;
#pragma unroll
        for (int j = 0; j < 2; ++j) {
            int g = tid + j * 512;
            int lg = g & 63;
            soffB[j] = (((g >> 6) * 16) + (lg & 15)) * K + (lg >> 4) * 8;
        }
    }
    const ushort* Abase = A + (size_t)bm * K;
    const ushort* Bbase = B + (size_t)bn * K;

    f32x4 acc[4][4];
#pragma unroll
    for (int m = 0; m < 4; ++m)
#pragma unroll
        for (int n = 0; n < 4; ++n) {
            f32x4 z = {0.f, 0.f, 0.f, 0.f};
            acc[m][n] = z;
        }

#define G256_STAGE(bb, k0) do {                                            \
        ushort* bufA_ = g2s + (bb) * 12288;                                \
        ushort* bufB_ = bufA_ + 4096;                                      \
        GLL(Abase + soffA + (k0), bufA_ + (wv * 64) * 8);                  \
        _Pragma("unroll")                                                  \
        for (int j_ = 0; j_ < 2; ++j_)                                     \
            GLL(Bbase + soffB[j_] + (k0), bufB_ + (j_ * 512 + wv * 64) * 8);\
    } while (0)

    const int T = K >> 5;
    G256_STAGE(0, 0);
    G256_STAGE(1, 32);
    int bb = 0;
    for (int t = 0; t < T; ++t) {
        if (t + 1 < T) {
            asm volatile("s_waitcnt vmcnt(3)" ::: "memory");
        } else {
            asm volatile("s_waitcnt vmcnt(0)" ::: "memory");
        }
        __builtin_amdgcn_s_barrier();          // all threads' tile-t loads landed
        // stage target = (bb+2)%3 : 0->2, 1->0, 2->1
        if (t + 2 < T) G256_STAGE((bb >= 1) ? (bb - 1) : (bb + 2), (t + 2) * 32);
        const ushort* LA = g2s + bb * 12288;
        const ushort* LB = LA + 4096;
        __builtin_amdgcn_s_setprio(1);
        {
            bf16x8 afv[4], bfv[4];
#pragma unroll
            for (int mf = 0; mf < 4; ++mf)
                afv[mf] = *(const bf16x8*)&LA[((wm * 4 + mf) * 64 + ln) * 8];
#pragma unroll
            for (int nf = 0; nf < 4; ++nf)
                bfv[nf] = *(const bf16x8*)&LB[((wn * 4 + nf) * 64 + ln) * 8];
#pragma unroll
            for (int mf = 0; mf < 4; ++mf)
#pragma unroll
                for (int nf = 0; nf < 4; ++nf)
                    acc[mf][nf] = __builtin_amdgcn_mfma_f32_16x16x32_bf16(
                        afv[mf], bfv[nf], acc[mf][nf], 0, 0, 0);
        }
        __builtin_amdgcn_s_setprio(0);
        bb = (bb == 2) ? 0 : bb + 1;
    }
#undef G256_STAGE

    // epilogue: dual-output split (NSPLIT % 256 == 0 -> block on one side)
    const bool inC1 = (bn >= NSPLIT);
    float* Cp = inC1 ? C1 : C0;
    const int ldc = inC1 ? ldc1 : ldc0;
    const int cb = bn + wn * 64 - (inC1 ? NSPLIT : 0);
#pragma unroll
    for (int mf = 0; mf < 4; ++mf) {
        const int row0 = bm + wm * 64 + mf * 16 + lkg * 4;
#pragma unroll
        for (int nf = 0; nf < 4; ++nf) {
            float* cp = Cp + (size_t)row0 * ldc + cb + nf * 16 + lrow;
#pragma unroll
            for (int j = 0; j < 4; ++j) cp[(size_t)j * ldc] = acc[mf][nf][j];
        }
    }
}

// ======== 128x128 triple-buffered counted-vmcnt bf16 GEMM (BK=32) ===========
__global__ __launch_bounds__(256, 2) void gemm128_kernel(
    const ushort* __restrict__ A, const ushort* __restrict__ B,
    float* __restrict__ C, int N, int K)
{
    extern __shared__ ushort g1s[];          // [3][A 4096 | B 4096] ushorts
    const int tid = threadIdx.x;
    const int wv = tid >> 6, ln = tid & 63;
    const int wm = wv >> 1, wn = wv & 1;
    const int lrow = ln & 15, lkg = ln >> 4;
    const int bm = blockIdx.y * 128, bn = blockIdx.x * 128;

    int soff[2];
#pragma unroll
    for (int j = 0; j < 2; ++j) {
        int g = tid + j * 256;
        int l = g & 63;
        soff[j] = (((g >> 6) * 16) + (l & 15)) * K + (l >> 4) * 8;
    }
    const ushort* Abase = A + (size_t)bm * K;
    const ushort* Bbase = B + (size_t)bn * K;

    f32x4 acc[4][4];
#pragma unroll
    for (int m = 0; m < 4; ++m)
#pragma unroll
        for (int n = 0; n < 4; ++n) {
            f32x4 z = {0.f, 0.f, 0.f, 0.f};
            acc[m][n] = z;
        }

#define G128_STAGE(bb, k0) do {                                            \
        ushort* bufA_ = g1s + (bb) * 8192;                                 \
        ushort* bufB_ = bufA_ + 4096;                                      \
        _Pragma("unroll")                                                  \
        for (int j_ = 0; j_ < 2; ++j_) {                                   \
            GLL(Abase + soff[j_] + (k0), bufA_ + (j_ * 256 + wv * 64) * 8);\
            GLL(Bbase + soff[j_] + (k0), bufB_ + (j_ * 256 + wv * 64) * 8);\
        }                                                                  \
    } while (0)

    const int T = K >> 5;
    G128_STAGE(0, 0);
    G128_STAGE(1, 32);
    int bb = 0;
    for (int t = 0; t < T; ++t) {
        if (t + 1 < T) {
            asm volatile("s_waitcnt vmcnt(4)" ::: "memory");
        } else {
            asm volatile("s_waitcnt vmcnt(0)" ::: "memory");
        }
        __builtin_amdgcn_s_barrier();
        if (t + 2 < T) G128_STAGE((bb >= 1) ? (bb - 1) : (bb + 2), (t + 2) * 32);
        const ushort* LA = g1s + bb * 8192;
        const ushort* LB = LA + 4096;
        __builtin_amdgcn_s_setprio(1);
        {
            bf16x8 afv[4], bfv[4];
#pragma unroll
            for (int mf = 0; mf < 4; ++mf)
                afv[mf] = *(const bf16x8*)&LA[((wm * 4 + mf) * 64 + ln) * 8];
#pragma unroll
            for (int nf = 0; nf < 4; ++nf)
                bfv[nf] = *(const bf16x8*)&LB[((wn * 4 + nf) * 64 + ln) * 8];
#pragma unroll
            for (int mf = 0; mf < 4; ++mf)
#pragma unroll
                for (int nf = 0; nf < 4; ++nf)
                    acc[mf][nf] = __builtin_amdgcn_mfma_f32_16x16x32_bf16(
                        afv[mf], bfv[nf], acc[mf][nf], 0, 0, 0);
        }
        __builtin_amdgcn_s_setprio(0);
        bb = (bb == 2) ? 0 : bb + 1;
    }
#undef G128_STAGE

#pragma unroll
    for (int mf = 0; mf < 4; ++mf) {
        const int row0 = bm + wm * 64 + mf * 16 + lkg * 4;
#pragma unroll
        for (int nf = 0; nf < 4; ++nf) {
            float* cp = C + (size_t)row0 * N + bn + wn * 64 + nf * 16 + lrow;
#pragma unroll
            for (int j = 0; j < 4; ++j) cp[(size_t)j * N] = acc[mf][nf][j];
        }
    }
}

// ================= causal depthwise conv1d (K=4) + SiLU =====================
__global__ __launch_bounds__(256) void conv_silu_kernel(
    const float* __restrict__ pre, const float* __restrict__ cw, float* __restrict__ out)
{
    int idx = blockIdx.x * 256 + threadIdx.x;
    const int NC4 = CONV_DIM / 4;
    int s = idx / NC4;
    int c = (idx % NC4) * 4;
    float w[4][4];
#pragma unroll
    for (int j = 0; j < 4; ++j) {
        float4 wj = *(const float4*)(cw + (size_t)(c + j) * 4);
        w[j][0] = wj.x; w[j][1] = wj.y; w[j][2] = wj.z; w[j][3] = wj.w;
    }
    float acc[4] = {0.f, 0.f, 0.f, 0.f};
#pragma unroll
    for (int t = 0; t < 4; ++t) {
        int ss = s - 3 + t;
        if (ss >= 0) {
            float4 x = *(const float4*)(pre + (size_t)ss * CONV_DIM + c);
            acc[0] = fmaf(x.x, w[0][t], acc[0]);
            acc[1] = fmaf(x.y, w[1][t], acc[1]);
            acc[2] = fmaf(x.z, w[2][t], acc[2]);
            acc[3] = fmaf(x.w, w[3][t], acc[3]);
        }
    }
    float4 o = make_float4(silu_f(acc[0]), silu_f(acc[1]), silu_f(acc[2]), silu_f(acc[3]));
    *(float4*)(out + (size_t)s * CONV_DIM + c) = o;
}

// ====== g = -exp(A_log)*softplus(a+dt_bias), beta = sigmoid(b) ==============
// ab buffer layout: [S][128], a at cols 0..31, b at cols 32..63
__global__ __launch_bounds__(256) void gb_kernel(
    const float* __restrict__ ab, const float* __restrict__ dt_bias,
    const float* __restrict__ A_log, float* __restrict__ g, float* __restrict__ beta)
{
    int idx = blockIdx.x * 256 + threadIdx.x;
    int s = idx >> 5, h = idx & 31;
    float av = ab[(size_t)s * 128 + h] + dt_bias[h];
    float sp = (av > 20.f) ? av : log1pf(__expf(av));
    g[idx] = -__expf(A_log[h]) * sp;
    beta[idx] = sigmoid_f(ab[(size_t)s * 128 + 32 + h]);
}

// ===== l2norm q,k: q -> bf16 (qnb), k -> f32 (kn) ===========================
__global__ __launch_bounds__(256) void l2norm_kernel(
    const float* __restrict__ mixed, ushort* __restrict__ qnb, float* __restrict__ kn)
{
    int gw = (blockIdx.x * 256 + threadIdx.x) >> 6;
    int lane = threadIdx.x & 63;
    int isk = gw >= S_LEN * NKH;
    int r = gw - isk * S_LEN * NKH;
    int s = r / NKH, kh = r % NKH;
    const float* src = mixed + (size_t)s * CONV_DIM + isk * KEY_DIM + kh * DKD;
    float2 x = *(const float2*)(src + lane * 2);
    float ss = x.x * x.x + x.y * x.y;
#pragma unroll
    for (int m = 1; m < 64; m <<= 1) ss += __shfl_xor(ss, m, 64);
    float scale = rsqrtf(ss + 1e-6f);
    if (!isk) {
        scale *= 0.08838834764831843f;   // DK^-0.5
        union { ushort u[2]; uint v; } p;
        p.u[0] = f2bf(x.x * scale); p.u[1] = f2bf(x.y * scale);
        *(uint*)(qnb + ((size_t)(s * NKH + kh)) * DKD + lane * 2) = p.v;
    } else {
        float* dst = kn + ((size_t)(s * NKH + kh)) * DKD + lane * 2;
        *(float2*)dst = make_float2(x.x * scale, x.y * scale);
    }
}

// ================= Phase A: per (head, chunk) intra-chunk work ==============
// blocked WY solve: off-diagonal via MFMA, 16x16 diagonal solves scalar fp32.
__global__ __launch_bounds__(256) void phaseA_kernel(
    const ushort* __restrict__ qnb, const float* __restrict__ kn,
    const float* __restrict__ mixed, const float* __restrict__ gbuf,
    const float* __restrict__ betabuf,
    float* __restrict__ u, ushort* __restrict__ kcd,
    ushort* __restrict__ scores, float* __restrict__ gcs_out,
    ushort* __restrict__ knT)
{
    extern __shared__ char pasm[];
    ushort* kb    = (ushort*)(pasm);            // 16KB frag [m4][ks4][64][8]
    ushort* qb    = (ushort*)(pasm + 16384);    // 16KB frag; later P f32[16][256]
    ushort* Xb    = (ushort*)(pasm + 32768);    // 32KB [t2(2)][ct(16)][64][8]
    float*  Adiag = (float*)(pasm + 65536);     // 4KB [4][16][16] fp32 diag blocks
    ushort* Ab    = (ushort*)(pasm + 69632);    // 4KB: 4 frags 16x32 bf16 (K=32 padded)
    float*  gcs_s = (float*)(pasm + 73728);     // 64 f
    float*  bet_s = (float*)(pasm + 73984);     // 64 f
    float*  scK_s = (float*)(pasm + 74240);     // 64 f : beta*exp(gcs)
    float*  Pf    = (float*)qb;                 // alias (qb dead after QK^T MFMA)

    const int n = blockIdx.x, h = blockIdx.y, kh = h >> 1;
    const int tid = threadIdx.x;
    const int s0 = n * CCH;
    const int wv = tid >> 6, ln = tid & 63;
    const int lrow = ln & 15, lkg = ln >> 4;

    float xr[64];
    if (tid < 128) {
        const float* vp = mixed + (size_t)s0 * CONV_DIM + 2 * KEY_DIM + h * DVD + tid;
#pragma unroll
        for (int i = 0; i < 64; ++i) xr[i] = vp[(size_t)i * CONV_DIM];
    } else {
        const float* kp = kn + ((size_t)s0 * NKH + kh) * DKD + (tid - 128);
#pragma unroll
        for (int i = 0; i < 64; ++i) xr[i] = kp[(size_t)i * (NKH * DKD)];
    }

    {
        uint4 z = {0, 0, 0, 0};
#pragma unroll
        for (int i = 0; i < 8; ++i)
            *(uint4*)&Xb[(i * 256 + tid) * 8] = z;
        *(uint4*)&Ab[tid * 8] = z;
    }

    if (tid < 64) {
        float gv = gbuf[(size_t)(s0 + tid) * NVH + h];
#pragma unroll
        for (int off = 1; off < 64; off <<= 1) {
            float pv = __shfl_up(gv, off, 64);
            if (tid >= off) gv += pv;
        }
        float bv = betabuf[(size_t)(s0 + tid) * NVH + h];
        gcs_s[tid] = gv;
        bet_s[tid] = bv;
        scK_s[tid] = bv * __expf(gv);
        gcs_out[(size_t)h * S_LEN + s0 + tid] = gv;
    }

    {
        const int r = tid >> 2, c0 = (tid & 3) * 32;
        const int mbase = (((r >> 4) * 4 + (tid & 3)) * 64 + (r & 15)) * 8;
        const float* ksrc = kn + ((size_t)(s0 + r) * NKH + kh) * DKD + c0;
#pragma unroll
        for (int j0 = 0; j0 < 4; ++j0) {
            float4 v0 = *(const float4*)(ksrc + j0 * 8);
            float4 v1 = *(const float4*)(ksrc + j0 * 8 + 4);
            union { ushort us[8]; uint4 v; } p;
            p.us[0] = f2bf(v0.x); p.us[1] = f2bf(v0.y); p.us[2] = f2bf(v0.z); p.us[3] = f2bf(v0.w);
            p.us[4] = f2bf(v1.x); p.us[5] = f2bf(v1.y); p.us[6] = f2bf(v1.z); p.us[7] = f2bf(v1.w);
            *(uint4*)&kb[mbase + (j0 << 7)] = p.v;
        }
        const ushort* qsrc = qnb + ((size_t)(s0 + r) * NKH + kh) * DKD + c0;
#pragma unroll
        for (int j0 = 0; j0 < 4; ++j0) {
            uint4 v = *(const uint4*)(qsrc + j0 * 8);
            *(uint4*)&qb[mbase + (j0 << 7)] = v;
        }
    }
    __syncthreads();    // B1

    f32x4 accA[4], accQ[4];
#pragma unroll
    for (int j = 0; j < 4; ++j) {
        f32x4 z = {0.f, 0.f, 0.f, 0.f};
        accA[j] = z; accQ[j] = z;
    }
#pragma unroll
    for (int ks = 0; ks < 4; ++ks) {
        bf16x8 a_k = *(const bf16x8*)&kb[((wv * 4 + ks) * 64 + ln) * 8];
        bf16x8 a_q = *(const bf16x8*)&qb[((wv * 4 + ks) * 64 + ln) * 8];
#pragma unroll
        for (int j = 0; j < 4; ++j) {
            bf16x8 b_k = *(const bf16x8*)&kb[((j * 4 + ks) * 64 + ln) * 8];
            accA[j] = __builtin_amdgcn_mfma_f32_16x16x32_bf16(a_k, b_k, accA[j], 0, 0, 0);
            accQ[j] = __builtin_amdgcn_mfma_f32_16x16x32_bf16(a_q, b_k, accQ[j], 0, 0, 0);
        }
    }
    {
        ushort* scp = scores + (size_t)(h * NCHK + n) * (CCH * CCH);
#pragma unroll
        for (int j = 0; j < 4; ++j) {
            const int c = j * 16 + lrow;
            const float gc = gcs_s[c];
#pragma unroll
            for (int jj = 0; jj < 4; ++jj) {
                const int i = wv * 16 + lkg * 4 + jj;
                const float e = __expf(gcs_s[i] - gc);
                float sv = (i >= c) ? (accQ[j][jj] * e) : 0.f;
                scp[i * CCH + c] = f2bf(sv);
                float aval = (i > c) ? (-bet_s[i] * accA[j][jj] * e) : 0.f;
                if (j == wv) {
                    Adiag[wv * 256 + (i & 15) * 16 + lrow] = aval;
                } else if (j < wv) {
                    const int f = (wv == 1) ? 0 : ((wv == 2) ? 1 : (2 + (j >> 1)));
                    const int lk = ((j & 1) << 4) | lrow;
                    const int lane2 = (i & 15) | ((lk >> 3) << 4);
                    Ab[(f * 64 + lane2) * 8 + (lk & 7)] = f2bf(aval);
                }
            }
        }
    }
    if (tid < 128) {
#pragma unroll
        for (int i4 = 0; i4 < 16; ++i4) {
            float4 b4 = *(const float4*)&bet_s[i4 * 4];
            xr[i4 * 4 + 0] *= b4.x; xr[i4 * 4 + 1] *= b4.y;
            xr[i4 * 4 + 2] *= b4.z; xr[i4 * 4 + 3] *= b4.w;
        }
    } else {
#pragma unroll
        for (int i4 = 0; i4 < 16; ++i4) {
            float4 b4 = *(const float4*)&scK_s[i4 * 4];
            xr[i4 * 4 + 0] *= b4.x; xr[i4 * 4 + 1] *= b4.y;
            xr[i4 * 4 + 2] *= b4.z; xr[i4 * 4 + 3] *= b4.w;
        }
    }
    __syncthreads();    // B2

    const int ct = tid >> 4, lct = tid & 15;
#pragma unroll
    for (int s = 0; s < 4; ++s) {
        float y[16];
        float pr[16];
        if (s > 0) {
#pragma unroll
            for (int r = 0; r < 16; ++r) pr[r] = Pf[r * 256 + tid];
        } else {
#pragma unroll
            for (int r = 0; r < 16; ++r) pr[r] = 0.f;
        }
#pragma unroll
        for (int r = 0; r < 16; ++r) {
            float acc = xr[s * 16 + r] + pr[r];
#pragma unroll
            for (int k4 = 0; k4 < 16; k4 += 4) {
                if (k4 < r) {
                    float4 a4 = *(const float4*)&Adiag[s * 256 + r * 16 + k4];
                    if (k4 + 0 < r) acc = fmaf(a4.x, y[k4 + 0], acc);
                    if (k4 + 1 < r) acc = fmaf(a4.y, y[k4 + 1], acc);
                    if (k4 + 2 < r) acc = fmaf(a4.z, y[k4 + 2], acc);
                    if (k4 + 3 < r) acc = fmaf(a4.w, y[k4 + 3], acc);
                }
            }
            y[r] = acc;
        }
        if (tid < 128) {
            float* up = u + (size_t)(h * NCHK + n) * (CCH * DVD) + (s * 16) * DVD + tid;
#pragma unroll
            for (int r = 0; r < 16; ++r) up[r * DVD] = y[r];
        } else {
            ushort* kp = kcd + (size_t)(h * NCHK + n) * (CCH * DKD) + (s * 16) * DKD + (tid - 128);
#pragma unroll
            for (int r = 0; r < 16; ++r) kp[r * DKD] = f2bf(y[r]);
        }
        if (s < 3) {
#pragma unroll
            for (int half = 0; half < 2; ++half) {
                union { ushort us[8]; uint4 v; } p;
#pragma unroll
                for (int e = 0; e < 8; ++e) p.us[e] = f2bf(y[half * 8 + e]);
                const int kg = (s & 1) * 2 + half;
                *(uint4*)&Xb[(((s >> 1) * 16 + ct) * 64 + (kg * 16 + lct)) * 8] = p.v;
            }
            __syncthreads();
            const int snx = s + 1;
            const int nT2 = (snx + 1) >> 1;
            f32x4 accP[4];
#pragma unroll
            for (int ctl = 0; ctl < 4; ++ctl) {
                f32x4 z = {0.f, 0.f, 0.f, 0.f};
                accP[ctl] = z;
            }
#pragma unroll
            for (int t2 = 0; t2 < 2; ++t2) {
                if (t2 < nT2) {
                    const int f = (snx == 1) ? 0 : ((snx == 2) ? 1 : (2 + t2));
                    bf16x8 a = *(const bf16x8*)&Ab[(f * 64 + ln) * 8];
#pragma unroll
                    for (int ctl = 0; ctl < 4; ++ctl) {
                        bf16x8 b = *(const bf16x8*)&Xb[((t2 * 16 + wv * 4 + ctl) * 64 + ln) * 8];
                        accP[ctl] = __builtin_amdgcn_mfma_f32_16x16x32_bf16(a, b, accP[ctl], 0, 0, 0);
                    }
                }
            }
#pragma unroll
            for (int ctl = 0; ctl < 4; ++ctl)
#pragma unroll
                for (int jj = 0; jj < 4; ++jj)
                    Pf[(lkg * 4 + jj) * 256 + wv * 64 + ctl * 16 + lrow] = accP[ctl][jj];
            __syncthreads();
        }
    }

    if (!(h & 1)) {
        const int dk = tid >> 1, ch = (tid & 1) * 32;
        ushort* dst = knT + ((size_t)(kh * NCHK + n) * DKD + dk) * CCH + ch;
        const int kpart = ((dk >> 5) * 64) * 8 + (((dk >> 3) & 3) << 4) * 8 + (dk & 7);
#pragma unroll
        for (int j0 = 0; j0 < 32; j0 += 8) {
            union { ushort us[8]; uint4 v; } p;
#pragma unroll
            for (int j = 0; j < 8; ++j) {
                const int row = ch + j0 + j;
                p.us[j] = kb[((row >> 4) * 4 * 64 + (row & 15)) * 8 + kpart];
            }
            *(uint4*)(dst + j0) = p.v;
        }
    }
}

// ================= Phase B: inter-chunk state scan (MFMA) ===================
__global__ __launch_bounds__(256) void phaseB_kernel(
    const ushort* __restrict__ qnb, const ushort* __restrict__ knT,
    const float* __restrict__ u, const ushort* __restrict__ kcd,
    const ushort* __restrict__ sc, const float* __restrict__ gcs,
    float* __restrict__ obuf)
{
    extern __shared__ ushort smu[];
    ushort* qorg  = smu;             // 8192  [m4][ks4][64][8]
    ushort* kcorg = smu + 8192;      // 8192
    ushort* scorg = smu + 16384;     // 4096
    ushort* kTorg = smu + 20480;     // 8192
    ushort* storg = smu + 28672;     // 2048  S^T bf16
    ushort* vnorg = smu + 30720;     // 1024
    ushort* vnsorg= smu + 31744;     // 1024
    float* gcs_s  = (float*)(smu + 32768);   // 64

    const int h = blockIdx.x;
    const int dvb = blockIdx.y;
    const int d0 = dvb * 16;
    const int kh = h >> 1;
    const int tid = threadIdx.x;
    const int wv = tid >> 6, ln = tid & 63;
    const int lrow = ln & 15, lkg = ln >> 4;

    for (int i = tid; i < 2048 / 8; i += 256) {
        uint4 z = {0, 0, 0, 0};
        *(uint4*)&storg[i * 8] = z;
    }

    const int q_lane  = lrow * (NKH * DKD) + kh * DKD + wv * 32 + lkg * 8;
    const int kc_lane = lrow * DKD + wv * 32 + lkg * 8;
    const int st_lane = ((tid >> 7) * 16 + lrow) * 64 + ((tid >> 6) & 1) * 32 + lkg * 8;
    const int dst_e   = wv * 512;

    f32x4 accS0 = {0.f, 0.f, 0.f, 0.f}, accS1 = {0.f, 0.f, 0.f, 0.f};

    for (int n = 0; n < NCHK; ++n) {
        const int s0 = n * CCH;
        const ushort* qsrc  = qnb + (size_t)s0 * (NKH * DKD);
        const ushort* kcsrc = kcd + (size_t)(h * NCHK + n) * (CCH * DKD);
        const ushort* scsrc = sc  + (size_t)(h * NCHK + n) * (CCH * CCH);
        const ushort* kTsrc = knT + (size_t)(kh * NCHK + n) * (DKD * CCH);
#pragma unroll
        for (int r = 0; r < 4; ++r) {
            GLL(qsrc + q_lane + r * 32768, &qorg[r * 2048 + dst_e]);
            GLL(kcsrc + kc_lane + r * 2048, &kcorg[r * 2048 + dst_e]);
            GLL(kTsrc + st_lane + r * 2048, &kTorg[r * 2048 + dst_e]);
        }
#pragma unroll
        for (int r = 0; r < 2; ++r)
            GLL(scsrc + st_lane + r * 2048, &scorg[r * 2048 + dst_e]);
        if (tid < 64) gcs_s[tid] = gcs[(size_t)h * S_LEN + s0 + tid];
        __syncthreads();                 // B1

        f32x4 accv = {0.f, 0.f, 0.f, 0.f};
        f32x4 acco = {0.f, 0.f, 0.f, 0.f};
#pragma unroll
        for (int ks = 0; ks < 4; ++ks) {
            bf16x8 b_st = *(const bf16x8*)&storg[(ks * 64 + ln) * 8];
            bf16x8 a_kc = *(const bf16x8*)&kcorg[((wv * 4 + ks) * 64 + ln) * 8];
            bf16x8 a_q  = *(const bf16x8*)&qorg[((wv * 4 + ks) * 64 + ln) * 8];
            accv = __builtin_amdgcn_mfma_f32_16x16x32_bf16(a_kc, b_st, accv, 0, 0, 0);
            acco = __builtin_amdgcn_mfma_f32_16x16x32_bf16(a_q, b_st, acco, 0, 0, 0);
        }
        const float* up = u + (size_t)(h * NCHK + n) * (CCH * DVD)
                            + (wv * 16 + lkg * 4) * DVD + d0 + lrow;
        float u0 = up[0], u1 = up[DVD], u2 = up[2 * DVD], u3 = up[3 * DVD];
        const float gl = gcs_s[63];
        float vn0 = u0 - accv[0], vn1 = u1 - accv[1];
        float vn2 = u2 - accv[2], vn3 = u3 - accv[3];
        {
            const int row = wv * 16 + lkg * 4;
            float g0 = gcs_s[row], g1 = gcs_s[row + 1], g2 = gcs_s[row + 2], g3 = gcs_s[row + 3];
            acco[0] *= __expf(g0); acco[1] *= __expf(g1);
            acco[2] *= __expf(g2); acco[3] *= __expf(g3);
            const int eb = ((wv >> 1) * 64 + ((wv & 1) * 2 + (lkg >> 1)) * 16 + lrow) * 8
                         + (lkg & 1) * 4;
            union { ushort u2a[4]; uint2 v; } pa, pb;
            pa.u2a[0] = f2bf(vn0); pa.u2a[1] = f2bf(vn1);
            pa.u2a[2] = f2bf(vn2); pa.u2a[3] = f2bf(vn3);
            pb.u2a[0] = f2bf(vn0 * __expf(gl - g0)); pb.u2a[1] = f2bf(vn1 * __expf(gl - g1));
            pb.u2a[2] = f2bf(vn2 * __expf(gl - g2)); pb.u2a[3] = f2bf(vn3 * __expf(gl - g3));
            *(uint2*)&vnorg[eb] = pa.v;
            *(uint2*)&vnsorg[eb] = pb.v;
        }
        __syncthreads();                 // B2

#pragma unroll
        for (int ks = 0; ks < 2; ++ks) {
            bf16x8 a_sc = *(const bf16x8*)&scorg[((wv * 2 + ks) * 64 + ln) * 8];
            bf16x8 b_vn = *(const bf16x8*)&vnorg[(ks * 64 + ln) * 8];
            acco = __builtin_amdgcn_mfma_f32_16x16x32_bf16(a_sc, b_vn, acco, 0, 0, 0);
        }
        float* op = obuf + (size_t)(s0 + wv * 16 + lkg * 4) * VAL_DIM + h * DVD + d0 + lrow;
        op[0] = acco[0]; op[VAL_DIM] = acco[1];
        op[2 * VAL_DIM] = acco[2]; op[3 * VAL_DIM] = acco[3];

        const float egl = __expf(gl);
        accS0 *= egl; accS1 *= egl;
#pragma unroll
        for (int ks = 0; ks < 2; ++ks) {
            bf16x8 a_vs = *(const bf16x8*)&vnsorg[(ks * 64 + ln) * 8];
            bf16x8 b_k0 = *(const bf16x8*)&kTorg[(((wv * 2 + 0) * 2 + ks) * 64 + ln) * 8];
            bf16x8 b_k1 = *(const bf16x8*)&kTorg[(((wv * 2 + 1) * 2 + ks) * 64 + ln) * 8];
            accS0 = __builtin_amdgcn_mfma_f32_16x16x32_bf16(a_vs, b_k0, accS0, 0, 0, 0);
            accS1 = __builtin_amdgcn_mfma_f32_16x16x32_bf16(a_vs, b_k1, accS1, 0, 0, 0);
        }
#pragma unroll
        for (int j = 0; j < 4; ++j) {
            storg[(wv * 64 + ((lrow >> 3)) * 16 + lkg * 4 + j) * 8 + (lrow & 7)] = f2bf(accS0[j]);
            storg[(wv * 64 + (2 + (lrow >> 3)) * 16 + lkg * 4 + j) * 8 + (lrow & 7)] = f2bf(accS1[j]);
        }
        __syncthreads();                 // B3
    }
}

// ================= RMSNorm * norm_w * silu(z) -> bf16 =======================
__global__ __launch_bounds__(256) void norm_kernel(
    const float* __restrict__ obuf, const float* __restrict__ z,
    const float* __restrict__ nw, ushort* __restrict__ hbuf)
{
    int row = (blockIdx.x * 256 + threadIdx.x) >> 6;
    int lane = threadIdx.x & 63;
    float2 x = *(const float2*)(obuf + (size_t)row * DVD + lane * 2);
    float ss = x.x * x.x + x.y * x.y;
#pragma unroll
    for (int m = 1; m < 64; m <<= 1) ss += __shfl_xor(ss, m, 64);
    float scale = rsqrtf(ss * (1.f / DVD) + 1e-6f);
    float2 zz = *(const float2*)(z + (size_t)row * DVD + lane * 2);
    float2 w2 = *(const float2*)(nw + lane * 2);
    float h0 = x.x * scale * w2.x * silu_f(zz.x);
    float h1 = x.y * scale * w2.y * silu_f(zz.y);
    union { ushort u[2]; uint v; } r;
    r.u[0] = f2bf(h0); r.u[1] = f2bf(h1);
    *(uint*)(hbuf + (size_t)row * DVD + lane * 2) = r.v;
}

// ============================================================================
extern "C" void kernel_launch(void* const* d_in, const int* in_sizes, int n_in,
                              void* d_out, int out_size, void* d_ws, size_t ws_size,
                              hipStream_t stream)
{
    (void)in_sizes; (void)n_in; (void)out_size; (void)ws_size;
    const float* x      = (const float*)d_in[0];
    const float* W_qkv  = (const float*)d_in[1];
    const float* W_z    = (const float*)d_in[2];
    const float* W_a    = (const float*)d_in[3];
    const float* W_b    = (const float*)d_in[4];
    const float* conv_w = (const float*)d_in[5];
    const float* dt_b   = (const float*)d_in[6];
    const float* A_log  = (const float*)d_in[7];
    const float* norm_w = (const float*)d_in[8];
    const float* W_out  = (const float*)d_in[9];
    float* out = (float*)d_out;

    // ---- workspace layout (bytes), overlaid by liveness; total ~202.1 MB ---
    char* ws = (char*)d_ws;
    // region A @0 (67,108,864): mixed_pre -> {u f32, kcd bf16, knT bf16}
    float*  mixed_pre = (float*)(ws);
    float*  u_buf     = (float*)(ws);                   // 33,554,432
    ushort* kcd_buf   = (ushort*)(ws + 33554432);       // 16,777,216
    ushort* knT_buf   = (ushort*)(ws + 50331648);       //  8,388,608
    // region B @67,108,864 (67,108,864): {wqz 50.3MB, xb 8.4MB} -> mixed ->
    //   {obuf 33.6, hbuf 16.8, wob 16.8}
    ushort* wqz       = (ushort*)(ws + 67108864);       // 50,331,648 (12288x2048)
    ushort* xb        = (ushort*)(ws + 117440512);      //  8,388,608
    float*  mixed     = (float*)(ws + 67108864);
    float*  obuf      = (float*)(ws + 67108864);
    ushort* hbuf      = (ushort*)(ws + 100663296);
    ushort* wob       = (ushort*)(ws + 117440512);
    // fixed regions
    float*  z_buf     = (float*)(ws + 134217728);       // 33,554,432
    ushort* sc_buf    = (ushort*)(ws + 167772160);      //  8,388,608 (step>=6)
    ushort* wabb      = (ushort*)(ws + 167772160);      //    524,288 (steps 1-3)
    float*  ab_buf    = (float*)(ws + 168296448);       //  1,048,576 (steps 3-4)
    ushort* qnb       = (ushort*)(ws + 176160768);      //  8,388,608
    float*  kn        = (float*)(ws + 184549376);       // 16,777,216
    float*  g_buf     = (float*)(ws + 201326592);       //    262,144
    float*  bet_buf   = (float*)(ws + 201588736);       //    262,144
    float*  gcs_buf   = (float*)(ws + 201850880);       //    262,144

    hipFuncSetAttribute((const void*)phaseA_kernel,
                        hipFuncAttributeMaxDynamicSharedMemorySize, PA_LDS_BYTES);
    hipFuncSetAttribute((const void*)phaseB_kernel,
                        hipFuncAttributeMaxDynamicSharedMemorySize, PB_LDS_BYTES);
    hipFuncSetAttribute((const void*)gemm256_kernel,
                        hipFuncAttributeMaxDynamicSharedMemorySize, G256_LDS_BYTES);
    hipFuncSetAttribute((const void*)gemm128_kernel,
                        hipFuncAttributeMaxDynamicSharedMemorySize, G128_LDS_BYTES);

    dim3 blk(256);
    // 1) casts to bf16 (W_qkv and W_z fused contiguously into wqz)
    cast_kernel<<<(S_LEN * HIDDIM / 8) / 256, blk, 0, stream>>>(x, xb, S_LEN * HIDDIM / 8);
    cast_kernel<<<(CONV_DIM * HIDDIM / 8) / 256, blk, 0, stream>>>(W_qkv, wqz, CONV_DIM * HIDDIM / 8);
    cast_kernel<<<(VAL_DIM * HIDDIM / 8) / 256, blk, 0, stream>>>(W_z, wqz + (size_t)CONV_DIM * HIDDIM, VAL_DIM * HIDDIM / 8);
    cast_ab_kernel<<<(128 * HIDDIM / 8) / 256, blk, 0, stream>>>(W_a, W_b, wabb);
    // 2) fused qkv+z projection (128x256 triple-buffered BK=32, 768 blocks)
    gemm256_kernel<<<dim3((CONV_DIM + VAL_DIM) / 256, S_LEN / 128), dim3(512), G256_LDS_BYTES, stream>>>(
        xb, wqz, mixed_pre, z_buf, HIDDIM, CONV_DIM, CONV_DIM, VAL_DIM);
    // 3) a/b projection
    gemm128_kernel<<<dim3(1, S_LEN / 128), blk, G128_LDS_BYTES, stream>>>(
        xb, wabb, ab_buf, 128, HIDDIM);
    // 4) conv + silu (fp32)
    conv_silu_kernel<<<(S_LEN * CONV_DIM / 4) / 256, blk, 0, stream>>>(mixed_pre, conv_w, mixed);
    // 5) gates
    gb_kernel<<<(S_LEN * NVH) / 256, blk, 0, stream>>>(ab_buf, dt_b, A_log, g_buf, bet_buf);
    // 6) l2norm q,k
    l2norm_kernel<<<(2 * S_LEN * NKH * 64) / 256, blk, 0, stream>>>(mixed, qnb, kn);
    // 7) phase A (intra-chunk, blocked-MFMA solve)
    phaseA_kernel<<<dim3(NCHK, NVH), blk, PA_LDS_BYTES, stream>>>(
        qnb, kn, mixed, g_buf, bet_buf, u_buf, kcd_buf, sc_buf, gcs_buf, knT_buf);
    // 8) phase B (inter-chunk scan, MFMA)
    phaseB_kernel<<<dim3(NVH, 8), blk, PB_LDS_BYTES, stream>>>(
        qnb, knT_buf, u_buf, kcd_buf, sc_buf, gcs_buf, obuf);
    // 9) W_out cast (mixed region now dead) + gated RMSNorm -> bf16
    cast_kernel<<<(HIDDIM * VAL_DIM / 8) / 256, blk, 0, stream>>>(W_out, wob, HIDDIM * VAL_DIM / 8);
    norm_kernel<<<(S_LEN * NVH * 64) / 256, blk, 0, stream>>>(obuf, z_buf, norm_w, hbuf);
    // 10) output projection (128^2 triple-buffered BK=32, 256 blocks)
    gemm128_kernel<<<dim3(HIDDIM / 128, S_LEN / 128), blk, G128_LDS_BYTES, stream>>>(
        hbuf, wob, out, HIDDIM, VAL_DIM);
}

// Round 12
// 478.593 us; speedup vs baseline: 1.2454x; 1.0275x over previous
//
#include <hip/hip_runtime.h>
#include <hip/hip_bf16.h>
#include <math.h>

// ---- problem constants ----
#define S_LEN   2048
#define HIDDIM  2048
#define NKH     16
#define NVH     32
#define DKD     128
#define DVD     128
#define CCH     64          // chunk
#define NCHK    32          // S/chunk
#define KEY_DIM 2048
#define VAL_DIM 4096
#define CONV_DIM 8192

#define PA_LDS_BYTES (16384 + 16384 + 32768 + 4096 + 4096 + 256 + 256 + 256)
#define PB_LDS_BYTES ((8192+8192+4096+8192+2048+1024+1024)*2 + 64*4)
// gemm256: 3 bufs x (A 128x32 + B 256x32) bf16 = 3 x 12288 ushorts = 72 KB
#define G256_LDS_BYTES (3 * 12288 * 2)
// gemm128: 3 bufs x (A 128x32 + B 128x32) = 3 x 8192 ushorts = 48 KB
#define G128_LDS_BYTES (3 * 8192 * 2)

typedef __bf16 bf16x8 __attribute__((ext_vector_type(8)));
typedef float f32x4 __attribute__((ext_vector_type(4)));

__device__ __forceinline__ float sigmoid_f(float x) { return 1.f / (1.f + __expf(-x)); }
__device__ __forceinline__ float silu_f(float x) { return x * sigmoid_f(x); }
__device__ __forceinline__ ushort f2bf(float f) {
    unsigned u = __float_as_uint(f);
    u += 0x7fffu + ((u >> 16) & 1u);          // RNE (inputs finite)
    return (ushort)(u >> 16);
}
__device__ __forceinline__ float bf2f(ushort u) {
    return __uint_as_float((unsigned)u << 16);
}

#define GLL(srcp, dstp) __builtin_amdgcn_global_load_lds( \
    (const __attribute__((address_space(1))) void*)(srcp), \
    (__attribute__((address_space(3))) void*)(dstp), 16, 0, 0)

// ================= fp32 -> bf16 cast (8 elems/thread) =======================
__global__ __launch_bounds__(256) void cast_kernel(
    const float* __restrict__ in, ushort* __restrict__ out, int n8)
{
    int t = blockIdx.x * 256 + threadIdx.x;
    if (t >= n8) return;
    float4 v0 = *(const float4*)(in + (size_t)t * 8);
    float4 v1 = *(const float4*)(in + (size_t)t * 8 + 4);
    union { ushort u[8]; uint4 v; } r;
    r.u[0] = f2bf(v0.x); r.u[1] = f2bf(v0.y); r.u[2] = f2bf(v0.z); r.u[3] = f2bf(v0.w);
    r.u[4] = f2bf(v1.x); r.u[5] = f2bf(v1.y); r.u[6] = f2bf(v1.z); r.u[7] = f2bf(v1.w);
    *(uint4*)(out + (size_t)t * 8) = r.v;
}

// ====== W_a,W_b -> one padded bf16 weight [128,2048] (rows 64..127 zero) ====
__global__ __launch_bounds__(256) void cast_ab_kernel(
    const float* __restrict__ Wa, const float* __restrict__ Wb, ushort* __restrict__ out)
{
    int t = blockIdx.x * 256 + threadIdx.x;          // 128*2048/8 = 32768 threads
    int row = t >> 8;
    int c8 = (t & 255) * 8;
    union { ushort u[8]; uint4 v; } r;
    if (row < 64) {
        const float* src = (row < 32) ? (Wa + (size_t)row * HIDDIM + c8)
                                      : (Wb + (size_t)(row - 32) * HIDDIM + c8);
        float4 v0 = *(const float4*)(src);
        float4 v1 = *(const float4*)(src + 4);
        r.u[0] = f2bf(v0.x); r.u[1] = f2bf(v0.y); r.u[2] = f2bf(v0.z); r.u[3] = f2bf(v0.w);
        r.u[4] = f2bf(v1.x); r.u[5] = f2bf(v1.y); r.u[6] = f2bf(v1.z); r.u[7] = f2bf(v1.w);
    } else {
        r.u[0] = r.u[1] = r.u[2] = r.u[3] = r.u[4] = r.u[5] = r.u[6] = r.u[7] = 0;
    }
    *(uint4*)(out + (size_t)t * 8) = r.v;
}

// ==== 128x256 triple-buffered counted-vmcnt bf16 GEMM (BK=32), dual out =====
// C0 f32; C1 f32 or bf16 (c1bf16 flag). Block cols < NSPLIT -> C0 else C1.
__global__ __launch_bounds__(512, 2) void gemm256_kernel(
    const ushort* __restrict__ A, const ushort* __restrict__ B,
    float* __restrict__ C0, void* __restrict__ C1,
    int K, int NSPLIT, int ldc0, int ldc1, int c1bf16)
{
    extern __shared__ ushort g2s[];          // [3][A 4096 | B 8192] ushorts
    const int tid = threadIdx.x;
    const int wv = tid >> 6, ln = tid & 63;
    const int wm = wv >> 2, wn = wv & 3;
    const int lrow = ln & 15, lkg = ln >> 4;
    const int bm = blockIdx.y * 128, bn = blockIdx.x * 256;

    int soffA, soffB[2];
    {
        int l = tid & 63;
        soffA = (((tid >> 6) * 16) + (l & 15)) * K + (l >> 4) * 8;
#pragma unroll
        for (int j = 0; j < 2; ++j) {
            int g = tid + j * 512;
            int lg = g & 63;
            soffB[j] = (((g >> 6) * 16) + (lg & 15)) * K + (lg >> 4) * 8;
        }
    }
    const ushort* Abase = A + (size_t)bm * K;
    const ushort* Bbase = B + (size_t)bn * K;

    f32x4 acc[4][4];
#pragma unroll
    for (int m = 0; m < 4; ++m)
#pragma unroll
        for (int n = 0; n < 4; ++n) {
            f32x4 z = {0.f, 0.f, 0.f, 0.f};
            acc[m][n] = z;
        }

#define G256_STAGE(bb, k0) do {                                            \
        ushort* bufA_ = g2s + (bb) * 12288;                                \
        ushort* bufB_ = bufA_ + 4096;                                      \
        GLL(Abase + soffA + (k0), bufA_ + (wv * 64) * 8);                  \
        _Pragma("unroll")                                                  \
        for (int j_ = 0; j_ < 2; ++j_)                                     \
            GLL(Bbase + soffB[j_] + (k0), bufB_ + (j_ * 512 + wv * 64) * 8);\
    } while (0)

    const int T = K >> 5;
    G256_STAGE(0, 0);
    G256_STAGE(1, 32);
    int bb = 0;
    for (int t = 0; t < T; ++t) {
        if (t + 1 < T) {
            asm volatile("s_waitcnt vmcnt(3)" ::: "memory");
        } else {
            asm volatile("s_waitcnt vmcnt(0)" ::: "memory");
        }
        __builtin_amdgcn_s_barrier();
        if (t + 2 < T) G256_STAGE((bb >= 1) ? (bb - 1) : (bb + 2), (t + 2) * 32);
        const ushort* LA = g2s + bb * 12288;
        const ushort* LB = LA + 4096;
        __builtin_amdgcn_s_setprio(1);
        {
            bf16x8 afv[4], bfv[4];
#pragma unroll
            for (int mf = 0; mf < 4; ++mf)
                afv[mf] = *(const bf16x8*)&LA[((wm * 4 + mf) * 64 + ln) * 8];
#pragma unroll
            for (int nf = 0; nf < 4; ++nf)
                bfv[nf] = *(const bf16x8*)&LB[((wn * 4 + nf) * 64 + ln) * 8];
#pragma unroll
            for (int mf = 0; mf < 4; ++mf)
#pragma unroll
                for (int nf = 0; nf < 4; ++nf)
                    acc[mf][nf] = __builtin_amdgcn_mfma_f32_16x16x32_bf16(
                        afv[mf], bfv[nf], acc[mf][nf], 0, 0, 0);
        }
        __builtin_amdgcn_s_setprio(0);
        bb = (bb == 2) ? 0 : bb + 1;
    }
#undef G256_STAGE

    const bool inC1 = (bn >= NSPLIT);
    const int cboff = bn + wn * 64 - (inC1 ? NSPLIT : 0);
    if (!inC1) {
#pragma unroll
        for (int mf = 0; mf < 4; ++mf) {
            const int row0 = bm + wm * 64 + mf * 16 + lkg * 4;
#pragma unroll
            for (int nf = 0; nf < 4; ++nf) {
                float* cp = C0 + (size_t)row0 * ldc0 + cboff + nf * 16 + lrow;
#pragma unroll
                for (int j = 0; j < 4; ++j) cp[(size_t)j * ldc0] = acc[mf][nf][j];
            }
        }
    } else if (!c1bf16) {
        float* C1f = (float*)C1;
#pragma unroll
        for (int mf = 0; mf < 4; ++mf) {
            const int row0 = bm + wm * 64 + mf * 16 + lkg * 4;
#pragma unroll
            for (int nf = 0; nf < 4; ++nf) {
                float* cp = C1f + (size_t)row0 * ldc1 + cboff + nf * 16 + lrow;
#pragma unroll
                for (int j = 0; j < 4; ++j) cp[(size_t)j * ldc1] = acc[mf][nf][j];
            }
        }
    } else {
        ushort* C1b = (ushort*)C1;
#pragma unroll
        for (int mf = 0; mf < 4; ++mf) {
            const int row0 = bm + wm * 64 + mf * 16 + lkg * 4;
#pragma unroll
            for (int nf = 0; nf < 4; ++nf) {
                ushort* cp = C1b + (size_t)row0 * ldc1 + cboff + nf * 16 + lrow;
#pragma unroll
                for (int j = 0; j < 4; ++j) cp[(size_t)j * ldc1] = f2bf(acc[mf][nf][j]);
            }
        }
    }
}

// ======== 128x128 triple-buffered counted-vmcnt bf16 GEMM (BK=32) ===========
__global__ __launch_bounds__(256, 2) void gemm128_kernel(
    const ushort* __restrict__ A, const ushort* __restrict__ B,
    float* __restrict__ C, int N, int K)
{
    extern __shared__ ushort g1s[];          // [3][A 4096 | B 4096] ushorts
    const int tid = threadIdx.x;
    const int wv = tid >> 6, ln = tid & 63;
    const int wm = wv >> 1, wn = wv & 1;
    const int lrow = ln & 15, lkg = ln >> 4;
    const int bm = blockIdx.y * 128, bn = blockIdx.x * 128;

    int soff[2];
#pragma unroll
    for (int j = 0; j < 2; ++j) {
        int g = tid + j * 256;
        int l = g & 63;
        soff[j] = (((g >> 6) * 16) + (l & 15)) * K + (l >> 4) * 8;
    }
    const ushort* Abase = A + (size_t)bm * K;
    const ushort* Bbase = B + (size_t)bn * K;

    f32x4 acc[4][4];
#pragma unroll
    for (int m = 0; m < 4; ++m)
#pragma unroll
        for (int n = 0; n < 4; ++n) {
            f32x4 z = {0.f, 0.f, 0.f, 0.f};
            acc[m][n] = z;
        }

#define G128_STAGE(bb, k0) do {                                            \
        ushort* bufA_ = g1s + (bb) * 8192;                                 \
        ushort* bufB_ = bufA_ + 4096;                                      \
        _Pragma("unroll")                                                  \
        for (int j_ = 0; j_ < 2; ++j_) {                                   \
            GLL(Abase + soff[j_] + (k0), bufA_ + (j_ * 256 + wv * 64) * 8);\
            GLL(Bbase + soff[j_] + (k0), bufB_ + (j_ * 256 + wv * 64) * 8);\
        }                                                                  \
    } while (0)

    const int T = K >> 5;
    G128_STAGE(0, 0);
    G128_STAGE(1, 32);
    int bb = 0;
    for (int t = 0; t < T; ++t) {
        if (t + 1 < T) {
            asm volatile("s_waitcnt vmcnt(4)" ::: "memory");
        } else {
            asm volatile("s_waitcnt vmcnt(0)" ::: "memory");
        }
        __builtin_amdgcn_s_barrier();
        if (t + 2 < T) G128_STAGE((bb >= 1) ? (bb - 1) : (bb + 2), (t + 2) * 32);
        const ushort* LA = g1s + bb * 8192;
        const ushort* LB = LA + 4096;
        __builtin_amdgcn_s_setprio(1);
        {
            bf16x8 afv[4], bfv[4];
#pragma unroll
            for (int mf = 0; mf < 4; ++mf)
                afv[mf] = *(const bf16x8*)&LA[((wm * 4 + mf) * 64 + ln) * 8];
#pragma unroll
            for (int nf = 0; nf < 4; ++nf)
                bfv[nf] = *(const bf16x8*)&LB[((wn * 4 + nf) * 64 + ln) * 8];
#pragma unroll
            for (int mf = 0; mf < 4; ++mf)
#pragma unroll
                for (int nf = 0; nf < 4; ++nf)
                    acc[mf][nf] = __builtin_amdgcn_mfma_f32_16x16x32_bf16(
                        afv[mf], bfv[nf], acc[mf][nf], 0, 0, 0);
        }
        __builtin_amdgcn_s_setprio(0);
        bb = (bb == 2) ? 0 : bb + 1;
    }
#undef G128_STAGE

#pragma unroll
    for (int mf = 0; mf < 4; ++mf) {
        const int row0 = bm + wm * 64 + mf * 16 + lkg * 4;
#pragma unroll
        for (int nf = 0; nf < 4; ++nf) {
            float* cp = C + (size_t)row0 * N + bn + wn * 64 + nf * 16 + lrow;
#pragma unroll
            for (int j = 0; j < 4; ++j) cp[(size_t)j * N] = acc[mf][nf][j];
        }
    }
}

// ===== fused front: conv1d(K=4)+SiLU + q/k L2norm + v split, 1 block/row ====
// reads mixed_pre[s-3..s]; writes qnb bf16, kn f32, vbuf f32 (compact 4096).
__global__ __launch_bounds__(256) void front_kernel(
    const float* __restrict__ pre, const float* __restrict__ cw,
    ushort* __restrict__ qnb, float* __restrict__ kn, float* __restrict__ vbuf)
{
    __shared__ float stage[4096];
    __shared__ float sums[32];
    __shared__ float scal[32];
    const int s = blockIdx.x;
    const int tid = threadIdx.x;

#pragma unroll
    for (int cg = 0; cg < 8; ++cg) {
        const int c = cg * 1024 + tid * 4;
        float w[4][4];
#pragma unroll
        for (int j = 0; j < 4; ++j) {
            float4 wj = *(const float4*)(cw + (size_t)(c + j) * 4);
            w[j][0] = wj.x; w[j][1] = wj.y; w[j][2] = wj.z; w[j][3] = wj.w;
        }
        float a0 = 0.f, a1 = 0.f, a2 = 0.f, a3 = 0.f;
#pragma unroll
        for (int t = 0; t < 4; ++t) {
            int ss = s - 3 + t;
            if (ss >= 0) {
                float4 x = *(const float4*)(pre + (size_t)ss * CONV_DIM + c);
                a0 = fmaf(x.x, w[0][t], a0);
                a1 = fmaf(x.y, w[1][t], a1);
                a2 = fmaf(x.z, w[2][t], a2);
                a3 = fmaf(x.w, w[3][t], a3);
            }
        }
        a0 = silu_f(a0); a1 = silu_f(a1); a2 = silu_f(a2); a3 = silu_f(a3);
        if (cg < 4) {
            float4 v4 = make_float4(a0, a1, a2, a3);
            *(float4*)&stage[c] = v4;
            float ss2 = a0 * a0 + a1 * a1 + a2 * a2 + a3 * a3;
#pragma unroll
            for (int m = 1; m < 32; m <<= 1) ss2 += __shfl_xor(ss2, m, 32);
            if ((tid & 31) == 0) sums[c >> 7] = ss2;   // each head written once
        } else {
            *(float4*)(vbuf + (size_t)s * VAL_DIM + (c - 4096)) =
                make_float4(a0, a1, a2, a3);
        }
    }
    __syncthreads();
    if (tid < 32) {
        float sc = rsqrtf(sums[tid] + 1e-6f);
        if (tid < 16) sc *= 0.08838834764831843f;     // q: DK^-0.5
        scal[tid] = sc;
    }
    __syncthreads();
#pragma unroll
    for (int j = 0; j < 4; ++j) {
        const int c = j * 1024 + tid * 4;
        float4 v4 = *(const float4*)&stage[c];
        const float sc = scal[c >> 7];
        v4.x *= sc; v4.y *= sc; v4.z *= sc; v4.w *= sc;
        if (c < 2048) {
            union { ushort u2[4]; uint2 v; } p;
            p.u2[0] = f2bf(v4.x); p.u2[1] = f2bf(v4.y);
            p.u2[2] = f2bf(v4.z); p.u2[3] = f2bf(v4.w);
            *(uint2*)(qnb + ((size_t)(s * NKH + (c >> 7))) * DKD + (c & 127)) = p.v;
        } else {
            *(float4*)(kn + ((size_t)(s * NKH + ((c >> 7) - 16))) * DKD + (c & 127)) = v4;
        }
    }
}

// ====== g = -exp(A_log)*softplus(a+dt_bias), beta = sigmoid(b) ==============
// ab buffer layout: [S][128], a at cols 0..31, b at cols 32..63
__global__ __launch_bounds__(256) void gb_kernel(
    const float* __restrict__ ab, const float* __restrict__ dt_bias,
    const float* __restrict__ A_log, float* __restrict__ g, float* __restrict__ beta)
{
    int idx = blockIdx.x * 256 + threadIdx.x;
    int s = idx >> 5, h = idx & 31;
    float av = ab[(size_t)s * 128 + h] + dt_bias[h];
    float sp = (av > 20.f) ? av : log1pf(__expf(av));
    g[idx] = -__expf(A_log[h]) * sp;
    beta[idx] = sigmoid_f(ab[(size_t)s * 128 + 32 + h]);
}

// ================= Phase A: per (head, chunk) intra-chunk work ==============
__global__ __launch_bounds__(256) void phaseA_kernel(
    const ushort* __restrict__ qnb, const float* __restrict__ kn,
    const float* __restrict__ vbuf, const float* __restrict__ gbuf,
    const float* __restrict__ betabuf,
    float* __restrict__ u, ushort* __restrict__ kcd,
    ushort* __restrict__ scores, float* __restrict__ gcs_out,
    ushort* __restrict__ knT)
{
    extern __shared__ char pasm[];
    ushort* kb    = (ushort*)(pasm);            // 16KB frag [m4][ks4][64][8]
    ushort* qb    = (ushort*)(pasm + 16384);    // 16KB frag; later P f32[16][256]
    ushort* Xb    = (ushort*)(pasm + 32768);    // 32KB [t2(2)][ct(16)][64][8]
    float*  Adiag = (float*)(pasm + 65536);     // 4KB
    ushort* Ab    = (ushort*)(pasm + 69632);    // 4KB
    float*  gcs_s = (float*)(pasm + 73728);
    float*  bet_s = (float*)(pasm + 73984);
    float*  scK_s = (float*)(pasm + 74240);
    float*  Pf    = (float*)qb;

    const int n = blockIdx.x, h = blockIdx.y, kh = h >> 1;
    const int tid = threadIdx.x;
    const int s0 = n * CCH;
    const int wv = tid >> 6, ln = tid & 63;
    const int lrow = ln & 15, lkg = ln >> 4;

    float xr[64];
    if (tid < 128) {
        const float* vp = vbuf + (size_t)s0 * VAL_DIM + h * DVD + tid;
#pragma unroll
        for (int i = 0; i < 64; ++i) xr[i] = vp[(size_t)i * VAL_DIM];
    } else {
        const float* kp = kn + ((size_t)s0 * NKH + kh) * DKD + (tid - 128);
#pragma unroll
        for (int i = 0; i < 64; ++i) xr[i] = kp[(size_t)i * (NKH * DKD)];
    }

    {
        uint4 z = {0, 0, 0, 0};
#pragma unroll
        for (int i = 0; i < 8; ++i)
            *(uint4*)&Xb[(i * 256 + tid) * 8] = z;
        *(uint4*)&Ab[tid * 8] = z;
    }

    if (tid < 64) {
        float gv = gbuf[(size_t)(s0 + tid) * NVH + h];
#pragma unroll
        for (int off = 1; off < 64; off <<= 1) {
            float pv = __shfl_up(gv, off, 64);
            if (tid >= off) gv += pv;
        }
        float bv = betabuf[(size_t)(s0 + tid) * NVH + h];
        gcs_s[tid] = gv;
        bet_s[tid] = bv;
        scK_s[tid] = bv * __expf(gv);
        gcs_out[(size_t)h * S_LEN + s0 + tid] = gv;
    }

    {
        const int r = tid >> 2, c0 = (tid & 3) * 32;
        const int mbase = (((r >> 4) * 4 + (tid & 3)) * 64 + (r & 15)) * 8;
        const float* ksrc = kn + ((size_t)(s0 + r) * NKH + kh) * DKD + c0;
#pragma unroll
        for (int j0 = 0; j0 < 4; ++j0) {
            float4 v0 = *(const float4*)(ksrc + j0 * 8);
            float4 v1 = *(const float4*)(ksrc + j0 * 8 + 4);
            union { ushort us[8]; uint4 v; } p;
            p.us[0] = f2bf(v0.x); p.us[1] = f2bf(v0.y); p.us[2] = f2bf(v0.z); p.us[3] = f2bf(v0.w);
            p.us[4] = f2bf(v1.x); p.us[5] = f2bf(v1.y); p.us[6] = f2bf(v1.z); p.us[7] = f2bf(v1.w);
            *(uint4*)&kb[mbase + (j0 << 7)] = p.v;
        }
        const ushort* qsrc = qnb + ((size_t)(s0 + r) * NKH + kh) * DKD + c0;
#pragma unroll
        for (int j0 = 0; j0 < 4; ++j0) {
            uint4 v = *(const uint4*)(qsrc + j0 * 8);
            *(uint4*)&qb[mbase + (j0 << 7)] = v;
        }
    }
    __syncthreads();    // B1

    f32x4 accA[4], accQ[4];
#pragma unroll
    for (int j = 0; j < 4; ++j) {
        f32x4 z = {0.f, 0.f, 0.f, 0.f};
        accA[j] = z; accQ[j] = z;
    }
#pragma unroll
    for (int ks = 0; ks < 4; ++ks) {
        bf16x8 a_k = *(const bf16x8*)&kb[((wv * 4 + ks) * 64 + ln) * 8];
        bf16x8 a_q = *(const bf16x8*)&qb[((wv * 4 + ks) * 64 + ln) * 8];
#pragma unroll
        for (int j = 0; j < 4; ++j) {
            bf16x8 b_k = *(const bf16x8*)&kb[((j * 4 + ks) * 64 + ln) * 8];
            accA[j] = __builtin_amdgcn_mfma_f32_16x16x32_bf16(a_k, b_k, accA[j], 0, 0, 0);
            accQ[j] = __builtin_amdgcn_mfma_f32_16x16x32_bf16(a_q, b_k, accQ[j], 0, 0, 0);
        }
    }
    {
        ushort* scp = scores + (size_t)(h * NCHK + n) * (CCH * CCH);
#pragma unroll
        for (int j = 0; j < 4; ++j) {
            const int c = j * 16 + lrow;
            const float gc = gcs_s[c];
#pragma unroll
            for (int jj = 0; jj < 4; ++jj) {
                const int i = wv * 16 + lkg * 4 + jj;
                const float e = __expf(gcs_s[i] - gc);
                float sv = (i >= c) ? (accQ[j][jj] * e) : 0.f;
                scp[i * CCH + c] = f2bf(sv);
                float aval = (i > c) ? (-bet_s[i] * accA[j][jj] * e) : 0.f;
                if (j == wv) {
                    Adiag[wv * 256 + (i & 15) * 16 + lrow] = aval;
                } else if (j < wv) {
                    const int f = (wv == 1) ? 0 : ((wv == 2) ? 1 : (2 + (j >> 1)));
                    const int lk = ((j & 1) << 4) | lrow;
                    const int lane2 = (i & 15) | ((lk >> 3) << 4);
                    Ab[(f * 64 + lane2) * 8 + (lk & 7)] = f2bf(aval);
                }
            }
        }
    }
    if (tid < 128) {
#pragma unroll
        for (int i4 = 0; i4 < 16; ++i4) {
            float4 b4 = *(const float4*)&bet_s[i4 * 4];
            xr[i4 * 4 + 0] *= b4.x; xr[i4 * 4 + 1] *= b4.y;
            xr[i4 * 4 + 2] *= b4.z; xr[i4 * 4 + 3] *= b4.w;
        }
    } else {
#pragma unroll
        for (int i4 = 0; i4 < 16; ++i4) {
            float4 b4 = *(const float4*)&scK_s[i4 * 4];
            xr[i4 * 4 + 0] *= b4.x; xr[i4 * 4 + 1] *= b4.y;
            xr[i4 * 4 + 2] *= b4.z; xr[i4 * 4 + 3] *= b4.w;
        }
    }
    __syncthreads();    // B2

    const int ct = tid >> 4, lct = tid & 15;
#pragma unroll
    for (int s = 0; s < 4; ++s) {
        float y[16];
        float pr[16];
        if (s > 0) {
#pragma unroll
            for (int r = 0; r < 16; ++r) pr[r] = Pf[r * 256 + tid];
        } else {
#pragma unroll
            for (int r = 0; r < 16; ++r) pr[r] = 0.f;
        }
#pragma unroll
        for (int r = 0; r < 16; ++r) {
            float acc = xr[s * 16 + r] + pr[r];
#pragma unroll
            for (int k4 = 0; k4 < 16; k4 += 4) {
                if (k4 < r) {
                    float4 a4 = *(const float4*)&Adiag[s * 256 + r * 16 + k4];
                    if (k4 + 0 < r) acc = fmaf(a4.x, y[k4 + 0], acc);
                    if (k4 + 1 < r) acc = fmaf(a4.y, y[k4 + 1], acc);
                    if (k4 + 2 < r) acc = fmaf(a4.z, y[k4 + 2], acc);
                    if (k4 + 3 < r) acc = fmaf(a4.w, y[k4 + 3], acc);
                }
            }
            y[r] = acc;
        }
        if (tid < 128) {
            float* up = u + (size_t)(h * NCHK + n) * (CCH * DVD) + (s * 16) * DVD + tid;
#pragma unroll
            for (int r = 0; r < 16; ++r) up[r * DVD] = y[r];
        } else {
            ushort* kp = kcd + (size_t)(h * NCHK + n) * (CCH * DKD) + (s * 16) * DKD + (tid - 128);
#pragma unroll
            for (int r = 0; r < 16; ++r) kp[r * DKD] = f2bf(y[r]);
        }
        if (s < 3) {
#pragma unroll
            for (int half = 0; half < 2; ++half) {
                union { ushort us[8]; uint4 v; } p;
#pragma unroll
                for (int e = 0; e < 8; ++e) p.us[e] = f2bf(y[half * 8 + e]);
                const int kg = (s & 1) * 2 + half;
                *(uint4*)&Xb[(((s >> 1) * 16 + ct) * 64 + (kg * 16 + lct)) * 8] = p.v;
            }
            __syncthreads();
            const int snx = s + 1;
            const int nT2 = (snx + 1) >> 1;
            f32x4 accP[4];
#pragma unroll
            for (int ctl = 0; ctl < 4; ++ctl) {
                f32x4 z = {0.f, 0.f, 0.f, 0.f};
                accP[ctl] = z;
            }
#pragma unroll
            for (int t2 = 0; t2 < 2; ++t2) {
                if (t2 < nT2) {
                    const int f = (snx == 1) ? 0 : ((snx == 2) ? 1 : (2 + t2));
                    bf16x8 a = *(const bf16x8*)&Ab[(f * 64 + ln) * 8];
#pragma unroll
                    for (int ctl = 0; ctl < 4; ++ctl) {
                        bf16x8 b = *(const bf16x8*)&Xb[((t2 * 16 + wv * 4 + ctl) * 64 + ln) * 8];
                        accP[ctl] = __builtin_amdgcn_mfma_f32_16x16x32_bf16(a, b, accP[ctl], 0, 0, 0);
                    }
                }
            }
#pragma unroll
            for (int ctl = 0; ctl < 4; ++ctl)
#pragma unroll
                for (int jj = 0; jj < 4; ++jj)
                    Pf[(lkg * 4 + jj) * 256 + wv * 64 + ctl * 16 + lrow] = accP[ctl][jj];
            __syncthreads();
        }
    }

    if (!(h & 1)) {
        const int dk = tid >> 1, ch = (tid & 1) * 32;
        ushort* dst = knT + ((size_t)(kh * NCHK + n) * DKD + dk) * CCH + ch;
        const int kpart = ((dk >> 5) * 64) * 8 + (((dk >> 3) & 3) << 4) * 8 + (dk & 7);
#pragma unroll
        for (int j0 = 0; j0 < 32; j0 += 8) {
            union { ushort us[8]; uint4 v; } p;
#pragma unroll
            for (int j = 0; j < 8; ++j) {
                const int row = ch + j0 + j;
                p.us[j] = kb[((row >> 4) * 4 * 64 + (row & 15)) * 8 + kpart];
            }
            *(uint4*)(dst + j0) = p.v;
        }
    }
}

// ================= Phase B: inter-chunk state scan (MFMA), bf16 o ===========
__global__ __launch_bounds__(256) void phaseB_kernel(
    const ushort* __restrict__ qnb, const ushort* __restrict__ knT,
    const float* __restrict__ u, const ushort* __restrict__ kcd,
    const ushort* __restrict__ sc, const float* __restrict__ gcs,
    ushort* __restrict__ obuf)
{
    extern __shared__ ushort smu[];
    ushort* qorg  = smu;             // 8192  [m4][ks4][64][8]
    ushort* kcorg = smu + 8192;      // 8192
    ushort* scorg = smu + 16384;     // 4096
    ushort* kTorg = smu + 20480;     // 8192
    ushort* storg = smu + 28672;     // 2048  S^T bf16
    ushort* vnorg = smu + 30720;     // 1024
    ushort* vnsorg= smu + 31744;     // 1024
    float* gcs_s  = (float*)(smu + 32768);   // 64

    const int h = blockIdx.x;
    const int dvb = blockIdx.y;
    const int d0 = dvb * 16;
    const int kh = h >> 1;
    const int tid = threadIdx.x;
    const int wv = tid >> 6, ln = tid & 63;
    const int lrow = ln & 15, lkg = ln >> 4;

    for (int i = tid; i < 2048 / 8; i += 256) {
        uint4 z = {0, 0, 0, 0};
        *(uint4*)&storg[i * 8] = z;
    }

    const int q_lane  = lrow * (NKH * DKD) + kh * DKD + wv * 32 + lkg * 8;
    const int kc_lane = lrow * DKD + wv * 32 + lkg * 8;
    const int st_lane = ((tid >> 7) * 16 + lrow) * 64 + ((tid >> 6) & 1) * 32 + lkg * 8;
    const int dst_e   = wv * 512;

    f32x4 accS0 = {0.f, 0.f, 0.f, 0.f}, accS1 = {0.f, 0.f, 0.f, 0.f};

    for (int n = 0; n < NCHK; ++n) {
        const int s0 = n * CCH;
        const ushort* qsrc  = qnb + (size_t)s0 * (NKH * DKD);
        const ushort* kcsrc = kcd + (size_t)(h * NCHK + n) * (CCH * DKD);
        const ushort* scsrc = sc  + (size_t)(h * NCHK + n) * (CCH * CCH);
        const ushort* kTsrc = knT + (size_t)(kh * NCHK + n) * (DKD * CCH);
#pragma unroll
        for (int r = 0; r < 4; ++r) {
            GLL(qsrc + q_lane + r * 32768, &qorg[r * 2048 + dst_e]);
            GLL(kcsrc + kc_lane + r * 2048, &kcorg[r * 2048 + dst_e]);
            GLL(kTsrc + st_lane + r * 2048, &kTorg[r * 2048 + dst_e]);
        }
#pragma unroll
        for (int r = 0; r < 2; ++r)
            GLL(scsrc + st_lane + r * 2048, &scorg[r * 2048 + dst_e]);
        if (tid < 64) gcs_s[tid] = gcs[(size_t)h * S_LEN + s0 + tid];
        __syncthreads();                 // B1

        f32x4 accv = {0.f, 0.f, 0.f, 0.f};
        f32x4 acco = {0.f, 0.f, 0.f, 0.f};
#pragma unroll
        for (int ks = 0; ks < 4; ++ks) {
            bf16x8 b_st = *(const bf16x8*)&storg[(ks * 64 + ln) * 8];
            bf16x8 a_kc = *(const bf16x8*)&kcorg[((wv * 4 + ks) * 64 + ln) * 8];
            bf16x8 a_q  = *(const bf16x8*)&qorg[((wv * 4 + ks) * 64 + ln) * 8];
            accv = __builtin_amdgcn_mfma_f32_16x16x32_bf16(a_kc, b_st, accv, 0, 0, 0);
            acco = __builtin_amdgcn_mfma_f32_16x16x32_bf16(a_q, b_st, acco, 0, 0, 0);
        }
        const float* up = u + (size_t)(h * NCHK + n) * (CCH * DVD)
                            + (wv * 16 + lkg * 4) * DVD + d0 + lrow;
        float u0 = up[0], u1 = up[DVD], u2 = up[2 * DVD], u3 = up[3 * DVD];
        const float gl = gcs_s[63];
        float vn0 = u0 - accv[0], vn1 = u1 - accv[1];
        float vn2 = u2 - accv[2], vn3 = u3 - accv[3];
        {
            const int row = wv * 16 + lkg * 4;
            float g0 = gcs_s[row], g1 = gcs_s[row + 1], g2 = gcs_s[row + 2], g3 = gcs_s[row + 3];
            acco[0] *= __expf(g0); acco[1] *= __expf(g1);
            acco[2] *= __expf(g2); acco[3] *= __expf(g3);
            const int eb = ((wv >> 1) * 64 + ((wv & 1) * 2 + (lkg >> 1)) * 16 + lrow) * 8
                         + (lkg & 1) * 4;
            union { ushort u2a[4]; uint2 v; } pa, pb;
            pa.u2a[0] = f2bf(vn0); pa.u2a[1] = f2bf(vn1);
            pa.u2a[2] = f2bf(vn2); pa.u2a[3] = f2bf(vn3);
            pb.u2a[0] = f2bf(vn0 * __expf(gl - g0)); pb.u2a[1] = f2bf(vn1 * __expf(gl - g1));
            pb.u2a[2] = f2bf(vn2 * __expf(gl - g2)); pb.u2a[3] = f2bf(vn3 * __expf(gl - g3));
            *(uint2*)&vnorg[eb] = pa.v;
            *(uint2*)&vnsorg[eb] = pb.v;
        }
        __syncthreads();                 // B2

#pragma unroll
        for (int ks = 0; ks < 2; ++ks) {
            bf16x8 a_sc = *(const bf16x8*)&scorg[((wv * 2 + ks) * 64 + ln) * 8];
            bf16x8 b_vn = *(const bf16x8*)&vnorg[(ks * 64 + ln) * 8];
            acco = __builtin_amdgcn_mfma_f32_16x16x32_bf16(a_sc, b_vn, acco, 0, 0, 0);
        }
        ushort* op = obuf + (size_t)(s0 + wv * 16 + lkg * 4) * VAL_DIM + h * DVD + d0 + lrow;
        op[0] = f2bf(acco[0]); op[VAL_DIM] = f2bf(acco[1]);
        op[2 * VAL_DIM] = f2bf(acco[2]); op[3 * VAL_DIM] = f2bf(acco[3]);

        const float egl = __expf(gl);
        accS0 *= egl; accS1 *= egl;
#pragma unroll
        for (int ks = 0; ks < 2; ++ks) {
            bf16x8 a_vs = *(const bf16x8*)&vnsorg[(ks * 64 + ln) * 8];
            bf16x8 b_k0 = *(const bf16x8*)&kTorg[(((wv * 2 + 0) * 2 + ks) * 64 + ln) * 8];
            bf16x8 b_k1 = *(const bf16x8*)&kTorg[(((wv * 2 + 1) * 2 + ks) * 64 + ln) * 8];
            accS0 = __builtin_amdgcn_mfma_f32_16x16x32_bf16(a_vs, b_k0, accS0, 0, 0, 0);
            accS1 = __builtin_amdgcn_mfma_f32_16x16x32_bf16(a_vs, b_k1, accS1, 0, 0, 0);
        }
#pragma unroll
        for (int j = 0; j < 4; ++j) {
            storg[(wv * 64 + ((lrow >> 3)) * 16 + lkg * 4 + j) * 8 + (lrow & 7)] = f2bf(accS0[j]);
            storg[(wv * 64 + (2 + (lrow >> 3)) * 16 + lkg * 4 + j) * 8 + (lrow & 7)] = f2bf(accS1[j]);
        }
        __syncthreads();                 // B3
    }
}

// ============ RMSNorm * norm_w * silu(z) -> bf16 (bf16 o and z) =============
__global__ __launch_bounds__(256) void norm_kernel(
    const ushort* __restrict__ obuf, const ushort* __restrict__ z,
    const float* __restrict__ nw, ushort* __restrict__ hbuf)
{
    int row = (blockIdx.x * 256 + threadIdx.x) >> 6;
    int lane = threadIdx.x & 63;
    uint ov = *(const uint*)(obuf + (size_t)row * DVD + lane * 2);
    float x0 = bf2f((ushort)ov), x1 = bf2f((ushort)(ov >> 16));
    float ss = x0 * x0 + x1 * x1;
#pragma unroll
    for (int m = 1; m < 64; m <<= 1) ss += __shfl_xor(ss, m, 64);
    float scale = rsqrtf(ss * (1.f / DVD) + 1e-6f);
    uint zv = *(const uint*)(z + (size_t)row * DVD + lane * 2);
    float z0 = bf2f((ushort)zv), z1 = bf2f((ushort)(zv >> 16));
    float2 w2 = *(const float2*)(nw + lane * 2);
    float h0 = x0 * scale * w2.x * silu_f(z0);
    float h1 = x1 * scale * w2.y * silu_f(z1);
    union { ushort u[2]; uint v; } r;
    r.u[0] = f2bf(h0); r.u[1] = f2bf(h1);
    *(uint*)(hbuf + (size_t)row * DVD + lane * 2) = r.v;
}

// ============================================================================
extern "C" void kernel_launch(void* const* d_in, const int* in_sizes, int n_in,
                              void* d_out, int out_size, void* d_ws, size_t ws_size,
                              hipStream_t stream)
{
    (void)in_sizes; (void)n_in; (void)out_size; (void)ws_size;
    const float* x      = (const float*)d_in[0];
    const float* W_qkv  = (const float*)d_in[1];
    const float* W_z    = (const float*)d_in[2];
    const float* W_a    = (const float*)d_in[3];
    const float* W_b    = (const float*)d_in[4];
    const float* conv_w = (const float*)d_in[5];
    const float* dt_b   = (const float*)d_in[6];
    const float* A_log  = (const float*)d_in[7];
    const float* norm_w = (const float*)d_in[8];
    const float* W_out  = (const float*)d_in[9];
    float* out = (float*)d_out;

    // ---- workspace layout (bytes), overlaid by liveness; total ~202.1 MB ---
    char* ws = (char*)d_ws;
    // region A @0 (67,108,864): mixed_pre f32 (steps 2-4) -> {u, kcd, knT}
    float*  mixed_pre = (float*)(ws);
    float*  u_buf     = (float*)(ws);                   // 33,554,432
    ushort* kcd_buf   = (ushort*)(ws + 33554432);       // 16,777,216
    ushort* knT_buf   = (ushort*)(ws + 50331648);       //  8,388,608
    // region B @67,108,864:
    //   steps 1-2: wqz 50.3MB [67108864,117440512) + xb 8.4MB [117440512,..)
    //   step 4-7 : vbuf f32 33.5MB [67108864,100663296)
    //   step 8+  : obuf bf16 16.8MB @67108864 ; hbuf bf16 @100663296 ;
    //              wob @117440512 (xb dead after step 3)
    ushort* wqz       = (ushort*)(ws + 67108864);
    ushort* xb        = (ushort*)(ws + 117440512);
    float*  vbuf      = (float*)(ws + 67108864);
    ushort* obuf      = (ushort*)(ws + 67108864);
    ushort* hbuf      = (ushort*)(ws + 100663296);
    ushort* wob       = (ushort*)(ws + 117440512);
    // fixed regions
    ushort* z_buf     = (ushort*)(ws + 134217728);      // 16,777,216 (bf16)
    ushort* sc_buf    = (ushort*)(ws + 167772160);      //  8,388,608 (step>=7)
    ushort* wabb      = (ushort*)(ws + 167772160);      //    524,288 (steps 1-3)
    float*  ab_buf    = (float*)(ws + 168296448);       //  1,048,576 (steps 3-5)
    ushort* qnb       = (ushort*)(ws + 176160768);      //  8,388,608
    float*  kn        = (float*)(ws + 184549376);       // 16,777,216
    float*  g_buf     = (float*)(ws + 201326592);       //    262,144
    float*  bet_buf   = (float*)(ws + 201588736);       //    262,144
    float*  gcs_buf   = (float*)(ws + 201850880);       //    262,144

    hipFuncSetAttribute((const void*)phaseA_kernel,
                        hipFuncAttributeMaxDynamicSharedMemorySize, PA_LDS_BYTES);
    hipFuncSetAttribute((const void*)phaseB_kernel,
                        hipFuncAttributeMaxDynamicSharedMemorySize, PB_LDS_BYTES);
    hipFuncSetAttribute((const void*)gemm256_kernel,
                        hipFuncAttributeMaxDynamicSharedMemorySize, G256_LDS_BYTES);
    hipFuncSetAttribute((const void*)gemm128_kernel,
                        hipFuncAttributeMaxDynamicSharedMemorySize, G128_LDS_BYTES);

    dim3 blk(256);
    // 1) casts to bf16 (W_qkv and W_z fused contiguously into wqz)
    cast_kernel<<<(S_LEN * HIDDIM / 8) / 256, blk, 0, stream>>>(x, xb, S_LEN * HIDDIM / 8);
    cast_kernel<<<(CONV_DIM * HIDDIM / 8) / 256, blk, 0, stream>>>(W_qkv, wqz, CONV_DIM * HIDDIM / 8);
    cast_kernel<<<(VAL_DIM * HIDDIM / 8) / 256, blk, 0, stream>>>(W_z, wqz + (size_t)CONV_DIM * HIDDIM, VAL_DIM * HIDDIM / 8);
    cast_ab_kernel<<<(128 * HIDDIM / 8) / 256, blk, 0, stream>>>(W_a, W_b, wabb);
    // 2) fused qkv+z projection (z output bf16)
    gemm256_kernel<<<dim3((CONV_DIM + VAL_DIM) / 256, S_LEN / 128), dim3(512), G256_LDS_BYTES, stream>>>(
        xb, wqz, mixed_pre, (void*)z_buf, HIDDIM, CONV_DIM, CONV_DIM, VAL_DIM, 1);
    // 3) a/b projection
    gemm128_kernel<<<dim3(1, S_LEN / 128), blk, G128_LDS_BYTES, stream>>>(
        xb, wabb, ab_buf, 128, HIDDIM);
    // 4) fused conv+silu+l2norm+v-split (replaces conv_silu + l2norm)
    front_kernel<<<S_LEN, blk, 0, stream>>>(mixed_pre, conv_w, qnb, kn, vbuf);
    // 5) gates
    gb_kernel<<<(S_LEN * NVH) / 256, blk, 0, stream>>>(ab_buf, dt_b, A_log, g_buf, bet_buf);
    // 7) phase A (intra-chunk, blocked-MFMA solve)
    phaseA_kernel<<<dim3(NCHK, NVH), blk, PA_LDS_BYTES, stream>>>(
        qnb, kn, vbuf, g_buf, bet_buf, u_buf, kcd_buf, sc_buf, gcs_buf, knT_buf);
    // 8) phase B (inter-chunk scan, MFMA, bf16 o)
    phaseB_kernel<<<dim3(NVH, 8), blk, PB_LDS_BYTES, stream>>>(
        qnb, knT_buf, u_buf, kcd_buf, sc_buf, gcs_buf, obuf);
    // 9) W_out cast (xb dead) + gated RMSNorm -> bf16
    cast_kernel<<<(HIDDIM * VAL_DIM / 8) / 256, blk, 0, stream>>>(W_out, wob, HIDDIM * VAL_DIM / 8);
    norm_kernel<<<(S_LEN * NVH * 64) / 256, blk, 0, stream>>>(obuf, z_buf, norm_w, hbuf);
    // 10) output projection (128^2 triple-buffered BK=32, 256 blocks)
    gemm128_kernel<<<dim3(HIDDIM / 128, S_LEN / 128), blk, G128_LDS_BYTES, stream>>>(
        hbuf, wob, out, HIDDIM, VAL_DIM);
}

// Round 13
// 467.698 us; speedup vs baseline: 1.2745x; 1.0233x over previous
//
#include <hip/hip_runtime.h>
#include <hip/hip_bf16.h>
#include <math.h>

// ---- problem constants ----
#define S_LEN   2048
#define HIDDIM  2048
#define NKH     16
#define NVH     32
#define DKD     128
#define DVD     128
#define CCH     64          // chunk
#define NCHK    32          // S/chunk
#define KEY_DIM 2048
#define VAL_DIM 4096
#define CONV_DIM 8192

#define PA_LDS_BYTES (16384 + 16384 + 32768 + 4096 + 4096 + 256 + 256 + 256)
// phaseB LDS: stage[2] x 29696 us {q 8192, kc 8192, sc 4096, kT 8192, u 1024}
// + storg 2048 + vnorg 1024 + vnsorg 1024 + gcsall 2048 floats
#define PB_LDS_BYTES ((2 * 29696 + 2048 + 1024 + 1024) * 2 + 2048 * 4)  // 135168
// gemm256: 3 bufs x (A 128x32 + B 256x32) bf16 = 3 x 12288 ushorts = 72 KB
#define G256_LDS_BYTES (3 * 12288 * 2)
// gemm128: 3 bufs x (A 128x32 + B 128x32) = 3 x 8192 ushorts = 48 KB
#define G128_LDS_BYTES (3 * 8192 * 2)

typedef __bf16 bf16x8 __attribute__((ext_vector_type(8)));
typedef float f32x4 __attribute__((ext_vector_type(4)));

__device__ __forceinline__ float sigmoid_f(float x) { return 1.f / (1.f + __expf(-x)); }
__device__ __forceinline__ float silu_f(float x) { return x * sigmoid_f(x); }
__device__ __forceinline__ ushort f2bf(float f) {
    unsigned u = __float_as_uint(f);
    u += 0x7fffu + ((u >> 16) & 1u);          // RNE (inputs finite)
    return (ushort)(u >> 16);
}
__device__ __forceinline__ float bf2f(ushort u) {
    return __uint_as_float((unsigned)u << 16);
}

#define GLL(srcp, dstp) __builtin_amdgcn_global_load_lds( \
    (const __attribute__((address_space(1))) void*)(srcp), \
    (__attribute__((address_space(3))) void*)(dstp), 16, 0, 0)

// ================= fp32 -> bf16 cast (8 elems/thread) =======================
__global__ __launch_bounds__(256) void cast_kernel(
    const float* __restrict__ in, ushort* __restrict__ out, int n8)
{
    int t = blockIdx.x * 256 + threadIdx.x;
    if (t >= n8) return;
    float4 v0 = *(const float4*)(in + (size_t)t * 8);
    float4 v1 = *(const float4*)(in + (size_t)t * 8 + 4);
    union { ushort u[8]; uint4 v; } r;
    r.u[0] = f2bf(v0.x); r.u[1] = f2bf(v0.y); r.u[2] = f2bf(v0.z); r.u[3] = f2bf(v0.w);
    r.u[4] = f2bf(v1.x); r.u[5] = f2bf(v1.y); r.u[6] = f2bf(v1.z); r.u[7] = f2bf(v1.w);
    *(uint4*)(out + (size_t)t * 8) = r.v;
}

// ====== W_a,W_b -> one padded bf16 weight [128,2048] (rows 64..127 zero) ====
__global__ __launch_bounds__(256) void cast_ab_kernel(
    const float* __restrict__ Wa, const float* __restrict__ Wb, ushort* __restrict__ out)
{
    int t = blockIdx.x * 256 + threadIdx.x;          // 128*2048/8 = 32768 threads
    int row = t >> 8;
    int c8 = (t & 255) * 8;
    union { ushort u[8]; uint4 v; } r;
    if (row < 64) {
        const float* src = (row < 32) ? (Wa + (size_t)row * HIDDIM + c8)
                                      : (Wb + (size_t)(row - 32) * HIDDIM + c8);
        float4 v0 = *(const float4*)(src);
        float4 v1 = *(const float4*)(src + 4);
        r.u[0] = f2bf(v0.x); r.u[1] = f2bf(v0.y); r.u[2] = f2bf(v0.z); r.u[3] = f2bf(v0.w);
        r.u[4] = f2bf(v1.x); r.u[5] = f2bf(v1.y); r.u[6] = f2bf(v1.z); r.u[7] = f2bf(v1.w);
    } else {
        r.u[0] = r.u[1] = r.u[2] = r.u[3] = r.u[4] = r.u[5] = r.u[6] = r.u[7] = 0;
    }
    *(uint4*)(out + (size_t)t * 8) = r.v;
}

// ==== 128x256 triple-buffered counted-vmcnt bf16 GEMM (BK=32), dual out =====
// C0 f32; C1 f32 or bf16 (c1bf16 flag). Block cols < NSPLIT -> C0 else C1.
__global__ __launch_bounds__(512, 2) void gemm256_kernel(
    const ushort* __restrict__ A, const ushort* __restrict__ B,
    float* __restrict__ C0, void* __restrict__ C1,
    int K, int NSPLIT, int ldc0, int ldc1, int c1bf16)
{
    extern __shared__ ushort g2s[];          // [3][A 4096 | B 8192] ushorts
    const int tid = threadIdx.x;
    const int wv = tid >> 6, ln = tid & 63;
    const int wm = wv >> 2, wn = wv & 3;
    const int lrow = ln & 15, lkg = ln >> 4;
    const int bm = blockIdx.y * 128, bn = blockIdx.x * 256;

    int soffA, soffB[2];
    {
        int l = tid & 63;
        soffA = (((tid >> 6) * 16) + (l & 15)) * K + (l >> 4) * 8;
#pragma unroll
        for (int j = 0; j < 2; ++j) {
            int g = tid + j * 512;
            int lg = g & 63;
            soffB[j] = (((g >> 6) * 16) + (lg & 15)) * K + (lg >> 4) * 8;
        }
    }
    const ushort* Abase = A + (size_t)bm * K;
    const ushort* Bbase = B + (size_t)bn * K;

    f32x4 acc[4][4];
#pragma unroll
    for (int m = 0; m < 4; ++m)
#pragma unroll
        for (int n = 0; n < 4; ++n) {
            f32x4 z = {0.f, 0.f, 0.f, 0.f};
            acc[m][n] = z;
        }

#define G256_STAGE(bb, k0) do {                                            \
        ushort* bufA_ = g2s + (bb) * 12288;                                \
        ushort* bufB_ = bufA_ + 4096;                                      \
        GLL(Abase + soffA + (k0), bufA_ + (wv * 64) * 8);                  \
        _Pragma("unroll")                                                  \
        for (int j_ = 0; j_ < 2; ++j_)                                     \
            GLL(Bbase + soffB[j_] + (k0), bufB_ + (j_ * 512 + wv * 64) * 8);\
    } while (0)

    const int T = K >> 5;
    G256_STAGE(0, 0);
    G256_STAGE(1, 32);
    int bb = 0;
    for (int t = 0; t < T; ++t) {
        if (t + 1 < T) {
            asm volatile("s_waitcnt vmcnt(3)" ::: "memory");
        } else {
            asm volatile("s_waitcnt vmcnt(0)" ::: "memory");
        }
        __builtin_amdgcn_s_barrier();
        if (t + 2 < T) G256_STAGE((bb >= 1) ? (bb - 1) : (bb + 2), (t + 2) * 32);
        const ushort* LA = g2s + bb * 12288;
        const ushort* LB = LA + 4096;
        __builtin_amdgcn_s_setprio(1);
        {
            bf16x8 afv[4], bfv[4];
#pragma unroll
            for (int mf = 0; mf < 4; ++mf)
                afv[mf] = *(const bf16x8*)&LA[((wm * 4 + mf) * 64 + ln) * 8];
#pragma unroll
            for (int nf = 0; nf < 4; ++nf)
                bfv[nf] = *(const bf16x8*)&LB[((wn * 4 + nf) * 64 + ln) * 8];
#pragma unroll
            for (int mf = 0; mf < 4; ++mf)
#pragma unroll
                for (int nf = 0; nf < 4; ++nf)
                    acc[mf][nf] = __builtin_amdgcn_mfma_f32_16x16x32_bf16(
                        afv[mf], bfv[nf], acc[mf][nf], 0, 0, 0);
        }
        __builtin_amdgcn_s_setprio(0);
        bb = (bb == 2) ? 0 : bb + 1;
    }
#undef G256_STAGE

    const bool inC1 = (bn >= NSPLIT);
    const int cboff = bn + wn * 64 - (inC1 ? NSPLIT : 0);
    if (!inC1) {
#pragma unroll
        for (int mf = 0; mf < 4; ++mf) {
            const int row0 = bm + wm * 64 + mf * 16 + lkg * 4;
#pragma unroll
            for (int nf = 0; nf < 4; ++nf) {
                float* cp = C0 + (size_t)row0 * ldc0 + cboff + nf * 16 + lrow;
#pragma unroll
                for (int j = 0; j < 4; ++j) cp[(size_t)j * ldc0] = acc[mf][nf][j];
            }
        }
    } else if (!c1bf16) {
        float* C1f = (float*)C1;
#pragma unroll
        for (int mf = 0; mf < 4; ++mf) {
            const int row0 = bm + wm * 64 + mf * 16 + lkg * 4;
#pragma unroll
            for (int nf = 0; nf < 4; ++nf) {
                float* cp = C1f + (size_t)row0 * ldc1 + cboff + nf * 16 + lrow;
#pragma unroll
                for (int j = 0; j < 4; ++j) cp[(size_t)j * ldc1] = acc[mf][nf][j];
            }
        }
    } else {
        ushort* C1b = (ushort*)C1;
#pragma unroll
        for (int mf = 0; mf < 4; ++mf) {
            const int row0 = bm + wm * 64 + mf * 16 + lkg * 4;
#pragma unroll
            for (int nf = 0; nf < 4; ++nf) {
                ushort* cp = C1b + (size_t)row0 * ldc1 + cboff + nf * 16 + lrow;
#pragma unroll
                for (int j = 0; j < 4; ++j) cp[(size_t)j * ldc1] = f2bf(acc[mf][nf][j]);
            }
        }
    }
}

// ======== 128x128 triple-buffered counted-vmcnt bf16 GEMM (BK=32) ===========
__global__ __launch_bounds__(256, 2) void gemm128_kernel(
    const ushort* __restrict__ A, const ushort* __restrict__ B,
    float* __restrict__ C, int N, int K)
{
    extern __shared__ ushort g1s[];          // [3][A 4096 | B 4096] ushorts
    const int tid = threadIdx.x;
    const int wv = tid >> 6, ln = tid & 63;
    const int wm = wv >> 1, wn = wv & 1;
    const int lrow = ln & 15, lkg = ln >> 4;
    const int bm = blockIdx.y * 128, bn = blockIdx.x * 128;

    int soff[2];
#pragma unroll
    for (int j = 0; j < 2; ++j) {
        int g = tid + j * 256;
        int l = g & 63;
        soff[j] = (((g >> 6) * 16) + (l & 15)) * K + (l >> 4) * 8;
    }
    const ushort* Abase = A + (size_t)bm * K;
    const ushort* Bbase = B + (size_t)bn * K;

    f32x4 acc[4][4];
#pragma unroll
    for (int m = 0; m < 4; ++m)
#pragma unroll
        for (int n = 0; n < 4; ++n) {
            f32x4 z = {0.f, 0.f, 0.f, 0.f};
            acc[m][n] = z;
        }

#define G128_STAGE(bb, k0) do {                                            \
        ushort* bufA_ = g1s + (bb) * 8192;                                 \
        ushort* bufB_ = bufA_ + 4096;                                      \
        _Pragma("unroll")                                                  \
        for (int j_ = 0; j_ < 2; ++j_) {                                   \
            GLL(Abase + soff[j_] + (k0), bufA_ + (j_ * 256 + wv * 64) * 8);\
            GLL(Bbase + soff[j_] + (k0), bufB_ + (j_ * 256 + wv * 64) * 8);\
        }                                                                  \
    } while (0)

    const int T = K >> 5;
    G128_STAGE(0, 0);
    G128_STAGE(1, 32);
    int bb = 0;
    for (int t = 0; t < T; ++t) {
        if (t + 1 < T) {
            asm volatile("s_waitcnt vmcnt(4)" ::: "memory");
        } else {
            asm volatile("s_waitcnt vmcnt(0)" ::: "memory");
        }
        __builtin_amdgcn_s_barrier();
        if (t + 2 < T) G128_STAGE((bb >= 1) ? (bb - 1) : (bb + 2), (t + 2) * 32);
        const ushort* LA = g1s + bb * 8192;
        const ushort* LB = LA + 4096;
        __builtin_amdgcn_s_setprio(1);
        {
            bf16x8 afv[4], bfv[4];
#pragma unroll
            for (int mf = 0; mf < 4; ++mf)
                afv[mf] = *(const bf16x8*)&LA[((wm * 4 + mf) * 64 + ln) * 8];
#pragma unroll
            for (int nf = 0; nf < 4; ++nf)
                bfv[nf] = *(const bf16x8*)&LB[((wn * 4 + nf) * 64 + ln) * 8];
#pragma unroll
            for (int mf = 0; mf < 4; ++mf)
#pragma unroll
                for (int nf = 0; nf < 4; ++nf)
                    acc[mf][nf] = __builtin_amdgcn_mfma_f32_16x16x32_bf16(
                        afv[mf], bfv[nf], acc[mf][nf], 0, 0, 0);
        }
        __builtin_amdgcn_s_setprio(0);
        bb = (bb == 2) ? 0 : bb + 1;
    }
#undef G128_STAGE

#pragma unroll
    for (int mf = 0; mf < 4; ++mf) {
        const int row0 = bm + wm * 64 + mf * 16 + lkg * 4;
#pragma unroll
        for (int nf = 0; nf < 4; ++nf) {
            float* cp = C + (size_t)row0 * N + bn + wn * 64 + nf * 16 + lrow;
#pragma unroll
            for (int j = 0; j < 4; ++j) cp[(size_t)j * N] = acc[mf][nf][j];
        }
    }
}

// ===== fused front: conv1d(K=4)+SiLU + q/k L2norm + v split, 1 block/row ====
__global__ __launch_bounds__(256) void front_kernel(
    const float* __restrict__ pre, const float* __restrict__ cw,
    ushort* __restrict__ qnb, float* __restrict__ kn, float* __restrict__ vbuf)
{
    __shared__ float stage[4096];
    __shared__ float sums[32];
    __shared__ float scal[32];
    const int s = blockIdx.x;
    const int tid = threadIdx.x;

#pragma unroll
    for (int cg = 0; cg < 8; ++cg) {
        const int c = cg * 1024 + tid * 4;
        float w[4][4];
#pragma unroll
        for (int j = 0; j < 4; ++j) {
            float4 wj = *(const float4*)(cw + (size_t)(c + j) * 4);
            w[j][0] = wj.x; w[j][1] = wj.y; w[j][2] = wj.z; w[j][3] = wj.w;
        }
        float a0 = 0.f, a1 = 0.f, a2 = 0.f, a3 = 0.f;
#pragma unroll
        for (int t = 0; t < 4; ++t) {
            int ss = s - 3 + t;
            if (ss >= 0) {
                float4 x = *(const float4*)(pre + (size_t)ss * CONV_DIM + c);
                a0 = fmaf(x.x, w[0][t], a0);
                a1 = fmaf(x.y, w[1][t], a1);
                a2 = fmaf(x.z, w[2][t], a2);
                a3 = fmaf(x.w, w[3][t], a3);
            }
        }
        a0 = silu_f(a0); a1 = silu_f(a1); a2 = silu_f(a2); a3 = silu_f(a3);
        if (cg < 4) {
            float4 v4 = make_float4(a0, a1, a2, a3);
            *(float4*)&stage[c] = v4;
            float ss2 = a0 * a0 + a1 * a1 + a2 * a2 + a3 * a3;
#pragma unroll
            for (int m = 1; m < 32; m <<= 1) ss2 += __shfl_xor(ss2, m, 32);
            if ((tid & 31) == 0) sums[c >> 7] = ss2;
        } else {
            *(float4*)(vbuf + (size_t)s * VAL_DIM + (c - 4096)) =
                make_float4(a0, a1, a2, a3);
        }
    }
    __syncthreads();
    if (tid < 32) {
        float sc = rsqrtf(sums[tid] + 1e-6f);
        if (tid < 16) sc *= 0.08838834764831843f;     // q: DK^-0.5
        scal[tid] = sc;
    }
    __syncthreads();
#pragma unroll
    for (int j = 0; j < 4; ++j) {
        const int c = j * 1024 + tid * 4;
        float4 v4 = *(const float4*)&stage[c];
        const float sc = scal[c >> 7];
        v4.x *= sc; v4.y *= sc; v4.z *= sc; v4.w *= sc;
        if (c < 2048) {
            union { ushort u2[4]; uint2 v; } p;
            p.u2[0] = f2bf(v4.x); p.u2[1] = f2bf(v4.y);
            p.u2[2] = f2bf(v4.z); p.u2[3] = f2bf(v4.w);
            *(uint2*)(qnb + ((size_t)(s * NKH + (c >> 7))) * DKD + (c & 127)) = p.v;
        } else {
            *(float4*)(kn + ((size_t)(s * NKH + ((c >> 7) - 16))) * DKD + (c & 127)) = v4;
        }
    }
}

// ====== g = -exp(A_log)*softplus(a+dt_bias), beta = sigmoid(b) ==============
__global__ __launch_bounds__(256) void gb_kernel(
    const float* __restrict__ ab, const float* __restrict__ dt_bias,
    const float* __restrict__ A_log, float* __restrict__ g, float* __restrict__ beta)
{
    int idx = blockIdx.x * 256 + threadIdx.x;
    int s = idx >> 5, h = idx & 31;
    float av = ab[(size_t)s * 128 + h] + dt_bias[h];
    float sp = (av > 20.f) ? av : log1pf(__expf(av));
    g[idx] = -__expf(A_log[h]) * sp;
    beta[idx] = sigmoid_f(ab[(size_t)s * 128 + 32 + h]);
}

// ================= Phase A: per (head, chunk) intra-chunk work ==============
// outputs: u bf16, kcd bf16, scores bf16, gcs f32, knT bf16 (even h only)
__global__ __launch_bounds__(256) void phaseA_kernel(
    const ushort* __restrict__ qnb, const float* __restrict__ kn,
    const float* __restrict__ vbuf, const float* __restrict__ gbuf,
    const float* __restrict__ betabuf,
    ushort* __restrict__ u, ushort* __restrict__ kcd,
    ushort* __restrict__ scores, float* __restrict__ gcs_out,
    ushort* __restrict__ knT)
{
    extern __shared__ char pasm[];
    ushort* kb    = (ushort*)(pasm);            // 16KB frag [m4][ks4][64][8]
    ushort* qb    = (ushort*)(pasm + 16384);    // 16KB frag; later P f32[16][256]
    ushort* Xb    = (ushort*)(pasm + 32768);    // 32KB [t2(2)][ct(16)][64][8]
    float*  Adiag = (float*)(pasm + 65536);     // 4KB
    ushort* Ab    = (ushort*)(pasm + 69632);    // 4KB
    float*  gcs_s = (float*)(pasm + 73728);
    float*  bet_s = (float*)(pasm + 73984);
    float*  scK_s = (float*)(pasm + 74240);
    float*  Pf    = (float*)qb;

    const int n = blockIdx.x, h = blockIdx.y, kh = h >> 1;
    const int tid = threadIdx.x;
    const int s0 = n * CCH;
    const int wv = tid >> 6, ln = tid & 63;
    const int lrow = ln & 15, lkg = ln >> 4;

    float xr[64];
    if (tid < 128) {
        const float* vp = vbuf + (size_t)s0 * VAL_DIM + h * DVD + tid;
#pragma unroll
        for (int i = 0; i < 64; ++i) xr[i] = vp[(size_t)i * VAL_DIM];
    } else {
        const float* kp = kn + ((size_t)s0 * NKH + kh) * DKD + (tid - 128);
#pragma unroll
        for (int i = 0; i < 64; ++i) xr[i] = kp[(size_t)i * (NKH * DKD)];
    }

    {
        uint4 z = {0, 0, 0, 0};
#pragma unroll
        for (int i = 0; i < 8; ++i)
            *(uint4*)&Xb[(i * 256 + tid) * 8] = z;
        *(uint4*)&Ab[tid * 8] = z;
    }

    if (tid < 64) {
        float gv = gbuf[(size_t)(s0 + tid) * NVH + h];
#pragma unroll
        for (int off = 1; off < 64; off <<= 1) {
            float pv = __shfl_up(gv, off, 64);
            if (tid >= off) gv += pv;
        }
        float bv = betabuf[(size_t)(s0 + tid) * NVH + h];
        gcs_s[tid] = gv;
        bet_s[tid] = bv;
        scK_s[tid] = bv * __expf(gv);
        gcs_out[(size_t)h * S_LEN + s0 + tid] = gv;
    }

    {
        const int r = tid >> 2, c0 = (tid & 3) * 32;
        const int mbase = (((r >> 4) * 4 + (tid & 3)) * 64 + (r & 15)) * 8;
        const float* ksrc = kn + ((size_t)(s0 + r) * NKH + kh) * DKD + c0;
#pragma unroll
        for (int j0 = 0; j0 < 4; ++j0) {
            float4 v0 = *(const float4*)(ksrc + j0 * 8);
            float4 v1 = *(const float4*)(ksrc + j0 * 8 + 4);
            union { ushort us[8]; uint4 v; } p;
            p.us[0] = f2bf(v0.x); p.us[1] = f2bf(v0.y); p.us[2] = f2bf(v0.z); p.us[3] = f2bf(v0.w);
            p.us[4] = f2bf(v1.x); p.us[5] = f2bf(v1.y); p.us[6] = f2bf(v1.z); p.us[7] = f2bf(v1.w);
            *(uint4*)&kb[mbase + (j0 << 7)] = p.v;
        }
        const ushort* qsrc = qnb + ((size_t)(s0 + r) * NKH + kh) * DKD + c0;
#pragma unroll
        for (int j0 = 0; j0 < 4; ++j0) {
            uint4 v = *(const uint4*)(qsrc + j0 * 8);
            *(uint4*)&qb[mbase + (j0 << 7)] = v;
        }
    }
    __syncthreads();    // B1

    f32x4 accA[4], accQ[4];
#pragma unroll
    for (int j = 0; j < 4; ++j) {
        f32x4 z = {0.f, 0.f, 0.f, 0.f};
        accA[j] = z; accQ[j] = z;
    }
#pragma unroll
    for (int ks = 0; ks < 4; ++ks) {
        bf16x8 a_k = *(const bf16x8*)&kb[((wv * 4 + ks) * 64 + ln) * 8];
        bf16x8 a_q = *(const bf16x8*)&qb[((wv * 4 + ks) * 64 + ln) * 8];
#pragma unroll
        for (int j = 0; j < 4; ++j) {
            bf16x8 b_k = *(const bf16x8*)&kb[((j * 4 + ks) * 64 + ln) * 8];
            accA[j] = __builtin_amdgcn_mfma_f32_16x16x32_bf16(a_k, b_k, accA[j], 0, 0, 0);
            accQ[j] = __builtin_amdgcn_mfma_f32_16x16x32_bf16(a_q, b_k, accQ[j], 0, 0, 0);
        }
    }
    {
        ushort* scp = scores + (size_t)(h * NCHK + n) * (CCH * CCH);
#pragma unroll
        for (int j = 0; j < 4; ++j) {
            const int c = j * 16 + lrow;
            const float gc = gcs_s[c];
#pragma unroll
            for (int jj = 0; jj < 4; ++jj) {
                const int i = wv * 16 + lkg * 4 + jj;
                const float e = __expf(gcs_s[i] - gc);
                float sv = (i >= c) ? (accQ[j][jj] * e) : 0.f;
                scp[i * CCH + c] = f2bf(sv);
                float aval = (i > c) ? (-bet_s[i] * accA[j][jj] * e) : 0.f;
                if (j == wv) {
                    Adiag[wv * 256 + (i & 15) * 16 + lrow] = aval;
                } else if (j < wv) {
                    const int f = (wv == 1) ? 0 : ((wv == 2) ? 1 : (2 + (j >> 1)));
                    const int lk = ((j & 1) << 4) | lrow;
                    const int lane2 = (i & 15) | ((lk >> 3) << 4);
                    Ab[(f * 64 + lane2) * 8 + (lk & 7)] = f2bf(aval);
                }
            }
        }
    }
    if (tid < 128) {
#pragma unroll
        for (int i4 = 0; i4 < 16; ++i4) {
            float4 b4 = *(const float4*)&bet_s[i4 * 4];
            xr[i4 * 4 + 0] *= b4.x; xr[i4 * 4 + 1] *= b4.y;
            xr[i4 * 4 + 2] *= b4.z; xr[i4 * 4 + 3] *= b4.w;
        }
    } else {
#pragma unroll
        for (int i4 = 0; i4 < 16; ++i4) {
            float4 b4 = *(const float4*)&scK_s[i4 * 4];
            xr[i4 * 4 + 0] *= b4.x; xr[i4 * 4 + 1] *= b4.y;
            xr[i4 * 4 + 2] *= b4.z; xr[i4 * 4 + 3] *= b4.w;
        }
    }
    __syncthreads();    // B2

    const int ct = tid >> 4, lct = tid & 15;
#pragma unroll
    for (int s = 0; s < 4; ++s) {
        float y[16];
        float pr[16];
        if (s > 0) {
#pragma unroll
            for (int r = 0; r < 16; ++r) pr[r] = Pf[r * 256 + tid];
        } else {
#pragma unroll
            for (int r = 0; r < 16; ++r) pr[r] = 0.f;
        }
#pragma unroll
        for (int r = 0; r < 16; ++r) {
            float acc = xr[s * 16 + r] + pr[r];
#pragma unroll
            for (int k4 = 0; k4 < 16; k4 += 4) {
                if (k4 < r) {
                    float4 a4 = *(const float4*)&Adiag[s * 256 + r * 16 + k4];
                    if (k4 + 0 < r) acc = fmaf(a4.x, y[k4 + 0], acc);
                    if (k4 + 1 < r) acc = fmaf(a4.y, y[k4 + 1], acc);
                    if (k4 + 2 < r) acc = fmaf(a4.z, y[k4 + 2], acc);
                    if (k4 + 3 < r) acc = fmaf(a4.w, y[k4 + 3], acc);
                }
            }
            y[r] = acc;
        }
        if (tid < 128) {
            ushort* up = u + (size_t)(h * NCHK + n) * (CCH * DVD) + (s * 16) * DVD + tid;
#pragma unroll
            for (int r = 0; r < 16; ++r) up[r * DVD] = f2bf(y[r]);
        } else {
            ushort* kp = kcd + (size_t)(h * NCHK + n) * (CCH * DKD) + (s * 16) * DKD + (tid - 128);
#pragma unroll
            for (int r = 0; r < 16; ++r) kp[r * DKD] = f2bf(y[r]);
        }
        if (s < 3) {
#pragma unroll
            for (int half = 0; half < 2; ++half) {
                union { ushort us[8]; uint4 v; } p;
#pragma unroll
                for (int e = 0; e < 8; ++e) p.us[e] = f2bf(y[half * 8 + e]);
                const int kg = (s & 1) * 2 + half;
                *(uint4*)&Xb[(((s >> 1) * 16 + ct) * 64 + (kg * 16 + lct)) * 8] = p.v;
            }
            __syncthreads();
            const int snx = s + 1;
            const int nT2 = (snx + 1) >> 1;
            f32x4 accP[4];
#pragma unroll
            for (int ctl = 0; ctl < 4; ++ctl) {
                f32x4 z = {0.f, 0.f, 0.f, 0.f};
                accP[ctl] = z;
            }
#pragma unroll
            for (int t2 = 0; t2 < 2; ++t2) {
                if (t2 < nT2) {
                    const int f = (snx == 1) ? 0 : ((snx == 2) ? 1 : (2 + t2));
                    bf16x8 a = *(const bf16x8*)&Ab[(f * 64 + ln) * 8];
#pragma unroll
                    for (int ctl = 0; ctl < 4; ++ctl) {
                        bf16x8 b = *(const bf16x8*)&Xb[((t2 * 16 + wv * 4 + ctl) * 64 + ln) * 8];
                        accP[ctl] = __builtin_amdgcn_mfma_f32_16x16x32_bf16(a, b, accP[ctl], 0, 0, 0);
                    }
                }
            }
#pragma unroll
            for (int ctl = 0; ctl < 4; ++ctl)
#pragma unroll
                for (int jj = 0; jj < 4; ++jj)
                    Pf[(lkg * 4 + jj) * 256 + wv * 64 + ctl * 16 + lrow] = accP[ctl][jj];
            __syncthreads();
        }
    }

    if (!(h & 1)) {
        const int dk = tid >> 1, ch = (tid & 1) * 32;
        ushort* dst = knT + ((size_t)(kh * NCHK + n) * DKD + dk) * CCH + ch;
        const int kpart = ((dk >> 5) * 64) * 8 + (((dk >> 3) & 3) << 4) * 8 + (dk & 7);
#pragma unroll
        for (int j0 = 0; j0 < 32; j0 += 8) {
            union { ushort us[8]; uint4 v; } p;
#pragma unroll
            for (int j = 0; j < 8; ++j) {
                const int row = ch + j0 + j;
                p.us[j] = kb[((row >> 4) * 4 * 64 + (row & 15)) * 8 + kpart];
            }
            *(uint4*)(dst + j0) = p.v;
        }
    }
}

// ====== Phase B: inter-chunk state scan (MFMA), prefetch-pipelined ==========
// stage[2] double buffer: chunk n+1's 15 GLLs issued at top of iter n; the
// vn-publish __syncthreads (full drain) lands them. gcs table preloaded once.
// 2 barriers/chunk (was 3); u staged as bf16 tile via GLL (waves 0-1).
__global__ __launch_bounds__(256) void phaseB_kernel(
    const ushort* __restrict__ qnb, const ushort* __restrict__ knT,
    const ushort* __restrict__ u, const ushort* __restrict__ kcd,
    const ushort* __restrict__ sc, const float* __restrict__ gcs,
    ushort* __restrict__ obuf)
{
    extern __shared__ ushort smu[];
    // stage buf b at b*29696: {q 8192, kc 8192, sc 4096, kT 8192, u 1024}
    ushort* storg  = smu + 59392;    // 2048  S^T bf16
    ushort* vnorg  = smu + 61440;    // 1024
    ushort* vnsorg = smu + 62464;    // 1024
    float*  gcsall = (float*)(smu + 63488);  // 2048 floats (8 KB)

    const int h = blockIdx.x;
    const int dvb = blockIdx.y;
    const int d0 = dvb * 16;
    const int kh = h >> 1;
    const int tid = threadIdx.x;
    const int wv = tid >> 6, ln = tid & 63;
    const int lrow = ln & 15, lkg = ln >> 4;

    {   // zero S^T
        uint4 z = {0, 0, 0, 0};
        *(uint4*)&storg[tid * 8] = z;
    }

    const int q_lane  = lrow * (NKH * DKD) + kh * DKD + wv * 32 + lkg * 8;
    const int kc_lane = lrow * DKD + wv * 32 + lkg * 8;
    const int st_lane = ((tid >> 7) * 16 + lrow) * 64 + ((tid >> 6) & 1) * 32 + lkg * 8;
    const int dst_e   = wv * 512;

#define PBSTG(bsel, nn) do {                                                  \
        const ushort* qsrc_  = qnb + (size_t)((nn) * CCH) * (NKH * DKD);      \
        const ushort* kcsrc_ = kcd + (size_t)(h * NCHK + (nn)) * (CCH * DKD); \
        const ushort* scsrc_ = sc  + (size_t)(h * NCHK + (nn)) * (CCH * CCH); \
        const ushort* kTsrc_ = knT + (size_t)(kh * NCHK + (nn)) * (DKD * CCH);\
        const ushort* usrc_  = u   + (size_t)(h * NCHK + (nn)) * (CCH * DVD) + d0; \
        ushort* base_ = smu + (bsel) * 29696;                                 \
        _Pragma("unroll")                                                     \
        for (int r_ = 0; r_ < 4; ++r_) {                                      \
            GLL(qsrc_ + q_lane + r_ * 32768, base_ + r_ * 2048 + dst_e);      \
            GLL(kcsrc_ + kc_lane + r_ * 2048, base_ + 8192 + r_ * 2048 + dst_e); \
            GLL(kTsrc_ + st_lane + r_ * 2048, base_ + 20480 + r_ * 2048 + dst_e); \
        }                                                                     \
        _Pragma("unroll")                                                     \
        for (int r_ = 0; r_ < 2; ++r_)                                        \
            GLL(scsrc_ + st_lane + r_ * 2048, base_ + 16384 + r_ * 2048 + dst_e); \
        if (tid < 128)                                                        \
            GLL(usrc_ + (tid >> 1) * DVD + (tid & 1) * 8, base_ + 28672 + tid * 8); \
    } while (0)

    // prologue: stage chunk 0; preload gcs table for this head
    PBSTG(0, 0);
    {
        float4 g0 = *(const float4*)(gcs + (size_t)h * S_LEN + tid * 8);
        float4 g1 = *(const float4*)(gcs + (size_t)h * S_LEN + tid * 8 + 4);
        *(float4*)&gcsall[tid * 8] = g0;
        *(float4*)&gcsall[tid * 8 + 4] = g1;
    }
    __syncthreads();                 // chunk0 + gcs table + storg-zero published

    f32x4 accS0 = {0.f, 0.f, 0.f, 0.f}, accS1 = {0.f, 0.f, 0.f, 0.f};

    for (int n = 0; n < NCHK; ++n) {
        const int cur = n & 1;
        if (n + 1 < NCHK) PBSTG(cur ^ 1, n + 1);   // prefetch next chunk
        const ushort* qorg  = smu + cur * 29696;
        const ushort* kcorg = qorg + 8192;
        const ushort* scorg = qorg + 16384;
        const ushort* kTorg = qorg + 20480;
        const ushort* uorg  = qorg + 28672;
        const float*  gcs_s = gcsall + n * 64;
        const int s0 = n * CCH;

        // ---- phase 1: accv = kcd@S, acco = q@S (old state) ----
        f32x4 accv = {0.f, 0.f, 0.f, 0.f};
        f32x4 acco = {0.f, 0.f, 0.f, 0.f};
#pragma unroll
        for (int ks = 0; ks < 4; ++ks) {
            bf16x8 b_st = *(const bf16x8*)&storg[(ks * 64 + ln) * 8];
            bf16x8 a_kc = *(const bf16x8*)&kcorg[((wv * 4 + ks) * 64 + ln) * 8];
            bf16x8 a_q  = *(const bf16x8*)&qorg[((wv * 4 + ks) * 64 + ln) * 8];
            accv = __builtin_amdgcn_mfma_f32_16x16x32_bf16(a_kc, b_st, accv, 0, 0, 0);
            acco = __builtin_amdgcn_mfma_f32_16x16x32_bf16(a_q, b_st, acco, 0, 0, 0);
        }
        const int row = wv * 16 + lkg * 4;
        float u0 = bf2f(uorg[(row + 0) * 16 + lrow]);
        float u1 = bf2f(uorg[(row + 1) * 16 + lrow]);
        float u2 = bf2f(uorg[(row + 2) * 16 + lrow]);
        float u3 = bf2f(uorg[(row + 3) * 16 + lrow]);
        const float gl = gcs_s[63];
        float vn0 = u0 - accv[0], vn1 = u1 - accv[1];
        float vn2 = u2 - accv[2], vn3 = u3 - accv[3];
        {
            float g0 = gcs_s[row], g1 = gcs_s[row + 1], g2 = gcs_s[row + 2], g3 = gcs_s[row + 3];
            acco[0] *= __expf(g0); acco[1] *= __expf(g1);
            acco[2] *= __expf(g2); acco[3] *= __expf(g3);
            const int eb = ((wv >> 1) * 64 + ((wv & 1) * 2 + (lkg >> 1)) * 16 + lrow) * 8
                         + (lkg & 1) * 4;
            union { ushort u2a[4]; uint2 v; } pa, pb;
            pa.u2a[0] = f2bf(vn0); pa.u2a[1] = f2bf(vn1);
            pa.u2a[2] = f2bf(vn2); pa.u2a[3] = f2bf(vn3);
            pb.u2a[0] = f2bf(vn0 * __expf(gl - g0)); pb.u2a[1] = f2bf(vn1 * __expf(gl - g1));
            pb.u2a[2] = f2bf(vn2 * __expf(gl - g2)); pb.u2a[3] = f2bf(vn3 * __expf(gl - g3));
            *(uint2*)&vnorg[eb] = pa.v;
            *(uint2*)&vnsorg[eb] = pb.v;
        }
        __syncthreads();                 // B2: v_new published (+ prefetch drained)

        // ---- phase 2: o += scores@v_new ; state update ----
#pragma unroll
        for (int ks = 0; ks < 2; ++ks) {
            bf16x8 a_sc = *(const bf16x8*)&scorg[((wv * 2 + ks) * 64 + ln) * 8];
            bf16x8 b_vn = *(const bf16x8*)&vnorg[(ks * 64 + ln) * 8];
            acco = __builtin_amdgcn_mfma_f32_16x16x32_bf16(a_sc, b_vn, acco, 0, 0, 0);
        }
        ushort* op = obuf + (size_t)(s0 + row) * VAL_DIM + h * DVD + d0 + lrow;
        op[0] = f2bf(acco[0]); op[VAL_DIM] = f2bf(acco[1]);
        op[2 * VAL_DIM] = f2bf(acco[2]); op[3 * VAL_DIM] = f2bf(acco[3]);

        const float egl = __expf(gl);
        accS0 *= egl; accS1 *= egl;
#pragma unroll
        for (int ks = 0; ks < 2; ++ks) {
            bf16x8 a_vs = *(const bf16x8*)&vnsorg[(ks * 64 + ln) * 8];
            bf16x8 b_k0 = *(const bf16x8*)&kTorg[(((wv * 2 + 0) * 2 + ks) * 64 + ln) * 8];
            bf16x8 b_k1 = *(const bf16x8*)&kTorg[(((wv * 2 + 1) * 2 + ks) * 64 + ln) * 8];
            accS0 = __builtin_amdgcn_mfma_f32_16x16x32_bf16(a_vs, b_k0, accS0, 0, 0, 0);
            accS1 = __builtin_amdgcn_mfma_f32_16x16x32_bf16(a_vs, b_k1, accS1, 0, 0, 0);
        }
#pragma unroll
        for (int j = 0; j < 4; ++j) {
            storg[(wv * 64 + ((lrow >> 3)) * 16 + lkg * 4 + j) * 8 + (lrow & 7)] = f2bf(accS0[j]);
            storg[(wv * 64 + (2 + (lrow >> 3)) * 16 + lkg * 4 + j) * 8 + (lrow & 7)] = f2bf(accS1[j]);
        }
        __syncthreads();                 // B3: S^T published; stage-buf reads done
    }
#undef PBSTG
}

// ============ RMSNorm * norm_w * silu(z) -> bf16 (bf16 o and z) =============
__global__ __launch_bounds__(256) void norm_kernel(
    const ushort* __restrict__ obuf, const ushort* __restrict__ z,
    const float* __restrict__ nw, ushort* __restrict__ hbuf)
{
    int row = (blockIdx.x * 256 + threadIdx.x) >> 6;
    int lane = threadIdx.x & 63;
    uint ov = *(const uint*)(obuf + (size_t)row * DVD + lane * 2);
    float x0 = bf2f((ushort)ov), x1 = bf2f((ushort)(ov >> 16));
    float ss = x0 * x0 + x1 * x1;
#pragma unroll
    for (int m = 1; m < 64; m <<= 1) ss += __shfl_xor(ss, m, 64);
    float scale = rsqrtf(ss * (1.f / DVD) + 1e-6f);
    uint zv = *(const uint*)(z + (size_t)row * DVD + lane * 2);
    float z0 = bf2f((ushort)zv), z1 = bf2f((ushort)(zv >> 16));
    float2 w2 = *(const float2*)(nw + lane * 2);
    float h0 = x0 * scale * w2.x * silu_f(z0);
    float h1 = x1 * scale * w2.y * silu_f(z1);
    union { ushort u[2]; uint v; } r;
    r.u[0] = f2bf(h0); r.u[1] = f2bf(h1);
    *(uint*)(hbuf + (size_t)row * DVD + lane * 2) = r.v;
}

// ============================================================================
extern "C" void kernel_launch(void* const* d_in, const int* in_sizes, int n_in,
                              void* d_out, int out_size, void* d_ws, size_t ws_size,
                              hipStream_t stream)
{
    (void)in_sizes; (void)n_in; (void)out_size; (void)ws_size;
    const float* x      = (const float*)d_in[0];
    const float* W_qkv  = (const float*)d_in[1];
    const float* W_z    = (const float*)d_in[2];
    const float* W_a    = (const float*)d_in[3];
    const float* W_b    = (const float*)d_in[4];
    const float* conv_w = (const float*)d_in[5];
    const float* dt_b   = (const float*)d_in[6];
    const float* A_log  = (const float*)d_in[7];
    const float* norm_w = (const float*)d_in[8];
    const float* W_out  = (const float*)d_in[9];
    float* out = (float*)d_out;

    // ---- workspace layout (bytes), overlaid by liveness ----
    char* ws = (char*)d_ws;
    // region A @0: mixed_pre f32 (steps 2-4) -> {u bf16, kcd bf16, knT bf16}
    float*  mixed_pre = (float*)(ws);
    ushort* u_buf     = (ushort*)(ws);                  // 16,777,216 (bf16)
    ushort* kcd_buf   = (ushort*)(ws + 33554432);       // 16,777,216
    ushort* knT_buf   = (ushort*)(ws + 50331648);       //  8,388,608
    // region B @67,108,864:
    //   steps 1-2: wqz 50.3MB + xb 8.4MB @117440512
    //   step 4-7 : vbuf f32 33.5MB
    //   step 8+  : obuf bf16 @67108864 ; hbuf @100663296 ; wob @117440512
    ushort* wqz       = (ushort*)(ws + 67108864);
    ushort* xb        = (ushort*)(ws + 117440512);
    float*  vbuf      = (float*)(ws + 67108864);
    ushort* obuf      = (ushort*)(ws + 67108864);
    ushort* hbuf      = (ushort*)(ws + 100663296);
    ushort* wob       = (ushort*)(ws + 117440512);
    // fixed regions
    ushort* z_buf     = (ushort*)(ws + 134217728);      // 16,777,216 (bf16)
    ushort* sc_buf    = (ushort*)(ws + 167772160);      //  8,388,608 (step>=7)
    ushort* wabb      = (ushort*)(ws + 167772160);      //    524,288 (steps 1-3)
    float*  ab_buf    = (float*)(ws + 168296448);       //  1,048,576 (steps 3-5)
    ushort* qnb       = (ushort*)(ws + 176160768);      //  8,388,608
    float*  kn        = (float*)(ws + 184549376);       // 16,777,216
    float*  g_buf     = (float*)(ws + 201326592);       //    262,144
    float*  bet_buf   = (float*)(ws + 201588736);       //    262,144
    float*  gcs_buf   = (float*)(ws + 201850880);       //    262,144

    hipFuncSetAttribute((const void*)phaseA_kernel,
                        hipFuncAttributeMaxDynamicSharedMemorySize, PA_LDS_BYTES);
    hipFuncSetAttribute((const void*)phaseB_kernel,
                        hipFuncAttributeMaxDynamicSharedMemorySize, PB_LDS_BYTES);
    hipFuncSetAttribute((const void*)gemm256_kernel,
                        hipFuncAttributeMaxDynamicSharedMemorySize, G256_LDS_BYTES);
    hipFuncSetAttribute((const void*)gemm128_kernel,
                        hipFuncAttributeMaxDynamicSharedMemorySize, G128_LDS_BYTES);

    dim3 blk(256);
    // 1) casts to bf16 (W_qkv and W_z fused contiguously into wqz)
    cast_kernel<<<(S_LEN * HIDDIM / 8) / 256, blk, 0, stream>>>(x, xb, S_LEN * HIDDIM / 8);
    cast_kernel<<<(CONV_DIM * HIDDIM / 8) / 256, blk, 0, stream>>>(W_qkv, wqz, CONV_DIM * HIDDIM / 8);
    cast_kernel<<<(VAL_DIM * HIDDIM / 8) / 256, blk, 0, stream>>>(W_z, wqz + (size_t)CONV_DIM * HIDDIM, VAL_DIM * HIDDIM / 8);
    cast_ab_kernel<<<(128 * HIDDIM / 8) / 256, blk, 0, stream>>>(W_a, W_b, wabb);
    // 2) fused qkv+z projection (z output bf16)
    gemm256_kernel<<<dim3((CONV_DIM + VAL_DIM) / 256, S_LEN / 128), dim3(512), G256_LDS_BYTES, stream>>>(
        xb, wqz, mixed_pre, (void*)z_buf, HIDDIM, CONV_DIM, CONV_DIM, VAL_DIM, 1);
    // 3) a/b projection
    gemm128_kernel<<<dim3(1, S_LEN / 128), blk, G128_LDS_BYTES, stream>>>(
        xb, wabb, ab_buf, 128, HIDDIM);
    // 4) fused conv+silu+l2norm+v-split
    front_kernel<<<S_LEN, blk, 0, stream>>>(mixed_pre, conv_w, qnb, kn, vbuf);
    // 5) gates
    gb_kernel<<<(S_LEN * NVH) / 256, blk, 0, stream>>>(ab_buf, dt_b, A_log, g_buf, bet_buf);
    // 7) phase A (intra-chunk, blocked-MFMA solve; u -> bf16)
    phaseA_kernel<<<dim3(NCHK, NVH), blk, PA_LDS_BYTES, stream>>>(
        qnb, kn, vbuf, g_buf, bet_buf, u_buf, kcd_buf, sc_buf, gcs_buf, knT_buf);
    // 8) phase B (inter-chunk scan, MFMA, prefetch-pipelined, bf16 o)
    phaseB_kernel<<<dim3(NVH, 8), blk, PB_LDS_BYTES, stream>>>(
        qnb, knT_buf, u_buf, kcd_buf, sc_buf, gcs_buf, obuf);
    // 9) W_out cast (xb dead) + gated RMSNorm -> bf16
    cast_kernel<<<(HIDDIM * VAL_DIM / 8) / 256, blk, 0, stream>>>(W_out, wob, HIDDIM * VAL_DIM / 8);
    norm_kernel<<<(S_LEN * NVH * 64) / 256, blk, 0, stream>>>(obuf, z_buf, norm_w, hbuf);
    // 10) output projection (128^2 triple-buffered BK=32, 256 blocks)
    gemm128_kernel<<<dim3(HIDDIM / 128, S_LEN / 128), blk, G128_LDS_BYTES, stream>>>(
        hbuf, wob, out, HIDDIM, VAL_DIM);
}

// Round 14
// 454.962 us; speedup vs baseline: 1.3101x; 1.0280x over previous
//
#include <hip/hip_runtime.h>
#include <hip/hip_bf16.h>
#include <math.h>

// ---- problem constants ----
#define S_LEN   2048
#define HIDDIM  2048
#define NKH     16
#define NVH     32
#define DKD     128
#define DVD     128
#define CCH     64          // chunk
#define NCHK    32          // S/chunk
#define KEY_DIM 2048
#define VAL_DIM 4096
#define CONV_DIM 8192

#define PA_LDS_BYTES (16384 + 16384 + 32768 + 4096 + 4096 + 256 + 256 + 256)
// phaseB LDS: stage[2] x 29696 us {q 8192, kc 8192, sc 4096, kT 8192, u 1024}
// + storg 2048 + vnorg 1024 + vnsorg 1024 + gcsall 2048 floats
#define PB_LDS_BYTES ((2 * 29696 + 2048 + 1024 + 1024) * 2 + 2048 * 4)  // 135168
// gemm256: 3 bufs x (A 128x32 + B 256x32) bf16 = 3 x 12288 ushorts = 72 KB
#define G256_LDS_BYTES (3 * 12288 * 2)
// gemm128: 3 bufs x (A 128x32 + B 128x32) = 3 x 8192 ushorts = 48 KB
#define G128_LDS_BYTES (3 * 8192 * 2)

typedef __bf16 bf16x8 __attribute__((ext_vector_type(8)));
typedef float f32x4 __attribute__((ext_vector_type(4)));

__device__ __forceinline__ float sigmoid_f(float x) { return 1.f / (1.f + __expf(-x)); }
__device__ __forceinline__ float silu_f(float x) { return x * sigmoid_f(x); }
__device__ __forceinline__ ushort f2bf(float f) {
    unsigned u = __float_as_uint(f);
    u += 0x7fffu + ((u >> 16) & 1u);          // RNE (inputs finite)
    return (ushort)(u >> 16);
}
__device__ __forceinline__ float bf2f(ushort u) {
    return __uint_as_float((unsigned)u << 16);
}

#define GLL(srcp, dstp) __builtin_amdgcn_global_load_lds( \
    (const __attribute__((address_space(1))) void*)(srcp), \
    (__attribute__((address_space(3))) void*)(dstp), 16, 0, 0)

// ==== merged fp32->bf16 cast: x -> xb, W_qkv|W_z -> wqz (one launch) ========
#define NX8  (S_LEN * HIDDIM / 8)                    // 524288
#define NQ8  (CONV_DIM * HIDDIM / 8)                 // 2097152
#define NZ8  (VAL_DIM * HIDDIM / 8)                  // 1048576
__global__ __launch_bounds__(256) void cast3_kernel(
    const float* __restrict__ x, const float* __restrict__ Wq,
    const float* __restrict__ Wz, ushort* __restrict__ xb,
    ushort* __restrict__ wqz)
{
    int t = blockIdx.x * 256 + threadIdx.x;
    const float* src;
    ushort* dst;
    if (t < NX8) { src = x + (size_t)t * 8; dst = xb + (size_t)t * 8; }
    else if (t < NX8 + NQ8) {
        size_t o = (size_t)(t - NX8) * 8;
        src = Wq + o; dst = wqz + o;
    } else {
        size_t o = (size_t)(t - NX8 - NQ8) * 8;
        src = Wz + o; dst = wqz + (size_t)NQ8 * 8 + o;
    }
    float4 v0 = *(const float4*)(src);
    float4 v1 = *(const float4*)(src + 4);
    union { ushort u[8]; uint4 v; } r;
    r.u[0] = f2bf(v0.x); r.u[1] = f2bf(v0.y); r.u[2] = f2bf(v0.z); r.u[3] = f2bf(v0.w);
    r.u[4] = f2bf(v1.x); r.u[5] = f2bf(v1.y); r.u[6] = f2bf(v1.z); r.u[7] = f2bf(v1.w);
    *(uint4*)dst = r.v;
}

// ================= fp32 -> bf16 cast (8 elems/thread) =======================
__global__ __launch_bounds__(256) void cast_kernel(
    const float* __restrict__ in, ushort* __restrict__ out, int n8)
{
    int t = blockIdx.x * 256 + threadIdx.x;
    if (t >= n8) return;
    float4 v0 = *(const float4*)(in + (size_t)t * 8);
    float4 v1 = *(const float4*)(in + (size_t)t * 8 + 4);
    union { ushort u[8]; uint4 v; } r;
    r.u[0] = f2bf(v0.x); r.u[1] = f2bf(v0.y); r.u[2] = f2bf(v0.z); r.u[3] = f2bf(v0.w);
    r.u[4] = f2bf(v1.x); r.u[5] = f2bf(v1.y); r.u[6] = f2bf(v1.z); r.u[7] = f2bf(v1.w);
    *(uint4*)(out + (size_t)t * 8) = r.v;
}

// ====== W_a,W_b -> one padded bf16 weight [128,2048] (rows 64..127 zero) ====
__global__ __launch_bounds__(256) void cast_ab_kernel(
    const float* __restrict__ Wa, const float* __restrict__ Wb, ushort* __restrict__ out)
{
    int t = blockIdx.x * 256 + threadIdx.x;          // 128*2048/8 = 32768 threads
    int row = t >> 8;
    int c8 = (t & 255) * 8;
    union { ushort u[8]; uint4 v; } r;
    if (row < 64) {
        const float* src = (row < 32) ? (Wa + (size_t)row * HIDDIM + c8)
                                      : (Wb + (size_t)(row - 32) * HIDDIM + c8);
        float4 v0 = *(const float4*)(src);
        float4 v1 = *(const float4*)(src + 4);
        r.u[0] = f2bf(v0.x); r.u[1] = f2bf(v0.y); r.u[2] = f2bf(v0.z); r.u[3] = f2bf(v0.w);
        r.u[4] = f2bf(v1.x); r.u[5] = f2bf(v1.y); r.u[6] = f2bf(v1.z); r.u[7] = f2bf(v1.w);
    } else {
        r.u[0] = r.u[1] = r.u[2] = r.u[3] = r.u[4] = r.u[5] = r.u[6] = r.u[7] = 0;
    }
    *(uint4*)(out + (size_t)t * 8) = r.v;
}

// ==== 128x256 triple-buffered counted-vmcnt bf16 GEMM (BK=32), dual out =====
// C0 f32; C1 f32 or bf16 (c1bf16 flag). Block cols < NSPLIT -> C0 else C1.
__global__ __launch_bounds__(512, 2) void gemm256_kernel(
    const ushort* __restrict__ A, const ushort* __restrict__ B,
    float* __restrict__ C0, void* __restrict__ C1,
    int K, int NSPLIT, int ldc0, int ldc1, int c1bf16)
{
    extern __shared__ ushort g2s[];          // [3][A 4096 | B 8192] ushorts
    const int tid = threadIdx.x;
    const int wv = tid >> 6, ln = tid & 63;
    const int wm = wv >> 2, wn = wv & 3;
    const int lrow = ln & 15, lkg = ln >> 4;
    const int bm = blockIdx.y * 128, bn = blockIdx.x * 256;

    int soffA, soffB[2];
    {
        int l = tid & 63;
        soffA = (((tid >> 6) * 16) + (l & 15)) * K + (l >> 4) * 8;
#pragma unroll
        for (int j = 0; j < 2; ++j) {
            int g = tid + j * 512;
            int lg = g & 63;
            soffB[j] = (((g >> 6) * 16) + (lg & 15)) * K + (lg >> 4) * 8;
        }
    }
    const ushort* Abase = A + (size_t)bm * K;
    const ushort* Bbase = B + (size_t)bn * K;

    f32x4 acc[4][4];
#pragma unroll
    for (int m = 0; m < 4; ++m)
#pragma unroll
        for (int n = 0; n < 4; ++n) {
            f32x4 z = {0.f, 0.f, 0.f, 0.f};
            acc[m][n] = z;
        }

#define G256_STAGE(bb, k0) do {                                            \
        ushort* bufA_ = g2s + (bb) * 12288;                                \
        ushort* bufB_ = bufA_ + 4096;                                      \
        GLL(Abase + soffA + (k0), bufA_ + (wv * 64) * 8);                  \
        _Pragma("unroll")                                                  \
        for (int j_ = 0; j_ < 2; ++j_)                                     \
            GLL(Bbase + soffB[j_] + (k0), bufB_ + (j_ * 512 + wv * 64) * 8);\
    } while (0)

    const int T = K >> 5;
    G256_STAGE(0, 0);
    G256_STAGE(1, 32);
    int bb = 0;
    for (int t = 0; t < T; ++t) {
        if (t + 1 < T) {
            asm volatile("s_waitcnt vmcnt(3)" ::: "memory");
        } else {
            asm volatile("s_waitcnt vmcnt(0)" ::: "memory");
        }
        __builtin_amdgcn_s_barrier();
        if (t + 2 < T) G256_STAGE((bb >= 1) ? (bb - 1) : (bb + 2), (t + 2) * 32);
        const ushort* LA = g2s + bb * 12288;
        const ushort* LB = LA + 4096;
        __builtin_amdgcn_s_setprio(1);
        {
            bf16x8 afv[4], bfv[4];
#pragma unroll
            for (int mf = 0; mf < 4; ++mf)
                afv[mf] = *(const bf16x8*)&LA[((wm * 4 + mf) * 64 + ln) * 8];
#pragma unroll
            for (int nf = 0; nf < 4; ++nf)
                bfv[nf] = *(const bf16x8*)&LB[((wn * 4 + nf) * 64 + ln) * 8];
#pragma unroll
            for (int mf = 0; mf < 4; ++mf)
#pragma unroll
                for (int nf = 0; nf < 4; ++nf)
                    acc[mf][nf] = __builtin_amdgcn_mfma_f32_16x16x32_bf16(
                        afv[mf], bfv[nf], acc[mf][nf], 0, 0, 0);
        }
        __builtin_amdgcn_s_setprio(0);
        bb = (bb == 2) ? 0 : bb + 1;
    }
#undef G256_STAGE

    const bool inC1 = (bn >= NSPLIT);
    const int cboff = bn + wn * 64 - (inC1 ? NSPLIT : 0);
    if (!inC1) {
#pragma unroll
        for (int mf = 0; mf < 4; ++mf) {
            const int row0 = bm + wm * 64 + mf * 16 + lkg * 4;
#pragma unroll
            for (int nf = 0; nf < 4; ++nf) {
                float* cp = C0 + (size_t)row0 * ldc0 + cboff + nf * 16 + lrow;
#pragma unroll
                for (int j = 0; j < 4; ++j) cp[(size_t)j * ldc0] = acc[mf][nf][j];
            }
        }
    } else if (!c1bf16) {
        float* C1f = (float*)C1;
#pragma unroll
        for (int mf = 0; mf < 4; ++mf) {
            const int row0 = bm + wm * 64 + mf * 16 + lkg * 4;
#pragma unroll
            for (int nf = 0; nf < 4; ++nf) {
                float* cp = C1f + (size_t)row0 * ldc1 + cboff + nf * 16 + lrow;
#pragma unroll
                for (int j = 0; j < 4; ++j) cp[(size_t)j * ldc1] = acc[mf][nf][j];
            }
        }
    } else {
        ushort* C1b = (ushort*)C1;
#pragma unroll
        for (int mf = 0; mf < 4; ++mf) {
            const int row0 = bm + wm * 64 + mf * 16 + lkg * 4;
#pragma unroll
            for (int nf = 0; nf < 4; ++nf) {
                ushort* cp = C1b + (size_t)row0 * ldc1 + cboff + nf * 16 + lrow;
#pragma unroll
                for (int j = 0; j < 4; ++j) cp[(size_t)j * ldc1] = f2bf(acc[mf][nf][j]);
            }
        }
    }
}

// ======== 128x128 triple-buffered counted-vmcnt bf16 GEMM (BK=32) ===========
__global__ __launch_bounds__(256, 2) void gemm128_kernel(
    const ushort* __restrict__ A, const ushort* __restrict__ B,
    float* __restrict__ C, int N, int K)
{
    extern __shared__ ushort g1s[];          // [3][A 4096 | B 4096] ushorts
    const int tid = threadIdx.x;
    const int wv = tid >> 6, ln = tid & 63;
    const int wm = wv >> 1, wn = wv & 1;
    const int lrow = ln & 15, lkg = ln >> 4;
    const int bm = blockIdx.y * 128, bn = blockIdx.x * 128;

    int soff[2];
#pragma unroll
    for (int j = 0; j < 2; ++j) {
        int g = tid + j * 256;
        int l = g & 63;
        soff[j] = (((g >> 6) * 16) + (l & 15)) * K + (l >> 4) * 8;
    }
    const ushort* Abase = A + (size_t)bm * K;
    const ushort* Bbase = B + (size_t)bn * K;

    f32x4 acc[4][4];
#pragma unroll
    for (int m = 0; m < 4; ++m)
#pragma unroll
        for (int n = 0; n < 4; ++n) {
            f32x4 z = {0.f, 0.f, 0.f, 0.f};
            acc[m][n] = z;
        }

#define G128_STAGE(bb, k0) do {                                            \
        ushort* bufA_ = g1s + (bb) * 8192;                                 \
        ushort* bufB_ = bufA_ + 4096;                                      \
        _Pragma("unroll")                                                  \
        for (int j_ = 0; j_ < 2; ++j_) {                                   \
            GLL(Abase + soff[j_] + (k0), bufA_ + (j_ * 256 + wv * 64) * 8);\
            GLL(Bbase + soff[j_] + (k0), bufB_ + (j_ * 256 + wv * 64) * 8);\
        }                                                                  \
    } while (0)

    const int T = K >> 5;
    G128_STAGE(0, 0);
    G128_STAGE(1, 32);
    int bb = 0;
    for (int t = 0; t < T; ++t) {
        if (t + 1 < T) {
            asm volatile("s_waitcnt vmcnt(4)" ::: "memory");
        } else {
            asm volatile("s_waitcnt vmcnt(0)" ::: "memory");
        }
        __builtin_amdgcn_s_barrier();
        if (t + 2 < T) G128_STAGE((bb >= 1) ? (bb - 1) : (bb + 2), (t + 2) * 32);
        const ushort* LA = g1s + bb * 8192;
        const ushort* LB = LA + 4096;
        __builtin_amdgcn_s_setprio(1);
        {
            bf16x8 afv[4], bfv[4];
#pragma unroll
            for (int mf = 0; mf < 4; ++mf)
                afv[mf] = *(const bf16x8*)&LA[((wm * 4 + mf) * 64 + ln) * 8];
#pragma unroll
            for (int nf = 0; nf < 4; ++nf)
                bfv[nf] = *(const bf16x8*)&LB[((wn * 4 + nf) * 64 + ln) * 8];
#pragma unroll
            for (int mf = 0; mf < 4; ++mf)
#pragma unroll
                for (int nf = 0; nf < 4; ++nf)
                    acc[mf][nf] = __builtin_amdgcn_mfma_f32_16x16x32_bf16(
                        afv[mf], bfv[nf], acc[mf][nf], 0, 0, 0);
        }
        __builtin_amdgcn_s_setprio(0);
        bb = (bb == 2) ? 0 : bb + 1;
    }
#undef G128_STAGE

#pragma unroll
    for (int mf = 0; mf < 4; ++mf) {
        const int row0 = bm + wm * 64 + mf * 16 + lkg * 4;
#pragma unroll
        for (int nf = 0; nf < 4; ++nf) {
            float* cp = C + (size_t)row0 * N + bn + wn * 64 + nf * 16 + lrow;
#pragma unroll
            for (int j = 0; j < 4; ++j) cp[(size_t)j * N] = acc[mf][nf][j];
        }
    }
}

// ===== fused front: conv1d(K=4)+SiLU + q/k L2norm + v split, 1 block/row ====
// writes qnb bf16, knb bf16, vbuf bf16 (compact 4096).
__global__ __launch_bounds__(256) void front_kernel(
    const float* __restrict__ pre, const float* __restrict__ cw,
    ushort* __restrict__ qnb, ushort* __restrict__ knb, ushort* __restrict__ vbuf)
{
    __shared__ float stage[4096];
    __shared__ float sums[32];
    __shared__ float scal[32];
    const int s = blockIdx.x;
    const int tid = threadIdx.x;

#pragma unroll
    for (int cg = 0; cg < 8; ++cg) {
        const int c = cg * 1024 + tid * 4;
        float w[4][4];
#pragma unroll
        for (int j = 0; j < 4; ++j) {
            float4 wj = *(const float4*)(cw + (size_t)(c + j) * 4);
            w[j][0] = wj.x; w[j][1] = wj.y; w[j][2] = wj.z; w[j][3] = wj.w;
        }
        float a0 = 0.f, a1 = 0.f, a2 = 0.f, a3 = 0.f;
#pragma unroll
        for (int t = 0; t < 4; ++t) {
            int ss = s - 3 + t;
            if (ss >= 0) {
                float4 x = *(const float4*)(pre + (size_t)ss * CONV_DIM + c);
                a0 = fmaf(x.x, w[0][t], a0);
                a1 = fmaf(x.y, w[1][t], a1);
                a2 = fmaf(x.z, w[2][t], a2);
                a3 = fmaf(x.w, w[3][t], a3);
            }
        }
        a0 = silu_f(a0); a1 = silu_f(a1); a2 = silu_f(a2); a3 = silu_f(a3);
        if (cg < 4) {
            float4 v4 = make_float4(a0, a1, a2, a3);
            *(float4*)&stage[c] = v4;
            float ss2 = a0 * a0 + a1 * a1 + a2 * a2 + a3 * a3;
#pragma unroll
            for (int m = 1; m < 32; m <<= 1) ss2 += __shfl_xor(ss2, m, 32);
            if ((tid & 31) == 0) sums[c >> 7] = ss2;
        } else {
            union { ushort u2[4]; uint2 v; } p;
            p.u2[0] = f2bf(a0); p.u2[1] = f2bf(a1);
            p.u2[2] = f2bf(a2); p.u2[3] = f2bf(a3);
            *(uint2*)(vbuf + (size_t)s * VAL_DIM + (c - 4096)) = p.v;
        }
    }
    __syncthreads();
    if (tid < 32) {
        float sc = rsqrtf(sums[tid] + 1e-6f);
        if (tid < 16) sc *= 0.08838834764831843f;     // q: DK^-0.5
        scal[tid] = sc;
    }
    __syncthreads();
#pragma unroll
    for (int j = 0; j < 4; ++j) {
        const int c = j * 1024 + tid * 4;
        float4 v4 = *(const float4*)&stage[c];
        const float sc = scal[c >> 7];
        union { ushort u2[4]; uint2 v; } p;
        p.u2[0] = f2bf(v4.x * sc); p.u2[1] = f2bf(v4.y * sc);
        p.u2[2] = f2bf(v4.z * sc); p.u2[3] = f2bf(v4.w * sc);
        if (c < 2048)
            *(uint2*)(qnb + ((size_t)(s * NKH + (c >> 7))) * DKD + (c & 127)) = p.v;
        else
            *(uint2*)(knb + ((size_t)(s * NKH + ((c >> 7) - 16))) * DKD + (c & 127)) = p.v;
    }
}

// ====== g = -exp(A_log)*softplus(a+dt_bias), beta = sigmoid(b) ==============
__global__ __launch_bounds__(256) void gb_kernel(
    const float* __restrict__ ab, const float* __restrict__ dt_bias,
    const float* __restrict__ A_log, float* __restrict__ g, float* __restrict__ beta)
{
    int idx = blockIdx.x * 256 + threadIdx.x;
    int s = idx >> 5, h = idx & 31;
    float av = ab[(size_t)s * 128 + h] + dt_bias[h];
    float sp = (av > 20.f) ? av : log1pf(__expf(av));
    g[idx] = -__expf(A_log[h]) * sp;
    beta[idx] = sigmoid_f(ab[(size_t)s * 128 + 32 + h]);
}

// ================= Phase A: per (head, chunk) intra-chunk work ==============
// outputs: u bf16, kcd bf16, scores bf16, gcs f32, knT bf16 (even h only)
__global__ __launch_bounds__(256) void phaseA_kernel(
    const ushort* __restrict__ qnb, const ushort* __restrict__ knb,
    const ushort* __restrict__ vbuf, const float* __restrict__ gbuf,
    const float* __restrict__ betabuf,
    ushort* __restrict__ u, ushort* __restrict__ kcd,
    ushort* __restrict__ scores, float* __restrict__ gcs_out,
    ushort* __restrict__ knT)
{
    extern __shared__ char pasm[];
    ushort* kb    = (ushort*)(pasm);            // 16KB frag [m4][ks4][64][8]
    ushort* qb    = (ushort*)(pasm + 16384);    // 16KB frag; later P f32[16][256]
    ushort* Xb    = (ushort*)(pasm + 32768);    // 32KB [t2(2)][ct(16)][64][8]
    float*  Adiag = (float*)(pasm + 65536);     // 4KB
    ushort* Ab    = (ushort*)(pasm + 69632);    // 4KB
    float*  gcs_s = (float*)(pasm + 73728);
    float*  bet_s = (float*)(pasm + 73984);
    float*  scK_s = (float*)(pasm + 74240);
    float*  Pf    = (float*)qb;

    const int n = blockIdx.x, h = blockIdx.y, kh = h >> 1;
    const int tid = threadIdx.x;
    const int s0 = n * CCH;
    const int wv = tid >> 6, ln = tid & 63;
    const int lrow = ln & 15, lkg = ln >> 4;

    float xr[64];
    if (tid < 128) {
        const ushort* vp = vbuf + (size_t)s0 * VAL_DIM + h * DVD + tid;
#pragma unroll
        for (int i = 0; i < 64; ++i) xr[i] = bf2f(vp[(size_t)i * VAL_DIM]);
    } else {
        const ushort* kp = knb + ((size_t)s0 * NKH + kh) * DKD + (tid - 128);
#pragma unroll
        for (int i = 0; i < 64; ++i) xr[i] = bf2f(kp[(size_t)i * (NKH * DKD)]);
    }

    {
        uint4 z = {0, 0, 0, 0};
#pragma unroll
        for (int i = 0; i < 8; ++i)
            *(uint4*)&Xb[(i * 256 + tid) * 8] = z;
        *(uint4*)&Ab[tid * 8] = z;
    }

    if (tid < 64) {
        float gv = gbuf[(size_t)(s0 + tid) * NVH + h];
#pragma unroll
        for (int off = 1; off < 64; off <<= 1) {
            float pv = __shfl_up(gv, off, 64);
            if (tid >= off) gv += pv;
        }
        float bv = betabuf[(size_t)(s0 + tid) * NVH + h];
        gcs_s[tid] = gv;
        bet_s[tid] = bv;
        scK_s[tid] = bv * __expf(gv);
        gcs_out[(size_t)h * S_LEN + s0 + tid] = gv;
    }

    {   // stage k and q (both bf16 now -> straight uint4 copies)
        const int r = tid >> 2, c0 = (tid & 3) * 32;
        const int mbase = (((r >> 4) * 4 + (tid & 3)) * 64 + (r & 15)) * 8;
        const ushort* ksrc = knb + ((size_t)(s0 + r) * NKH + kh) * DKD + c0;
        const ushort* qsrc = qnb + ((size_t)(s0 + r) * NKH + kh) * DKD + c0;
#pragma unroll
        for (int j0 = 0; j0 < 4; ++j0) {
            *(uint4*)&kb[mbase + (j0 << 7)] = *(const uint4*)(ksrc + j0 * 8);
            *(uint4*)&qb[mbase + (j0 << 7)] = *(const uint4*)(qsrc + j0 * 8);
        }
    }
    __syncthreads();    // B1

    f32x4 accA[4], accQ[4];
#pragma unroll
    for (int j = 0; j < 4; ++j) {
        f32x4 z = {0.f, 0.f, 0.f, 0.f};
        accA[j] = z; accQ[j] = z;
    }
#pragma unroll
    for (int ks = 0; ks < 4; ++ks) {
        bf16x8 a_k = *(const bf16x8*)&kb[((wv * 4 + ks) * 64 + ln) * 8];
        bf16x8 a_q = *(const bf16x8*)&qb[((wv * 4 + ks) * 64 + ln) * 8];
#pragma unroll
        for (int j = 0; j < 4; ++j) {
            bf16x8 b_k = *(const bf16x8*)&kb[((j * 4 + ks) * 64 + ln) * 8];
            accA[j] = __builtin_amdgcn_mfma_f32_16x16x32_bf16(a_k, b_k, accA[j], 0, 0, 0);
            accQ[j] = __builtin_amdgcn_mfma_f32_16x16x32_bf16(a_q, b_k, accQ[j], 0, 0, 0);
        }
    }
    {
        ushort* scp = scores + (size_t)(h * NCHK + n) * (CCH * CCH);
#pragma unroll
        for (int j = 0; j < 4; ++j) {
            const int c = j * 16 + lrow;
            const float gc = gcs_s[c];
#pragma unroll
            for (int jj = 0; jj < 4; ++jj) {
                const int i = wv * 16 + lkg * 4 + jj;
                const float e = __expf(gcs_s[i] - gc);
                float sv = (i >= c) ? (accQ[j][jj] * e) : 0.f;
                scp[i * CCH + c] = f2bf(sv);
                float aval = (i > c) ? (-bet_s[i] * accA[j][jj] * e) : 0.f;
                if (j == wv) {
                    Adiag[wv * 256 + (i & 15) * 16 + lrow] = aval;
                } else if (j < wv) {
                    const int f = (wv == 1) ? 0 : ((wv == 2) ? 1 : (2 + (j >> 1)));
                    const int lk = ((j & 1) << 4) | lrow;
                    const int lane2 = (i & 15) | ((lk >> 3) << 4);
                    Ab[(f * 64 + lane2) * 8 + (lk & 7)] = f2bf(aval);
                }
            }
        }
    }
    if (tid < 128) {
#pragma unroll
        for (int i4 = 0; i4 < 16; ++i4) {
            float4 b4 = *(const float4*)&bet_s[i4 * 4];
            xr[i4 * 4 + 0] *= b4.x; xr[i4 * 4 + 1] *= b4.y;
            xr[i4 * 4 + 2] *= b4.z; xr[i4 * 4 + 3] *= b4.w;
        }
    } else {
#pragma unroll
        for (int i4 = 0; i4 < 16; ++i4) {
            float4 b4 = *(const float4*)&scK_s[i4 * 4];
            xr[i4 * 4 + 0] *= b4.x; xr[i4 * 4 + 1] *= b4.y;
            xr[i4 * 4 + 2] *= b4.z; xr[i4 * 4 + 3] *= b4.w;
        }
    }
    __syncthreads();    // B2

    const int ct = tid >> 4, lct = tid & 15;
#pragma unroll
    for (int s = 0; s < 4; ++s) {
        float y[16];
        float pr[16];
        if (s > 0) {
#pragma unroll
            for (int r = 0; r < 16; ++r) pr[r] = Pf[r * 256 + tid];
        } else {
#pragma unroll
            for (int r = 0; r < 16; ++r) pr[r] = 0.f;
        }
#pragma unroll
        for (int r = 0; r < 16; ++r) {
            float acc = xr[s * 16 + r] + pr[r];
#pragma unroll
            for (int k4 = 0; k4 < 16; k4 += 4) {
                if (k4 < r) {
                    float4 a4 = *(const float4*)&Adiag[s * 256 + r * 16 + k4];
                    if (k4 + 0 < r) acc = fmaf(a4.x, y[k4 + 0], acc);
                    if (k4 + 1 < r) acc = fmaf(a4.y, y[k4 + 1], acc);
                    if (k4 + 2 < r) acc = fmaf(a4.z, y[k4 + 2], acc);
                    if (k4 + 3 < r) acc = fmaf(a4.w, y[k4 + 3], acc);
                }
            }
            y[r] = acc;
        }
        if (tid < 128) {
            ushort* up = u + (size_t)(h * NCHK + n) * (CCH * DVD) + (s * 16) * DVD + tid;
#pragma unroll
            for (int r = 0; r < 16; ++r) up[r * DVD] = f2bf(y[r]);
        } else {
            ushort* kp = kcd + (size_t)(h * NCHK + n) * (CCH * DKD) + (s * 16) * DKD + (tid - 128);
#pragma unroll
            for (int r = 0; r < 16; ++r) kp[r * DKD] = f2bf(y[r]);
        }
        if (s < 3) {
#pragma unroll
            for (int half = 0; half < 2; ++half) {
                union { ushort us[8]; uint4 v; } p;
#pragma unroll
                for (int e = 0; e < 8; ++e) p.us[e] = f2bf(y[half * 8 + e]);
                const int kg = (s & 1) * 2 + half;
                *(uint4*)&Xb[(((s >> 1) * 16 + ct) * 64 + (kg * 16 + lct)) * 8] = p.v;
            }
            __syncthreads();
            const int snx = s + 1;
            const int nT2 = (snx + 1) >> 1;
            f32x4 accP[4];
#pragma unroll
            for (int ctl = 0; ctl < 4; ++ctl) {
                f32x4 z = {0.f, 0.f, 0.f, 0.f};
                accP[ctl] = z;
            }
#pragma unroll
            for (int t2 = 0; t2 < 2; ++t2) {
                if (t2 < nT2) {
                    const int f = (snx == 1) ? 0 : ((snx == 2) ? 1 : (2 + t2));
                    bf16x8 a = *(const bf16x8*)&Ab[(f * 64 + ln) * 8];
#pragma unroll
                    for (int ctl = 0; ctl < 4; ++ctl) {
                        bf16x8 b = *(const bf16x8*)&Xb[((t2 * 16 + wv * 4 + ctl) * 64 + ln) * 8];
                        accP[ctl] = __builtin_amdgcn_mfma_f32_16x16x32_bf16(a, b, accP[ctl], 0, 0, 0);
                    }
                }
            }
#pragma unroll
            for (int ctl = 0; ctl < 4; ++ctl)
#pragma unroll
                for (int jj = 0; jj < 4; ++jj)
                    Pf[(lkg * 4 + jj) * 256 + wv * 64 + ctl * 16 + lrow] = accP[ctl][jj];
            __syncthreads();
        }
    }

    if (!(h & 1)) {
        const int dk = tid >> 1, ch = (tid & 1) * 32;
        ushort* dst = knT + ((size_t)(kh * NCHK + n) * DKD + dk) * CCH + ch;
        const int kpart = ((dk >> 5) * 64) * 8 + (((dk >> 3) & 3) << 4) * 8 + (dk & 7);
#pragma unroll
        for (int j0 = 0; j0 < 32; j0 += 8) {
            union { ushort us[8]; uint4 v; } p;
#pragma unroll
            for (int j = 0; j < 8; ++j) {
                const int row = ch + j0 + j;
                p.us[j] = kb[((row >> 4) * 4 * 64 + (row & 15)) * 8 + kpart];
            }
            *(uint4*)(dst + j0) = p.v;
        }
    }
}

// ====== Phase B: inter-chunk state scan (MFMA), prefetch-pipelined ==========
__global__ __launch_bounds__(256) void phaseB_kernel(
    const ushort* __restrict__ qnb, const ushort* __restrict__ knT,
    const ushort* __restrict__ u, const ushort* __restrict__ kcd,
    const ushort* __restrict__ sc, const float* __restrict__ gcs,
    ushort* __restrict__ obuf)
{
    extern __shared__ ushort smu[];
    // stage buf b at b*29696: {q 8192, kc 8192, sc 4096, kT 8192, u 1024}
    ushort* storg  = smu + 59392;    // 2048  S^T bf16
    ushort* vnorg  = smu + 61440;    // 1024
    ushort* vnsorg = smu + 62464;    // 1024
    float*  gcsall = (float*)(smu + 63488);  // 2048 floats (8 KB)

    const int h = blockIdx.x;
    const int dvb = blockIdx.y;
    const int d0 = dvb * 16;
    const int kh = h >> 1;
    const int tid = threadIdx.x;
    const int wv = tid >> 6, ln = tid & 63;
    const int lrow = ln & 15, lkg = ln >> 4;

    {   // zero S^T
        uint4 z = {0, 0, 0, 0};
        *(uint4*)&storg[tid * 8] = z;
    }

    const int q_lane  = lrow * (NKH * DKD) + kh * DKD + wv * 32 + lkg * 8;
    const int kc_lane = lrow * DKD + wv * 32 + lkg * 8;
    const int st_lane = ((tid >> 7) * 16 + lrow) * 64 + ((tid >> 6) & 1) * 32 + lkg * 8;
    const int dst_e   = wv * 512;

#define PBSTG(bsel, nn) do {                                                  \
        const ushort* qsrc_  = qnb + (size_t)((nn) * CCH) * (NKH * DKD);      \
        const ushort* kcsrc_ = kcd + (size_t)(h * NCHK + (nn)) * (CCH * DKD); \
        const ushort* scsrc_ = sc  + (size_t)(h * NCHK + (nn)) * (CCH * CCH); \
        const ushort* kTsrc_ = knT + (size_t)(kh * NCHK + (nn)) * (DKD * CCH);\
        const ushort* usrc_  = u   + (size_t)(h * NCHK + (nn)) * (CCH * DVD) + d0; \
        ushort* base_ = smu + (bsel) * 29696;                                 \
        _Pragma("unroll")                                                     \
        for (int r_ = 0; r_ < 4; ++r_) {                                      \
            GLL(qsrc_ + q_lane + r_ * 32768, base_ + r_ * 2048 + dst_e);      \
            GLL(kcsrc_ + kc_lane + r_ * 2048, base_ + 8192 + r_ * 2048 + dst_e); \
            GLL(kTsrc_ + st_lane + r_ * 2048, base_ + 20480 + r_ * 2048 + dst_e); \
        }                                                                     \
        _Pragma("unroll")                                                     \
        for (int r_ = 0; r_ < 2; ++r_)                                        \
            GLL(scsrc_ + st_lane + r_ * 2048, base_ + 16384 + r_ * 2048 + dst_e); \
        if (tid < 128)                                                        \
            GLL(usrc_ + (tid >> 1) * DVD + (tid & 1) * 8, base_ + 28672 + tid * 8); \
    } while (0)

    PBSTG(0, 0);
    {
        float4 g0 = *(const float4*)(gcs + (size_t)h * S_LEN + tid * 8);
        float4 g1 = *(const float4*)(gcs + (size_t)h * S_LEN + tid * 8 + 4);
        *(float4*)&gcsall[tid * 8] = g0;
        *(float4*)&gcsall[tid * 8 + 4] = g1;
    }
    __syncthreads();

    f32x4 accS0 = {0.f, 0.f, 0.f, 0.f}, accS1 = {0.f, 0.f, 0.f, 0.f};

    for (int n = 0; n < NCHK; ++n) {
        const int cur = n & 1;
        if (n + 1 < NCHK) PBSTG(cur ^ 1, n + 1);
        const ushort* qorg  = smu + cur * 29696;
        const ushort* kcorg = qorg + 8192;
        const ushort* scorg = qorg + 16384;
        const ushort* kTorg = qorg + 20480;
        const ushort* uorg  = qorg + 28672;
        const float*  gcs_s = gcsall + n * 64;
        const int s0 = n * CCH;

        f32x4 accv = {0.f, 0.f, 0.f, 0.f};
        f32x4 acco = {0.f, 0.f, 0.f, 0.f};
#pragma unroll
        for (int ks = 0; ks < 4; ++ks) {
            bf16x8 b_st = *(const bf16x8*)&storg[(ks * 64 + ln) * 8];
            bf16x8 a_kc = *(const bf16x8*)&kcorg[((wv * 4 + ks) * 64 + ln) * 8];
            bf16x8 a_q  = *(const bf16x8*)&qorg[((wv * 4 + ks) * 64 + ln) * 8];
            accv = __builtin_amdgcn_mfma_f32_16x16x32_bf16(a_kc, b_st, accv, 0, 0, 0);
            acco = __builtin_amdgcn_mfma_f32_16x16x32_bf16(a_q, b_st, acco, 0, 0, 0);
        }
        const int row = wv * 16 + lkg * 4;
        float u0 = bf2f(uorg[(row + 0) * 16 + lrow]);
        float u1 = bf2f(uorg[(row + 1) * 16 + lrow]);
        float u2 = bf2f(uorg[(row + 2) * 16 + lrow]);
        float u3 = bf2f(uorg[(row + 3) * 16 + lrow]);
        const float gl = gcs_s[63];
        float vn0 = u0 - accv[0], vn1 = u1 - accv[1];
        float vn2 = u2 - accv[2], vn3 = u3 - accv[3];
        {
            float g0 = gcs_s[row], g1 = gcs_s[row + 1], g2 = gcs_s[row + 2], g3 = gcs_s[row + 3];
            acco[0] *= __expf(g0); acco[1] *= __expf(g1);
            acco[2] *= __expf(g2); acco[3] *= __expf(g3);
            const int eb = ((wv >> 1) * 64 + ((wv & 1) * 2 + (lkg >> 1)) * 16 + lrow) * 8
                         + (lkg & 1) * 4;
            union { ushort u2a[4]; uint2 v; } pa, pb;
            pa.u2a[0] = f2bf(vn0); pa.u2a[1] = f2bf(vn1);
            pa.u2a[2] = f2bf(vn2); pa.u2a[3] = f2bf(vn3);
            pb.u2a[0] = f2bf(vn0 * __expf(gl - g0)); pb.u2a[1] = f2bf(vn1 * __expf(gl - g1));
            pb.u2a[2] = f2bf(vn2 * __expf(gl - g2)); pb.u2a[3] = f2bf(vn3 * __expf(gl - g3));
            *(uint2*)&vnorg[eb] = pa.v;
            *(uint2*)&vnsorg[eb] = pb.v;
        }
        __syncthreads();                 // B2: v_new published (+ prefetch drained)

#pragma unroll
        for (int ks = 0; ks < 2; ++ks) {
            bf16x8 a_sc = *(const bf16x8*)&scorg[((wv * 2 + ks) * 64 + ln) * 8];
            bf16x8 b_vn = *(const bf16x8*)&vnorg[(ks * 64 + ln) * 8];
            acco = __builtin_amdgcn_mfma_f32_16x16x32_bf16(a_sc, b_vn, acco, 0, 0, 0);
        }
        ushort* op = obuf + (size_t)(s0 + row) * VAL_DIM + h * DVD + d0 + lrow;
        op[0] = f2bf(acco[0]); op[VAL_DIM] = f2bf(acco[1]);
        op[2 * VAL_DIM] = f2bf(acco[2]); op[3 * VAL_DIM] = f2bf(acco[3]);

        const float egl = __expf(gl);
        accS0 *= egl; accS1 *= egl;
#pragma unroll
        for (int ks = 0; ks < 2; ++ks) {
            bf16x8 a_vs = *(const bf16x8*)&vnsorg[(ks * 64 + ln) * 8];
            bf16x8 b_k0 = *(const bf16x8*)&kTorg[(((wv * 2 + 0) * 2 + ks) * 64 + ln) * 8];
            bf16x8 b_k1 = *(const bf16x8*)&kTorg[(((wv * 2 + 1) * 2 + ks) * 64 + ln) * 8];
            accS0 = __builtin_amdgcn_mfma_f32_16x16x32_bf16(a_vs, b_k0, accS0, 0, 0, 0);
            accS1 = __builtin_amdgcn_mfma_f32_16x16x32_bf16(a_vs, b_k1, accS1, 0, 0, 0);
        }
#pragma unroll
        for (int j = 0; j < 4; ++j) {
            storg[(wv * 64 + ((lrow >> 3)) * 16 + lkg * 4 + j) * 8 + (lrow & 7)] = f2bf(accS0[j]);
            storg[(wv * 64 + (2 + (lrow >> 3)) * 16 + lkg * 4 + j) * 8 + (lrow & 7)] = f2bf(accS1[j]);
        }
        __syncthreads();                 // B3
    }
#undef PBSTG
}

// ============ RMSNorm * norm_w * silu(z) -> bf16 (bf16 o and z) =============
__global__ __launch_bounds__(256) void norm_kernel(
    const ushort* __restrict__ obuf, const ushort* __restrict__ z,
    const float* __restrict__ nw, ushort* __restrict__ hbuf)
{
    int row = (blockIdx.x * 256 + threadIdx.x) >> 6;
    int lane = threadIdx.x & 63;
    uint ov = *(const uint*)(obuf + (size_t)row * DVD + lane * 2);
    float x0 = bf2f((ushort)ov), x1 = bf2f((ushort)(ov >> 16));
    float ss = x0 * x0 + x1 * x1;
#pragma unroll
    for (int m = 1; m < 64; m <<= 1) ss += __shfl_xor(ss, m, 64);
    float scale = rsqrtf(ss * (1.f / DVD) + 1e-6f);
    uint zv = *(const uint*)(z + (size_t)row * DVD + lane * 2);
    float z0 = bf2f((ushort)zv), z1 = bf2f((ushort)(zv >> 16));
    float2 w2 = *(const float2*)(nw + lane * 2);
    float h0 = x0 * scale * w2.x * silu_f(z0);
    float h1 = x1 * scale * w2.y * silu_f(z1);
    union { ushort u[2]; uint v; } r;
    r.u[0] = f2bf(h0); r.u[1] = f2bf(h1);
    *(uint*)(hbuf + (size_t)row * DVD + lane * 2) = r.v;
}

// ============================================================================
extern "C" void kernel_launch(void* const* d_in, const int* in_sizes, int n_in,
                              void* d_out, int out_size, void* d_ws, size_t ws_size,
                              hipStream_t stream)
{
    (void)in_sizes; (void)n_in; (void)out_size; (void)ws_size;
    const float* x      = (const float*)d_in[0];
    const float* W_qkv  = (const float*)d_in[1];
    const float* W_z    = (const float*)d_in[2];
    const float* W_a    = (const float*)d_in[3];
    const float* W_b    = (const float*)d_in[4];
    const float* conv_w = (const float*)d_in[5];
    const float* dt_b   = (const float*)d_in[6];
    const float* A_log  = (const float*)d_in[7];
    const float* norm_w = (const float*)d_in[8];
    const float* W_out  = (const float*)d_in[9];
    float* out = (float*)d_out;

    // ---- workspace layout (bytes), overlaid by liveness ----
    char* ws = (char*)d_ws;
    // region A @0: mixed_pre f32 (steps 2-4) -> {u bf16, kcd bf16, knT bf16}
    float*  mixed_pre = (float*)(ws);
    ushort* u_buf     = (ushort*)(ws);                  // 16,777,216 (bf16)
    ushort* kcd_buf   = (ushort*)(ws + 33554432);       // 16,777,216
    ushort* knT_buf   = (ushort*)(ws + 50331648);       //  8,388,608
    // region B @67,108,864:
    //   steps 1-2: wqz 50.3MB + xb 8.4MB @117440512
    //   step 4-7 : vbuf bf16 16.8MB
    //   step 8+  : obuf bf16 @83886080 ; hbuf @100663296 ; wob @117440512
    ushort* wqz       = (ushort*)(ws + 67108864);
    ushort* xb        = (ushort*)(ws + 117440512);
    ushort* vbuf      = (ushort*)(ws + 67108864);       // 16,777,216 (bf16)
    ushort* obuf      = (ushort*)(ws + 83886080);       // 16,777,216 (bf16)
    ushort* hbuf      = (ushort*)(ws + 100663296);
    ushort* wob       = (ushort*)(ws + 117440512);
    // fixed regions
    ushort* z_buf     = (ushort*)(ws + 134217728);      // 16,777,216 (bf16)
    ushort* sc_buf    = (ushort*)(ws + 167772160);      //  8,388,608 (step>=7)
    ushort* wabb      = (ushort*)(ws + 167772160);      //    524,288 (steps 1-3)
    float*  ab_buf    = (float*)(ws + 168296448);       //  1,048,576 (steps 3-5)
    ushort* qnb       = (ushort*)(ws + 176160768);      //  8,388,608
    ushort* knb       = (ushort*)(ws + 184549376);      //  8,388,608 (bf16)
    float*  g_buf     = (float*)(ws + 201326592);       //    262,144
    float*  bet_buf   = (float*)(ws + 201588736);       //    262,144
    float*  gcs_buf   = (float*)(ws + 201850880);       //    262,144

    hipFuncSetAttribute((const void*)phaseA_kernel,
                        hipFuncAttributeMaxDynamicSharedMemorySize, PA_LDS_BYTES);
    hipFuncSetAttribute((const void*)phaseB_kernel,
                        hipFuncAttributeMaxDynamicSharedMemorySize, PB_LDS_BYTES);
    hipFuncSetAttribute((const void*)gemm256_kernel,
                        hipFuncAttributeMaxDynamicSharedMemorySize, G256_LDS_BYTES);
    hipFuncSetAttribute((const void*)gemm128_kernel,
                        hipFuncAttributeMaxDynamicSharedMemorySize, G128_LDS_BYTES);

    dim3 blk(256);
    // 1) merged casts: x->xb, W_qkv|W_z->wqz (one launch) + ab
    cast3_kernel<<<(NX8 + NQ8 + NZ8) / 256, blk, 0, stream>>>(x, W_qkv, W_z, xb, wqz);
    cast_ab_kernel<<<(128 * HIDDIM / 8) / 256, blk, 0, stream>>>(W_a, W_b, wabb);
    // 2) fused qkv+z projection (z output bf16)
    gemm256_kernel<<<dim3((CONV_DIM + VAL_DIM) / 256, S_LEN / 128), dim3(512), G256_LDS_BYTES, stream>>>(
        xb, wqz, mixed_pre, (void*)z_buf, HIDDIM, CONV_DIM, CONV_DIM, VAL_DIM, 1);
    // 3) a/b projection
    gemm128_kernel<<<dim3(1, S_LEN / 128), blk, G128_LDS_BYTES, stream>>>(
        xb, wabb, ab_buf, 128, HIDDIM);
    // 4) fused conv+silu+l2norm+v-split (all outputs bf16)
    front_kernel<<<S_LEN, blk, 0, stream>>>(mixed_pre, conv_w, qnb, knb, vbuf);
    // 5) gates
    gb_kernel<<<(S_LEN * NVH) / 256, blk, 0, stream>>>(ab_buf, dt_b, A_log, g_buf, bet_buf);
    // 7) phase A (intra-chunk, blocked-MFMA solve; bf16 in/out)
    phaseA_kernel<<<dim3(NCHK, NVH), blk, PA_LDS_BYTES, stream>>>(
        qnb, knb, vbuf, g_buf, bet_buf, u_buf, kcd_buf, sc_buf, gcs_buf, knT_buf);
    // 8) phase B (inter-chunk scan, MFMA, prefetch-pipelined, bf16 o)
    phaseB_kernel<<<dim3(NVH, 8), blk, PB_LDS_BYTES, stream>>>(
        qnb, knT_buf, u_buf, kcd_buf, sc_buf, gcs_buf, obuf);
    // 9) W_out cast (xb dead) + gated RMSNorm -> bf16
    cast_kernel<<<(HIDDIM * VAL_DIM / 8) / 256, blk, 0, stream>>>(W_out, wob, HIDDIM * VAL_DIM / 8);
    norm_kernel<<<(S_LEN * NVH * 64) / 256, blk, 0, stream>>>(obuf, z_buf, norm_w, hbuf);
    // 10) output projection (128^2 triple-buffered BK=32, 256 blocks)
    gemm128_kernel<<<dim3(HIDDIM / 128, S_LEN / 128), blk, G128_LDS_BYTES, stream>>>(
        hbuf, wob, out, HIDDIM, VAL_DIM);
}

// Round 15
// 449.562 us; speedup vs baseline: 1.3259x; 1.0120x over previous
//
#include <hip/hip_runtime.h>
#include <hip/hip_bf16.h>
#include <math.h>

// ---- problem constants ----
#define S_LEN   2048
#define HIDDIM  2048
#define NKH     16
#define NVH     32
#define DKD     128
#define DVD     128
#define CCH     64          // chunk
#define NCHK    32          // S/chunk
#define KEY_DIM 2048
#define VAL_DIM 4096
#define CONV_DIM 8192

#define PA_LDS_BYTES (16384 + 16384 + 32768 + 4096 + 4096 + 256 + 256 + 256)
// phaseB LDS: stage[2] x 29696 us {q 8192, kc 8192, sc 4096, kT 8192, u 1024}
// + storg 2048 + vnorg 1024 + vnsorg 1024 + gcsall 2048 floats
#define PB_LDS_BYTES ((2 * 29696 + 2048 + 1024 + 1024) * 2 + 2048 * 4)  // 135168
// gemm256: 3 bufs x (A 128x32 + B 256x32) bf16 = 3 x 12288 ushorts = 72 KB
#define G256_LDS_BYTES (3 * 12288 * 2)
// gemm128: 3 bufs x (A 128x32 + B 128x32) = 3 x 8192 ushorts = 48 KB
#define G128_LDS_BYTES (3 * 8192 * 2)

typedef __bf16 bf16x8 __attribute__((ext_vector_type(8)));
typedef float f32x4 __attribute__((ext_vector_type(4)));

__device__ __forceinline__ float sigmoid_f(float x) { return 1.f / (1.f + __expf(-x)); }
__device__ __forceinline__ float silu_f(float x) { return x * sigmoid_f(x); }
__device__ __forceinline__ ushort f2bf(float f) {
    unsigned u = __float_as_uint(f);
    u += 0x7fffu + ((u >> 16) & 1u);          // RNE (inputs finite)
    return (ushort)(u >> 16);
}
__device__ __forceinline__ float bf2f(ushort u) {
    return __uint_as_float((unsigned)u << 16);
}

#define GLL(srcp, dstp) __builtin_amdgcn_global_load_lds( \
    (const __attribute__((address_space(1))) void*)(srcp), \
    (__attribute__((address_space(3))) void*)(dstp), 16, 0, 0)

// == merged fp32->bf16 cast: x->xb, W_qkv|W_z->wqz, W_out->wob (one launch) ==
#define NX8  (S_LEN * HIDDIM / 8)                    // 524288
#define NQ8  (CONV_DIM * HIDDIM / 8)                 // 2097152
#define NZ8  (VAL_DIM * HIDDIM / 8)                  // 1048576
#define NW8  (HIDDIM * VAL_DIM / 8)                  // 1048576
__global__ __launch_bounds__(256) void cast4_kernel(
    const float* __restrict__ x, const float* __restrict__ Wq,
    const float* __restrict__ Wz, const float* __restrict__ Wo,
    ushort* __restrict__ xb, ushort* __restrict__ wqz, ushort* __restrict__ wob)
{
    int t = blockIdx.x * 256 + threadIdx.x;
    const float* src;
    ushort* dst;
    if (t < NX8) { src = x + (size_t)t * 8; dst = xb + (size_t)t * 8; }
    else if (t < NX8 + NQ8) {
        size_t o = (size_t)(t - NX8) * 8;
        src = Wq + o; dst = wqz + o;
    } else if (t < NX8 + NQ8 + NZ8) {
        size_t o = (size_t)(t - NX8 - NQ8) * 8;
        src = Wz + o; dst = wqz + (size_t)NQ8 * 8 + o;
    } else {
        size_t o = (size_t)(t - NX8 - NQ8 - NZ8) * 8;
        src = Wo + o; dst = wob + o;
    }
    float4 v0 = *(const float4*)(src);
    float4 v1 = *(const float4*)(src + 4);
    union { ushort u[8]; uint4 v; } r;
    r.u[0] = f2bf(v0.x); r.u[1] = f2bf(v0.y); r.u[2] = f2bf(v0.z); r.u[3] = f2bf(v0.w);
    r.u[4] = f2bf(v1.x); r.u[5] = f2bf(v1.y); r.u[6] = f2bf(v1.z); r.u[7] = f2bf(v1.w);
    *(uint4*)dst = r.v;
}

// ====== W_a,W_b -> one padded bf16 weight [128,2048] (rows 64..127 zero) ====
__global__ __launch_bounds__(256) void cast_ab_kernel(
    const float* __restrict__ Wa, const float* __restrict__ Wb, ushort* __restrict__ out)
{
    int t = blockIdx.x * 256 + threadIdx.x;          // 128*2048/8 = 32768 threads
    int row = t >> 8;
    int c8 = (t & 255) * 8;
    union { ushort u[8]; uint4 v; } r;
    if (row < 64) {
        const float* src = (row < 32) ? (Wa + (size_t)row * HIDDIM + c8)
                                      : (Wb + (size_t)(row - 32) * HIDDIM + c8);
        float4 v0 = *(const float4*)(src);
        float4 v1 = *(const float4*)(src + 4);
        r.u[0] = f2bf(v0.x); r.u[1] = f2bf(v0.y); r.u[2] = f2bf(v0.z); r.u[3] = f2bf(v0.w);
        r.u[4] = f2bf(v1.x); r.u[5] = f2bf(v1.y); r.u[6] = f2bf(v1.z); r.u[7] = f2bf(v1.w);
    } else {
        r.u[0] = r.u[1] = r.u[2] = r.u[3] = r.u[4] = r.u[5] = r.u[6] = r.u[7] = 0;
    }
    *(uint4*)(out + (size_t)t * 8) = r.v;
}

// ==== 128x256 triple-buffered counted-vmcnt bf16 GEMM (BK=32) ===============
// Both outputs bf16: block cols < NSPLIT -> C0 else C1.
__global__ __launch_bounds__(512, 2) void gemm256_kernel(
    const ushort* __restrict__ A, const ushort* __restrict__ B,
    ushort* __restrict__ C0, ushort* __restrict__ C1,
    int K, int NSPLIT, int ldc0, int ldc1)
{
    extern __shared__ ushort g2s[];          // [3][A 4096 | B 8192] ushorts
    const int tid = threadIdx.x;
    const int wv = tid >> 6, ln = tid & 63;
    const int wm = wv >> 2, wn = wv & 3;
    const int lrow = ln & 15, lkg = ln >> 4;
    const int bm = blockIdx.y * 128, bn = blockIdx.x * 256;

    int soffA, soffB[2];
    {
        int l = tid & 63;
        soffA = (((tid >> 6) * 16) + (l & 15)) * K + (l >> 4) * 8;
#pragma unroll
        for (int j = 0; j < 2; ++j) {
            int g = tid + j * 512;
            int lg = g & 63;
            soffB[j] = (((g >> 6) * 16) + (lg & 15)) * K + (lg >> 4) * 8;
        }
    }
    const ushort* Abase = A + (size_t)bm * K;
    const ushort* Bbase = B + (size_t)bn * K;

    f32x4 acc[4][4];
#pragma unroll
    for (int m = 0; m < 4; ++m)
#pragma unroll
        for (int n = 0; n < 4; ++n) {
            f32x4 z = {0.f, 0.f, 0.f, 0.f};
            acc[m][n] = z;
        }

#define G256_STAGE(bb, k0) do {                                            \
        ushort* bufA_ = g2s + (bb) * 12288;                                \
        ushort* bufB_ = bufA_ + 4096;                                      \
        GLL(Abase + soffA + (k0), bufA_ + (wv * 64) * 8);                  \
        _Pragma("unroll")                                                  \
        for (int j_ = 0; j_ < 2; ++j_)                                     \
            GLL(Bbase + soffB[j_] + (k0), bufB_ + (j_ * 512 + wv * 64) * 8);\
    } while (0)

    const int T = K >> 5;
    G256_STAGE(0, 0);
    G256_STAGE(1, 32);
    int bb = 0;
    for (int t = 0; t < T; ++t) {
        if (t + 1 < T) {
            asm volatile("s_waitcnt vmcnt(3)" ::: "memory");
        } else {
            asm volatile("s_waitcnt vmcnt(0)" ::: "memory");
        }
        __builtin_amdgcn_s_barrier();
        if (t + 2 < T) G256_STAGE((bb >= 1) ? (bb - 1) : (bb + 2), (t + 2) * 32);
        const ushort* LA = g2s + bb * 12288;
        const ushort* LB = LA + 4096;
        __builtin_amdgcn_s_setprio(1);
        {
            bf16x8 afv[4], bfv[4];
#pragma unroll
            for (int mf = 0; mf < 4; ++mf)
                afv[mf] = *(const bf16x8*)&LA[((wm * 4 + mf) * 64 + ln) * 8];
#pragma unroll
            for (int nf = 0; nf < 4; ++nf)
                bfv[nf] = *(const bf16x8*)&LB[((wn * 4 + nf) * 64 + ln) * 8];
#pragma unroll
            for (int mf = 0; mf < 4; ++mf)
#pragma unroll
                for (int nf = 0; nf < 4; ++nf)
                    acc[mf][nf] = __builtin_amdgcn_mfma_f32_16x16x32_bf16(
                        afv[mf], bfv[nf], acc[mf][nf], 0, 0, 0);
        }
        __builtin_amdgcn_s_setprio(0);
        bb = (bb == 2) ? 0 : bb + 1;
    }
#undef G256_STAGE

    const bool inC1 = (bn >= NSPLIT);
    ushort* Cp = inC1 ? C1 : C0;
    const int ldc = inC1 ? ldc1 : ldc0;
    const int cboff = bn + wn * 64 - (inC1 ? NSPLIT : 0);
#pragma unroll
    for (int mf = 0; mf < 4; ++mf) {
        const int row0 = bm + wm * 64 + mf * 16 + lkg * 4;
#pragma unroll
        for (int nf = 0; nf < 4; ++nf) {
            ushort* cp = Cp + (size_t)row0 * ldc + cboff + nf * 16 + lrow;
#pragma unroll
            for (int j = 0; j < 4; ++j) cp[(size_t)j * ldc] = f2bf(acc[mf][nf][j]);
        }
    }
}

// ======== 128x128 triple-buffered counted-vmcnt bf16 GEMM (BK=32) ===========
__global__ __launch_bounds__(256, 2) void gemm128_kernel(
    const ushort* __restrict__ A, const ushort* __restrict__ B,
    float* __restrict__ C, int N, int K)
{
    extern __shared__ ushort g1s[];          // [3][A 4096 | B 4096] ushorts
    const int tid = threadIdx.x;
    const int wv = tid >> 6, ln = tid & 63;
    const int wm = wv >> 1, wn = wv & 1;
    const int lrow = ln & 15, lkg = ln >> 4;
    const int bm = blockIdx.y * 128, bn = blockIdx.x * 128;

    int soff[2];
#pragma unroll
    for (int j = 0; j < 2; ++j) {
        int g = tid + j * 256;
        int l = g & 63;
        soff[j] = (((g >> 6) * 16) + (l & 15)) * K + (l >> 4) * 8;
    }
    const ushort* Abase = A + (size_t)bm * K;
    const ushort* Bbase = B + (size_t)bn * K;

    f32x4 acc[4][4];
#pragma unroll
    for (int m = 0; m < 4; ++m)
#pragma unroll
        for (int n = 0; n < 4; ++n) {
            f32x4 z = {0.f, 0.f, 0.f, 0.f};
            acc[m][n] = z;
        }

#define G128_STAGE(bb, k0) do {                                            \
        ushort* bufA_ = g1s + (bb) * 8192;                                 \
        ushort* bufB_ = bufA_ + 4096;                                      \
        _Pragma("unroll")                                                  \
        for (int j_ = 0; j_ < 2; ++j_) {                                   \
            GLL(Abase + soff[j_] + (k0), bufA_ + (j_ * 256 + wv * 64) * 8);\
            GLL(Bbase + soff[j_] + (k0), bufB_ + (j_ * 256 + wv * 64) * 8);\
        }                                                                  \
    } while (0)

    const int T = K >> 5;
    G128_STAGE(0, 0);
    G128_STAGE(1, 32);
    int bb = 0;
    for (int t = 0; t < T; ++t) {
        if (t + 1 < T) {
            asm volatile("s_waitcnt vmcnt(4)" ::: "memory");
        } else {
            asm volatile("s_waitcnt vmcnt(0)" ::: "memory");
        }
        __builtin_amdgcn_s_barrier();
        if (t + 2 < T) G128_STAGE((bb >= 1) ? (bb - 1) : (bb + 2), (t + 2) * 32);
        const ushort* LA = g1s + bb * 8192;
        const ushort* LB = LA + 4096;
        __builtin_amdgcn_s_setprio(1);
        {
            bf16x8 afv[4], bfv[4];
#pragma unroll
            for (int mf = 0; mf < 4; ++mf)
                afv[mf] = *(const bf16x8*)&LA[((wm * 4 + mf) * 64 + ln) * 8];
#pragma unroll
            for (int nf = 0; nf < 4; ++nf)
                bfv[nf] = *(const bf16x8*)&LB[((wn * 4 + nf) * 64 + ln) * 8];
#pragma unroll
            for (int mf = 0; mf < 4; ++mf)
#pragma unroll
                for (int nf = 0; nf < 4; ++nf)
                    acc[mf][nf] = __builtin_amdgcn_mfma_f32_16x16x32_bf16(
                        afv[mf], bfv[nf], acc[mf][nf], 0, 0, 0);
        }
        __builtin_amdgcn_s_setprio(0);
        bb = (bb == 2) ? 0 : bb + 1;
    }
#undef G128_STAGE

#pragma unroll
    for (int mf = 0; mf < 4; ++mf) {
        const int row0 = bm + wm * 64 + mf * 16 + lkg * 4;
#pragma unroll
        for (int nf = 0; nf < 4; ++nf) {
            float* cp = C + (size_t)row0 * N + bn + wn * 64 + nf * 16 + lrow;
#pragma unroll
            for (int j = 0; j < 4; ++j) cp[(size_t)j * N] = acc[mf][nf][j];
        }
    }
}

// ===== fused front: conv1d(K=4)+SiLU + q/k L2norm + v split, 1 block/row ====
// reads mixed_pre bf16; writes qnb bf16, knb bf16, vbuf bf16 (compact 4096).
__global__ __launch_bounds__(256) void front_kernel(
    const ushort* __restrict__ pre, const float* __restrict__ cw,
    ushort* __restrict__ qnb, ushort* __restrict__ knb, ushort* __restrict__ vbuf)
{
    __shared__ float stage[4096];
    __shared__ float sums[32];
    __shared__ float scal[32];
    const int s = blockIdx.x;
    const int tid = threadIdx.x;

#pragma unroll
    for (int cg = 0; cg < 8; ++cg) {
        const int c = cg * 1024 + tid * 4;
        float w[4][4];
#pragma unroll
        for (int j = 0; j < 4; ++j) {
            float4 wj = *(const float4*)(cw + (size_t)(c + j) * 4);
            w[j][0] = wj.x; w[j][1] = wj.y; w[j][2] = wj.z; w[j][3] = wj.w;
        }
        float a0 = 0.f, a1 = 0.f, a2 = 0.f, a3 = 0.f;
#pragma unroll
        for (int t = 0; t < 4; ++t) {
            int ss = s - 3 + t;
            if (ss >= 0) {
                uint2 xv = *(const uint2*)(pre + (size_t)ss * CONV_DIM + c);
                a0 = fmaf(bf2f((ushort)xv.x), w[0][t], a0);
                a1 = fmaf(bf2f((ushort)(xv.x >> 16)), w[1][t], a1);
                a2 = fmaf(bf2f((ushort)xv.y), w[2][t], a2);
                a3 = fmaf(bf2f((ushort)(xv.y >> 16)), w[3][t], a3);
            }
        }
        a0 = silu_f(a0); a1 = silu_f(a1); a2 = silu_f(a2); a3 = silu_f(a3);
        if (cg < 4) {
            float4 v4 = make_float4(a0, a1, a2, a3);
            *(float4*)&stage[c] = v4;
            float ss2 = a0 * a0 + a1 * a1 + a2 * a2 + a3 * a3;
#pragma unroll
            for (int m = 1; m < 32; m <<= 1) ss2 += __shfl_xor(ss2, m, 32);
            if ((tid & 31) == 0) sums[c >> 7] = ss2;
        } else {
            union { ushort u2[4]; uint2 v; } p;
            p.u2[0] = f2bf(a0); p.u2[1] = f2bf(a1);
            p.u2[2] = f2bf(a2); p.u2[3] = f2bf(a3);
            *(uint2*)(vbuf + (size_t)s * VAL_DIM + (c - 4096)) = p.v;
        }
    }
    __syncthreads();
    if (tid < 32) {
        float sc = rsqrtf(sums[tid] + 1e-6f);
        if (tid < 16) sc *= 0.08838834764831843f;     // q: DK^-0.5
        scal[tid] = sc;
    }
    __syncthreads();
#pragma unroll
    for (int j = 0; j < 4; ++j) {
        const int c = j * 1024 + tid * 4;
        float4 v4 = *(const float4*)&stage[c];
        const float sc = scal[c >> 7];
        union { ushort u2[4]; uint2 v; } p;
        p.u2[0] = f2bf(v4.x * sc); p.u2[1] = f2bf(v4.y * sc);
        p.u2[2] = f2bf(v4.z * sc); p.u2[3] = f2bf(v4.w * sc);
        if (c < 2048)
            *(uint2*)(qnb + ((size_t)(s * NKH + (c >> 7))) * DKD + (c & 127)) = p.v;
        else
            *(uint2*)(knb + ((size_t)(s * NKH + ((c >> 7) - 16))) * DKD + (c & 127)) = p.v;
    }
}

// ====== g = -exp(A_log)*softplus(a+dt_bias), beta = sigmoid(b) ==============
__global__ __launch_bounds__(256) void gb_kernel(
    const float* __restrict__ ab, const float* __restrict__ dt_bias,
    const float* __restrict__ A_log, float* __restrict__ g, float* __restrict__ beta)
{
    int idx = blockIdx.x * 256 + threadIdx.x;
    int s = idx >> 5, h = idx & 31;
    float av = ab[(size_t)s * 128 + h] + dt_bias[h];
    float sp = (av > 20.f) ? av : log1pf(__expf(av));
    g[idx] = -__expf(A_log[h]) * sp;
    beta[idx] = sigmoid_f(ab[(size_t)s * 128 + 32 + h]);
}

// ================= Phase A: per (head, chunk) intra-chunk work ==============
// outputs: u bf16, kcd bf16, scores bf16, gcs f32, knT bf16 (even h only)
__global__ __launch_bounds__(256) void phaseA_kernel(
    const ushort* __restrict__ qnb, const ushort* __restrict__ knb,
    const ushort* __restrict__ vbuf, const float* __restrict__ gbuf,
    const float* __restrict__ betabuf,
    ushort* __restrict__ u, ushort* __restrict__ kcd,
    ushort* __restrict__ scores, float* __restrict__ gcs_out,
    ushort* __restrict__ knT)
{
    extern __shared__ char pasm[];
    ushort* kb    = (ushort*)(pasm);            // 16KB frag [m4][ks4][64][8]
    ushort* qb    = (ushort*)(pasm + 16384);    // 16KB frag; later P f32[16][256]
    ushort* Xb    = (ushort*)(pasm + 32768);    // 32KB [t2(2)][ct(16)][64][8]
    float*  Adiag = (float*)(pasm + 65536);     // 4KB
    ushort* Ab    = (ushort*)(pasm + 69632);    // 4KB
    float*  gcs_s = (float*)(pasm + 73728);
    float*  bet_s = (float*)(pasm + 73984);
    float*  scK_s = (float*)(pasm + 74240);
    float*  Pf    = (float*)qb;

    const int n = blockIdx.x, h = blockIdx.y, kh = h >> 1;
    const int tid = threadIdx.x;
    const int s0 = n * CCH;
    const int wv = tid >> 6, ln = tid & 63;
    const int lrow = ln & 15, lkg = ln >> 4;

    float xr[64];
    if (tid < 128) {
        const ushort* vp = vbuf + (size_t)s0 * VAL_DIM + h * DVD + tid;
#pragma unroll
        for (int i = 0; i < 64; ++i) xr[i] = bf2f(vp[(size_t)i * VAL_DIM]);
    } else {
        const ushort* kp = knb + ((size_t)s0 * NKH + kh) * DKD + (tid - 128);
#pragma unroll
        for (int i = 0; i < 64; ++i) xr[i] = bf2f(kp[(size_t)i * (NKH * DKD)]);
    }

    {
        uint4 z = {0, 0, 0, 0};
#pragma unroll
        for (int i = 0; i < 8; ++i)
            *(uint4*)&Xb[(i * 256 + tid) * 8] = z;
        *(uint4*)&Ab[tid * 8] = z;
    }

    if (tid < 64) {
        float gv = gbuf[(size_t)(s0 + tid) * NVH + h];
#pragma unroll
        for (int off = 1; off < 64; off <<= 1) {
            float pv = __shfl_up(gv, off, 64);
            if (tid >= off) gv += pv;
        }
        float bv = betabuf[(size_t)(s0 + tid) * NVH + h];
        gcs_s[tid] = gv;
        bet_s[tid] = bv;
        scK_s[tid] = bv * __expf(gv);
        gcs_out[(size_t)h * S_LEN + s0 + tid] = gv;
    }

    {   // stage k and q (both bf16 -> straight uint4 copies)
        const int r = tid >> 2, c0 = (tid & 3) * 32;
        const int mbase = (((r >> 4) * 4 + (tid & 3)) * 64 + (r & 15)) * 8;
        const ushort* ksrc = knb + ((size_t)(s0 + r) * NKH + kh) * DKD + c0;
        const ushort* qsrc = qnb + ((size_t)(s0 + r) * NKH + kh) * DKD + c0;
#pragma unroll
        for (int j0 = 0; j0 < 4; ++j0) {
            *(uint4*)&kb[mbase + (j0 << 7)] = *(const uint4*)(ksrc + j0 * 8);
            *(uint4*)&qb[mbase + (j0 << 7)] = *(const uint4*)(qsrc + j0 * 8);
        }
    }
    __syncthreads();    // B1

    f32x4 accA[4], accQ[4];
#pragma unroll
    for (int j = 0; j < 4; ++j) {
        f32x4 z = {0.f, 0.f, 0.f, 0.f};
        accA[j] = z; accQ[j] = z;
    }
#pragma unroll
    for (int ks = 0; ks < 4; ++ks) {
        bf16x8 a_k = *(const bf16x8*)&kb[((wv * 4 + ks) * 64 + ln) * 8];
        bf16x8 a_q = *(const bf16x8*)&qb[((wv * 4 + ks) * 64 + ln) * 8];
#pragma unroll
        for (int j = 0; j < 4; ++j) {
            bf16x8 b_k = *(const bf16x8*)&kb[((j * 4 + ks) * 64 + ln) * 8];
            accA[j] = __builtin_amdgcn_mfma_f32_16x16x32_bf16(a_k, b_k, accA[j], 0, 0, 0);
            accQ[j] = __builtin_amdgcn_mfma_f32_16x16x32_bf16(a_q, b_k, accQ[j], 0, 0, 0);
        }
    }
    {
        ushort* scp = scores + (size_t)(h * NCHK + n) * (CCH * CCH);
#pragma unroll
        for (int j = 0; j < 4; ++j) {
            const int c = j * 16 + lrow;
            const float gc = gcs_s[c];
#pragma unroll
            for (int jj = 0; jj < 4; ++jj) {
                const int i = wv * 16 + lkg * 4 + jj;
                const float e = __expf(gcs_s[i] - gc);
                float sv = (i >= c) ? (accQ[j][jj] * e) : 0.f;
                scp[i * CCH + c] = f2bf(sv);
                float aval = (i > c) ? (-bet_s[i] * accA[j][jj] * e) : 0.f;
                if (j == wv) {
                    Adiag[wv * 256 + (i & 15) * 16 + lrow] = aval;
                } else if (j < wv) {
                    const int f = (wv == 1) ? 0 : ((wv == 2) ? 1 : (2 + (j >> 1)));
                    const int lk = ((j & 1) << 4) | lrow;
                    const int lane2 = (i & 15) | ((lk >> 3) << 4);
                    Ab[(f * 64 + lane2) * 8 + (lk & 7)] = f2bf(aval);
                }
            }
        }
    }
    if (tid < 128) {
#pragma unroll
        for (int i4 = 0; i4 < 16; ++i4) {
            float4 b4 = *(const float4*)&bet_s[i4 * 4];
            xr[i4 * 4 + 0] *= b4.x; xr[i4 * 4 + 1] *= b4.y;
            xr[i4 * 4 + 2] *= b4.z; xr[i4 * 4 + 3] *= b4.w;
        }
    } else {
#pragma unroll
        for (int i4 = 0; i4 < 16; ++i4) {
            float4 b4 = *(const float4*)&scK_s[i4 * 4];
            xr[i4 * 4 + 0] *= b4.x; xr[i4 * 4 + 1] *= b4.y;
            xr[i4 * 4 + 2] *= b4.z; xr[i4 * 4 + 3] *= b4.w;
        }
    }
    __syncthreads();    // B2

    const int ct = tid >> 4, lct = tid & 15;
#pragma unroll
    for (int s = 0; s < 4; ++s) {
        float y[16];
        float pr[16];
        if (s > 0) {
#pragma unroll
            for (int r = 0; r < 16; ++r) pr[r] = Pf[r * 256 + tid];
        } else {
#pragma unroll
            for (int r = 0; r < 16; ++r) pr[r] = 0.f;
        }
#pragma unroll
        for (int r = 0; r < 16; ++r) {
            float acc = xr[s * 16 + r] + pr[r];
#pragma unroll
            for (int k4 = 0; k4 < 16; k4 += 4) {
                if (k4 < r) {
                    float4 a4 = *(const float4*)&Adiag[s * 256 + r * 16 + k4];
                    if (k4 + 0 < r) acc = fmaf(a4.x, y[k4 + 0], acc);
                    if (k4 + 1 < r) acc = fmaf(a4.y, y[k4 + 1], acc);
                    if (k4 + 2 < r) acc = fmaf(a4.z, y[k4 + 2], acc);
                    if (k4 + 3 < r) acc = fmaf(a4.w, y[k4 + 3], acc);
                }
            }
            y[r] = acc;
        }
        if (tid < 128) {
            ushort* up = u + (size_t)(h * NCHK + n) * (CCH * DVD) + (s * 16) * DVD + tid;
#pragma unroll
            for (int r = 0; r < 16; ++r) up[r * DVD] = f2bf(y[r]);
        } else {
            ushort* kp = kcd + (size_t)(h * NCHK + n) * (CCH * DKD) + (s * 16) * DKD + (tid - 128);
#pragma unroll
            for (int r = 0; r < 16; ++r) kp[r * DKD] = f2bf(y[r]);
        }
        if (s < 3) {
#pragma unroll
            for (int half = 0; half < 2; ++half) {
                union { ushort us[8]; uint4 v; } p;
#pragma unroll
                for (int e = 0; e < 8; ++e) p.us[e] = f2bf(y[half * 8 + e]);
                const int kg = (s & 1) * 2 + half;
                *(uint4*)&Xb[(((s >> 1) * 16 + ct) * 64 + (kg * 16 + lct)) * 8] = p.v;
            }
            __syncthreads();
            const int snx = s + 1;
            const int nT2 = (snx + 1) >> 1;
            f32x4 accP[4];
#pragma unroll
            for (int ctl = 0; ctl < 4; ++ctl) {
                f32x4 z = {0.f, 0.f, 0.f, 0.f};
                accP[ctl] = z;
            }
#pragma unroll
            for (int t2 = 0; t2 < 2; ++t2) {
                if (t2 < nT2) {
                    const int f = (snx == 1) ? 0 : ((snx == 2) ? 1 : (2 + t2));
                    bf16x8 a = *(const bf16x8*)&Ab[(f * 64 + ln) * 8];
#pragma unroll
                    for (int ctl = 0; ctl < 4; ++ctl) {
                        bf16x8 b = *(const bf16x8*)&Xb[((t2 * 16 + wv * 4 + ctl) * 64 + ln) * 8];
                        accP[ctl] = __builtin_amdgcn_mfma_f32_16x16x32_bf16(a, b, accP[ctl], 0, 0, 0);
                    }
                }
            }
#pragma unroll
            for (int ctl = 0; ctl < 4; ++ctl)
#pragma unroll
                for (int jj = 0; jj < 4; ++jj)
                    Pf[(lkg * 4 + jj) * 256 + wv * 64 + ctl * 16 + lrow] = accP[ctl][jj];
            __syncthreads();
        }
    }

    if (!(h & 1)) {
        const int dk = tid >> 1, ch = (tid & 1) * 32;
        ushort* dst = knT + ((size_t)(kh * NCHK + n) * DKD + dk) * CCH + ch;
        const int kpart = ((dk >> 5) * 64) * 8 + (((dk >> 3) & 3) << 4) * 8 + (dk & 7);
#pragma unroll
        for (int j0 = 0; j0 < 32; j0 += 8) {
            union { ushort us[8]; uint4 v; } p;
#pragma unroll
            for (int j = 0; j < 8; ++j) {
                const int row = ch + j0 + j;
                p.us[j] = kb[((row >> 4) * 4 * 64 + (row & 15)) * 8 + kpart];
            }
            *(uint4*)(dst + j0) = p.v;
        }
    }
}

// ====== Phase B: inter-chunk state scan (MFMA), prefetch-pipelined ==========
__global__ __launch_bounds__(256) void phaseB_kernel(
    const ushort* __restrict__ qnb, const ushort* __restrict__ knT,
    const ushort* __restrict__ u, const ushort* __restrict__ kcd,
    const ushort* __restrict__ sc, const float* __restrict__ gcs,
    ushort* __restrict__ obuf)
{
    extern __shared__ ushort smu[];
    // stage buf b at b*29696: {q 8192, kc 8192, sc 4096, kT 8192, u 1024}
    ushort* storg  = smu + 59392;    // 2048  S^T bf16
    ushort* vnorg  = smu + 61440;    // 1024
    ushort* vnsorg = smu + 62464;    // 1024
    float*  gcsall = (float*)(smu + 63488);  // 2048 floats (8 KB)

    const int h = blockIdx.x;
    const int dvb = blockIdx.y;
    const int d0 = dvb * 16;
    const int kh = h >> 1;
    const int tid = threadIdx.x;
    const int wv = tid >> 6, ln = tid & 63;
    const int lrow = ln & 15, lkg = ln >> 4;

    {   // zero S^T
        uint4 z = {0, 0, 0, 0};
        *(uint4*)&storg[tid * 8] = z;
    }

    const int q_lane  = lrow * (NKH * DKD) + kh * DKD + wv * 32 + lkg * 8;
    const int kc_lane = lrow * DKD + wv * 32 + lkg * 8;
    const int st_lane = ((tid >> 7) * 16 + lrow) * 64 + ((tid >> 6) & 1) * 32 + lkg * 8;
    const int dst_e   = wv * 512;

#define PBSTG(bsel, nn) do {                                                  \
        const ushort* qsrc_  = qnb + (size_t)((nn) * CCH) * (NKH * DKD);      \
        const ushort* kcsrc_ = kcd + (size_t)(h * NCHK + (nn)) * (CCH * DKD); \
        const ushort* scsrc_ = sc  + (size_t)(h * NCHK + (nn)) * (CCH * CCH); \
        const ushort* kTsrc_ = knT + (size_t)(kh * NCHK + (nn)) * (DKD * CCH);\
        const ushort* usrc_  = u   + (size_t)(h * NCHK + (nn)) * (CCH * DVD) + d0; \
        ushort* base_ = smu + (bsel) * 29696;                                 \
        _Pragma("unroll")                                                     \
        for (int r_ = 0; r_ < 4; ++r_) {                                      \
            GLL(qsrc_ + q_lane + r_ * 32768, base_ + r_ * 2048 + dst_e);      \
            GLL(kcsrc_ + kc_lane + r_ * 2048, base_ + 8192 + r_ * 2048 + dst_e); \
            GLL(kTsrc_ + st_lane + r_ * 2048, base_ + 20480 + r_ * 2048 + dst_e); \
        }                                                                     \
        _Pragma("unroll")                                                     \
        for (int r_ = 0; r_ < 2; ++r_)                                        \
            GLL(scsrc_ + st_lane + r_ * 2048, base_ + 16384 + r_ * 2048 + dst_e); \
        if (tid < 128)                                                        \
            GLL(usrc_ + (tid >> 1) * DVD + (tid & 1) * 8, base_ + 28672 + tid * 8); \
    } while (0)

    PBSTG(0, 0);
    {
        float4 g0 = *(const float4*)(gcs + (size_t)h * S_LEN + tid * 8);
        float4 g1 = *(const float4*)(gcs + (size_t)h * S_LEN + tid * 8 + 4);
        *(float4*)&gcsall[tid * 8] = g0;
        *(float4*)&gcsall[tid * 8 + 4] = g1;
    }
    __syncthreads();

    f32x4 accS0 = {0.f, 0.f, 0.f, 0.f}, accS1 = {0.f, 0.f, 0.f, 0.f};

    for (int n = 0; n < NCHK; ++n) {
        const int cur = n & 1;
        if (n + 1 < NCHK) PBSTG(cur ^ 1, n + 1);
        const ushort* qorg  = smu + cur * 29696;
        const ushort* kcorg = qorg + 8192;
        const ushort* scorg = qorg + 16384;
        const ushort* kTorg = qorg + 20480;
        const ushort* uorg  = qorg + 28672;
        const float*  gcs_s = gcsall + n * 64;
        const int s0 = n * CCH;

        f32x4 accv = {0.f, 0.f, 0.f, 0.f};
        f32x4 acco = {0.f, 0.f, 0.f, 0.f};
#pragma unroll
        for (int ks = 0; ks < 4; ++ks) {
            bf16x8 b_st = *(const bf16x8*)&storg[(ks * 64 + ln) * 8];
            bf16x8 a_kc = *(const bf16x8*)&kcorg[((wv * 4 + ks) * 64 + ln) * 8];
            bf16x8 a_q  = *(const bf16x8*)&qorg[((wv * 4 + ks) * 64 + ln) * 8];
            accv = __builtin_amdgcn_mfma_f32_16x16x32_bf16(a_kc, b_st, accv, 0, 0, 0);
            acco = __builtin_amdgcn_mfma_f32_16x16x32_bf16(a_q, b_st, acco, 0, 0, 0);
        }
        const int row = wv * 16 + lkg * 4;
        float u0 = bf2f(uorg[(row + 0) * 16 + lrow]);
        float u1 = bf2f(uorg[(row + 1) * 16 + lrow]);
        float u2 = bf2f(uorg[(row + 2) * 16 + lrow]);
        float u3 = bf2f(uorg[(row + 3) * 16 + lrow]);
        const float gl = gcs_s[63];
        float vn0 = u0 - accv[0], vn1 = u1 - accv[1];
        float vn2 = u2 - accv[2], vn3 = u3 - accv[3];
        {
            float g0 = gcs_s[row], g1 = gcs_s[row + 1], g2 = gcs_s[row + 2], g3 = gcs_s[row + 3];
            acco[0] *= __expf(g0); acco[1] *= __expf(g1);
            acco[2] *= __expf(g2); acco[3] *= __expf(g3);
            const int eb = ((wv >> 1) * 64 + ((wv & 1) * 2 + (lkg >> 1)) * 16 + lrow) * 8
                         + (lkg & 1) * 4;
            union { ushort u2a[4]; uint2 v; } pa, pb;
            pa.u2a[0] = f2bf(vn0); pa.u2a[1] = f2bf(vn1);
            pa.u2a[2] = f2bf(vn2); pa.u2a[3] = f2bf(vn3);
            pb.u2a[0] = f2bf(vn0 * __expf(gl - g0)); pb.u2a[1] = f2bf(vn1 * __expf(gl - g1));
            pb.u2a[2] = f2bf(vn2 * __expf(gl - g2)); pb.u2a[3] = f2bf(vn3 * __expf(gl - g3));
            *(uint2*)&vnorg[eb] = pa.v;
            *(uint2*)&vnsorg[eb] = pb.v;
        }
        __syncthreads();                 // B2: v_new published (+ prefetch drained)

#pragma unroll
        for (int ks = 0; ks < 2; ++ks) {
            bf16x8 a_sc = *(const bf16x8*)&scorg[((wv * 2 + ks) * 64 + ln) * 8];
            bf16x8 b_vn = *(const bf16x8*)&vnorg[(ks * 64 + ln) * 8];
            acco = __builtin_amdgcn_mfma_f32_16x16x32_bf16(a_sc, b_vn, acco, 0, 0, 0);
        }
        ushort* op = obuf + (size_t)(s0 + row) * VAL_DIM + h * DVD + d0 + lrow;
        op[0] = f2bf(acco[0]); op[VAL_DIM] = f2bf(acco[1]);
        op[2 * VAL_DIM] = f2bf(acco[2]); op[3 * VAL_DIM] = f2bf(acco[3]);

        const float egl = __expf(gl);
        accS0 *= egl; accS1 *= egl;
#pragma unroll
        for (int ks = 0; ks < 2; ++ks) {
            bf16x8 a_vs = *(const bf16x8*)&vnsorg[(ks * 64 + ln) * 8];
            bf16x8 b_k0 = *(const bf16x8*)&kTorg[(((wv * 2 + 0) * 2 + ks) * 64 + ln) * 8];
            bf16x8 b_k1 = *(const bf16x8*)&kTorg[(((wv * 2 + 1) * 2 + ks) * 64 + ln) * 8];
            accS0 = __builtin_amdgcn_mfma_f32_16x16x32_bf16(a_vs, b_k0, accS0, 0, 0, 0);
            accS1 = __builtin_amdgcn_mfma_f32_16x16x32_bf16(a_vs, b_k1, accS1, 0, 0, 0);
        }
#pragma unroll
        for (int j = 0; j < 4; ++j) {
            storg[(wv * 64 + ((lrow >> 3)) * 16 + lkg * 4 + j) * 8 + (lrow & 7)] = f2bf(accS0[j]);
            storg[(wv * 64 + (2 + (lrow >> 3)) * 16 + lkg * 4 + j) * 8 + (lrow & 7)] = f2bf(accS1[j]);
        }
        __syncthreads();                 // B3
    }
#undef PBSTG
}

// ============ RMSNorm * norm_w * silu(z) -> bf16 (bf16 o and z) =============
__global__ __launch_bounds__(256) void norm_kernel(
    const ushort* __restrict__ obuf, const ushort* __restrict__ z,
    const float* __restrict__ nw, ushort* __restrict__ hbuf)
{
    int row = (blockIdx.x * 256 + threadIdx.x) >> 6;
    int lane = threadIdx.x & 63;
    uint ov = *(const uint*)(obuf + (size_t)row * DVD + lane * 2);
    float x0 = bf2f((ushort)ov), x1 = bf2f((ushort)(ov >> 16));
    float ss = x0 * x0 + x1 * x1;
#pragma unroll
    for (int m = 1; m < 64; m <<= 1) ss += __shfl_xor(ss, m, 64);
    float scale = rsqrtf(ss * (1.f / DVD) + 1e-6f);
    uint zv = *(const uint*)(z + (size_t)row * DVD + lane * 2);
    float z0 = bf2f((ushort)zv), z1 = bf2f((ushort)(zv >> 16));
    float2 w2 = *(const float2*)(nw + lane * 2);
    float h0 = x0 * scale * w2.x * silu_f(z0);
    float h1 = x1 * scale * w2.y * silu_f(z1);
    union { ushort u[2]; uint v; } r;
    r.u[0] = f2bf(h0); r.u[1] = f2bf(h1);
    *(uint*)(hbuf + (size_t)row * DVD + lane * 2) = r.v;
}

// ============================================================================
extern "C" void kernel_launch(void* const* d_in, const int* in_sizes, int n_in,
                              void* d_out, int out_size, void* d_ws, size_t ws_size,
                              hipStream_t stream)
{
    (void)in_sizes; (void)n_in; (void)out_size; (void)ws_size;
    const float* x      = (const float*)d_in[0];
    const float* W_qkv  = (const float*)d_in[1];
    const float* W_z    = (const float*)d_in[2];
    const float* W_a    = (const float*)d_in[3];
    const float* W_b    = (const float*)d_in[4];
    const float* conv_w = (const float*)d_in[5];
    const float* dt_b   = (const float*)d_in[6];
    const float* A_log  = (const float*)d_in[7];
    const float* norm_w = (const float*)d_in[8];
    const float* W_out  = (const float*)d_in[9];
    float* out = (float*)d_out;

    // ---- workspace layout (bytes), overlaid by liveness; total ~218.9 MB ---
    char* ws = (char*)d_ws;
    // region A @0: mixed_pre bf16 33.5MB (steps 2-4) -> {u bf16, kcd, knT}
    ushort* mixed_pre = (ushort*)(ws);                  // 33,554,432 (bf16)
    ushort* u_buf     = (ushort*)(ws);                  // 16,777,216 (bf16)
    ushort* kcd_buf   = (ushort*)(ws + 33554432);       // 16,777,216
    ushort* knT_buf   = (ushort*)(ws + 50331648);       //  8,388,608
    // region B @67,108,864:
    //   steps 1-2: wqz 50.3MB + xb 8.4MB @117440512
    //   step 4-7 : vbuf bf16 16.8MB
    //   step 8+  : obuf bf16 @83886080 ; hbuf @100663296
    ushort* wqz       = (ushort*)(ws + 67108864);
    ushort* xb        = (ushort*)(ws + 117440512);
    ushort* vbuf      = (ushort*)(ws + 67108864);       // 16,777,216 (bf16)
    ushort* obuf      = (ushort*)(ws + 83886080);       // 16,777,216 (bf16)
    ushort* hbuf      = (ushort*)(ws + 100663296);
    // fixed regions
    ushort* z_buf     = (ushort*)(ws + 134217728);      // 16,777,216 (bf16)
    ushort* sc_buf    = (ushort*)(ws + 167772160);      //  8,388,608 (step>=7)
    ushort* wabb      = (ushort*)(ws + 167772160);      //    524,288 (steps 1-3)
    float*  ab_buf    = (float*)(ws + 168296448);       //  1,048,576 (steps 3-5)
    ushort* qnb       = (ushort*)(ws + 176160768);      //  8,388,608
    ushort* knb       = (ushort*)(ws + 184549376);      //  8,388,608 (bf16)
    float*  g_buf     = (float*)(ws + 201326592);       //    262,144
    float*  bet_buf   = (float*)(ws + 201588736);       //    262,144
    float*  gcs_buf   = (float*)(ws + 201850880);       //    262,144
    ushort* wob       = (ushort*)(ws + 202113024);      // 16,777,216 -> 218.9MB

    hipFuncSetAttribute((const void*)phaseA_kernel,
                        hipFuncAttributeMaxDynamicSharedMemorySize, PA_LDS_BYTES);
    hipFuncSetAttribute((const void*)phaseB_kernel,
                        hipFuncAttributeMaxDynamicSharedMemorySize, PB_LDS_BYTES);
    hipFuncSetAttribute((const void*)gemm256_kernel,
                        hipFuncAttributeMaxDynamicSharedMemorySize, G256_LDS_BYTES);
    hipFuncSetAttribute((const void*)gemm128_kernel,
                        hipFuncAttributeMaxDynamicSharedMemorySize, G128_LDS_BYTES);

    dim3 blk(256);
    // 1) merged casts: x->xb, W_qkv|W_z->wqz, W_out->wob (one launch) + ab
    cast4_kernel<<<(NX8 + NQ8 + NZ8 + NW8) / 256, blk, 0, stream>>>(
        x, W_qkv, W_z, W_out, xb, wqz, wob);
    cast_ab_kernel<<<(128 * HIDDIM / 8) / 256, blk, 0, stream>>>(W_a, W_b, wabb);
    // 2) fused qkv+z projection (both outputs bf16)
    gemm256_kernel<<<dim3((CONV_DIM + VAL_DIM) / 256, S_LEN / 128), dim3(512), G256_LDS_BYTES, stream>>>(
        xb, wqz, mixed_pre, z_buf, HIDDIM, CONV_DIM, CONV_DIM, VAL_DIM);
    // 3) a/b projection
    gemm128_kernel<<<dim3(1, S_LEN / 128), blk, G128_LDS_BYTES, stream>>>(
        xb, wabb, ab_buf, 128, HIDDIM);
    // 4) fused conv+silu+l2norm+v-split (bf16 in/out)
    front_kernel<<<S_LEN, blk, 0, stream>>>(mixed_pre, conv_w, qnb, knb, vbuf);
    // 5) gates
    gb_kernel<<<(S_LEN * NVH) / 256, blk, 0, stream>>>(ab_buf, dt_b, A_log, g_buf, bet_buf);
    // 7) phase A (intra-chunk, blocked-MFMA solve; bf16 in/out)
    phaseA_kernel<<<dim3(NCHK, NVH), blk, PA_LDS_BYTES, stream>>>(
        qnb, knb, vbuf, g_buf, bet_buf, u_buf, kcd_buf, sc_buf, gcs_buf, knT_buf);
    // 8) phase B (inter-chunk scan, MFMA, prefetch-pipelined, bf16 o)
    phaseB_kernel<<<dim3(NVH, 8), blk, PB_LDS_BYTES, stream>>>(
        qnb, knT_buf, u_buf, kcd_buf, sc_buf, gcs_buf, obuf);
    // 9) gated RMSNorm -> bf16
    norm_kernel<<<(S_LEN * NVH * 64) / 256, blk, 0, stream>>>(obuf, z_buf, norm_w, hbuf);
    // 10) output projection (128^2 triple-buffered BK=32, 256 blocks)
    gemm128_kernel<<<dim3(HIDDIM / 128, S_LEN / 128), blk, G128_LDS_BYTES, stream>>>(
        hbuf, wob, out, HIDDIM, VAL_DIM);
}

// Round 16
// 440.917 us; speedup vs baseline: 1.3519x; 1.0196x over previous
//
#include <hip/hip_runtime.h>
#include <hip/hip_bf16.h>
#include <math.h>

// ---- problem constants ----
#define S_LEN   2048
#define HIDDIM  2048
#define NKH     16
#define NVH     32
#define DKD     128
#define DVD     128
#define CCH     64          // chunk
#define NCHK    32          // S/chunk
#define KEY_DIM 2048
#define VAL_DIM 4096
#define CONV_DIM 8192

#define PA_LDS_BYTES (16384 + 16384 + 32768 + 4096 + 4096 + 256 + 256 + 256)
#define PB_LDS_BYTES ((2 * 29696 + 2048 + 1024 + 1024) * 2 + 2048 * 4)  // 135168
// gemm256: 3 bufs x (A 256x32 + B 256x32) bf16 = 3 x 16384 ushorts = 96 KB
#define G256_LDS_BYTES (3 * 16384 * 2)
// gemm128: 3 bufs x (A 128x32 + B 128x32) = 3 x 8192 ushorts = 48 KB
#define G128_LDS_BYTES (3 * 8192 * 2)

typedef __bf16 bf16x8 __attribute__((ext_vector_type(8)));
typedef float f32x4 __attribute__((ext_vector_type(4)));

__device__ __forceinline__ float sigmoid_f(float x) { return 1.f / (1.f + __expf(-x)); }
__device__ __forceinline__ float silu_f(float x) { return x * sigmoid_f(x); }
__device__ __forceinline__ ushort f2bf(float f) {
    unsigned u = __float_as_uint(f);
    u += 0x7fffu + ((u >> 16) & 1u);          // RNE (inputs finite)
    return (ushort)(u >> 16);
}
__device__ __forceinline__ float bf2f(ushort u) {
    return __uint_as_float((unsigned)u << 16);
}

#define GLL(srcp, dstp) __builtin_amdgcn_global_load_lds( \
    (const __attribute__((address_space(1))) void*)(srcp), \
    (__attribute__((address_space(3))) void*)(dstp), 16, 0, 0)

// == merged fp32->bf16 cast: x->xb, W_qkv|W_z->wqz, W_out->wob (one launch) ==
#define NX8  (S_LEN * HIDDIM / 8)                    // 524288
#define NQ8  (CONV_DIM * HIDDIM / 8)                 // 2097152
#define NZ8  (VAL_DIM * HIDDIM / 8)                  // 1048576
#define NW8  (HIDDIM * VAL_DIM / 8)                  // 1048576
__global__ __launch_bounds__(256) void cast4_kernel(
    const float* __restrict__ x, const float* __restrict__ Wq,
    const float* __restrict__ Wz, const float* __restrict__ Wo,
    ushort* __restrict__ xb, ushort* __restrict__ wqz, ushort* __restrict__ wob)
{
    int t = blockIdx.x * 256 + threadIdx.x;
    const float* src;
    ushort* dst;
    if (t < NX8) { src = x + (size_t)t * 8; dst = xb + (size_t)t * 8; }
    else if (t < NX8 + NQ8) {
        size_t o = (size_t)(t - NX8) * 8;
        src = Wq + o; dst = wqz + o;
    } else if (t < NX8 + NQ8 + NZ8) {
        size_t o = (size_t)(t - NX8 - NQ8) * 8;
        src = Wz + o; dst = wqz + (size_t)NQ8 * 8 + o;
    } else {
        size_t o = (size_t)(t - NX8 - NQ8 - NZ8) * 8;
        src = Wo + o; dst = wob + o;
    }
    float4 v0 = *(const float4*)(src);
    float4 v1 = *(const float4*)(src + 4);
    union { ushort u[8]; uint4 v; } r;
    r.u[0] = f2bf(v0.x); r.u[1] = f2bf(v0.y); r.u[2] = f2bf(v0.z); r.u[3] = f2bf(v0.w);
    r.u[4] = f2bf(v1.x); r.u[5] = f2bf(v1.y); r.u[6] = f2bf(v1.z); r.u[7] = f2bf(v1.w);
    *(uint4*)dst = r.v;
}

// ====== W_a,W_b -> one padded bf16 weight [128,2048] (rows 64..127 zero) ====
__global__ __launch_bounds__(256) void cast_ab_kernel(
    const float* __restrict__ Wa, const float* __restrict__ Wb, ushort* __restrict__ out)
{
    int t = blockIdx.x * 256 + threadIdx.x;          // 128*2048/8 = 32768 threads
    int row = t >> 8;
    int c8 = (t & 255) * 8;
    union { ushort u[8]; uint4 v; } r;
    if (row < 64) {
        const float* src = (row < 32) ? (Wa + (size_t)row * HIDDIM + c8)
                                      : (Wb + (size_t)(row - 32) * HIDDIM + c8);
        float4 v0 = *(const float4*)(src);
        float4 v1 = *(const float4*)(src + 4);
        r.u[0] = f2bf(v0.x); r.u[1] = f2bf(v0.y); r.u[2] = f2bf(v0.z); r.u[3] = f2bf(v0.w);
        r.u[4] = f2bf(v1.x); r.u[5] = f2bf(v1.y); r.u[6] = f2bf(v1.z); r.u[7] = f2bf(v1.w);
    } else {
        r.u[0] = r.u[1] = r.u[2] = r.u[3] = r.u[4] = r.u[5] = r.u[6] = r.u[7] = 0;
    }
    *(uint4*)(out + (size_t)t * 8) = r.v;
}

// ==== 256x256 triple-buffered counted-vmcnt bf16 GEMM, 64x128 wave tile =====
// 512 thr = 8 waves (4M x 2N), acc[4][8] -> 0.375 fragment-reads/MFMA
// (was 0.5): cuts per-CU LDS read pressure 25%. Schedule identical to the
// proven triple-buffer: tile t computes buf t%3, tile t+2 staged during t,
// top-of-tile wait vmcnt(4). Both outputs bf16; cols < NSPLIT -> C0 else C1.
__global__ __launch_bounds__(512, 1) void gemm256_kernel(
    const ushort* __restrict__ A, const ushort* __restrict__ B,
    ushort* __restrict__ C0, ushort* __restrict__ C1,
    int K, int NSPLIT, int ldc0, int ldc1)
{
    extern __shared__ ushort g2s[];          // [3][A 8192 | B 8192] ushorts
    const int tid = threadIdx.x;
    const int wv = tid >> 6, ln = tid & 63;
    const int wm = wv >> 1, wn = wv & 1;
    const int lrow = ln & 15, lkg = ln >> 4;
    const int bm = blockIdx.y * 256, bn = blockIdx.x * 256;

    // staging: granule g -> frag=g>>6, l=g&63 -> elem (frag*16+(l&15), (l>>4)*8)
    // per thread: granules tid and tid+512 (1024 granules per matrix)
    int soff[2];
#pragma unroll
    for (int j = 0; j < 2; ++j) {
        int g = tid + j * 512;
        int l = g & 63;
        soff[j] = (((g >> 6) * 16) + (l & 15)) * K + (l >> 4) * 8;
    }
    const ushort* Abase = A + (size_t)bm * K;
    const ushort* Bbase = B + (size_t)bn * K;

    f32x4 acc[4][8];
#pragma unroll
    for (int m = 0; m < 4; ++m)
#pragma unroll
        for (int n = 0; n < 8; ++n) {
            f32x4 z = {0.f, 0.f, 0.f, 0.f};
            acc[m][n] = z;
        }

#define G256_STAGE(bb, k0) do {                                            \
        ushort* bufA_ = g2s + (bb) * 16384;                                \
        ushort* bufB_ = bufA_ + 8192;                                      \
        _Pragma("unroll")                                                  \
        for (int j_ = 0; j_ < 2; ++j_) {                                   \
            GLL(Abase + soff[j_] + (k0), bufA_ + (j_ * 512 + wv * 64) * 8);\
            GLL(Bbase + soff[j_] + (k0), bufB_ + (j_ * 512 + wv * 64) * 8);\
        }                                                                  \
    } while (0)

    const int T = K >> 5;
    G256_STAGE(0, 0);
    G256_STAGE(1, 32);
    int bb = 0;
    for (int t = 0; t < T; ++t) {
        if (t + 1 < T) {
            asm volatile("s_waitcnt vmcnt(4)" ::: "memory");
        } else {
            asm volatile("s_waitcnt vmcnt(0)" ::: "memory");
        }
        __builtin_amdgcn_s_barrier();          // all threads' tile-t loads landed
        // stage target = (bb+2)%3 : 0->2, 1->0, 2->1
        if (t + 2 < T) G256_STAGE((bb >= 1) ? (bb - 1) : (bb + 2), (t + 2) * 32);
        const ushort* LA = g2s + bb * 16384;
        const ushort* LB = LA + 8192;
        __builtin_amdgcn_s_setprio(1);
        {
            bf16x8 afv[4], bfv[8];
#pragma unroll
            for (int mf = 0; mf < 4; ++mf)
                afv[mf] = *(const bf16x8*)&LA[((wm * 4 + mf) * 64 + ln) * 8];
#pragma unroll
            for (int nf = 0; nf < 8; ++nf)
                bfv[nf] = *(const bf16x8*)&LB[((wn * 8 + nf) * 64 + ln) * 8];
#pragma unroll
            for (int mf = 0; mf < 4; ++mf)
#pragma unroll
                for (int nf = 0; nf < 8; ++nf)
                    acc[mf][nf] = __builtin_amdgcn_mfma_f32_16x16x32_bf16(
                        afv[mf], bfv[nf], acc[mf][nf], 0, 0, 0);
        }
        __builtin_amdgcn_s_setprio(0);
        bb = (bb == 2) ? 0 : bb + 1;
    }
#undef G256_STAGE

    const bool inC1 = (bn >= NSPLIT);
    ushort* Cp = inC1 ? C1 : C0;
    const int ldc = inC1 ? ldc1 : ldc0;
    const int cboff = bn + wn * 128 - (inC1 ? NSPLIT : 0);
#pragma unroll
    for (int mf = 0; mf < 4; ++mf) {
        const int row0 = bm + wm * 64 + mf * 16 + lkg * 4;
#pragma unroll
        for (int nf = 0; nf < 8; ++nf) {
            ushort* cp = Cp + (size_t)row0 * ldc + cboff + nf * 16 + lrow;
#pragma unroll
            for (int j = 0; j < 4; ++j) cp[(size_t)j * ldc] = f2bf(acc[mf][nf][j]);
        }
    }
}

// ======== 128x128 triple-buffered counted-vmcnt bf16 GEMM (BK=32) ===========
__global__ __launch_bounds__(256, 2) void gemm128_kernel(
    const ushort* __restrict__ A, const ushort* __restrict__ B,
    float* __restrict__ C, int N, int K)
{
    extern __shared__ ushort g1s[];          // [3][A 4096 | B 4096] ushorts
    const int tid = threadIdx.x;
    const int wv = tid >> 6, ln = tid & 63;
    const int wm = wv >> 1, wn = wv & 1;
    const int lrow = ln & 15, lkg = ln >> 4;
    const int bm = blockIdx.y * 128, bn = blockIdx.x * 128;

    int soff[2];
#pragma unroll
    for (int j = 0; j < 2; ++j) {
        int g = tid + j * 256;
        int l = g & 63;
        soff[j] = (((g >> 6) * 16) + (l & 15)) * K + (l >> 4) * 8;
    }
    const ushort* Abase = A + (size_t)bm * K;
    const ushort* Bbase = B + (size_t)bn * K;

    f32x4 acc[4][4];
#pragma unroll
    for (int m = 0; m < 4; ++m)
#pragma unroll
        for (int n = 0; n < 4; ++n) {
            f32x4 z = {0.f, 0.f, 0.f, 0.f};
            acc[m][n] = z;
        }

#define G128_STAGE(bb, k0) do {                                            \
        ushort* bufA_ = g1s + (bb) * 8192;                                 \
        ushort* bufB_ = bufA_ + 4096;                                      \
        _Pragma("unroll")                                                  \
        for (int j_ = 0; j_ < 2; ++j_) {                                   \
            GLL(Abase + soff[j_] + (k0), bufA_ + (j_ * 256 + wv * 64) * 8);\
            GLL(Bbase + soff[j_] + (k0), bufB_ + (j_ * 256 + wv * 64) * 8);\
        }                                                                  \
    } while (0)

    const int T = K >> 5;
    G128_STAGE(0, 0);
    G128_STAGE(1, 32);
    int bb = 0;
    for (int t = 0; t < T; ++t) {
        if (t + 1 < T) {
            asm volatile("s_waitcnt vmcnt(4)" ::: "memory");
        } else {
            asm volatile("s_waitcnt vmcnt(0)" ::: "memory");
        }
        __builtin_amdgcn_s_barrier();
        if (t + 2 < T) G128_STAGE((bb >= 1) ? (bb - 1) : (bb + 2), (t + 2) * 32);
        const ushort* LA = g1s + bb * 8192;
        const ushort* LB = LA + 4096;
        __builtin_amdgcn_s_setprio(1);
        {
            bf16x8 afv[4], bfv[4];
#pragma unroll
            for (int mf = 0; mf < 4; ++mf)
                afv[mf] = *(const bf16x8*)&LA[((wm * 4 + mf) * 64 + ln) * 8];
#pragma unroll
            for (int nf = 0; nf < 4; ++nf)
                bfv[nf] = *(const bf16x8*)&LB[((wn * 4 + nf) * 64 + ln) * 8];
#pragma unroll
            for (int mf = 0; mf < 4; ++mf)
#pragma unroll
                for (int nf = 0; nf < 4; ++nf)
                    acc[mf][nf] = __builtin_amdgcn_mfma_f32_16x16x32_bf16(
                        afv[mf], bfv[nf], acc[mf][nf], 0, 0, 0);
        }
        __builtin_amdgcn_s_setprio(0);
        bb = (bb == 2) ? 0 : bb + 1;
    }
#undef G128_STAGE

#pragma unroll
    for (int mf = 0; mf < 4; ++mf) {
        const int row0 = bm + wm * 64 + mf * 16 + lkg * 4;
#pragma unroll
        for (int nf = 0; nf < 4; ++nf) {
            float* cp = C + (size_t)row0 * N + bn + wn * 64 + nf * 16 + lrow;
#pragma unroll
            for (int j = 0; j < 4; ++j) cp[(size_t)j * N] = acc[mf][nf][j];
        }
    }
}

// ===== fused front: conv1d(K=4)+SiLU + q/k L2norm + v split, 1 block/row ====
__global__ __launch_bounds__(256) void front_kernel(
    const ushort* __restrict__ pre, const float* __restrict__ cw,
    ushort* __restrict__ qnb, ushort* __restrict__ knb, ushort* __restrict__ vbuf)
{
    __shared__ float stage[4096];
    __shared__ float sums[32];
    __shared__ float scal[32];
    const int s = blockIdx.x;
    const int tid = threadIdx.x;

#pragma unroll
    for (int cg = 0; cg < 8; ++cg) {
        const int c = cg * 1024 + tid * 4;
        float w[4][4];
#pragma unroll
        for (int j = 0; j < 4; ++j) {
            float4 wj = *(const float4*)(cw + (size_t)(c + j) * 4);
            w[j][0] = wj.x; w[j][1] = wj.y; w[j][2] = wj.z; w[j][3] = wj.w;
        }
        float a0 = 0.f, a1 = 0.f, a2 = 0.f, a3 = 0.f;
#pragma unroll
        for (int t = 0; t < 4; ++t) {
            int ss = s - 3 + t;
            if (ss >= 0) {
                uint2 xv = *(const uint2*)(pre + (size_t)ss * CONV_DIM + c);
                a0 = fmaf(bf2f((ushort)xv.x), w[0][t], a0);
                a1 = fmaf(bf2f((ushort)(xv.x >> 16)), w[1][t], a1);
                a2 = fmaf(bf2f((ushort)xv.y), w[2][t], a2);
                a3 = fmaf(bf2f((ushort)(xv.y >> 16)), w[3][t], a3);
            }
        }
        a0 = silu_f(a0); a1 = silu_f(a1); a2 = silu_f(a2); a3 = silu_f(a3);
        if (cg < 4) {
            float4 v4 = make_float4(a0, a1, a2, a3);
            *(float4*)&stage[c] = v4;
            float ss2 = a0 * a0 + a1 * a1 + a2 * a2 + a3 * a3;
#pragma unroll
            for (int m = 1; m < 32; m <<= 1) ss2 += __shfl_xor(ss2, m, 32);
            if ((tid & 31) == 0) sums[c >> 7] = ss2;
        } else {
            union { ushort u2[4]; uint2 v; } p;
            p.u2[0] = f2bf(a0); p.u2[1] = f2bf(a1);
            p.u2[2] = f2bf(a2); p.u2[3] = f2bf(a3);
            *(uint2*)(vbuf + (size_t)s * VAL_DIM + (c - 4096)) = p.v;
        }
    }
    __syncthreads();
    if (tid < 32) {
        float sc = rsqrtf(sums[tid] + 1e-6f);
        if (tid < 16) sc *= 0.08838834764831843f;     // q: DK^-0.5
        scal[tid] = sc;
    }
    __syncthreads();
#pragma unroll
    for (int j = 0; j < 4; ++j) {
        const int c = j * 1024 + tid * 4;
        float4 v4 = *(const float4*)&stage[c];
        const float sc = scal[c >> 7];
        union { ushort u2[4]; uint2 v; } p;
        p.u2[0] = f2bf(v4.x * sc); p.u2[1] = f2bf(v4.y * sc);
        p.u2[2] = f2bf(v4.z * sc); p.u2[3] = f2bf(v4.w * sc);
        if (c < 2048)
            *(uint2*)(qnb + ((size_t)(s * NKH + (c >> 7))) * DKD + (c & 127)) = p.v;
        else
            *(uint2*)(knb + ((size_t)(s * NKH + ((c >> 7) - 16))) * DKD + (c & 127)) = p.v;
    }
}

// ====== g = -exp(A_log)*softplus(a+dt_bias), beta = sigmoid(b) ==============
__global__ __launch_bounds__(256) void gb_kernel(
    const float* __restrict__ ab, const float* __restrict__ dt_bias,
    const float* __restrict__ A_log, float* __restrict__ g, float* __restrict__ beta)
{
    int idx = blockIdx.x * 256 + threadIdx.x;
    int s = idx >> 5, h = idx & 31;
    float av = ab[(size_t)s * 128 + h] + dt_bias[h];
    float sp = (av > 20.f) ? av : log1pf(__expf(av));
    g[idx] = -__expf(A_log[h]) * sp;
    beta[idx] = sigmoid_f(ab[(size_t)s * 128 + 32 + h]);
}

// ================= Phase A: per (head, chunk) intra-chunk work ==============
// outputs: u bf16, kcd bf16, scores bf16, gcs f32, knT bf16 (even h only)
__global__ __launch_bounds__(256) void phaseA_kernel(
    const ushort* __restrict__ qnb, const ushort* __restrict__ knb,
    const ushort* __restrict__ vbuf, const float* __restrict__ gbuf,
    const float* __restrict__ betabuf,
    ushort* __restrict__ u, ushort* __restrict__ kcd,
    ushort* __restrict__ scores, float* __restrict__ gcs_out,
    ushort* __restrict__ knT)
{
    extern __shared__ char pasm[];
    ushort* kb    = (ushort*)(pasm);            // 16KB frag [m4][ks4][64][8]
    ushort* qb    = (ushort*)(pasm + 16384);    // 16KB frag; later P f32[16][256]
    ushort* Xb    = (ushort*)(pasm + 32768);    // 32KB [t2(2)][ct(16)][64][8]
    float*  Adiag = (float*)(pasm + 65536);     // 4KB
    ushort* Ab    = (ushort*)(pasm + 69632);    // 4KB
    float*  gcs_s = (float*)(pasm + 73728);
    float*  bet_s = (float*)(pasm + 73984);
    float*  scK_s = (float*)(pasm + 74240);
    float*  Pf    = (float*)qb;

    const int n = blockIdx.x, h = blockIdx.y, kh = h >> 1;
    const int tid = threadIdx.x;
    const int s0 = n * CCH;
    const int wv = tid >> 6, ln = tid & 63;
    const int lrow = ln & 15, lkg = ln >> 4;

    float xr[64];
    if (tid < 128) {
        const ushort* vp = vbuf + (size_t)s0 * VAL_DIM + h * DVD + tid;
#pragma unroll
        for (int i = 0; i < 64; ++i) xr[i] = bf2f(vp[(size_t)i * VAL_DIM]);
    } else {
        const ushort* kp = knb + ((size_t)s0 * NKH + kh) * DKD + (tid - 128);
#pragma unroll
        for (int i = 0; i < 64; ++i) xr[i] = bf2f(kp[(size_t)i * (NKH * DKD)]);
    }

    {
        uint4 z = {0, 0, 0, 0};
#pragma unroll
        for (int i = 0; i < 8; ++i)
            *(uint4*)&Xb[(i * 256 + tid) * 8] = z;
        *(uint4*)&Ab[tid * 8] = z;
    }

    if (tid < 64) {
        float gv = gbuf[(size_t)(s0 + tid) * NVH + h];
#pragma unroll
        for (int off = 1; off < 64; off <<= 1) {
            float pv = __shfl_up(gv, off, 64);
            if (tid >= off) gv += pv;
        }
        float bv = betabuf[(size_t)(s0 + tid) * NVH + h];
        gcs_s[tid] = gv;
        bet_s[tid] = bv;
        scK_s[tid] = bv * __expf(gv);
        gcs_out[(size_t)h * S_LEN + s0 + tid] = gv;
    }

    {   // stage k and q (both bf16 -> straight uint4 copies)
        const int r = tid >> 2, c0 = (tid & 3) * 32;
        const int mbase = (((r >> 4) * 4 + (tid & 3)) * 64 + (r & 15)) * 8;
        const ushort* ksrc = knb + ((size_t)(s0 + r) * NKH + kh) * DKD + c0;
        const ushort* qsrc = qnb + ((size_t)(s0 + r) * NKH + kh) * DKD + c0;
#pragma unroll
        for (int j0 = 0; j0 < 4; ++j0) {
            *(uint4*)&kb[mbase + (j0 << 7)] = *(const uint4*)(ksrc + j0 * 8);
            *(uint4*)&qb[mbase + (j0 << 7)] = *(const uint4*)(qsrc + j0 * 8);
        }
    }
    __syncthreads();    // B1

    f32x4 accA[4], accQ[4];
#pragma unroll
    for (int j = 0; j < 4; ++j) {
        f32x4 z = {0.f, 0.f, 0.f, 0.f};
        accA[j] = z; accQ[j] = z;
    }
#pragma unroll
    for (int ks = 0; ks < 4; ++ks) {
        bf16x8 a_k = *(const bf16x8*)&kb[((wv * 4 + ks) * 64 + ln) * 8];
        bf16x8 a_q = *(const bf16x8*)&qb[((wv * 4 + ks) * 64 + ln) * 8];
#pragma unroll
        for (int j = 0; j < 4; ++j) {
            bf16x8 b_k = *(const bf16x8*)&kb[((j * 4 + ks) * 64 + ln) * 8];
            accA[j] = __builtin_amdgcn_mfma_f32_16x16x32_bf16(a_k, b_k, accA[j], 0, 0, 0);
            accQ[j] = __builtin_amdgcn_mfma_f32_16x16x32_bf16(a_q, b_k, accQ[j], 0, 0, 0);
        }
    }
    {
        ushort* scp = scores + (size_t)(h * NCHK + n) * (CCH * CCH);
#pragma unroll
        for (int j = 0; j < 4; ++j) {
            const int c = j * 16 + lrow;
            const float gc = gcs_s[c];
#pragma unroll
            for (int jj = 0; jj < 4; ++jj) {
                const int i = wv * 16 + lkg * 4 + jj;
                const float e = __expf(gcs_s[i] - gc);
                float sv = (i >= c) ? (accQ[j][jj] * e) : 0.f;
                scp[i * CCH + c] = f2bf(sv);
                float aval = (i > c) ? (-bet_s[i] * accA[j][jj] * e) : 0.f;
                if (j == wv) {
                    Adiag[wv * 256 + (i & 15) * 16 + lrow] = aval;
                } else if (j < wv) {
                    const int f = (wv == 1) ? 0 : ((wv == 2) ? 1 : (2 + (j >> 1)));
                    const int lk = ((j & 1) << 4) | lrow;
                    const int lane2 = (i & 15) | ((lk >> 3) << 4);
                    Ab[(f * 64 + lane2) * 8 + (lk & 7)] = f2bf(aval);
                }
            }
        }
    }
    if (tid < 128) {
#pragma unroll
        for (int i4 = 0; i4 < 16; ++i4) {
            float4 b4 = *(const float4*)&bet_s[i4 * 4];
            xr[i4 * 4 + 0] *= b4.x; xr[i4 * 4 + 1] *= b4.y;
            xr[i4 * 4 + 2] *= b4.z; xr[i4 * 4 + 3] *= b4.w;
        }
    } else {
#pragma unroll
        for (int i4 = 0; i4 < 16; ++i4) {
            float4 b4 = *(const float4*)&scK_s[i4 * 4];
            xr[i4 * 4 + 0] *= b4.x; xr[i4 * 4 + 1] *= b4.y;
            xr[i4 * 4 + 2] *= b4.z; xr[i4 * 4 + 3] *= b4.w;
        }
    }
    __syncthreads();    // B2

    const int ct = tid >> 4, lct = tid & 15;
#pragma unroll
    for (int s = 0; s < 4; ++s) {
        float y[16];
        float pr[16];
        if (s > 0) {
#pragma unroll
            for (int r = 0; r < 16; ++r) pr[r] = Pf[r * 256 + tid];
        } else {
#pragma unroll
            for (int r = 0; r < 16; ++r) pr[r] = 0.f;
        }
#pragma unroll
        for (int r = 0; r < 16; ++r) {
            float acc = xr[s * 16 + r] + pr[r];
#pragma unroll
            for (int k4 = 0; k4 < 16; k4 += 4) {
                if (k4 < r) {
                    float4 a4 = *(const float4*)&Adiag[s * 256 + r * 16 + k4];
                    if (k4 + 0 < r) acc = fmaf(a4.x, y[k4 + 0], acc);
                    if (k4 + 1 < r) acc = fmaf(a4.y, y[k4 + 1], acc);
                    if (k4 + 2 < r) acc = fmaf(a4.z, y[k4 + 2], acc);
                    if (k4 + 3 < r) acc = fmaf(a4.w, y[k4 + 3], acc);
                }
            }
            y[r] = acc;
        }
        if (tid < 128) {
            ushort* up = u + (size_t)(h * NCHK + n) * (CCH * DVD) + (s * 16) * DVD + tid;
#pragma unroll
            for (int r = 0; r < 16; ++r) up[r * DVD] = f2bf(y[r]);
        } else {
            ushort* kp = kcd + (size_t)(h * NCHK + n) * (CCH * DKD) + (s * 16) * DKD + (tid - 128);
#pragma unroll
            for (int r = 0; r < 16; ++r) kp[r * DKD] = f2bf(y[r]);
        }
        if (s < 3) {
#pragma unroll
            for (int half = 0; half < 2; ++half) {
                union { ushort us[8]; uint4 v; } p;
#pragma unroll
                for (int e = 0; e < 8; ++e) p.us[e] = f2bf(y[half * 8 + e]);
                const int kg = (s & 1) * 2 + half;
                *(uint4*)&Xb[(((s >> 1) * 16 + ct) * 64 + (kg * 16 + lct)) * 8] = p.v;
            }
            __syncthreads();
            const int snx = s + 1;
            const int nT2 = (snx + 1) >> 1;
            f32x4 accP[4];
#pragma unroll
            for (int ctl = 0; ctl < 4; ++ctl) {
                f32x4 z = {0.f, 0.f, 0.f, 0.f};
                accP[ctl] = z;
            }
#pragma unroll
            for (int t2 = 0; t2 < 2; ++t2) {
                if (t2 < nT2) {
                    const int f = (snx == 1) ? 0 : ((snx == 2) ? 1 : (2 + t2));
                    bf16x8 a = *(const bf16x8*)&Ab[(f * 64 + ln) * 8];
#pragma unroll
                    for (int ctl = 0; ctl < 4; ++ctl) {
                        bf16x8 b = *(const bf16x8*)&Xb[((t2 * 16 + wv * 4 + ctl) * 64 + ln) * 8];
                        accP[ctl] = __builtin_amdgcn_mfma_f32_16x16x32_bf16(a, b, accP[ctl], 0, 0, 0);
                    }
                }
            }
#pragma unroll
            for (int ctl = 0; ctl < 4; ++ctl)
#pragma unroll
                for (int jj = 0; jj < 4; ++jj)
                    Pf[(lkg * 4 + jj) * 256 + wv * 64 + ctl * 16 + lrow] = accP[ctl][jj];
            __syncthreads();
        }
    }

    if (!(h & 1)) {
        const int dk = tid >> 1, ch = (tid & 1) * 32;
        ushort* dst = knT + ((size_t)(kh * NCHK + n) * DKD + dk) * CCH + ch;
        const int kpart = ((dk >> 5) * 64) * 8 + (((dk >> 3) & 3) << 4) * 8 + (dk & 7);
#pragma unroll
        for (int j0 = 0; j0 < 32; j0 += 8) {
            union { ushort us[8]; uint4 v; } p;
#pragma unroll
            for (int j = 0; j < 8; ++j) {
                const int row = ch + j0 + j;
                p.us[j] = kb[((row >> 4) * 4 * 64 + (row & 15)) * 8 + kpart];
            }
            *(uint4*)(dst + j0) = p.v;
        }
    }
}

// ====== Phase B: inter-chunk state scan (MFMA), prefetch-pipelined ==========
__global__ __launch_bounds__(256) void phaseB_kernel(
    const ushort* __restrict__ qnb, const ushort* __restrict__ knT,
    const ushort* __restrict__ u, const ushort* __restrict__ kcd,
    const ushort* __restrict__ sc, const float* __restrict__ gcs,
    ushort* __restrict__ obuf)
{
    extern __shared__ ushort smu[];
    // stage buf b at b*29696: {q 8192, kc 8192, sc 4096, kT 8192, u 1024}
    ushort* storg  = smu + 59392;    // 2048  S^T bf16
    ushort* vnorg  = smu + 61440;    // 1024
    ushort* vnsorg = smu + 62464;    // 1024
    float*  gcsall = (float*)(smu + 63488);  // 2048 floats (8 KB)

    const int h = blockIdx.x;
    const int dvb = blockIdx.y;
    const int d0 = dvb * 16;
    const int kh = h >> 1;
    const int tid = threadIdx.x;
    const int wv = tid >> 6, ln = tid & 63;
    const int lrow = ln & 15, lkg = ln >> 4;

    {   // zero S^T
        uint4 z = {0, 0, 0, 0};
        *(uint4*)&storg[tid * 8] = z;
    }

    const int q_lane  = lrow * (NKH * DKD) + kh * DKD + wv * 32 + lkg * 8;
    const int kc_lane = lrow * DKD + wv * 32 + lkg * 8;
    const int st_lane = ((tid >> 7) * 16 + lrow) * 64 + ((tid >> 6) & 1) * 32 + lkg * 8;
    const int dst_e   = wv * 512;

#define PBSTG(bsel, nn) do {                                                  \
        const ushort* qsrc_  = qnb + (size_t)((nn) * CCH) * (NKH * DKD);      \
        const ushort* kcsrc_ = kcd + (size_t)(h * NCHK + (nn)) * (CCH * DKD); \
        const ushort* scsrc_ = sc  + (size_t)(h * NCHK + (nn)) * (CCH * CCH); \
        const ushort* kTsrc_ = knT + (size_t)(kh * NCHK + (nn)) * (DKD * CCH);\
        const ushort* usrc_  = u   + (size_t)(h * NCHK + (nn)) * (CCH * DVD) + d0; \
        ushort* base_ = smu + (bsel) * 29696;                                 \
        _Pragma("unroll")                                                     \
        for (int r_ = 0; r_ < 4; ++r_) {                                      \
            GLL(qsrc_ + q_lane + r_ * 32768, base_ + r_ * 2048 + dst_e);      \
            GLL(kcsrc_ + kc_lane + r_ * 2048, base_ + 8192 + r_ * 2048 + dst_e); \
            GLL(kTsrc_ + st_lane + r_ * 2048, base_ + 20480 + r_ * 2048 + dst_e); \
        }                                                                     \
        _Pragma("unroll")                                                     \
        for (int r_ = 0; r_ < 2; ++r_)                                        \
            GLL(scsrc_ + st_lane + r_ * 2048, base_ + 16384 + r_ * 2048 + dst_e); \
        if (tid < 128)                                                        \
            GLL(usrc_ + (tid >> 1) * DVD + (tid & 1) * 8, base_ + 28672 + tid * 8); \
    } while (0)

    PBSTG(0, 0);
    {
        float4 g0 = *(const float4*)(gcs + (size_t)h * S_LEN + tid * 8);
        float4 g1 = *(const float4*)(gcs + (size_t)h * S_LEN + tid * 8 + 4);
        *(float4*)&gcsall[tid * 8] = g0;
        *(float4*)&gcsall[tid * 8 + 4] = g1;
    }
    __syncthreads();

    f32x4 accS0 = {0.f, 0.f, 0.f, 0.f}, accS1 = {0.f, 0.f, 0.f, 0.f};

    for (int n = 0; n < NCHK; ++n) {
        const int cur = n & 1;
        if (n + 1 < NCHK) PBSTG(cur ^ 1, n + 1);
        const ushort* qorg  = smu + cur * 29696;
        const ushort* kcorg = qorg + 8192;
        const ushort* scorg = qorg + 16384;
        const ushort* kTorg = qorg + 20480;
        const ushort* uorg  = qorg + 28672;
        const float*  gcs_s = gcsall + n * 64;
        const int s0 = n * CCH;

        f32x4 accv = {0.f, 0.f, 0.f, 0.f};
        f32x4 acco = {0.f, 0.f, 0.f, 0.f};
#pragma unroll
        for (int ks = 0; ks < 4; ++ks) {
            bf16x8 b_st = *(const bf16x8*)&storg[(ks * 64 + ln) * 8];
            bf16x8 a_kc = *(const bf16x8*)&kcorg[((wv * 4 + ks) * 64 + ln) * 8];
            bf16x8 a_q  = *(const bf16x8*)&qorg[((wv * 4 + ks) * 64 + ln) * 8];
            accv = __builtin_amdgcn_mfma_f32_16x16x32_bf16(a_kc, b_st, accv, 0, 0, 0);
            acco = __builtin_amdgcn_mfma_f32_16x16x32_bf16(a_q, b_st, acco, 0, 0, 0);
        }
        const int row = wv * 16 + lkg * 4;
        float u0 = bf2f(uorg[(row + 0) * 16 + lrow]);
        float u1 = bf2f(uorg[(row + 1) * 16 + lrow]);
        float u2 = bf2f(uorg[(row + 2) * 16 + lrow]);
        float u3 = bf2f(uorg[(row + 3) * 16 + lrow]);
        const float gl = gcs_s[63];
        float vn0 = u0 - accv[0], vn1 = u1 - accv[1];
        float vn2 = u2 - accv[2], vn3 = u3 - accv[3];
        {
            float g0 = gcs_s[row], g1 = gcs_s[row + 1], g2 = gcs_s[row + 2], g3 = gcs_s[row + 3];
            acco[0] *= __expf(g0); acco[1] *= __expf(g1);
            acco[2] *= __expf(g2); acco[3] *= __expf(g3);
            const int eb = ((wv >> 1) * 64 + ((wv & 1) * 2 + (lkg >> 1)) * 16 + lrow) * 8
                         + (lkg & 1) * 4;
            union { ushort u2a[4]; uint2 v; } pa, pb;
            pa.u2a[0] = f2bf(vn0); pa.u2a[1] = f2bf(vn1);
            pa.u2a[2] = f2bf(vn2); pa.u2a[3] = f2bf(vn3);
            pb.u2a[0] = f2bf(vn0 * __expf(gl - g0)); pb.u2a[1] = f2bf(vn1 * __expf(gl - g1));
            pb.u2a[2] = f2bf(vn2 * __expf(gl - g2)); pb.u2a[3] = f2bf(vn3 * __expf(gl - g3));
            *(uint2*)&vnorg[eb] = pa.v;
            *(uint2*)&vnsorg[eb] = pb.v;
        }
        __syncthreads();                 // B2: v_new published (+ prefetch drained)

#pragma unroll
        for (int ks = 0; ks < 2; ++ks) {
            bf16x8 a_sc = *(const bf16x8*)&scorg[((wv * 2 + ks) * 64 + ln) * 8];
            bf16x8 b_vn = *(const bf16x8*)&vnorg[(ks * 64 + ln) * 8];
            acco = __builtin_amdgcn_mfma_f32_16x16x32_bf16(a_sc, b_vn, acco, 0, 0, 0);
        }
        ushort* op = obuf + (size_t)(s0 + row) * VAL_DIM + h * DVD + d0 + lrow;
        op[0] = f2bf(acco[0]); op[VAL_DIM] = f2bf(acco[1]);
        op[2 * VAL_DIM] = f2bf(acco[2]); op[3 * VAL_DIM] = f2bf(acco[3]);

        const float egl = __expf(gl);
        accS0 *= egl; accS1 *= egl;
#pragma unroll
        for (int ks = 0; ks < 2; ++ks) {
            bf16x8 a_vs = *(const bf16x8*)&vnsorg[(ks * 64 + ln) * 8];
            bf16x8 b_k0 = *(const bf16x8*)&kTorg[(((wv * 2 + 0) * 2 + ks) * 64 + ln) * 8];
            bf16x8 b_k1 = *(const bf16x8*)&kTorg[(((wv * 2 + 1) * 2 + ks) * 64 + ln) * 8];
            accS0 = __builtin_amdgcn_mfma_f32_16x16x32_bf16(a_vs, b_k0, accS0, 0, 0, 0);
            accS1 = __builtin_amdgcn_mfma_f32_16x16x32_bf16(a_vs, b_k1, accS1, 0, 0, 0);
        }
#pragma unroll
        for (int j = 0; j < 4; ++j) {
            storg[(wv * 64 + ((lrow >> 3)) * 16 + lkg * 4 + j) * 8 + (lrow & 7)] = f2bf(accS0[j]);
            storg[(wv * 64 + (2 + (lrow >> 3)) * 16 + lkg * 4 + j) * 8 + (lrow & 7)] = f2bf(accS1[j]);
        }
        __syncthreads();                 // B3
    }
#undef PBSTG
}

// ============ RMSNorm * norm_w * silu(z) -> bf16 (bf16 o and z) =============
__global__ __launch_bounds__(256) void norm_kernel(
    const ushort* __restrict__ obuf, const ushort* __restrict__ z,
    const float* __restrict__ nw, ushort* __restrict__ hbuf)
{
    int row = (blockIdx.x * 256 + threadIdx.x) >> 6;
    int lane = threadIdx.x & 63;
    uint ov = *(const uint*)(obuf + (size_t)row * DVD + lane * 2);
    float x0 = bf2f((ushort)ov), x1 = bf2f((ushort)(ov >> 16));
    float ss = x0 * x0 + x1 * x1;
#pragma unroll
    for (int m = 1; m < 64; m <<= 1) ss += __shfl_xor(ss, m, 64);
    float scale = rsqrtf(ss * (1.f / DVD) + 1e-6f);
    uint zv = *(const uint*)(z + (size_t)row * DVD + lane * 2);
    float z0 = bf2f((ushort)zv), z1 = bf2f((ushort)(zv >> 16));
    float2 w2 = *(const float2*)(nw + lane * 2);
    float h0 = x0 * scale * w2.x * silu_f(z0);
    float h1 = x1 * scale * w2.y * silu_f(z1);
    union { ushort u[2]; uint v; } r;
    r.u[0] = f2bf(h0); r.u[1] = f2bf(h1);
    *(uint*)(hbuf + (size_t)row * DVD + lane * 2) = r.v;
}

// ============================================================================
extern "C" void kernel_launch(void* const* d_in, const int* in_sizes, int n_in,
                              void* d_out, int out_size, void* d_ws, size_t ws_size,
                              hipStream_t stream)
{
    (void)in_sizes; (void)n_in; (void)out_size; (void)ws_size;
    const float* x      = (const float*)d_in[0];
    const float* W_qkv  = (const float*)d_in[1];
    const float* W_z    = (const float*)d_in[2];
    const float* W_a    = (const float*)d_in[3];
    const float* W_b    = (const float*)d_in[4];
    const float* conv_w = (const float*)d_in[5];
    const float* dt_b   = (const float*)d_in[6];
    const float* A_log  = (const float*)d_in[7];
    const float* norm_w = (const float*)d_in[8];
    const float* W_out  = (const float*)d_in[9];
    float* out = (float*)d_out;

    // ---- workspace layout (bytes), overlaid by liveness; total ~218.9 MB ---
    char* ws = (char*)d_ws;
    // region A @0: mixed_pre bf16 33.5MB (steps 2-4) -> {u bf16, kcd, knT}
    ushort* mixed_pre = (ushort*)(ws);                  // 33,554,432 (bf16)
    ushort* u_buf     = (ushort*)(ws);                  // 16,777,216 (bf16)
    ushort* kcd_buf   = (ushort*)(ws + 33554432);       // 16,777,216
    ushort* knT_buf   = (ushort*)(ws + 50331648);       //  8,388,608
    // region B @67,108,864:
    //   steps 1-2: wqz 50.3MB + xb 8.4MB @117440512
    //   step 4-7 : vbuf bf16 16.8MB
    //   step 8+  : obuf bf16 @83886080 ; hbuf @100663296
    ushort* wqz       = (ushort*)(ws + 67108864);
    ushort* xb        = (ushort*)(ws + 117440512);
    ushort* vbuf      = (ushort*)(ws + 67108864);       // 16,777,216 (bf16)
    ushort* obuf      = (ushort*)(ws + 83886080);       // 16,777,216 (bf16)
    ushort* hbuf      = (ushort*)(ws + 100663296);
    // fixed regions
    ushort* z_buf     = (ushort*)(ws + 134217728);      // 16,777,216 (bf16)
    ushort* sc_buf    = (ushort*)(ws + 167772160);      //  8,388,608 (step>=7)
    ushort* wabb      = (ushort*)(ws + 167772160);      //    524,288 (steps 1-3)
    float*  ab_buf    = (float*)(ws + 168296448);       //  1,048,576 (steps 3-5)
    ushort* qnb       = (ushort*)(ws + 176160768);      //  8,388,608
    ushort* knb       = (ushort*)(ws + 184549376);      //  8,388,608 (bf16)
    float*  g_buf     = (float*)(ws + 201326592);       //    262,144
    float*  bet_buf   = (float*)(ws + 201588736);       //    262,144
    float*  gcs_buf   = (float*)(ws + 201850880);       //    262,144
    ushort* wob       = (ushort*)(ws + 202113024);      // 16,777,216 -> 218.9MB

    hipFuncSetAttribute((const void*)phaseA_kernel,
                        hipFuncAttributeMaxDynamicSharedMemorySize, PA_LDS_BYTES);
    hipFuncSetAttribute((const void*)phaseB_kernel,
                        hipFuncAttributeMaxDynamicSharedMemorySize, PB_LDS_BYTES);
    hipFuncSetAttribute((const void*)gemm256_kernel,
                        hipFuncAttributeMaxDynamicSharedMemorySize, G256_LDS_BYTES);
    hipFuncSetAttribute((const void*)gemm128_kernel,
                        hipFuncAttributeMaxDynamicSharedMemorySize, G128_LDS_BYTES);

    dim3 blk(256);
    // 1) merged casts: x->xb, W_qkv|W_z->wqz, W_out->wob (one launch) + ab
    cast4_kernel<<<(NX8 + NQ8 + NZ8 + NW8) / 256, blk, 0, stream>>>(
        x, W_qkv, W_z, W_out, xb, wqz, wob);
    cast_ab_kernel<<<(128 * HIDDIM / 8) / 256, blk, 0, stream>>>(W_a, W_b, wabb);
    // 2) fused qkv+z projection (256^2 tile, 64x128 wave, both outputs bf16)
    gemm256_kernel<<<dim3((CONV_DIM + VAL_DIM) / 256, S_LEN / 256), dim3(512), G256_LDS_BYTES, stream>>>(
        xb, wqz, mixed_pre, z_buf, HIDDIM, CONV_DIM, CONV_DIM, VAL_DIM);
    // 3) a/b projection
    gemm128_kernel<<<dim3(1, S_LEN / 128), blk, G128_LDS_BYTES, stream>>>(
        xb, wabb, ab_buf, 128, HIDDIM);
    // 4) fused conv+silu+l2norm+v-split (bf16 in/out)
    front_kernel<<<S_LEN, blk, 0, stream>>>(mixed_pre, conv_w, qnb, knb, vbuf);
    // 5) gates
    gb_kernel<<<(S_LEN * NVH) / 256, blk, 0, stream>>>(ab_buf, dt_b, A_log, g_buf, bet_buf);
    // 7) phase A (intra-chunk, blocked-MFMA solve; bf16 in/out)
    phaseA_kernel<<<dim3(NCHK, NVH), blk, PA_LDS_BYTES, stream>>>(
        qnb, knb, vbuf, g_buf, bet_buf, u_buf, kcd_buf, sc_buf, gcs_buf, knT_buf);
    // 8) phase B (inter-chunk scan, MFMA, prefetch-pipelined, bf16 o)
    phaseB_kernel<<<dim3(NVH, 8), blk, PB_LDS_BYTES, stream>>>(
        qnb, knT_buf, u_buf, kcd_buf, sc_buf, gcs_buf, obuf);
    // 9) gated RMSNorm -> bf16
    norm_kernel<<<(S_LEN * NVH * 64) / 256, blk, 0, stream>>>(obuf, z_buf, norm_w, hbuf);
    // 10) output projection (128^2 triple-buffered BK=32, 256 blocks)
    gemm128_kernel<<<dim3(HIDDIM / 128, S_LEN / 128), blk, G128_LDS_BYTES, stream>>>(
        hbuf, wob, out, HIDDIM, VAL_DIM);
}

// Round 17
// 408.535 us; speedup vs baseline: 1.4590x; 1.0793x over previous
//
#include <hip/hip_runtime.h>
#include <hip/hip_bf16.h>
#include <math.h>

// ---- problem constants ----
#define S_LEN   2048
#define HIDDIM  2048
#define NKH     16
#define NVH     32
#define DKD     128
#define DVD     128
#define CCH     64          // chunk
#define NCHK    32          // S/chunk
#define KEY_DIM 2048
#define VAL_DIM 4096
#define CONV_DIM 8192

#define PA_LDS_BYTES (16384 + 16384 + 32768 + 4096 + 4096 + 256 + 256 + 256)
#define PB_LDS_BYTES ((2 * 29696 + 2048 + 1024 + 1024) * 2 + 2048 * 4)  // 135168
// gemm256: 3 bufs x (A 256x32 + B 256x32) bf16 = 3 x 16384 ushorts = 96 KB
#define G256_LDS_BYTES (3 * 16384 * 2)
// gemm128: 3 bufs x (A 128x32 + B 128x32) = 3 x 8192 ushorts = 48 KB
#define G128_LDS_BYTES (3 * 8192 * 2)

typedef __bf16 bf16x8 __attribute__((ext_vector_type(8)));
typedef float f32x4 __attribute__((ext_vector_type(4)));

__device__ __forceinline__ float sigmoid_f(float x) { return 1.f / (1.f + __expf(-x)); }
__device__ __forceinline__ float silu_f(float x) { return x * sigmoid_f(x); }
__device__ __forceinline__ ushort f2bf(float f) {
    unsigned u = __float_as_uint(f);
    u += 0x7fffu + ((u >> 16) & 1u);          // RNE (inputs finite)
    return (ushort)(u >> 16);
}
__device__ __forceinline__ float bf2f(ushort u) {
    return __uint_as_float((unsigned)u << 16);
}

#define GLL(srcp, dstp) __builtin_amdgcn_global_load_lds( \
    (const __attribute__((address_space(1))) void*)(srcp), \
    (__attribute__((address_space(3))) void*)(dstp), 16, 0, 0)

// == merged fp32->bf16 cast: x, W_qkv|W_z, W_out, W_ab-padded (one launch) ===
#define NX8  (S_LEN * HIDDIM / 8)                    // 524288
#define NQ8  (CONV_DIM * HIDDIM / 8)                 // 2097152
#define NZ8  (VAL_DIM * HIDDIM / 8)                  // 1048576
#define NW8  (HIDDIM * VAL_DIM / 8)                  // 1048576
#define NA8  (256 * HIDDIM / 8)                      // 65536
__global__ __launch_bounds__(256) void cast5_kernel(
    const float* __restrict__ x, const float* __restrict__ Wq,
    const float* __restrict__ Wz, const float* __restrict__ Wo,
    const float* __restrict__ Wa, const float* __restrict__ Wb,
    ushort* __restrict__ xb, ushort* __restrict__ wqz, ushort* __restrict__ wob,
    ushort* __restrict__ wab)
{
    int t = blockIdx.x * 256 + threadIdx.x;
    const float* src;
    ushort* dst;
    if (t < NX8) { src = x + (size_t)t * 8; dst = xb + (size_t)t * 8; }
    else if (t < NX8 + NQ8) {
        size_t o = (size_t)(t - NX8) * 8;
        src = Wq + o; dst = wqz + o;
    } else if (t < NX8 + NQ8 + NZ8) {
        size_t o = (size_t)(t - NX8 - NQ8) * 8;
        src = Wz + o; dst = wqz + (size_t)NQ8 * 8 + o;
    } else if (t < NX8 + NQ8 + NZ8 + NW8) {
        size_t o = (size_t)(t - NX8 - NQ8 - NZ8) * 8;
        src = Wo + o; dst = wob + o;
    } else {
        int g = t - NX8 - NQ8 - NZ8 - NW8;           // 0..65535
        int row = g >> 8;
        int c8 = (g & 255) * 8;
        dst = wab + (size_t)g * 8;
        if (row >= 64) {
            uint4 z = {0, 0, 0, 0};
            *(uint4*)dst = z;
            return;
        }
        src = (row < 32) ? (Wa + (size_t)row * HIDDIM + c8)
                         : (Wb + (size_t)(row - 32) * HIDDIM + c8);
    }
    float4 v0 = *(const float4*)(src);
    float4 v1 = *(const float4*)(src + 4);
    union { ushort u[8]; uint4 v; } r;
    r.u[0] = f2bf(v0.x); r.u[1] = f2bf(v0.y); r.u[2] = f2bf(v0.z); r.u[3] = f2bf(v0.w);
    r.u[4] = f2bf(v1.x); r.u[5] = f2bf(v1.y); r.u[6] = f2bf(v1.z); r.u[7] = f2bf(v1.w);
    *(uint4*)dst = r.v;
}

// ==== 256x256 triple-buffered counted-vmcnt bf16 GEMM, 64x128 wave tile =====
// 512 thr = 8 waves (4M x 2N), acc[4][8]. Grid (49, 8) = 392 blocks with
// XCD-chunked swizzle: each XCD owns one bm-row (A-panel L2-pinned).
// 3-way epilogue: cols < NS1 -> C0 bf16, < NS2 -> C1 bf16, else C2 f32.
__global__ __launch_bounds__(512, 1) void gemm256_kernel(
    const ushort* __restrict__ A, const ushort* __restrict__ B,
    ushort* __restrict__ C0, ushort* __restrict__ C1, float* __restrict__ C2,
    int K, int NS1, int NS2, int ldc0, int ldc1, int ldc2)
{
    extern __shared__ ushort g2s[];          // [3][A 8192 | B 8192] ushorts
    const int tid = threadIdx.x;
    const int wv = tid >> 6, ln = tid & 63;
    const int wm = wv >> 1, wn = wv & 1;
    const int lrow = ln & 15, lkg = ln >> 4;
    // XCD-chunked swizzle over 392 blocks (392 % 8 == 0): xcd k -> by = k
    const int bid = blockIdx.y * 49 + blockIdx.x;
    const int swz = (bid & 7) * 49 + (bid >> 3);
    const int bm = (swz / 49) * 256, bn = (swz % 49) * 256;

    int soff[2];
#pragma unroll
    for (int j = 0; j < 2; ++j) {
        int g = tid + j * 512;
        int l = g & 63;
        soff[j] = (((g >> 6) * 16) + (l & 15)) * K + (l >> 4) * 8;
    }
    const ushort* Abase = A + (size_t)bm * K;
    const ushort* Bbase = B + (size_t)bn * K;

    f32x4 acc[4][8];
#pragma unroll
    for (int m = 0; m < 4; ++m)
#pragma unroll
        for (int n = 0; n < 8; ++n) {
            f32x4 z = {0.f, 0.f, 0.f, 0.f};
            acc[m][n] = z;
        }

#define G256_STAGE(bb, k0) do {                                            \
        ushort* bufA_ = g2s + (bb) * 16384;                                \
        ushort* bufB_ = bufA_ + 8192;                                      \
        _Pragma("unroll")                                                  \
        for (int j_ = 0; j_ < 2; ++j_) {                                   \
            GLL(Abase + soff[j_] + (k0), bufA_ + (j_ * 512 + wv * 64) * 8);\
            GLL(Bbase + soff[j_] + (k0), bufB_ + (j_ * 512 + wv * 64) * 8);\
        }                                                                  \
    } while (0)

    const int T = K >> 5;
    G256_STAGE(0, 0);
    G256_STAGE(1, 32);
    int bb = 0;
    for (int t = 0; t < T; ++t) {
        if (t + 1 < T) {
            asm volatile("s_waitcnt vmcnt(4)" ::: "memory");
        } else {
            asm volatile("s_waitcnt vmcnt(0)" ::: "memory");
        }
        __builtin_amdgcn_s_barrier();
        if (t + 2 < T) G256_STAGE((bb >= 1) ? (bb - 1) : (bb + 2), (t + 2) * 32);
        const ushort* LA = g2s + bb * 16384;
        const ushort* LB = LA + 8192;
        __builtin_amdgcn_s_setprio(1);
        {
            bf16x8 afv[4], bfv[8];
#pragma unroll
            for (int mf = 0; mf < 4; ++mf)
                afv[mf] = *(const bf16x8*)&LA[((wm * 4 + mf) * 64 + ln) * 8];
#pragma unroll
            for (int nf = 0; nf < 8; ++nf)
                bfv[nf] = *(const bf16x8*)&LB[((wn * 8 + nf) * 64 + ln) * 8];
#pragma unroll
            for (int mf = 0; mf < 4; ++mf)
#pragma unroll
                for (int nf = 0; nf < 8; ++nf)
                    acc[mf][nf] = __builtin_amdgcn_mfma_f32_16x16x32_bf16(
                        afv[mf], bfv[nf], acc[mf][nf], 0, 0, 0);
        }
        __builtin_amdgcn_s_setprio(0);
        bb = (bb == 2) ? 0 : bb + 1;
    }
#undef G256_STAGE

    if (bn < NS2) {   // bf16 outputs (whole block on one side; NS1,NS2 %256==0)
        const bool inC1 = (bn >= NS1);
        ushort* Cp = inC1 ? C1 : C0;
        const int ldc = inC1 ? ldc1 : ldc0;
        const int cboff = bn + wn * 128 - (inC1 ? NS1 : 0);
#pragma unroll
        for (int mf = 0; mf < 4; ++mf) {
            const int row0 = bm + wm * 64 + mf * 16 + lkg * 4;
#pragma unroll
            for (int nf = 0; nf < 8; ++nf) {
                ushort* cp = Cp + (size_t)row0 * ldc + cboff + nf * 16 + lrow;
#pragma unroll
                for (int j = 0; j < 4; ++j) cp[(size_t)j * ldc] = f2bf(acc[mf][nf][j]);
            }
        }
    } else {          // f32 ab output
        const int cboff = bn + wn * 128 - NS2;
#pragma unroll
        for (int mf = 0; mf < 4; ++mf) {
            const int row0 = bm + wm * 64 + mf * 16 + lkg * 4;
#pragma unroll
            for (int nf = 0; nf < 8; ++nf) {
                float* cp = C2 + (size_t)row0 * ldc2 + cboff + nf * 16 + lrow;
#pragma unroll
                for (int j = 0; j < 4; ++j) cp[(size_t)j * ldc2] = acc[mf][nf][j];
            }
        }
    }
}

// ======== 128x128 triple-buffered counted-vmcnt bf16 GEMM (BK=32) ===========
__global__ __launch_bounds__(256, 2) void gemm128_kernel(
    const ushort* __restrict__ A, const ushort* __restrict__ B,
    float* __restrict__ C, int N, int K)
{
    extern __shared__ ushort g1s[];          // [3][A 4096 | B 4096] ushorts
    const int tid = threadIdx.x;
    const int wv = tid >> 6, ln = tid & 63;
    const int wm = wv >> 1, wn = wv & 1;
    const int lrow = ln & 15, lkg = ln >> 4;
    const int bm = blockIdx.y * 128, bn = blockIdx.x * 128;

    int soff[2];
#pragma unroll
    for (int j = 0; j < 2; ++j) {
        int g = tid + j * 256;
        int l = g & 63;
        soff[j] = (((g >> 6) * 16) + (l & 15)) * K + (l >> 4) * 8;
    }
    const ushort* Abase = A + (size_t)bm * K;
    const ushort* Bbase = B + (size_t)bn * K;

    f32x4 acc[4][4];
#pragma unroll
    for (int m = 0; m < 4; ++m)
#pragma unroll
        for (int n = 0; n < 4; ++n) {
            f32x4 z = {0.f, 0.f, 0.f, 0.f};
            acc[m][n] = z;
        }

#define G128_STAGE(bb, k0) do {                                            \
        ushort* bufA_ = g1s + (bb) * 8192;                                 \
        ushort* bufB_ = bufA_ + 4096;                                      \
        _Pragma("unroll")                                                  \
        for (int j_ = 0; j_ < 2; ++j_) {                                   \
            GLL(Abase + soff[j_] + (k0), bufA_ + (j_ * 256 + wv * 64) * 8);\
            GLL(Bbase + soff[j_] + (k0), bufB_ + (j_ * 256 + wv * 64) * 8);\
        }                                                                  \
    } while (0)

    const int T = K >> 5;
    G128_STAGE(0, 0);
    G128_STAGE(1, 32);
    int bb = 0;
    for (int t = 0; t < T; ++t) {
        if (t + 1 < T) {
            asm volatile("s_waitcnt vmcnt(4)" ::: "memory");
        } else {
            asm volatile("s_waitcnt vmcnt(0)" ::: "memory");
        }
        __builtin_amdgcn_s_barrier();
        if (t + 2 < T) G128_STAGE((bb >= 1) ? (bb - 1) : (bb + 2), (t + 2) * 32);
        const ushort* LA = g1s + bb * 8192;
        const ushort* LB = LA + 4096;
        __builtin_amdgcn_s_setprio(1);
        {
            bf16x8 afv[4], bfv[4];
#pragma unroll
            for (int mf = 0; mf < 4; ++mf)
                afv[mf] = *(const bf16x8*)&LA[((wm * 4 + mf) * 64 + ln) * 8];
#pragma unroll
            for (int nf = 0; nf < 4; ++nf)
                bfv[nf] = *(const bf16x8*)&LB[((wn * 4 + nf) * 64 + ln) * 8];
#pragma unroll
            for (int mf = 0; mf < 4; ++mf)
#pragma unroll
                for (int nf = 0; nf < 4; ++nf)
                    acc[mf][nf] = __builtin_amdgcn_mfma_f32_16x16x32_bf16(
                        afv[mf], bfv[nf], acc[mf][nf], 0, 0, 0);
        }
        __builtin_amdgcn_s_setprio(0);
        bb = (bb == 2) ? 0 : bb + 1;
    }
#undef G128_STAGE

#pragma unroll
    for (int mf = 0; mf < 4; ++mf) {
        const int row0 = bm + wm * 64 + mf * 16 + lkg * 4;
#pragma unroll
        for (int nf = 0; nf < 4; ++nf) {
            float* cp = C + (size_t)row0 * N + bn + wn * 64 + nf * 16 + lrow;
#pragma unroll
            for (int j = 0; j < 4; ++j) cp[(size_t)j * N] = acc[mf][nf][j];
        }
    }
}

// ===== fused front: conv1d(K=4)+SiLU + q/k L2norm + v split, 1 block/row ====
__global__ __launch_bounds__(256) void front_kernel(
    const ushort* __restrict__ pre, const float* __restrict__ cw,
    ushort* __restrict__ qnb, ushort* __restrict__ knb, ushort* __restrict__ vbuf)
{
    __shared__ float stage[4096];
    __shared__ float sums[32];
    __shared__ float scal[32];
    const int s = blockIdx.x;
    const int tid = threadIdx.x;

#pragma unroll
    for (int cg = 0; cg < 8; ++cg) {
        const int c = cg * 1024 + tid * 4;
        float w[4][4];
#pragma unroll
        for (int j = 0; j < 4; ++j) {
            float4 wj = *(const float4*)(cw + (size_t)(c + j) * 4);
            w[j][0] = wj.x; w[j][1] = wj.y; w[j][2] = wj.z; w[j][3] = wj.w;
        }
        float a0 = 0.f, a1 = 0.f, a2 = 0.f, a3 = 0.f;
#pragma unroll
        for (int t = 0; t < 4; ++t) {
            int ss = s - 3 + t;
            if (ss >= 0) {
                uint2 xv = *(const uint2*)(pre + (size_t)ss * CONV_DIM + c);
                a0 = fmaf(bf2f((ushort)xv.x), w[0][t], a0);
                a1 = fmaf(bf2f((ushort)(xv.x >> 16)), w[1][t], a1);
                a2 = fmaf(bf2f((ushort)xv.y), w[2][t], a2);
                a3 = fmaf(bf2f((ushort)(xv.y >> 16)), w[3][t], a3);
            }
        }
        a0 = silu_f(a0); a1 = silu_f(a1); a2 = silu_f(a2); a3 = silu_f(a3);
        if (cg < 4) {
            float4 v4 = make_float4(a0, a1, a2, a3);
            *(float4*)&stage[c] = v4;
            float ss2 = a0 * a0 + a1 * a1 + a2 * a2 + a3 * a3;
#pragma unroll
            for (int m = 1; m < 32; m <<= 1) ss2 += __shfl_xor(ss2, m, 32);
            if ((tid & 31) == 0) sums[c >> 7] = ss2;
        } else {
            union { ushort u2[4]; uint2 v; } p;
            p.u2[0] = f2bf(a0); p.u2[1] = f2bf(a1);
            p.u2[2] = f2bf(a2); p.u2[3] = f2bf(a3);
            *(uint2*)(vbuf + (size_t)s * VAL_DIM + (c - 4096)) = p.v;
        }
    }
    __syncthreads();
    if (tid < 32) {
        float sc = rsqrtf(sums[tid] + 1e-6f);
        if (tid < 16) sc *= 0.08838834764831843f;     // q: DK^-0.5
        scal[tid] = sc;
    }
    __syncthreads();
#pragma unroll
    for (int j = 0; j < 4; ++j) {
        const int c = j * 1024 + tid * 4;
        float4 v4 = *(const float4*)&stage[c];
        const float sc = scal[c >> 7];
        union { ushort u2[4]; uint2 v; } p;
        p.u2[0] = f2bf(v4.x * sc); p.u2[1] = f2bf(v4.y * sc);
        p.u2[2] = f2bf(v4.z * sc); p.u2[3] = f2bf(v4.w * sc);
        if (c < 2048)
            *(uint2*)(qnb + ((size_t)(s * NKH + (c >> 7))) * DKD + (c & 127)) = p.v;
        else
            *(uint2*)(knb + ((size_t)(s * NKH + ((c >> 7) - 16))) * DKD + (c & 127)) = p.v;
    }
}

// ====== g = -exp(A_log)*softplus(a+dt_bias), beta = sigmoid(b) ==============
// ab buffer layout: [S][256], a at cols 0..31, b at cols 32..63
__global__ __launch_bounds__(256) void gb_kernel(
    const float* __restrict__ ab, const float* __restrict__ dt_bias,
    const float* __restrict__ A_log, float* __restrict__ g, float* __restrict__ beta)
{
    int idx = blockIdx.x * 256 + threadIdx.x;
    int s = idx >> 5, h = idx & 31;
    float av = ab[(size_t)s * 256 + h] + dt_bias[h];
    float sp = (av > 20.f) ? av : log1pf(__expf(av));
    g[idx] = -__expf(A_log[h]) * sp;
    beta[idx] = sigmoid_f(ab[(size_t)s * 256 + 32 + h]);
}

// ================= Phase A: per (head, chunk) intra-chunk work ==============
// outputs: u bf16, kcd bf16, scores bf16, gcs f32, knT bf16 (even h only)
__global__ __launch_bounds__(256) void phaseA_kernel(
    const ushort* __restrict__ qnb, const ushort* __restrict__ knb,
    const ushort* __restrict__ vbuf, const float* __restrict__ gbuf,
    const float* __restrict__ betabuf,
    ushort* __restrict__ u, ushort* __restrict__ kcd,
    ushort* __restrict__ scores, float* __restrict__ gcs_out,
    ushort* __restrict__ knT)
{
    extern __shared__ char pasm[];
    ushort* kb    = (ushort*)(pasm);            // 16KB frag [m4][ks4][64][8]
    ushort* qb    = (ushort*)(pasm + 16384);    // 16KB frag; later P f32[16][256]
    ushort* Xb    = (ushort*)(pasm + 32768);    // 32KB [t2(2)][ct(16)][64][8]
    float*  Adiag = (float*)(pasm + 65536);     // 4KB
    ushort* Ab    = (ushort*)(pasm + 69632);    // 4KB
    float*  gcs_s = (float*)(pasm + 73728);
    float*  bet_s = (float*)(pasm + 73984);
    float*  scK_s = (float*)(pasm + 74240);
    float*  Pf    = (float*)qb;

    const int n = blockIdx.x, h = blockIdx.y, kh = h >> 1;
    const int tid = threadIdx.x;
    const int s0 = n * CCH;
    const int wv = tid >> 6, ln = tid & 63;
    const int lrow = ln & 15, lkg = ln >> 4;

    float xr[64];
    if (tid < 128) {
        const ushort* vp = vbuf + (size_t)s0 * VAL_DIM + h * DVD + tid;
#pragma unroll
        for (int i = 0; i < 64; ++i) xr[i] = bf2f(vp[(size_t)i * VAL_DIM]);
    } else {
        const ushort* kp = knb + ((size_t)s0 * NKH + kh) * DKD + (tid - 128);
#pragma unroll
        for (int i = 0; i < 64; ++i) xr[i] = bf2f(kp[(size_t)i * (NKH * DKD)]);
    }

    {
        uint4 z = {0, 0, 0, 0};
#pragma unroll
        for (int i = 0; i < 8; ++i)
            *(uint4*)&Xb[(i * 256 + tid) * 8] = z;
        *(uint4*)&Ab[tid * 8] = z;
    }

    if (tid < 64) {
        float gv = gbuf[(size_t)(s0 + tid) * NVH + h];
#pragma unroll
        for (int off = 1; off < 64; off <<= 1) {
            float pv = __shfl_up(gv, off, 64);
            if (tid >= off) gv += pv;
        }
        float bv = betabuf[(size_t)(s0 + tid) * NVH + h];
        gcs_s[tid] = gv;
        bet_s[tid] = bv;
        scK_s[tid] = bv * __expf(gv);
        gcs_out[(size_t)h * S_LEN + s0 + tid] = gv;
    }

    {   // stage k and q (both bf16 -> straight uint4 copies)
        const int r = tid >> 2, c0 = (tid & 3) * 32;
        const int mbase = (((r >> 4) * 4 + (tid & 3)) * 64 + (r & 15)) * 8;
        const ushort* ksrc = knb + ((size_t)(s0 + r) * NKH + kh) * DKD + c0;
        const ushort* qsrc = qnb + ((size_t)(s0 + r) * NKH + kh) * DKD + c0;
#pragma unroll
        for (int j0 = 0; j0 < 4; ++j0) {
            *(uint4*)&kb[mbase + (j0 << 7)] = *(const uint4*)(ksrc + j0 * 8);
            *(uint4*)&qb[mbase + (j0 << 7)] = *(const uint4*)(qsrc + j0 * 8);
        }
    }
    __syncthreads();    // B1

    f32x4 accA[4], accQ[4];
#pragma unroll
    for (int j = 0; j < 4; ++j) {
        f32x4 z = {0.f, 0.f, 0.f, 0.f};
        accA[j] = z; accQ[j] = z;
    }
#pragma unroll
    for (int ks = 0; ks < 4; ++ks) {
        bf16x8 a_k = *(const bf16x8*)&kb[((wv * 4 + ks) * 64 + ln) * 8];
        bf16x8 a_q = *(const bf16x8*)&qb[((wv * 4 + ks) * 64 + ln) * 8];
#pragma unroll
        for (int j = 0; j < 4; ++j) {
            bf16x8 b_k = *(const bf16x8*)&kb[((j * 4 + ks) * 64 + ln) * 8];
            accA[j] = __builtin_amdgcn_mfma_f32_16x16x32_bf16(a_k, b_k, accA[j], 0, 0, 0);
            accQ[j] = __builtin_amdgcn_mfma_f32_16x16x32_bf16(a_q, b_k, accQ[j], 0, 0, 0);
        }
    }
    {
        ushort* scp = scores + (size_t)(h * NCHK + n) * (CCH * CCH);
#pragma unroll
        for (int j = 0; j < 4; ++j) {
            const int c = j * 16 + lrow;
            const float gc = gcs_s[c];
#pragma unroll
            for (int jj = 0; jj < 4; ++jj) {
                const int i = wv * 16 + lkg * 4 + jj;
                const float e = __expf(gcs_s[i] - gc);
                float sv = (i >= c) ? (accQ[j][jj] * e) : 0.f;
                scp[i * CCH + c] = f2bf(sv);
                float aval = (i > c) ? (-bet_s[i] * accA[j][jj] * e) : 0.f;
                if (j == wv) {
                    Adiag[wv * 256 + (i & 15) * 16 + lrow] = aval;
                } else if (j < wv) {
                    const int f = (wv == 1) ? 0 : ((wv == 2) ? 1 : (2 + (j >> 1)));
                    const int lk = ((j & 1) << 4) | lrow;
                    const int lane2 = (i & 15) | ((lk >> 3) << 4);
                    Ab[(f * 64 + lane2) * 8 + (lk & 7)] = f2bf(aval);
                }
            }
        }
    }
    if (tid < 128) {
#pragma unroll
        for (int i4 = 0; i4 < 16; ++i4) {
            float4 b4 = *(const float4*)&bet_s[i4 * 4];
            xr[i4 * 4 + 0] *= b4.x; xr[i4 * 4 + 1] *= b4.y;
            xr[i4 * 4 + 2] *= b4.z; xr[i4 * 4 + 3] *= b4.w;
        }
    } else {
#pragma unroll
        for (int i4 = 0; i4 < 16; ++i4) {
            float4 b4 = *(const float4*)&scK_s[i4 * 4];
            xr[i4 * 4 + 0] *= b4.x; xr[i4 * 4 + 1] *= b4.y;
            xr[i4 * 4 + 2] *= b4.z; xr[i4 * 4 + 3] *= b4.w;
        }
    }
    __syncthreads();    // B2

    const int ct = tid >> 4, lct = tid & 15;
#pragma unroll
    for (int s = 0; s < 4; ++s) {
        float y[16];
        float pr[16];
        if (s > 0) {
#pragma unroll
            for (int r = 0; r < 16; ++r) pr[r] = Pf[r * 256 + tid];
        } else {
#pragma unroll
            for (int r = 0; r < 16; ++r) pr[r] = 0.f;
        }
#pragma unroll
        for (int r = 0; r < 16; ++r) {
            float acc = xr[s * 16 + r] + pr[r];
#pragma unroll
            for (int k4 = 0; k4 < 16; k4 += 4) {
                if (k4 < r) {
                    float4 a4 = *(const float4*)&Adiag[s * 256 + r * 16 + k4];
                    if (k4 + 0 < r) acc = fmaf(a4.x, y[k4 + 0], acc);
                    if (k4 + 1 < r) acc = fmaf(a4.y, y[k4 + 1], acc);
                    if (k4 + 2 < r) acc = fmaf(a4.z, y[k4 + 2], acc);
                    if (k4 + 3 < r) acc = fmaf(a4.w, y[k4 + 3], acc);
                }
            }
            y[r] = acc;
        }
        if (tid < 128) {
            ushort* up = u + (size_t)(h * NCHK + n) * (CCH * DVD) + (s * 16) * DVD + tid;
#pragma unroll
            for (int r = 0; r < 16; ++r) up[r * DVD] = f2bf(y[r]);
        } else {
            ushort* kp = kcd + (size_t)(h * NCHK + n) * (CCH * DKD) + (s * 16) * DKD + (tid - 128);
#pragma unroll
            for (int r = 0; r < 16; ++r) kp[r * DKD] = f2bf(y[r]);
        }
        if (s < 3) {
#pragma unroll
            for (int half = 0; half < 2; ++half) {
                union { ushort us[8]; uint4 v; } p;
#pragma unroll
                for (int e = 0; e < 8; ++e) p.us[e] = f2bf(y[half * 8 + e]);
                const int kg = (s & 1) * 2 + half;
                *(uint4*)&Xb[(((s >> 1) * 16 + ct) * 64 + (kg * 16 + lct)) * 8] = p.v;
            }
            __syncthreads();
            const int snx = s + 1;
            const int nT2 = (snx + 1) >> 1;
            f32x4 accP[4];
#pragma unroll
            for (int ctl = 0; ctl < 4; ++ctl) {
                f32x4 z = {0.f, 0.f, 0.f, 0.f};
                accP[ctl] = z;
            }
#pragma unroll
            for (int t2 = 0; t2 < 2; ++t2) {
                if (t2 < nT2) {
                    const int f = (snx == 1) ? 0 : ((snx == 2) ? 1 : (2 + t2));
                    bf16x8 a = *(const bf16x8*)&Ab[(f * 64 + ln) * 8];
#pragma unroll
                    for (int ctl = 0; ctl < 4; ++ctl) {
                        bf16x8 b = *(const bf16x8*)&Xb[((t2 * 16 + wv * 4 + ctl) * 64 + ln) * 8];
                        accP[ctl] = __builtin_amdgcn_mfma_f32_16x16x32_bf16(a, b, accP[ctl], 0, 0, 0);
                    }
                }
            }
#pragma unroll
            for (int ctl = 0; ctl < 4; ++ctl)
#pragma unroll
                for (int jj = 0; jj < 4; ++jj)
                    Pf[(lkg * 4 + jj) * 256 + wv * 64 + ctl * 16 + lrow] = accP[ctl][jj];
            __syncthreads();
        }
    }

    if (!(h & 1)) {
        const int dk = tid >> 1, ch = (tid & 1) * 32;
        ushort* dst = knT + ((size_t)(kh * NCHK + n) * DKD + dk) * CCH + ch;
        const int kpart = ((dk >> 5) * 64) * 8 + (((dk >> 3) & 3) << 4) * 8 + (dk & 7);
#pragma unroll
        for (int j0 = 0; j0 < 32; j0 += 8) {
            union { ushort us[8]; uint4 v; } p;
#pragma unroll
            for (int j = 0; j < 8; ++j) {
                const int row = ch + j0 + j;
                p.us[j] = kb[((row >> 4) * 4 * 64 + (row & 15)) * 8 + kpart];
            }
            *(uint4*)(dst + j0) = p.v;
        }
    }
}

// ====== Phase B: inter-chunk state scan (MFMA), prefetch-pipelined ==========
__global__ __launch_bounds__(256) void phaseB_kernel(
    const ushort* __restrict__ qnb, const ushort* __restrict__ knT,
    const ushort* __restrict__ u, const ushort* __restrict__ kcd,
    const ushort* __restrict__ sc, const float* __restrict__ gcs,
    ushort* __restrict__ obuf)
{
    extern __shared__ ushort smu[];
    // stage buf b at b*29696: {q 8192, kc 8192, sc 4096, kT 8192, u 1024}
    ushort* storg  = smu + 59392;    // 2048  S^T bf16
    ushort* vnorg  = smu + 61440;    // 1024
    ushort* vnsorg = smu + 62464;    // 1024
    float*  gcsall = (float*)(smu + 63488);  // 2048 floats (8 KB)

    const int h = blockIdx.x;
    const int dvb = blockIdx.y;
    const int d0 = dvb * 16;
    const int kh = h >> 1;
    const int tid = threadIdx.x;
    const int wv = tid >> 6, ln = tid & 63;
    const int lrow = ln & 15, lkg = ln >> 4;

    {   // zero S^T
        uint4 z = {0, 0, 0, 0};
        *(uint4*)&storg[tid * 8] = z;
    }

    const int q_lane  = lrow * (NKH * DKD) + kh * DKD + wv * 32 + lkg * 8;
    const int kc_lane = lrow * DKD + wv * 32 + lkg * 8;
    const int st_lane = ((tid >> 7) * 16 + lrow) * 64 + ((tid >> 6) & 1) * 32 + lkg * 8;
    const int dst_e   = wv * 512;

#define PBSTG(bsel, nn) do {                                                  \
        const ushort* qsrc_  = qnb + (size_t)((nn) * CCH) * (NKH * DKD);      \
        const ushort* kcsrc_ = kcd + (size_t)(h * NCHK + (nn)) * (CCH * DKD); \
        const ushort* scsrc_ = sc  + (size_t)(h * NCHK + (nn)) * (CCH * CCH); \
        const ushort* kTsrc_ = knT + (size_t)(kh * NCHK + (nn)) * (DKD * CCH);\
        const ushort* usrc_  = u   + (size_t)(h * NCHK + (nn)) * (CCH * DVD) + d0; \
        ushort* base_ = smu + (bsel) * 29696;                                 \
        _Pragma("unroll")                                                     \
        for (int r_ = 0; r_ < 4; ++r_) {                                      \
            GLL(qsrc_ + q_lane + r_ * 32768, base_ + r_ * 2048 + dst_e);      \
            GLL(kcsrc_ + kc_lane + r_ * 2048, base_ + 8192 + r_ * 2048 + dst_e); \
            GLL(kTsrc_ + st_lane + r_ * 2048, base_ + 20480 + r_ * 2048 + dst_e); \
        }                                                                     \
        _Pragma("unroll")                                                     \
        for (int r_ = 0; r_ < 2; ++r_)                                        \
            GLL(scsrc_ + st_lane + r_ * 2048, base_ + 16384 + r_ * 2048 + dst_e); \
        if (tid < 128)                                                        \
            GLL(usrc_ + (tid >> 1) * DVD + (tid & 1) * 8, base_ + 28672 + tid * 8); \
    } while (0)

    PBSTG(0, 0);
    {
        float4 g0 = *(const float4*)(gcs + (size_t)h * S_LEN + tid * 8);
        float4 g1 = *(const float4*)(gcs + (size_t)h * S_LEN + tid * 8 + 4);
        *(float4*)&gcsall[tid * 8] = g0;
        *(float4*)&gcsall[tid * 8 + 4] = g1;
    }
    __syncthreads();

    f32x4 accS0 = {0.f, 0.f, 0.f, 0.f}, accS1 = {0.f, 0.f, 0.f, 0.f};

    for (int n = 0; n < NCHK; ++n) {
        const int cur = n & 1;
        if (n + 1 < NCHK) PBSTG(cur ^ 1, n + 1);
        const ushort* qorg  = smu + cur * 29696;
        const ushort* kcorg = qorg + 8192;
        const ushort* scorg = qorg + 16384;
        const ushort* kTorg = qorg + 20480;
        const ushort* uorg  = qorg + 28672;
        const float*  gcs_s = gcsall + n * 64;
        const int s0 = n * CCH;

        f32x4 accv = {0.f, 0.f, 0.f, 0.f};
        f32x4 acco = {0.f, 0.f, 0.f, 0.f};
#pragma unroll
        for (int ks = 0; ks < 4; ++ks) {
            bf16x8 b_st = *(const bf16x8*)&storg[(ks * 64 + ln) * 8];
            bf16x8 a_kc = *(const bf16x8*)&kcorg[((wv * 4 + ks) * 64 + ln) * 8];
            bf16x8 a_q  = *(const bf16x8*)&qorg[((wv * 4 + ks) * 64 + ln) * 8];
            accv = __builtin_amdgcn_mfma_f32_16x16x32_bf16(a_kc, b_st, accv, 0, 0, 0);
            acco = __builtin_amdgcn_mfma_f32_16x16x32_bf16(a_q, b_st, acco, 0, 0, 0);
        }
        const int row = wv * 16 + lkg * 4;
        float u0 = bf2f(uorg[(row + 0) * 16 + lrow]);
        float u1 = bf2f(uorg[(row + 1) * 16 + lrow]);
        float u2 = bf2f(uorg[(row + 2) * 16 + lrow]);
        float u3 = bf2f(uorg[(row + 3) * 16 + lrow]);
        const float gl = gcs_s[63];
        float vn0 = u0 - accv[0], vn1 = u1 - accv[1];
        float vn2 = u2 - accv[2], vn3 = u3 - accv[3];
        {
            float g0 = gcs_s[row], g1 = gcs_s[row + 1], g2 = gcs_s[row + 2], g3 = gcs_s[row + 3];
            acco[0] *= __expf(g0); acco[1] *= __expf(g1);
            acco[2] *= __expf(g2); acco[3] *= __expf(g3);
            const int eb = ((wv >> 1) * 64 + ((wv & 1) * 2 + (lkg >> 1)) * 16 + lrow) * 8
                         + (lkg & 1) * 4;
            union { ushort u2a[4]; uint2 v; } pa, pb;
            pa.u2a[0] = f2bf(vn0); pa.u2a[1] = f2bf(vn1);
            pa.u2a[2] = f2bf(vn2); pa.u2a[3] = f2bf(vn3);
            pb.u2a[0] = f2bf(vn0 * __expf(gl - g0)); pb.u2a[1] = f2bf(vn1 * __expf(gl - g1));
            pb.u2a[2] = f2bf(vn2 * __expf(gl - g2)); pb.u2a[3] = f2bf(vn3 * __expf(gl - g3));
            *(uint2*)&vnorg[eb] = pa.v;
            *(uint2*)&vnsorg[eb] = pb.v;
        }
        __syncthreads();                 // B2: v_new published (+ prefetch drained)

#pragma unroll
        for (int ks = 0; ks < 2; ++ks) {
            bf16x8 a_sc = *(const bf16x8*)&scorg[((wv * 2 + ks) * 64 + ln) * 8];
            bf16x8 b_vn = *(const bf16x8*)&vnorg[(ks * 64 + ln) * 8];
            acco = __builtin_amdgcn_mfma_f32_16x16x32_bf16(a_sc, b_vn, acco, 0, 0, 0);
        }
        ushort* op = obuf + (size_t)(s0 + row) * VAL_DIM + h * DVD + d0 + lrow;
        op[0] = f2bf(acco[0]); op[VAL_DIM] = f2bf(acco[1]);
        op[2 * VAL_DIM] = f2bf(acco[2]); op[3 * VAL_DIM] = f2bf(acco[3]);

        const float egl = __expf(gl);
        accS0 *= egl; accS1 *= egl;
#pragma unroll
        for (int ks = 0; ks < 2; ++ks) {
            bf16x8 a_vs = *(const bf16x8*)&vnsorg[(ks * 64 + ln) * 8];
            bf16x8 b_k0 = *(const bf16x8*)&kTorg[(((wv * 2 + 0) * 2 + ks) * 64 + ln) * 8];
            bf16x8 b_k1 = *(const bf16x8*)&kTorg[(((wv * 2 + 1) * 2 + ks) * 64 + ln) * 8];
            accS0 = __builtin_amdgcn_mfma_f32_16x16x32_bf16(a_vs, b_k0, accS0, 0, 0, 0);
            accS1 = __builtin_amdgcn_mfma_f32_16x16x32_bf16(a_vs, b_k1, accS1, 0, 0, 0);
        }
#pragma unroll
        for (int j = 0; j < 4; ++j) {
            storg[(wv * 64 + ((lrow >> 3)) * 16 + lkg * 4 + j) * 8 + (lrow & 7)] = f2bf(accS0[j]);
            storg[(wv * 64 + (2 + (lrow >> 3)) * 16 + lkg * 4 + j) * 8 + (lrow & 7)] = f2bf(accS1[j]);
        }
        __syncthreads();                 // B3
    }
#undef PBSTG
}

// ============ RMSNorm * norm_w * silu(z) -> bf16 (bf16 o and z) =============
__global__ __launch_bounds__(256) void norm_kernel(
    const ushort* __restrict__ obuf, const ushort* __restrict__ z,
    const float* __restrict__ nw, ushort* __restrict__ hbuf)
{
    int row = (blockIdx.x * 256 + threadIdx.x) >> 6;
    int lane = threadIdx.x & 63;
    uint ov = *(const uint*)(obuf + (size_t)row * DVD + lane * 2);
    float x0 = bf2f((ushort)ov), x1 = bf2f((ushort)(ov >> 16));
    float ss = x0 * x0 + x1 * x1;
#pragma unroll
    for (int m = 1; m < 64; m <<= 1) ss += __shfl_xor(ss, m, 64);
    float scale = rsqrtf(ss * (1.f / DVD) + 1e-6f);
    uint zv = *(const uint*)(z + (size_t)row * DVD + lane * 2);
    float z0 = bf2f((ushort)zv), z1 = bf2f((ushort)(zv >> 16));
    float2 w2 = *(const float2*)(nw + lane * 2);
    float h0 = x0 * scale * w2.x * silu_f(z0);
    float h1 = x1 * scale * w2.y * silu_f(z1);
    union { ushort u[2]; uint v; } r;
    r.u[0] = f2bf(h0); r.u[1] = f2bf(h1);
    *(uint*)(hbuf + (size_t)row * DVD + lane * 2) = r.v;
}

// ============================================================================
extern "C" void kernel_launch(void* const* d_in, const int* in_sizes, int n_in,
                              void* d_out, int out_size, void* d_ws, size_t ws_size,
                              hipStream_t stream)
{
    (void)in_sizes; (void)n_in; (void)out_size; (void)ws_size;
    const float* x      = (const float*)d_in[0];
    const float* W_qkv  = (const float*)d_in[1];
    const float* W_z    = (const float*)d_in[2];
    const float* W_a    = (const float*)d_in[3];
    const float* W_b    = (const float*)d_in[4];
    const float* conv_w = (const float*)d_in[5];
    const float* dt_b   = (const float*)d_in[6];
    const float* A_log  = (const float*)d_in[7];
    const float* norm_w = (const float*)d_in[8];
    const float* W_out  = (const float*)d_in[9];
    float* out = (float*)d_out;

    // ---- workspace layout (bytes), overlaid by liveness; total ~218.9 MB ---
    char* ws = (char*)d_ws;
    // region A @0: mixed_pre bf16 33.5MB (steps 2-4) -> {u bf16, kcd, knT}
    ushort* mixed_pre = (ushort*)(ws);                  // 33,554,432 (bf16)
    ushort* u_buf     = (ushort*)(ws);                  // 16,777,216 (bf16)
    ushort* kcd_buf   = (ushort*)(ws + 33554432);       // 16,777,216
    ushort* knT_buf   = (ushort*)(ws + 50331648);       //  8,388,608
    // region B @67,108,864:
    //   steps 1-2: wqz 50.3MB [.., 117440512) + wab 1MB + xb 8.4MB
    //   step 4-7 : vbuf bf16 16.8MB @67108864
    //   step 8+  : obuf bf16 @83886080 ; hbuf @100663296
    ushort* wqz       = (ushort*)(ws + 67108864);       // 12288x2048 bf16
    ushort* wab       = (ushort*)(ws + 117440512);      //   256x2048 bf16 (1MB)
    ushort* xb        = (ushort*)(ws + 118489088);      //  8,388,608
    ushort* vbuf      = (ushort*)(ws + 67108864);       // 16,777,216 (bf16)
    ushort* obuf      = (ushort*)(ws + 83886080);       // 16,777,216 (bf16)
    ushort* hbuf      = (ushort*)(ws + 100663296);
    // fixed regions
    ushort* z_buf     = (ushort*)(ws + 134217728);      // 16,777,216 (bf16)
    ushort* sc_buf    = (ushort*)(ws + 167772160);      //  8,388,608 (step>=7)
    float*  ab_buf    = (float*)(ws + 167772160);       //  2,097,152 (steps 2-5, pre-sc)
    ushort* qnb       = (ushort*)(ws + 176160768);      //  8,388,608
    ushort* knb       = (ushort*)(ws + 184549376);      //  8,388,608 (bf16)
    float*  g_buf     = (float*)(ws + 201326592);       //    262,144
    float*  bet_buf   = (float*)(ws + 201588736);       //    262,144
    float*  gcs_buf   = (float*)(ws + 201850880);       //    262,144
    ushort* wob       = (ushort*)(ws + 202113024);      // 16,777,216 -> 218.9MB

    hipFuncSetAttribute((const void*)phaseA_kernel,
                        hipFuncAttributeMaxDynamicSharedMemorySize, PA_LDS_BYTES);
    hipFuncSetAttribute((const void*)phaseB_kernel,
                        hipFuncAttributeMaxDynamicSharedMemorySize, PB_LDS_BYTES);
    hipFuncSetAttribute((const void*)gemm256_kernel,
                        hipFuncAttributeMaxDynamicSharedMemorySize, G256_LDS_BYTES);
    hipFuncSetAttribute((const void*)gemm128_kernel,
                        hipFuncAttributeMaxDynamicSharedMemorySize, G128_LDS_BYTES);

    dim3 blk(256);
    // 1) merged casts: x->xb, W_qkv|W_z->wqz, W_out->wob, W_ab->wab (one launch)
    cast5_kernel<<<(NX8 + NQ8 + NZ8 + NW8 + NA8) / 256, blk, 0, stream>>>(
        x, W_qkv, W_z, W_out, W_a, W_b, xb, wqz, wob, wab);
    // 2) fused qkv+z+ab projection (256^2 tile, 64x128 wave, XCD-chunk swizzle)
    gemm256_kernel<<<dim3(49, S_LEN / 256), dim3(512), G256_LDS_BYTES, stream>>>(
        xb, wqz, mixed_pre, z_buf, ab_buf, HIDDIM,
        CONV_DIM, CONV_DIM + VAL_DIM, CONV_DIM, VAL_DIM, 256);
    // 4) fused conv+silu+l2norm+v-split (bf16 in/out)
    front_kernel<<<S_LEN, blk, 0, stream>>>(mixed_pre, conv_w, qnb, knb, vbuf);
    // 5) gates (ab stride 256)
    gb_kernel<<<(S_LEN * NVH) / 256, blk, 0, stream>>>(ab_buf, dt_b, A_log, g_buf, bet_buf);
    // 7) phase A (intra-chunk, blocked-MFMA solve; bf16 in/out)
    phaseA_kernel<<<dim3(NCHK, NVH), blk, PA_LDS_BYTES, stream>>>(
        qnb, knb, vbuf, g_buf, bet_buf, u_buf, kcd_buf, sc_buf, gcs_buf, knT_buf);
    // 8) phase B (inter-chunk scan, MFMA, prefetch-pipelined, bf16 o)
    phaseB_kernel<<<dim3(NVH, 8), blk, PB_LDS_BYTES, stream>>>(
        qnb, knT_buf, u_buf, kcd_buf, sc_buf, gcs_buf, obuf);
    // 9) gated RMSNorm -> bf16
    norm_kernel<<<(S_LEN * NVH * 64) / 256, blk, 0, stream>>>(obuf, z_buf, norm_w, hbuf);
    // 10) output projection (128^2 triple-buffered BK=32, 256 blocks)
    gemm128_kernel<<<dim3(HIDDIM / 128, S_LEN / 128), blk, G128_LDS_BYTES, stream>>>(
        hbuf, wob, out, HIDDIM, VAL_DIM);
}